// Round 12
// baseline (1394.057 us; speedup 1.0000x reference)
//
#include <hip/hip_runtime.h>
#include <math.h>

#define TLEN 160000
#define NA 625      // n1 (time rows) / ka (freq elements)
#define NB 256      // n2 (time elements) / kb (freq rows)
#define TD 2500
#define KC 128      // conv half width (~5 sigma_t, sigma_t = 25.46)
#define NTAP 257
#define SROWS 337
#define TWO_PI 6.283185307179586f

struct c2 { float x, y; };

__device__ __forceinline__ c2 cmul(c2 a, c2 b){ return c2{a.x*b.x - a.y*b.y, a.x*b.y + a.y*b.x}; }
__device__ __forceinline__ c2 cmulc(c2 a, c2 b){ return c2{a.x*b.x + a.y*b.y, a.y*b.x - a.x*b.y}; } // a*conj(b)
__device__ __forceinline__ c2 cadd(c2 a, c2 b){ return c2{a.x+b.x, a.y+b.y}; }
__device__ __forceinline__ c2 csub(c2 a, c2 b){ return c2{a.x-b.x, a.y-b.y}; }
__device__ __forceinline__ c2 cmac(c2 acc, c2 v, float wr, float wi){
  acc.x += v.x*wr - v.y*wi; acc.y += v.x*wi + v.y*wr; return acc;
}
__device__ __forceinline__ c2 cis(float ang){ c2 r; __sincosf(ang, &r.y, &r.x); return r; }
__device__ __forceinline__ int SW(int i){ return i + (i >> 4); }
__device__ __forceinline__ int SW2(int i){ return i + (i >> 2); }   // float-plane swizzle (pow2 strides)
__device__ __forceinline__ int SW64(int i){ return i + (i >> 6); }
// wave-local "syncthreads" for wave-private LDS: LDS-ONLY wait (lgkmcnt(0)).
// NOT __threadfence_block(): that is a workgroup fence and drains vmcnt(0) too,
// serializing in-flight global stores into every FFT stage boundary.
__device__ __forceinline__ void wsync(){
  __builtin_amdgcn_wave_barrier();
  asm volatile("s_waitcnt lgkmcnt(0)" ::: "memory");
  __builtin_amdgcn_sched_barrier(0);
  __builtin_amdgcn_wave_barrier();
}

template<int S>
__device__ __forceinline__ void dft4(c2& a0, c2& a1, c2& a2, c2& a3){
  c2 t0 = cadd(a0,a2), t1 = csub(a0,a2), t2 = cadd(a1,a3), t3 = csub(a1,a3);
  float fs = (float)S;
  a0 = cadd(t0,t2); a2 = csub(t0,t2);
  a1 = c2{t1.x - fs*t3.y, t1.y + fs*t3.x};
  a3 = c2{t1.x + fs*t3.y, t1.y - fs*t3.x};
}

template<int S>
__device__ __forceinline__ void dft5(const c2 a[5], c2 b[5]){
  const float C1 = 0.30901699437494742f, C2 = -0.80901699437494745f;
  const float S1 = 0.95105651629515353f * (float)S, S2 = 0.58778525229247314f * (float)S;
  b[0] = cadd(cadd(a[0],a[1]), cadd(cadd(a[2],a[3]),a[4]));
  c2 r;
  r = a[0]; r = cmac(r,a[1],C1, S1); r = cmac(r,a[2],C2, S2); r = cmac(r,a[3],C2,-S2); r = cmac(r,a[4],C1,-S1); b[1]=r;
  r = a[0]; r = cmac(r,a[1],C2, S2); r = cmac(r,a[2],C1,-S1); r = cmac(r,a[3],C1, S1); r = cmac(r,a[4],C2,-S2); b[2]=r;
  r = a[0]; r = cmac(r,a[1],C2,-S2); r = cmac(r,a[2],C1, S1); r = cmac(r,a[3],C1,-S1); r = cmac(r,a[4],C2, S2); b[3]=r;
  r = a[0]; r = cmac(r,a[1],C1,-S1); r = cmac(r,a[2],C2,-S2); r = cmac(r,a[3],C2, S2); r = cmac(r,a[4],C1, S1); b[4]=r;
}

// ---------------- 256-point row FFT (x-chain only; 64-thread = single-wave blocks) ----------------
template<int S, int INMODE, int OUTMODE>
__global__ __launch_bounds__(64) void k_fft256(const void* __restrict__ inp, void* __restrict__ outp){
  __shared__ c2 lds[2][272];
  int g = blockIdx.x;
  int arr = g / NA, n1 = g - arr*NA;
  int j = threadIdx.x;
  c2 v[4];
  if (INMODE == 0){
    const c2* ip = (const c2*)inp + (size_t)arr*TLEN + (size_t)n1*NB;
    #pragma unroll
    for (int q=0;q<4;q++) v[q] = ip[j + 64*q];
  } else if (INMODE == 1){
    const float* ip = (const float*)inp + (size_t)arr*TLEN + (size_t)n1*NB;
    #pragma unroll
    for (int q=0;q<4;q++) v[q] = c2{ip[j + 64*q], 0.0f};
  } else {
    const float* ip = (const float*)inp + (size_t)arr*TLEN;
    #pragma unroll
    for (int q=0;q<4;q++) v[q] = c2{ip[n1 + NA*(j + 64*q)], 0.0f};
  }
  dft4<S>(v[0],v[1],v[2],v[3]);
  #pragma unroll
  for (int r=0;r<4;r++) lds[0][SW(4*j + r)] = v[r];
  wsync();
  { // L = 4
    int k = j & 3;
    c2 w = cis((float)S * TWO_PI * (float)k * (1.0f/16.0f));
    c2 w2 = cmul(w,w), w3 = cmul(w2,w);
    v[0] = lds[0][SW(j)];
    v[1] = cmul(lds[0][SW(j+64)], w);
    v[2] = cmul(lds[0][SW(j+128)], w2);
    v[3] = cmul(lds[0][SW(j+192)], w3);
    dft4<S>(v[0],v[1],v[2],v[3]);
    int base = 4*(j-k)+k;
    #pragma unroll
    for (int r=0;r<4;r++) lds[1][SW(base + 4*r)] = v[r];
  }
  wsync();
  { // L = 16
    int k = j & 15;
    c2 w = cis((float)S * TWO_PI * (float)k * (1.0f/64.0f));
    c2 w2 = cmul(w,w), w3 = cmul(w2,w);
    v[0] = lds[1][SW(j)];
    v[1] = cmul(lds[1][SW(j+64)], w);
    v[2] = cmul(lds[1][SW(j+128)], w2);
    v[3] = cmul(lds[1][SW(j+192)], w3);
    dft4<S>(v[0],v[1],v[2],v[3]);
    int base = 4*(j-k)+k;
    #pragma unroll
    for (int r=0;r<4;r++) lds[0][SW(base + 16*r)] = v[r];
  }
  wsync();
  { // L = 64
    c2 w = cis((float)S * TWO_PI * (float)j * (1.0f/256.0f));
    c2 w2 = cmul(w,w), w3 = cmul(w2,w);
    v[0] = lds[0][SW(j)];
    v[1] = cmul(lds[0][SW(j+64)], w);
    v[2] = cmul(lds[0][SW(j+128)], w2);
    v[3] = cmul(lds[0][SW(j+192)], w3);
    dft4<S>(v[0],v[1],v[2],v[3]);
    if (OUTMODE == 0){
      c2* op = (c2*)outp + (size_t)arr*TLEN + (size_t)n1*NB;
      #pragma unroll
      for (int r=0;r<4;r++){
        int kb = j + 64*r;
        c2 tw = cis((float)S * TWO_PI * (float)(n1*kb) * (1.0f/160000.0f));
        op[kb] = cmul(v[r], tw);
      }
    } else {
      float* op = (float*)outp + (size_t)arr*TLEN + (size_t)n1*NB;
      #pragma unroll
      for (int r=0;r<4;r++){
        c2 z = v[r];
        op[j + 64*r] = sqrtf(z.x*z.x + z.y*z.y) * (1.0f/160000.0f);
      }
    }
  }
}

// ---------------- fused gather + inverse 256-FFT + abs (+ optional forward 256-FFT -> B) --------
#define GCH     12
#define GNCH    53                        // ceil(625/12)
#define GTF     273                       // tile float-plane stride; 273 % 32 = 17
#define SCR     320                       // per-plane scratch floats; SW2(255)+1 = 319
#define G_LDSB  ((2*GCH*GTF + 4*2*SCR)*4) // 36448 B dynamic
template<int WRITEB>
__global__ __launch_bounds__(256) void k_fft256g(const c2* __restrict__ inp, float* __restrict__ outp,
                                                 c2* __restrict__ outB){
  extern __shared__ float smemg[];
  float* tr = smemg;                           // [GCH][GTF]
  float* ti = smemg + GCH*GTF;                 // [GCH][GTF]
  int g = blockIdx.x;
  int arr = g / GNCH, chunk = g - arr*GNCH;
  int n1_0 = chunk*GCH;
  int rows = NA - n1_0; if (rows > GCH) rows = GCH;
  const c2* ip = inp + (size_t)arr*TLEN;
  if (rows == GCH){
    for (int e = threadIdx.x; e < 256*GCH; e += 256){
      int kb = e / GCH, i = e - kb*GCH;        // const divisor
      c2 z = ip[(size_t)kb*NA + n1_0 + i];
      tr[i*GTF + kb] = z.x; ti[i*GTF + kb] = z.y;
    }
  } else {
    for (int e = threadIdx.x; e < 256*rows; e += 256){
      int kb = e / rows, i = e - kb*rows;
      c2 z = ip[(size_t)kb*NA + n1_0 + i];
      tr[i*GTF + kb] = z.x; ti[i*GTF + kb] = z.y;
    }
  }
  __syncthreads();
  int gq = threadIdx.x >> 6, j = threadIdx.x & 63;
  float* sr = smemg + 2*GCH*GTF + gq*(2*SCR);
  float* si = sr + SCR;
  // hoisted stage twiddles (inverse; forward = conjugate via cmulc)
  c2 w4  = cis(TWO_PI * (float)(j & 3)  * (1.0f/16.0f));
  c2 w4b = cmul(w4,w4),  w4c = cmul(w4b,w4);
  c2 w16 = cis(TWO_PI * (float)(j & 15) * (1.0f/64.0f));
  c2 w16b= cmul(w16,w16), w16c= cmul(w16b,w16);
  c2 w64 = cis(TWO_PI * (float)j * (1.0f/256.0f));
  c2 w64b= cmul(w64,w64), w64c= cmul(w64b,w64);
  int b4 = 4*(j-(j&3))+(j&3);
  int b16= 4*(j-(j&15))+(j&15);
  float* op0 = outp + (size_t)arr*TLEN;
  for (int t = 0; t < 3; t++){
    int n1i = gq + 4*t;
    if (n1i >= rows) break;
    int n1 = n1_0 + n1i;
    c2 v[4];
    #pragma unroll
    for (int q=0;q<4;q++) v[q] = c2{tr[n1i*GTF + j + 64*q], ti[n1i*GTF + j + 64*q]};
    dft4<1>(v[0],v[1],v[2],v[3]);
    #pragma unroll
    for (int r=0;r<4;r++){ sr[SW2(4*j + r)] = v[r].x; si[SW2(4*j + r)] = v[r].y; }
    wsync();
    { // L=4
      v[0] = c2{sr[SW2(j)],     si[SW2(j)]};
      v[1] = cmul(c2{sr[SW2(j+64)],  si[SW2(j+64)]},  w4);
      v[2] = cmul(c2{sr[SW2(j+128)], si[SW2(j+128)]}, w4b);
      v[3] = cmul(c2{sr[SW2(j+192)], si[SW2(j+192)]}, w4c);
      dft4<1>(v[0],v[1],v[2],v[3]);
      wsync();
      #pragma unroll
      for (int r=0;r<4;r++){ sr[SW2(b4 + 4*r)] = v[r].x; si[SW2(b4 + 4*r)] = v[r].y; }
    }
    wsync();
    { // L=16
      v[0] = c2{sr[SW2(j)],     si[SW2(j)]};
      v[1] = cmul(c2{sr[SW2(j+64)],  si[SW2(j+64)]},  w16);
      v[2] = cmul(c2{sr[SW2(j+128)], si[SW2(j+128)]}, w16b);
      v[3] = cmul(c2{sr[SW2(j+192)], si[SW2(j+192)]}, w16c);
      dft4<1>(v[0],v[1],v[2],v[3]);
      wsync();
      #pragma unroll
      for (int r=0;r<4;r++){ sr[SW2(b16 + 16*r)] = v[r].x; si[SW2(b16 + 16*r)] = v[r].y; }
    }
    wsync();
    float av[4];
    { // L=64 + abs
      v[0] = c2{sr[SW2(j)],     si[SW2(j)]};
      v[1] = cmul(c2{sr[SW2(j+64)],  si[SW2(j+64)]},  w64);
      v[2] = cmul(c2{sr[SW2(j+128)], si[SW2(j+128)]}, w64b);
      v[3] = cmul(c2{sr[SW2(j+192)], si[SW2(j+192)]}, w64c);
      dft4<1>(v[0],v[1],v[2],v[3]);
      float* op = op0 + (size_t)n1*NB;
      #pragma unroll
      for (int r=0;r<4;r++){
        c2 z = v[r];
        av[r] = sqrtf(z.x*z.x + z.y*z.y) * (1.0f/160000.0f);
        op[j + 64*r] = av[r];
      }
    }
    if (WRITEB){
      wsync();
      #pragma unroll
      for (int q=0;q<4;q++) v[q] = c2{av[q], 0.0f};
      dft4<-1>(v[0],v[1],v[2],v[3]);
      #pragma unroll
      for (int r=0;r<4;r++){ sr[SW2(4*j + r)] = v[r].x; si[SW2(4*j + r)] = v[r].y; }
      wsync();
      { // L=4
        v[0] = c2{sr[SW2(j)],     si[SW2(j)]};
        v[1] = cmulc(c2{sr[SW2(j+64)],  si[SW2(j+64)]},  w4);
        v[2] = cmulc(c2{sr[SW2(j+128)], si[SW2(j+128)]}, w4b);
        v[3] = cmulc(c2{sr[SW2(j+192)], si[SW2(j+192)]}, w4c);
        dft4<-1>(v[0],v[1],v[2],v[3]);
        wsync();
        #pragma unroll
        for (int r=0;r<4;r++){ sr[SW2(b4 + 4*r)] = v[r].x; si[SW2(b4 + 4*r)] = v[r].y; }
      }
      wsync();
      { // L=16
        v[0] = c2{sr[SW2(j)],     si[SW2(j)]};
        v[1] = cmulc(c2{sr[SW2(j+64)],  si[SW2(j+64)]},  w16);
        v[2] = cmulc(c2{sr[SW2(j+128)], si[SW2(j+128)]}, w16b);
        v[3] = cmulc(c2{sr[SW2(j+192)], si[SW2(j+192)]}, w16c);
        dft4<-1>(v[0],v[1],v[2],v[3]);
        wsync();
        #pragma unroll
        for (int r=0;r<4;r++){ sr[SW2(b16 + 16*r)] = v[r].x; si[SW2(b16 + 16*r)] = v[r].y; }
      }
      wsync();
      { // L=64 + row twiddle -> overwrite dead tile row (transposed store)
        v[0] = c2{sr[SW2(j)],     si[SW2(j)]};
        v[1] = cmulc(c2{sr[SW2(j+64)],  si[SW2(j+64)]},  w64);
        v[2] = cmulc(c2{sr[SW2(j+128)], si[SW2(j+128)]}, w64b);
        v[3] = cmulc(c2{sr[SW2(j+192)], si[SW2(j+192)]}, w64c);
        dft4<-1>(v[0],v[1],v[2],v[3]);
        #pragma unroll
        for (int r=0;r<4;r++){
          int kb = j + 64*r;
          c2 tw = cis(-TWO_PI * (float)(n1*kb) * (1.0f/160000.0f));
          c2 z = cmul(v[r], tw);
          tr[n1i*GTF + kb] = z.x;
          ti[n1i*GTF + kb] = z.y;
        }
      }
    }
    wsync();
  }
  if (WRITEB){
    __syncthreads();
    c2* op = outB + (size_t)arr*TLEN;
    if (rows == GCH){
      for (int e = threadIdx.x; e < 256*GCH; e += 256){
        int kb = e / GCH, i = e - kb*GCH;
        op[(size_t)kb*NA + n1_0 + i] = c2{tr[i*GTF + kb], ti[i*GTF + kb]};
      }
    } else {
      for (int e = threadIdx.x; e < 256*rows; e += 256){
        int kb = e / rows, i = e - kb*rows;
        op[(size_t)kb*NA + n1_0 + i] = c2{tr[i*GTF + kb], ti[i*GTF + kb]};
      }
    }
  }
}

// ---------------- 625-point row FFT (radix-5 Stockham), float-plane LDS + W625 LUT ----------------
// FILT: 0 none, 1 psi1 (input Xf), 2 psi2 (input U1h). TW: output twiddle (incremental).
// kamax: when TW==0, only outputs n1 <= kamax are written (partial-spectrum store).
template<int S, int FILT, int TW>
__global__ __launch_bounds__(128) void k_fft625(const c2* __restrict__ inp, c2* __restrict__ outp,
                                                int cblk, int BLK, int nj2, int j2base, int scBase,
                                                int kamax){
  __shared__ float l0r[625], l0i[625], l1r[625], l1i[625];
  __shared__ float lutr[625], luti[625];
  for (int m = threadIdx.x; m < 625; m += 128){
    c2 z = cis(TWO_PI * (float)m * (1.0f/625.0f));
    lutr[m] = z.x; luti[m] = z.y;
  }
  int g = blockIdx.x;
  int i = g / NB, kb = g - i*NB;
  int j = threadIdx.x;
  const c2* ip;
  int j1 = 0, j2 = 0;
  if (FILT == 0){
    ip = inp + (size_t)i*TLEN;
  } else if (FILT == 1){
    int bt = i / BLK; j1 = cblk*BLK + (i - bt*BLK);
    ip = inp + (size_t)bt*TLEN;
  } else {
    int g2 = scBase + i;
    int npb = BLK*nj2;
    int bt = g2 / npb, rr = g2 - bt*npb;
    int jloc = rr / nj2; j2 = j2base + (rr - jloc*nj2);
    ip = inp + (size_t)(bt*BLK + jloc)*TLEN;
  }
  ip += (size_t)kb*NA;
  float xi = 0.0f, sig = 0.0f, inv2s = 0.0f;
  int klo = 0, khi = 0;
  if (FILT != 0){
    if (FILT == 1){ xi = 0.4f * exp2f(-(float)j1 * 0.0625f); sig = xi * 0.04427378243f; }
    else          { xi = 0.4f * exp2f(-(float)j2);           sig = 0.35f * xi; }
    inv2s = 0.5f / (sig*sig);
    klo = (int)((xi - 6.0f*sig) * (float)TLEN); if (klo < 0) klo = 0;
    khi = (int)((xi + 6.0f*sig) * (float)TLEN) + 1; if (khi > TLEN/2 - 1) khi = TLEN/2 - 1;
  }
  c2 a[5], b[5];
  if (j < 125){
    if (FILT == 0){
      #pragma unroll
      for (int q=0;q<5;q++) a[q] = ip[j + 125*q];
      dft5<S>(a, b);
    } else {
      bool any = false;
      #pragma unroll
      for (int q=0;q<5;q++){
        int ka = j + 125*q;
        int k = kb + 256*ka;
        c2 val = c2{0.0f, 0.0f};
        if (k >= klo && k <= khi){
          val = ip[ka];
          float d = (float)k * (1.0f/(float)TLEN) - xi;
          float f = __expf(-d*d*inv2s);
          val.x *= f; val.y *= f;
          any = true;
        }
        a[q] = val;
      }
      if (any){
        dft5<S>(a, b);
      } else {
        #pragma unroll
        for (int r=0;r<5;r++) b[r] = c2{0.0f,0.0f};
      }
    }
    #pragma unroll
    for (int r=0;r<5;r++){ int s = 5*j + r; l0r[s] = b[r].x; l0i[s] = b[r].y; }
  }
  __syncthreads();   // also covers LUT fill
  if (j < 125){ // L = 5
    int k = j % 5;
    c2 w  = c2{lutr[25*k],  (S>0)? luti[25*k]  : -luti[25*k]};
    c2 w2 = c2{lutr[50*k],  (S>0)? luti[50*k]  : -luti[50*k]};
    c2 w3 = c2{lutr[75*k],  (S>0)? luti[75*k]  : -luti[75*k]};
    c2 w4 = c2{lutr[100*k], (S>0)? luti[100*k] : -luti[100*k]};
    a[0] = c2{l0r[j],     l0i[j]};
    a[1] = cmul(c2{l0r[j+125], l0i[j+125]}, w);
    a[2] = cmul(c2{l0r[j+250], l0i[j+250]}, w2);
    a[3] = cmul(c2{l0r[j+375], l0i[j+375]}, w3);
    a[4] = cmul(c2{l0r[j+500], l0i[j+500]}, w4);
    dft5<S>(a, b);
    int base = 5*(j-k)+k;
    #pragma unroll
    for (int r=0;r<5;r++){ int s = base + 5*r; l1r[s] = b[r].x; l1i[s] = b[r].y; }
  }
  __syncthreads();
  if (j < 125){ // L = 25
    int k = j % 25;
    c2 w  = c2{lutr[5*k],  (S>0)? luti[5*k]  : -luti[5*k]};
    c2 w2 = c2{lutr[10*k], (S>0)? luti[10*k] : -luti[10*k]};
    c2 w3 = c2{lutr[15*k], (S>0)? luti[15*k] : -luti[15*k]};
    c2 w4 = c2{lutr[20*k], (S>0)? luti[20*k] : -luti[20*k]};
    a[0] = c2{l1r[j],     l1i[j]};
    a[1] = cmul(c2{l1r[j+125], l1i[j+125]}, w);
    a[2] = cmul(c2{l1r[j+250], l1i[j+250]}, w2);
    a[3] = cmul(c2{l1r[j+375], l1i[j+375]}, w3);
    a[4] = cmul(c2{l1r[j+500], l1i[j+500]}, w4);
    dft5<S>(a, b);
    int base = 5*(j-k)+k;
    #pragma unroll
    for (int r=0;r<5;r++){ int s = base + 25*r; l0r[s] = b[r].x; l0i[s] = b[r].y; }
  }
  __syncthreads();
  if (j < 125){ // L = 125
    c2 w  = c2{lutr[j],   (S>0)? luti[j]   : -luti[j]};
    c2 w2 = c2{lutr[2*j], (S>0)? luti[2*j] : -luti[2*j]};
    c2 w3 = c2{lutr[3*j], (S>0)? luti[3*j] : -luti[3*j]};
    c2 w4 = c2{lutr[4*j], (S>0)? luti[4*j] : -luti[4*j]};
    a[0] = c2{l0r[j],     l0i[j]};
    a[1] = cmul(c2{l0r[j+125], l0i[j+125]}, w);
    a[2] = cmul(c2{l0r[j+250], l0i[j+250]}, w2);
    a[3] = cmul(c2{l0r[j+375], l0i[j+375]}, w3);
    a[4] = cmul(c2{l0r[j+500], l0i[j+500]}, w4);
    dft5<S>(a, b);
    c2* op = outp + (size_t)i*TLEN + (size_t)kb*NA;
    if (TW){
      // incremental output twiddle: tw(n1=j) base, step = tw(125*kb)
      c2 twb = cis((float)S * TWO_PI * (float)(j*kb)   * (1.0f/160000.0f));
      c2 tws = cis((float)S * TWO_PI * (float)(125*kb) * (1.0f/160000.0f));
      #pragma unroll
      for (int r=0;r<5;r++){
        int n1 = j + 125*r;
        op[n1] = cmul(b[r], twb);
        twb = cmul(twb, tws);
      }
    } else {
      #pragma unroll
      for (int r=0;r<5;r++){
        int n1 = j + 125*r;
        if (n1 <= kamax) op[n1] = b[r];
      }
    }
  }
}

// ---------------- complex transpose (x-chain only) ----------------
__global__ __launch_bounds__(256) void k_transpose(const c2* __restrict__ in, c2* __restrict__ out,
                                                   int R, int C, int tilesR, int tilesC){
  __shared__ c2 tile[32][33];
  int bi = blockIdx.x;
  int arr = bi / (tilesR*tilesC);
  int tt = bi - arr*(tilesR*tilesC);
  int tr = tt / tilesC, tc = tt - tr*tilesC;
  const c2* ip = in + (size_t)arr*TLEN;
  c2* op = out + (size_t)arr*TLEN;
  int tx = threadIdx.x & 31, ty = threadIdx.x >> 5;
  #pragma unroll
  for (int i=0;i<4;i++){
    int r = tr*32 + ty + i*8, cc = tc*32 + tx;
    if (r < R && cc < C) tile[ty+i*8][tx] = ip[(size_t)r*C + cc];
  }
  __syncthreads();
  #pragma unroll
  for (int i=0;i<4;i++){
    int r = tc*32 + ty + i*8, cc = tr*32 + tx;
    if (r < C && cc < R) op[(size_t)r*R + cc] = tile[tx][ty+i*8];
  }
}

// ---------------- Gaussian lowpass + decimate-by-64, natural layout (S0 only) ----------------
__global__ __launch_bounds__(256) void k_conv(const float* __restrict__ inp, float* __restrict__ S){
  __shared__ float w[NTAP];
  for (int i=threadIdx.x; i<NTAP; i+=256){
    float d = (float)(i - KC);
    w[i] = 0.015666427f * __expf(-7.7106284e-4f * d * d);
  }
  __syncthreads();
  int g = blockIdx.x;
  int arr = g / 10;
  int t = (g - arr*10)*256 + threadIdx.x;
  if (t >= TD) return;
  int srow = arr * SROWS;
  const float* ip = inp + (size_t)arr*TLEN;
  float acc = 0.0f;
  int n = 64*t - KC; if (n < 0) n += TLEN;
  for (int m=0;m<NTAP;m++){
    acc += ip[n] * w[m];
    n++; if (n == TLEN) n = 0;
  }
  S[(size_t)srow*TD + t] = acc;
}

// ---------------- fused LDS stage + conv for scrambled-layout U (S1/S2 rows) ----------------
#define CONV_NCOL 27
#define CONV_NU   16875
#define CONV_USZ  17138
#define CONV_LDSB ((CONV_USZ + NTAP + 1)*4)
template<int MODE>
__global__ __launch_bounds__(256) void k_conv2(const float* __restrict__ inp, float* __restrict__ S,
                                               int cblk, int BLK, int nj2, int j2base, int scBase){
  extern __shared__ float smem[];
  float* u = smem;
  float* w = smem + CONV_USZ;
  for (int i=threadIdx.x; i<NTAP; i+=256){
    float d = (float)(i - KC);
    w[i] = 0.015666427f * __expf(-7.7106284e-4f * d * d);
  }
  int g = blockIdx.x;
  int arr = g / 10;
  int b = g - arr*10;
  int nlo = 16000*b - KC;
  int n2_0 = (nlo >= 0) ? (nlo/625) : -1;
  const float* ip = inp + (size_t)arr*TLEN;
  for (int e = threadIdx.x; e < CONV_NU; e += 256){
    int n1 = e / CONV_NCOL;
    int c  = e - n1*CONV_NCOL;
    int n2 = n2_0 + c;
    n2 &= 255;
    u[SW64(n1 + 625*c)] = ip[n1*NB + n2];
  }
  __syncthreads();
  int tl = threadIdx.x;
  if (tl >= 250) return;
  int t = 250*b + tl;
  int srow;
  if (MODE == 1){
    int a2 = arr / BLK; int j1 = cblk*BLK + (arr - a2*BLK);
    srow = a2*SROWS + 1 + j1;
  } else {
    int g2 = scBase + arr; int npb = BLK*nj2;
    int a2 = g2/npb, rr = g2 - a2*npb;
    int jloc = rr/nj2; int j2 = j2base + (rr - jloc*nj2);
    int j1 = cblk*BLK + jloc;
    int full = j1 >> 4;
    int cum = 16*(5*full - (full*(full-1))/2) + (j1 & 15)*(5 - full);
    int P = cum + j2 - full - 1;
    srow = a2*SROWS + 97 + P;
  }
  int base = 64*t - KC - 625*n2_0;
  float acc = 0.0f;
  #pragma unroll 4
  for (int m=0;m<NTAP;m++){
    acc += u[SW64(base + m)] * w[m];
  }
  S[(size_t)srow*TD + t] = acc;
}

// ---------------- global min/max + finalize ----------------
__global__ __launch_bounds__(256) void k_minmax1(const float* __restrict__ S, int n, float* pmn, float* pmx){
  __shared__ float smn[256], smx[256];
  float mn = 3.4028235e38f, mx = -3.4028235e38f;
  for (size_t i = (size_t)blockIdx.x*256 + threadIdx.x; i < (size_t)n; i += (size_t)gridDim.x*256){
    float v = S[i]; mn = fminf(mn,v); mx = fmaxf(mx,v);
  }
  smn[threadIdx.x]=mn; smx[threadIdx.x]=mx; __syncthreads();
  for (int s=128;s>0;s>>=1){
    if ((int)threadIdx.x < s){
      smn[threadIdx.x]=fminf(smn[threadIdx.x],smn[threadIdx.x+s]);
      smx[threadIdx.x]=fmaxf(smx[threadIdx.x],smx[threadIdx.x+s]);
    }
    __syncthreads();
  }
  if (threadIdx.x==0){ pmn[blockIdx.x]=smn[0]; pmx[blockIdx.x]=smx[0]; }
}
__global__ __launch_bounds__(256) void k_minmax2(const float* __restrict__ pmn, const float* __restrict__ pmx,
                                                 int nb, float* scal){
  __shared__ float smn[256], smx[256];
  float mn = 3.4028235e38f, mx = -3.4028235e38f;
  for (int i = threadIdx.x; i < nb; i += 256){ mn = fminf(mn,pmn[i]); mx = fmaxf(mx,pmx[i]); }
  smn[threadIdx.x]=mn; smx[threadIdx.x]=mx; __syncthreads();
  for (int s=128;s>0;s>>=1){
    if ((int)threadIdx.x < s){
      smn[threadIdx.x]=fminf(smn[threadIdx.x],smn[threadIdx.x+s]);
      smx[threadIdx.x]=fmaxf(smx[threadIdx.x],smx[threadIdx.x+s]);
    }
    __syncthreads();
  }
  if (threadIdx.x==0){ scal[0]=smn[0]; scal[1]=smx[0]; }
}
__global__ __launch_bounds__(256) void k_final(const float* __restrict__ S, const float* __restrict__ scal,
                                               float* __restrict__ out, int n){
  int i = blockIdx.x*256 + threadIdx.x;
  if (i >= n) return;
  float mn = scal[0];
  float r = scal[1] - mn;
  if (r == 0.0f) r = 1.0f;
  int half = SROWS*TD;
  int a = i / half; int rest = i - a*half;
  out[i] = (S[(size_t)(a & 1)*half + rest] - mn) / r;
}

extern "C" void kernel_launch(void* const* d_in, const int* in_sizes, int n_in,
                              void* d_out, int out_size, void* d_ws, size_t ws_size,
                              hipStream_t stream){
  (void)in_sizes; (void)n_in;
  const float* x = (const float*)d_in[0];

  int BLK = 16;
  while (BLK > 1){
    size_t CH = 2*(size_t)BLK;
    // Xf + A(3 slots; slot1 doubles as B) + U1h + Ur(3 slots) + Sb + reductions
    size_t needb = 2560000ULL + 3ULL*CH*TLEN*8ULL + CH*TLEN*8ULL
                 + 3ULL*CH*TLEN*4ULL + 6740000ULL + 8192ULL + 4096ULL;
    if (needb <= ws_size) break;
    BLK >>= 1;
  }
  {
    size_t CH = 2;
    size_t needmin = 2560000ULL + 3ULL*CH*TLEN*8ULL + CH*TLEN*8ULL
                   + 3ULL*CH*TLEN*4ULL + 6740000ULL + 8192ULL + 4096ULL;
    if (ws_size < needmin) return;
  }
  int CH = 2*BLK;

  char* p = (char*)d_ws;
  auto carve = [&](size_t bytes)->void*{ void* r = (void*)p; p += (bytes + 255) & ~(size_t)255; return r; };
  c2*    Xf  = (c2*)carve(2ULL*TLEN*sizeof(c2));
  c2*    A   = (c2*)carve(3ULL*CH*TLEN*sizeof(c2));      // 3 slots for sc-triple batching
  c2*    B   = A + (size_t)CH*TLEN;                       // alias: slot 1 (dead A-slot during F3)
  c2*    U1h = (c2*)carve((size_t)CH*TLEN*sizeof(c2));
  float* Ur  = (float*)carve(3ULL*CH*TLEN*sizeof(float)); // 3 slots
  float* Sb  = (float*)carve(2ULL*SROWS*TD*sizeof(float));
  float* pmn = (float*)carve(512*4);
  float* pmx = (float*)carve(512*4);
  float* scal = (float*)carve(256);

  // ---- forward FFT of x -> Xf ----
  k_fft256<-1,2,0><<<2*NA, 64, 0, stream>>>((const void*)x, (void*)A);
  k_transpose<<<2*20*8, 256, 0, stream>>>(A, U1h, NA, NB, 20, 8);
  k_fft625<-1,0,0><<<2*NB, 128, 0, stream>>>(U1h, Xf, 0,0,0,0,0, 314);  // only ka<=314 read by psi1
  // ---- S0 ----
  k_conv<<<2*10, 256, 0, stream>>>(x, Sb);

  int NCB = 96 / BLK;
  for (int c = 0; c < NCB; c++){
    int cq = (c*BLK)/16;
    int nj2 = 5 - cq;
    int j2base = cq + 1;
    // F3 partial-spectrum bound from the widest psi2 in this block (j2 = j2base)
    float xi2 = 0.4f * exp2f(-(float)j2base);
    int khi2 = (int)(3.1f * xi2 * 160000.0f) + 1; if (khi2 > TLEN/2 - 1) khi2 = TLEN/2 - 1;
    int kamax = (khi2 >> 8) + 1; if (kamax > 624) kamax = 624;
    // ---- order 1 ----
    k_fft625<1,1,1><<<CH*NB, 128, 0, stream>>>(Xf, A, c, BLK, 0,0,0, 624);
    if (nj2 > 0){
      k_fft256g<1><<<CH*GNCH, 256, G_LDSB, stream>>>(A, Ur, B);       // |ifft| -> Ur, fft -> B (=A slot1)
      k_conv2<1><<<CH*10, 256, CONV_LDSB, stream>>>(Ur, Sb, c, BLK, 0,0,0);
      k_fft625<-1,0,0><<<CH*NB, 128, 0, stream>>>(B, U1h, 0,0,0,0,0, kamax);
      // ---- order 2, sc batched in triples ----
      for (int scStart = 0; scStart < nj2; scStart += 3){
        int nsc = nj2 - scStart; if (nsc > 3) nsc = 3;
        k_fft625<1,2,1><<<nsc*CH*NB, 128, 0, stream>>>(U1h, A, c, BLK, nj2, j2base, scStart*CH, 624);
        k_fft256g<0><<<nsc*CH*GNCH, 256, G_LDSB, stream>>>(A, Ur, (c2*)nullptr);
        k_conv2<2><<<nsc*CH*10, 256, CONV_LDSB, stream>>>(Ur, Sb, c, BLK, nj2, j2base, scStart*CH);
      }
    } else {
      k_fft256g<0><<<CH*GNCH, 256, G_LDSB, stream>>>(A, Ur, (c2*)nullptr);
      k_conv2<1><<<CH*10, 256, CONV_LDSB, stream>>>(Ur, Sb, c, BLK, 0,0,0);
    }
  }

  // ---- global min-max normalize (standardize cancels) + tile(3,1,1) ----
  k_minmax1<<<512, 256, 0, stream>>>(Sb, 2*SROWS*TD, pmn, pmx);
  k_minmax2<<<1, 256, 0, stream>>>(pmn, pmx, 512, scal);
  k_final<<<(out_size+255)/256, 256, 0, stream>>>(Sb, scal, (float*)d_out, out_size);
}

// Round 13
// 1354.493 us; speedup vs baseline: 1.0292x; 1.0292x over previous
//
#include <hip/hip_runtime.h>
#include <math.h>

#define TLEN 160000
#define NA 625      // n1 (time rows) / ka (freq elements)
#define NB 256      // n2 (time elements) / kb (freq rows)
#define TD 2500
#define KC 128      // conv half width (~5 sigma_t, sigma_t = 25.46)
#define NTAP 257
#define SROWS 337
#define TWO_PI 6.283185307179586f

struct c2 { float x, y; };

__device__ __forceinline__ c2 cmul(c2 a, c2 b){ return c2{a.x*b.x - a.y*b.y, a.x*b.y + a.y*b.x}; }
__device__ __forceinline__ c2 cmulc(c2 a, c2 b){ return c2{a.x*b.x + a.y*b.y, a.y*b.x - a.x*b.y}; } // a*conj(b)
__device__ __forceinline__ c2 cadd(c2 a, c2 b){ return c2{a.x+b.x, a.y+b.y}; }
__device__ __forceinline__ c2 csub(c2 a, c2 b){ return c2{a.x-b.x, a.y-b.y}; }
__device__ __forceinline__ c2 cmac(c2 acc, c2 v, float wr, float wi){
  acc.x += v.x*wr - v.y*wi; acc.y += v.x*wi + v.y*wr; return acc;
}
__device__ __forceinline__ c2 cis(float ang){ c2 r; __sincosf(ang, &r.y, &r.x); return r; }
__device__ __forceinline__ int SW(int i){ return i + (i >> 4); }
__device__ __forceinline__ int SW2(int i){ return i + (i >> 2); }
__device__ __forceinline__ int SW64(int i){ return i + (i >> 6); }
// bf16-pair packing for S2-only intermediates (halves their HBM traffic)
__device__ __forceinline__ unsigned pack_bf(c2 z){
  unsigned xr = __float_as_uint(z.x), xi = __float_as_uint(z.y);
  xr += 0x8000u + ((xr >> 16) & 1u);
  xi += 0x8000u + ((xi >> 16) & 1u);
  return (xr >> 16) | (xi & 0xFFFF0000u);   // lo16 = re, hi16 = im
}
__device__ __forceinline__ c2 unpack_bf(unsigned p){
  return c2{ __uint_as_float(p << 16), __uint_as_float(p & 0xFFFF0000u) };
}
// wave-local "syncthreads" for wave-private LDS: LDS-only wait.
__device__ __forceinline__ void wsync(){
  __builtin_amdgcn_wave_barrier();
  asm volatile("s_waitcnt lgkmcnt(0)" ::: "memory");
  __builtin_amdgcn_sched_barrier(0);
  __builtin_amdgcn_wave_barrier();
}

template<int S>
__device__ __forceinline__ void dft4(c2& a0, c2& a1, c2& a2, c2& a3){
  c2 t0 = cadd(a0,a2), t1 = csub(a0,a2), t2 = cadd(a1,a3), t3 = csub(a1,a3);
  float fs = (float)S;
  a0 = cadd(t0,t2); a2 = csub(t0,t2);
  a1 = c2{t1.x - fs*t3.y, t1.y + fs*t3.x};
  a3 = c2{t1.x + fs*t3.y, t1.y - fs*t3.x};
}

template<int S>
__device__ __forceinline__ void dft5(const c2 a[5], c2 b[5]){
  const float C1 = 0.30901699437494742f, C2 = -0.80901699437494745f;
  const float S1 = 0.95105651629515353f * (float)S, S2 = 0.58778525229247314f * (float)S;
  b[0] = cadd(cadd(a[0],a[1]), cadd(cadd(a[2],a[3]),a[4]));
  c2 r;
  r = a[0]; r = cmac(r,a[1],C1, S1); r = cmac(r,a[2],C2, S2); r = cmac(r,a[3],C2,-S2); r = cmac(r,a[4],C1,-S1); b[1]=r;
  r = a[0]; r = cmac(r,a[1],C2, S2); r = cmac(r,a[2],C1,-S1); r = cmac(r,a[3],C1, S1); r = cmac(r,a[4],C2,-S2); b[2]=r;
  r = a[0]; r = cmac(r,a[1],C2,-S2); r = cmac(r,a[2],C1, S1); r = cmac(r,a[3],C1,-S1); r = cmac(r,a[4],C2, S2); b[3]=r;
  r = a[0]; r = cmac(r,a[1],C1,-S1); r = cmac(r,a[2],C2,-S2); r = cmac(r,a[3],C2, S2); r = cmac(r,a[4],C1, S1); b[4]=r;
}

// ---------------- 256-point row FFT (x-chain only; single-wave blocks) ----------------
template<int S, int INMODE, int OUTMODE>
__global__ __launch_bounds__(64) void k_fft256(const void* __restrict__ inp, void* __restrict__ outp){
  __shared__ c2 lds[2][272];
  int g = blockIdx.x;
  int arr = g / NA, n1 = g - arr*NA;
  int j = threadIdx.x;
  c2 v[4];
  if (INMODE == 0){
    const c2* ip = (const c2*)inp + (size_t)arr*TLEN + (size_t)n1*NB;
    #pragma unroll
    for (int q=0;q<4;q++) v[q] = ip[j + 64*q];
  } else if (INMODE == 1){
    const float* ip = (const float*)inp + (size_t)arr*TLEN + (size_t)n1*NB;
    #pragma unroll
    for (int q=0;q<4;q++) v[q] = c2{ip[j + 64*q], 0.0f};
  } else {
    const float* ip = (const float*)inp + (size_t)arr*TLEN;
    #pragma unroll
    for (int q=0;q<4;q++) v[q] = c2{ip[n1 + NA*(j + 64*q)], 0.0f};
  }
  dft4<S>(v[0],v[1],v[2],v[3]);
  #pragma unroll
  for (int r=0;r<4;r++) lds[0][SW(4*j + r)] = v[r];
  wsync();
  { // L = 4
    int k = j & 3;
    c2 w = cis((float)S * TWO_PI * (float)k * (1.0f/16.0f));
    c2 w2 = cmul(w,w), w3 = cmul(w2,w);
    v[0] = lds[0][SW(j)];
    v[1] = cmul(lds[0][SW(j+64)], w);
    v[2] = cmul(lds[0][SW(j+128)], w2);
    v[3] = cmul(lds[0][SW(j+192)], w3);
    dft4<S>(v[0],v[1],v[2],v[3]);
    int base = 4*(j-k)+k;
    #pragma unroll
    for (int r=0;r<4;r++) lds[1][SW(base + 4*r)] = v[r];
  }
  wsync();
  { // L = 16
    int k = j & 15;
    c2 w = cis((float)S * TWO_PI * (float)k * (1.0f/64.0f));
    c2 w2 = cmul(w,w), w3 = cmul(w2,w);
    v[0] = lds[1][SW(j)];
    v[1] = cmul(lds[1][SW(j+64)], w);
    v[2] = cmul(lds[1][SW(j+128)], w2);
    v[3] = cmul(lds[1][SW(j+192)], w3);
    dft4<S>(v[0],v[1],v[2],v[3]);
    int base = 4*(j-k)+k;
    #pragma unroll
    for (int r=0;r<4;r++) lds[0][SW(base + 16*r)] = v[r];
  }
  wsync();
  { // L = 64
    c2 w = cis((float)S * TWO_PI * (float)j * (1.0f/256.0f));
    c2 w2 = cmul(w,w), w3 = cmul(w2,w);
    v[0] = lds[0][SW(j)];
    v[1] = cmul(lds[0][SW(j+64)], w);
    v[2] = cmul(lds[0][SW(j+128)], w2);
    v[3] = cmul(lds[0][SW(j+192)], w3);
    dft4<S>(v[0],v[1],v[2],v[3]);
    if (OUTMODE == 0){
      c2* op = (c2*)outp + (size_t)arr*TLEN + (size_t)n1*NB;
      #pragma unroll
      for (int r=0;r<4;r++){
        int kb = j + 64*r;
        c2 tw = cis((float)S * TWO_PI * (float)(n1*kb) * (1.0f/160000.0f));
        op[kb] = cmul(v[r], tw);
      }
    } else {
      float* op = (float*)outp + (size_t)arr*TLEN + (size_t)n1*NB;
      #pragma unroll
      for (int r=0;r<4;r++){
        c2 z = v[r];
        op[j + 64*r] = sqrtf(z.x*z.x + z.y*z.y) * (1.0f/160000.0f);
      }
    }
  }
}

// ---------------- fused gather + inverse 256-FFT + abs (+ optional forward 256-FFT -> B) --------
// PIN: input is packed bf16 (order-2 stream). WRITEB output B is packed bf16.
#define GCH     12
#define GNCH    53                        // ceil(625/12)
#define GTF     273                       // tile float-plane stride; 273 % 32 = 17
#define SCR     320                       // per-plane scratch floats
#define G_LDSB  ((2*GCH*GTF + 4*2*SCR)*4) // 36448 B dynamic
template<int WRITEB, int PIN>
__global__ __launch_bounds__(256) void k_fft256g(const void* __restrict__ inpv, float* __restrict__ outp,
                                                 unsigned* __restrict__ outB){
  extern __shared__ float smemg[];
  float* tr = smemg;                           // [GCH][GTF]
  float* ti = smemg + GCH*GTF;                 // [GCH][GTF]
  int g = blockIdx.x;
  int arr = g / GNCH, chunk = g - arr*GNCH;
  int n1_0 = chunk*GCH;
  int rows = NA - n1_0; if (rows > GCH) rows = GCH;
  const c2* ipc = (const c2*)inpv;
  const unsigned* ipu = (const unsigned*)inpv;
  size_t base = (size_t)arr*TLEN;
  if (rows == GCH){
    for (int e = threadIdx.x; e < 256*GCH; e += 256){
      int kb = e / GCH, i = e - kb*GCH;        // const divisor
      size_t idx = base + (size_t)kb*NA + n1_0 + i;
      c2 z = PIN ? unpack_bf(ipu[idx]) : ipc[idx];
      tr[i*GTF + kb] = z.x; ti[i*GTF + kb] = z.y;
    }
  } else {
    for (int e = threadIdx.x; e < 256*rows; e += 256){
      int kb = e / rows, i = e - kb*rows;
      size_t idx = base + (size_t)kb*NA + n1_0 + i;
      c2 z = PIN ? unpack_bf(ipu[idx]) : ipc[idx];
      tr[i*GTF + kb] = z.x; ti[i*GTF + kb] = z.y;
    }
  }
  __syncthreads();
  int gq = threadIdx.x >> 6, j = threadIdx.x & 63;
  float* sr = smemg + 2*GCH*GTF + gq*(2*SCR);
  float* si = sr + SCR;
  c2 w4  = cis(TWO_PI * (float)(j & 3)  * (1.0f/16.0f));
  c2 w4b = cmul(w4,w4),  w4c = cmul(w4b,w4);
  c2 w16 = cis(TWO_PI * (float)(j & 15) * (1.0f/64.0f));
  c2 w16b= cmul(w16,w16), w16c= cmul(w16b,w16);
  c2 w64 = cis(TWO_PI * (float)j * (1.0f/256.0f));
  c2 w64b= cmul(w64,w64), w64c= cmul(w64b,w64);
  int b4 = 4*(j-(j&3))+(j&3);
  int b16= 4*(j-(j&15))+(j&15);
  float* op0 = outp + (size_t)arr*TLEN;
  for (int t = 0; t < 3; t++){
    int n1i = gq + 4*t;
    if (n1i >= rows) break;
    int n1 = n1_0 + n1i;
    c2 v[4];
    #pragma unroll
    for (int q=0;q<4;q++) v[q] = c2{tr[n1i*GTF + j + 64*q], ti[n1i*GTF + j + 64*q]};
    dft4<1>(v[0],v[1],v[2],v[3]);
    #pragma unroll
    for (int r=0;r<4;r++){ sr[SW2(4*j + r)] = v[r].x; si[SW2(4*j + r)] = v[r].y; }
    wsync();
    { // L=4
      v[0] = c2{sr[SW2(j)],     si[SW2(j)]};
      v[1] = cmul(c2{sr[SW2(j+64)],  si[SW2(j+64)]},  w4);
      v[2] = cmul(c2{sr[SW2(j+128)], si[SW2(j+128)]}, w4b);
      v[3] = cmul(c2{sr[SW2(j+192)], si[SW2(j+192)]}, w4c);
      dft4<1>(v[0],v[1],v[2],v[3]);
      wsync();
      #pragma unroll
      for (int r=0;r<4;r++){ sr[SW2(b4 + 4*r)] = v[r].x; si[SW2(b4 + 4*r)] = v[r].y; }
    }
    wsync();
    { // L=16
      v[0] = c2{sr[SW2(j)],     si[SW2(j)]};
      v[1] = cmul(c2{sr[SW2(j+64)],  si[SW2(j+64)]},  w16);
      v[2] = cmul(c2{sr[SW2(j+128)], si[SW2(j+128)]}, w16b);
      v[3] = cmul(c2{sr[SW2(j+192)], si[SW2(j+192)]}, w16c);
      dft4<1>(v[0],v[1],v[2],v[3]);
      wsync();
      #pragma unroll
      for (int r=0;r<4;r++){ sr[SW2(b16 + 16*r)] = v[r].x; si[SW2(b16 + 16*r)] = v[r].y; }
    }
    wsync();
    float av[4];
    { // L=64 + abs
      v[0] = c2{sr[SW2(j)],     si[SW2(j)]};
      v[1] = cmul(c2{sr[SW2(j+64)],  si[SW2(j+64)]},  w64);
      v[2] = cmul(c2{sr[SW2(j+128)], si[SW2(j+128)]}, w64b);
      v[3] = cmul(c2{sr[SW2(j+192)], si[SW2(j+192)]}, w64c);
      dft4<1>(v[0],v[1],v[2],v[3]);
      float* op = op0 + (size_t)n1*NB;
      #pragma unroll
      for (int r=0;r<4;r++){
        c2 z = v[r];
        av[r] = sqrtf(z.x*z.x + z.y*z.y) * (1.0f/160000.0f);
        op[j + 64*r] = av[r];
      }
    }
    if (WRITEB){
      wsync();
      #pragma unroll
      for (int q=0;q<4;q++) v[q] = c2{av[q], 0.0f};
      dft4<-1>(v[0],v[1],v[2],v[3]);
      #pragma unroll
      for (int r=0;r<4;r++){ sr[SW2(4*j + r)] = v[r].x; si[SW2(4*j + r)] = v[r].y; }
      wsync();
      { // L=4
        v[0] = c2{sr[SW2(j)],     si[SW2(j)]};
        v[1] = cmulc(c2{sr[SW2(j+64)],  si[SW2(j+64)]},  w4);
        v[2] = cmulc(c2{sr[SW2(j+128)], si[SW2(j+128)]}, w4b);
        v[3] = cmulc(c2{sr[SW2(j+192)], si[SW2(j+192)]}, w4c);
        dft4<-1>(v[0],v[1],v[2],v[3]);
        wsync();
        #pragma unroll
        for (int r=0;r<4;r++){ sr[SW2(b4 + 4*r)] = v[r].x; si[SW2(b4 + 4*r)] = v[r].y; }
      }
      wsync();
      { // L=16
        v[0] = c2{sr[SW2(j)],     si[SW2(j)]};
        v[1] = cmulc(c2{sr[SW2(j+64)],  si[SW2(j+64)]},  w16);
        v[2] = cmulc(c2{sr[SW2(j+128)], si[SW2(j+128)]}, w16b);
        v[3] = cmulc(c2{sr[SW2(j+192)], si[SW2(j+192)]}, w16c);
        dft4<-1>(v[0],v[1],v[2],v[3]);
        wsync();
        #pragma unroll
        for (int r=0;r<4;r++){ sr[SW2(b16 + 16*r)] = v[r].x; si[SW2(b16 + 16*r)] = v[r].y; }
      }
      wsync();
      { // L=64 + row twiddle -> overwrite dead tile row (transposed store)
        v[0] = c2{sr[SW2(j)],     si[SW2(j)]};
        v[1] = cmulc(c2{sr[SW2(j+64)],  si[SW2(j+64)]},  w64);
        v[2] = cmulc(c2{sr[SW2(j+128)], si[SW2(j+128)]}, w64b);
        v[3] = cmulc(c2{sr[SW2(j+192)], si[SW2(j+192)]}, w64c);
        dft4<-1>(v[0],v[1],v[2],v[3]);
        #pragma unroll
        for (int r=0;r<4;r++){
          int kb = j + 64*r;
          c2 tw = cis(-TWO_PI * (float)(n1*kb) * (1.0f/160000.0f));
          c2 z = cmul(v[r], tw);
          tr[n1i*GTF + kb] = z.x;
          ti[n1i*GTF + kb] = z.y;
        }
      }
    }
    wsync();
  }
  if (WRITEB){
    __syncthreads();
    unsigned* op = outB + (size_t)arr*TLEN;
    if (rows == GCH){
      for (int e = threadIdx.x; e < 256*GCH; e += 256){
        int kb = e / GCH, i = e - kb*GCH;
        op[(size_t)kb*NA + n1_0 + i] = pack_bf(c2{tr[i*GTF + kb], ti[i*GTF + kb]});
      }
    } else {
      for (int e = threadIdx.x; e < 256*rows; e += 256){
        int kb = e / rows, i = e - kb*rows;
        op[(size_t)kb*NA + n1_0 + i] = pack_bf(c2{tr[i*GTF + kb], ti[i*GTF + kb]});
      }
    }
  }
}

// ---------------- 625-point row FFT (radix-5 Stockham), float-plane LDS + W625 LUT ----------------
// FILT: 0 none, 1 psi1 (input Xf), 2 psi2 (input U1h). TW: output twiddle (incremental).
// PIN/POUT: packed-bf16 input/output (S2-only streams).
template<int S, int FILT, int TW, int PIN, int POUT>
__global__ __launch_bounds__(128) void k_fft625(const void* __restrict__ inpv, void* __restrict__ outpv,
                                                int cblk, int BLK, int nj2, int j2base, int scBase,
                                                int kamax){
  __shared__ float l0r[625], l0i[625], l1r[625], l1i[625];
  __shared__ float lutr[625], luti[625];
  for (int m = threadIdx.x; m < 625; m += 128){
    c2 z = cis(TWO_PI * (float)m * (1.0f/625.0f));
    lutr[m] = z.x; luti[m] = z.y;
  }
  int g = blockIdx.x;
  int i = g / NB, kb = g - i*NB;
  int j = threadIdx.x;
  const c2* ipc = (const c2*)inpv;
  const unsigned* ipu = (const unsigned*)inpv;
  size_t ibase;
  int j1 = 0, j2 = 0;
  if (FILT == 0){
    ibase = (size_t)i*TLEN;
  } else if (FILT == 1){
    int bt = i / BLK; j1 = cblk*BLK + (i - bt*BLK);
    ibase = (size_t)bt*TLEN;
  } else {
    int g2 = scBase + i;
    int npb = BLK*nj2;
    int bt = g2 / npb, rr = g2 - bt*npb;
    int jloc = rr / nj2; j2 = j2base + (rr - jloc*nj2);
    ibase = (size_t)(bt*BLK + jloc)*TLEN;
  }
  ibase += (size_t)kb*NA;
  float xi = 0.0f, sig = 0.0f, inv2s = 0.0f;
  int klo = 0, khi = 0;
  if (FILT != 0){
    if (FILT == 1){ xi = 0.4f * exp2f(-(float)j1 * 0.0625f); sig = xi * 0.04427378243f; }
    else          { xi = 0.4f * exp2f(-(float)j2);           sig = 0.35f * xi; }
    inv2s = 0.5f / (sig*sig);
    klo = (int)((xi - 6.0f*sig) * (float)TLEN); if (klo < 0) klo = 0;
    khi = (int)((xi + 6.0f*sig) * (float)TLEN) + 1; if (khi > TLEN/2 - 1) khi = TLEN/2 - 1;
  }
  c2 a[5], b[5];
  if (j < 125){
    if (FILT == 0){
      #pragma unroll
      for (int q=0;q<5;q++){
        size_t idx = ibase + j + 125*q;
        a[q] = PIN ? unpack_bf(ipu[idx]) : ipc[idx];
      }
      dft5<S>(a, b);
    } else {
      bool any = false;
      #pragma unroll
      for (int q=0;q<5;q++){
        int ka = j + 125*q;
        int k = kb + 256*ka;
        c2 val = c2{0.0f, 0.0f};
        if (k >= klo && k <= khi){
          size_t idx = ibase + ka;
          val = PIN ? unpack_bf(ipu[idx]) : ipc[idx];
          float d = (float)k * (1.0f/(float)TLEN) - xi;
          float f = __expf(-d*d*inv2s);
          val.x *= f; val.y *= f;
          any = true;
        }
        a[q] = val;
      }
      if (any){
        dft5<S>(a, b);
      } else {
        #pragma unroll
        for (int r=0;r<5;r++) b[r] = c2{0.0f,0.0f};
      }
    }
    #pragma unroll
    for (int r=0;r<5;r++){ int s = 5*j + r; l0r[s] = b[r].x; l0i[s] = b[r].y; }
  }
  __syncthreads();   // also covers LUT fill
  if (j < 125){ // L = 5
    int k = j % 5;
    c2 w  = c2{lutr[25*k],  (S>0)? luti[25*k]  : -luti[25*k]};
    c2 w2 = c2{lutr[50*k],  (S>0)? luti[50*k]  : -luti[50*k]};
    c2 w3 = c2{lutr[75*k],  (S>0)? luti[75*k]  : -luti[75*k]};
    c2 w4 = c2{lutr[100*k], (S>0)? luti[100*k] : -luti[100*k]};
    a[0] = c2{l0r[j],     l0i[j]};
    a[1] = cmul(c2{l0r[j+125], l0i[j+125]}, w);
    a[2] = cmul(c2{l0r[j+250], l0i[j+250]}, w2);
    a[3] = cmul(c2{l0r[j+375], l0i[j+375]}, w3);
    a[4] = cmul(c2{l0r[j+500], l0i[j+500]}, w4);
    dft5<S>(a, b);
    int base = 5*(j-k)+k;
    #pragma unroll
    for (int r=0;r<5;r++){ int s = base + 5*r; l1r[s] = b[r].x; l1i[s] = b[r].y; }
  }
  __syncthreads();
  if (j < 125){ // L = 25
    int k = j % 25;
    c2 w  = c2{lutr[5*k],  (S>0)? luti[5*k]  : -luti[5*k]};
    c2 w2 = c2{lutr[10*k], (S>0)? luti[10*k] : -luti[10*k]};
    c2 w3 = c2{lutr[15*k], (S>0)? luti[15*k] : -luti[15*k]};
    c2 w4 = c2{lutr[20*k], (S>0)? luti[20*k] : -luti[20*k]};
    a[0] = c2{l1r[j],     l1i[j]};
    a[1] = cmul(c2{l1r[j+125], l1i[j+125]}, w);
    a[2] = cmul(c2{l1r[j+250], l1i[j+250]}, w2);
    a[3] = cmul(c2{l1r[j+375], l1i[j+375]}, w3);
    a[4] = cmul(c2{l1r[j+500], l1i[j+500]}, w4);
    dft5<S>(a, b);
    int base = 5*(j-k)+k;
    #pragma unroll
    for (int r=0;r<5;r++){ int s = base + 25*r; l0r[s] = b[r].x; l0i[s] = b[r].y; }
  }
  __syncthreads();
  if (j < 125){ // L = 125
    c2 w  = c2{lutr[j],   (S>0)? luti[j]   : -luti[j]};
    c2 w2 = c2{lutr[2*j], (S>0)? luti[2*j] : -luti[2*j]};
    c2 w3 = c2{lutr[3*j], (S>0)? luti[3*j] : -luti[3*j]};
    c2 w4 = c2{lutr[4*j], (S>0)? luti[4*j] : -luti[4*j]};
    a[0] = c2{l0r[j],     l0i[j]};
    a[1] = cmul(c2{l0r[j+125], l0i[j+125]}, w);
    a[2] = cmul(c2{l0r[j+250], l0i[j+250]}, w2);
    a[3] = cmul(c2{l0r[j+375], l0i[j+375]}, w3);
    a[4] = cmul(c2{l0r[j+500], l0i[j+500]}, w4);
    dft5<S>(a, b);
    size_t obase = (size_t)i*TLEN + (size_t)kb*NA;
    if (TW){
      c2 twb = cis((float)S * TWO_PI * (float)(j*kb)   * (1.0f/160000.0f));
      c2 tws = cis((float)S * TWO_PI * (float)(125*kb) * (1.0f/160000.0f));
      #pragma unroll
      for (int r=0;r<5;r++){
        int n1 = j + 125*r;
        c2 z = cmul(b[r], twb);
        if (POUT) ((unsigned*)outpv)[obase + n1] = pack_bf(z);
        else      ((c2*)outpv)[obase + n1] = z;
        twb = cmul(twb, tws);
      }
    } else {
      #pragma unroll
      for (int r=0;r<5;r++){
        int n1 = j + 125*r;
        if (n1 <= kamax){
          if (POUT) ((unsigned*)outpv)[obase + n1] = pack_bf(b[r]);
          else      ((c2*)outpv)[obase + n1] = b[r];
        }
      }
    }
  }
}

// ---------------- complex transpose (x-chain only) ----------------
__global__ __launch_bounds__(256) void k_transpose(const c2* __restrict__ in, c2* __restrict__ out,
                                                   int R, int C, int tilesR, int tilesC){
  __shared__ c2 tile[32][33];
  int bi = blockIdx.x;
  int arr = bi / (tilesR*tilesC);
  int tt = bi - arr*(tilesR*tilesC);
  int tr = tt / tilesC, tc = tt - tr*tilesC;
  const c2* ip = in + (size_t)arr*TLEN;
  c2* op = out + (size_t)arr*TLEN;
  int tx = threadIdx.x & 31, ty = threadIdx.x >> 5;
  #pragma unroll
  for (int i=0;i<4;i++){
    int r = tr*32 + ty + i*8, cc = tc*32 + tx;
    if (r < R && cc < C) tile[ty+i*8][tx] = ip[(size_t)r*C + cc];
  }
  __syncthreads();
  #pragma unroll
  for (int i=0;i<4;i++){
    int r = tc*32 + ty + i*8, cc = tr*32 + tx;
    if (r < C && cc < R) op[(size_t)r*R + cc] = tile[tx][ty+i*8];
  }
}

// ---------------- Gaussian lowpass + decimate-by-64, natural layout (S0 only) ----------------
__global__ __launch_bounds__(256) void k_conv(const float* __restrict__ inp, float* __restrict__ S){
  __shared__ float w[NTAP];
  for (int i=threadIdx.x; i<NTAP; i+=256){
    float d = (float)(i - KC);
    w[i] = 0.015666427f * __expf(-7.7106284e-4f * d * d);
  }
  __syncthreads();
  int g = blockIdx.x;
  int arr = g / 10;
  int t = (g - arr*10)*256 + threadIdx.x;
  if (t >= TD) return;
  int srow = arr * SROWS;
  const float* ip = inp + (size_t)arr*TLEN;
  float acc = 0.0f;
  int n = 64*t - KC; if (n < 0) n += TLEN;
  for (int m=0;m<NTAP;m++){
    acc += ip[n] * w[m];
    n++; if (n == TLEN) n = 0;
  }
  S[(size_t)srow*TD + t] = acc;
}

// ---------------- fused LDS stage + conv for scrambled-layout U (S1/S2 rows) ----------------
#define CONV_NCOL 27
#define CONV_NU   16875
#define CONV_USZ  17138
#define CONV_LDSB ((CONV_USZ + NTAP + 1)*4)
template<int MODE>
__global__ __launch_bounds__(256) void k_conv2(const float* __restrict__ inp, float* __restrict__ S,
                                               int cblk, int BLK, int nj2, int j2base, int scBase){
  extern __shared__ float smem[];
  float* u = smem;
  float* w = smem + CONV_USZ;
  for (int i=threadIdx.x; i<NTAP; i+=256){
    float d = (float)(i - KC);
    w[i] = 0.015666427f * __expf(-7.7106284e-4f * d * d);
  }
  int g = blockIdx.x;
  int arr = g / 10;
  int b = g - arr*10;
  int nlo = 16000*b - KC;
  int n2_0 = (nlo >= 0) ? (nlo/625) : -1;
  const float* ip = inp + (size_t)arr*TLEN;
  for (int e = threadIdx.x; e < CONV_NU; e += 256){
    int n1 = e / CONV_NCOL;
    int c  = e - n1*CONV_NCOL;
    int n2 = n2_0 + c;
    n2 &= 255;
    u[SW64(n1 + 625*c)] = ip[n1*NB + n2];
  }
  __syncthreads();
  int tl = threadIdx.x;
  if (tl >= 250) return;
  int t = 250*b + tl;
  int srow;
  if (MODE == 1){
    int a2 = arr / BLK; int j1 = cblk*BLK + (arr - a2*BLK);
    srow = a2*SROWS + 1 + j1;
  } else {
    int g2 = scBase + arr; int npb = BLK*nj2;
    int a2 = g2/npb, rr = g2 - a2*npb;
    int jloc = rr/nj2; int j2 = j2base + (rr - jloc*nj2);
    int j1 = cblk*BLK + jloc;
    int full = j1 >> 4;
    int cum = 16*(5*full - (full*(full-1))/2) + (j1 & 15)*(5 - full);
    int P = cum + j2 - full - 1;
    srow = a2*SROWS + 97 + P;
  }
  int base = 64*t - KC - 625*n2_0;
  float acc = 0.0f;
  #pragma unroll 4
  for (int m=0;m<NTAP;m++){
    acc += u[SW64(base + m)] * w[m];
  }
  S[(size_t)srow*TD + t] = acc;
}

// ---------------- global min/max + finalize ----------------
__global__ __launch_bounds__(256) void k_minmax1(const float* __restrict__ S, int n, float* pmn, float* pmx){
  __shared__ float smn[256], smx[256];
  float mn = 3.4028235e38f, mx = -3.4028235e38f;
  for (size_t i = (size_t)blockIdx.x*256 + threadIdx.x; i < (size_t)n; i += (size_t)gridDim.x*256){
    float v = S[i]; mn = fminf(mn,v); mx = fmaxf(mx,v);
  }
  smn[threadIdx.x]=mn; smx[threadIdx.x]=mx; __syncthreads();
  for (int s=128;s>0;s>>=1){
    if ((int)threadIdx.x < s){
      smn[threadIdx.x]=fminf(smn[threadIdx.x],smn[threadIdx.x+s]);
      smx[threadIdx.x]=fmaxf(smx[threadIdx.x],smx[threadIdx.x+s]);
    }
    __syncthreads();
  }
  if (threadIdx.x==0){ pmn[blockIdx.x]=smn[0]; pmx[blockIdx.x]=smx[0]; }
}
__global__ __launch_bounds__(256) void k_minmax2(const float* __restrict__ pmn, const float* __restrict__ pmx,
                                                 int nb, float* scal){
  __shared__ float smn[256], smx[256];
  float mn = 3.4028235e38f, mx = -3.4028235e38f;
  for (int i = threadIdx.x; i < nb; i += 256){ mn = fminf(mn,pmn[i]); mx = fmaxf(mx,pmx[i]); }
  smn[threadIdx.x]=mn; smx[threadIdx.x]=mx; __syncthreads();
  for (int s=128;s>0;s>>=1){
    if ((int)threadIdx.x < s){
      smn[threadIdx.x]=fminf(smn[threadIdx.x],smn[threadIdx.x+s]);
      smx[threadIdx.x]=fmaxf(smx[threadIdx.x],smx[threadIdx.x+s]);
    }
    __syncthreads();
  }
  if (threadIdx.x==0){ scal[0]=smn[0]; scal[1]=smx[0]; }
}
__global__ __launch_bounds__(256) void k_final(const float* __restrict__ S, const float* __restrict__ scal,
                                               float* __restrict__ out, int n){
  int i = blockIdx.x*256 + threadIdx.x;
  if (i >= n) return;
  float mn = scal[0];
  float r = scal[1] - mn;
  if (r == 0.0f) r = 1.0f;
  int half = SROWS*TD;
  int a = i / half; int rest = i - a*half;
  out[i] = (S[(size_t)(a & 1)*half + rest] - mn) / r;
}

extern "C" void kernel_launch(void* const* d_in, const int* in_sizes, int n_in,
                              void* d_out, int out_size, void* d_ws, size_t ws_size,
                              hipStream_t stream){
  (void)in_sizes; (void)n_in;
  const float* x = (const float*)d_in[0];

  int BLK = 16;
  while (BLK > 1){
    size_t CH = 2*(size_t)BLK;
    // Xf(f32) + A1(f32) + B(u32) + U1h(u32) + A2(3,u32) + Ur(3,f32) + Sb + misc
    size_t needb = 2560000ULL + CH*TLEN*8ULL + CH*TLEN*4ULL + CH*TLEN*4ULL
                 + 3ULL*CH*TLEN*4ULL + 3ULL*CH*TLEN*4ULL + 6740000ULL + 8192ULL + 4096ULL;
    if (needb <= ws_size) break;
    BLK >>= 1;
  }
  {
    size_t CH = 2;
    size_t needmin = 2560000ULL + CH*TLEN*8ULL + CH*TLEN*4ULL + CH*TLEN*4ULL
                   + 3ULL*CH*TLEN*4ULL + 3ULL*CH*TLEN*4ULL + 6740000ULL + 8192ULL + 4096ULL;
    if (ws_size < needmin) return;
  }
  int CH = 2*BLK;

  char* p = (char*)d_ws;
  auto carve = [&](size_t bytes)->void*{ void* r = (void*)p; p += (bytes + 255) & ~(size_t)255; return r; };
  c2*       Xf  = (c2*)carve(2ULL*TLEN*sizeof(c2));
  c2*       A1  = (c2*)carve((size_t)CH*TLEN*sizeof(c2));       // order-1 intermediate (f32)
  unsigned* B   = (unsigned*)carve((size_t)CH*TLEN*4ULL);       // packed bf16 (S2 stream)
  unsigned* U1h = (unsigned*)carve((size_t)CH*TLEN*4ULL);       // packed bf16
  unsigned* A2  = (unsigned*)carve(3ULL*CH*TLEN*4ULL);          // packed bf16, 3 sc-slots
  float*    Ur  = (float*)carve(3ULL*CH*TLEN*sizeof(float));    // 3 sc-slots
  float*    Sb  = (float*)carve(2ULL*SROWS*TD*sizeof(float));
  float*    pmn = (float*)carve(512*4);
  float*    pmx = (float*)carve(512*4);
  float*    scal = (float*)carve(256);

  // ---- forward FFT of x -> Xf (f32 chain; U1h buffer reused as c2 scratch here) ----
  k_fft256<-1,2,0><<<2*NA, 64, 0, stream>>>((const void*)x, (void*)A1);
  k_transpose<<<2*20*8, 256, 0, stream>>>(A1, (c2*)U1h, NA, NB, 20, 8);
  k_fft625<-1,0,0,0,0><<<2*NB, 128, 0, stream>>>((const void*)U1h, (void*)Xf, 0,0,0,0,0, 314);
  // ---- S0 ----
  k_conv<<<2*10, 256, 0, stream>>>(x, Sb);

  int NCB = 96 / BLK;
  for (int c = 0; c < NCB; c++){
    int cq = (c*BLK)/16;
    int nj2 = 5 - cq;
    int j2base = cq + 1;
    float xi2 = 0.4f * exp2f(-(float)j2base);
    int khi2 = (int)(3.1f * xi2 * 160000.0f) + 1; if (khi2 > TLEN/2 - 1) khi2 = TLEN/2 - 1;
    int kamax = (khi2 >> 8) + 1; if (kamax > 624) kamax = 624;
    // ---- order 1 (f32 path) ----
    k_fft625<1,1,1,0,0><<<CH*NB, 128, 0, stream>>>((const void*)Xf, (void*)A1, c, BLK, 0,0,0, 624);
    if (nj2 > 0){
      k_fft256g<1,0><<<CH*GNCH, 256, G_LDSB, stream>>>((const void*)A1, Ur, B);   // |ifft|->Ur, fft->B(bf16)
      k_conv2<1><<<CH*10, 256, CONV_LDSB, stream>>>(Ur, Sb, c, BLK, 0,0,0);
      k_fft625<-1,0,0,1,1><<<CH*NB, 128, 0, stream>>>((const void*)B, (void*)U1h, 0,0,0,0,0, kamax);
      // ---- order 2 (bf16 stream), sc batched in triples ----
      for (int scStart = 0; scStart < nj2; scStart += 3){
        int nsc = nj2 - scStart; if (nsc > 3) nsc = 3;
        k_fft625<1,2,1,1,1><<<nsc*CH*NB, 128, 0, stream>>>((const void*)U1h, (void*)A2, c, BLK, nj2, j2base, scStart*CH, 624);
        k_fft256g<0,1><<<nsc*CH*GNCH, 256, G_LDSB, stream>>>((const void*)A2, Ur, (unsigned*)nullptr);
        k_conv2<2><<<nsc*CH*10, 256, CONV_LDSB, stream>>>(Ur, Sb, c, BLK, nj2, j2base, scStart*CH);
      }
    } else {
      k_fft256g<0,0><<<CH*GNCH, 256, G_LDSB, stream>>>((const void*)A1, Ur, (unsigned*)nullptr);
      k_conv2<1><<<CH*10, 256, CONV_LDSB, stream>>>(Ur, Sb, c, BLK, 0,0,0);
    }
  }

  // ---- global min-max normalize (standardize cancels) + tile(3,1,1) ----
  k_minmax1<<<512, 256, 0, stream>>>(Sb, 2*SROWS*TD, pmn, pmx);
  k_minmax2<<<1, 256, 0, stream>>>(pmn, pmx, 512, scal);
  k_final<<<(out_size+255)/256, 256, 0, stream>>>(Sb, scal, (float*)d_out, out_size);
}

// Round 14
// 1291.610 us; speedup vs baseline: 1.0793x; 1.0487x over previous
//
#include <hip/hip_runtime.h>
#include <math.h>

#define TLEN 160000
#define NA 625      // n1 (time rows) / ka (freq elements)
#define NB 256      // n2 (time elements) / kb (freq rows)
#define TD 2500
#define KC 128      // conv half width (~5 sigma_t, sigma_t = 25.46)
#define NTAP 257
#define SROWS 337
#define TWO_PI 6.283185307179586f

struct c2 { float x, y; };

__device__ __forceinline__ c2 cmul(c2 a, c2 b){ return c2{a.x*b.x - a.y*b.y, a.x*b.y + a.y*b.x}; }
__device__ __forceinline__ c2 cmulc(c2 a, c2 b){ return c2{a.x*b.x + a.y*b.y, a.y*b.x - a.x*b.y}; } // a*conj(b)
__device__ __forceinline__ c2 cadd(c2 a, c2 b){ return c2{a.x+b.x, a.y+b.y}; }
__device__ __forceinline__ c2 csub(c2 a, c2 b){ return c2{a.x-b.x, a.y-b.y}; }
__device__ __forceinline__ c2 cmac(c2 acc, c2 v, float wr, float wi){
  acc.x += v.x*wr - v.y*wi; acc.y += v.x*wi + v.y*wr; return acc;
}
__device__ __forceinline__ c2 cis(float ang){ c2 r; __sincosf(ang, &r.y, &r.x); return r; }
__device__ __forceinline__ int SW(int i){ return i + (i >> 4); }
__device__ __forceinline__ int SW2(int i){ return i + (i >> 2); }
__device__ __forceinline__ int SW64(int i){ return i + (i >> 6); }
// bf16-pair packing for S2-only intermediates (halves their HBM traffic)
__device__ __forceinline__ unsigned pack_bf(c2 z){
  unsigned xr = __float_as_uint(z.x), xi = __float_as_uint(z.y);
  xr += 0x8000u + ((xr >> 16) & 1u);
  xi += 0x8000u + ((xi >> 16) & 1u);
  return (xr >> 16) | (xi & 0xFFFF0000u);   // lo16 = re, hi16 = im
}
__device__ __forceinline__ c2 unpack_bf(unsigned p){
  return c2{ __uint_as_float(p << 16), __uint_as_float(p & 0xFFFF0000u) };
}
// wave-local "syncthreads" for wave-private LDS: LDS-only wait.
__device__ __forceinline__ void wsync(){
  __builtin_amdgcn_wave_barrier();
  asm volatile("s_waitcnt lgkmcnt(0)" ::: "memory");
  __builtin_amdgcn_sched_barrier(0);
  __builtin_amdgcn_wave_barrier();
}

template<int S>
__device__ __forceinline__ void dft4(c2& a0, c2& a1, c2& a2, c2& a3){
  c2 t0 = cadd(a0,a2), t1 = csub(a0,a2), t2 = cadd(a1,a3), t3 = csub(a1,a3);
  float fs = (float)S;
  a0 = cadd(t0,t2); a2 = csub(t0,t2);
  a1 = c2{t1.x - fs*t3.y, t1.y + fs*t3.x};
  a3 = c2{t1.x + fs*t3.y, t1.y - fs*t3.x};
}

template<int S>
__device__ __forceinline__ void dft5(const c2 a[5], c2 b[5]){
  const float C1 = 0.30901699437494742f, C2 = -0.80901699437494745f;
  const float S1 = 0.95105651629515353f * (float)S, S2 = 0.58778525229247314f * (float)S;
  b[0] = cadd(cadd(a[0],a[1]), cadd(cadd(a[2],a[3]),a[4]));
  c2 r;
  r = a[0]; r = cmac(r,a[1],C1, S1); r = cmac(r,a[2],C2, S2); r = cmac(r,a[3],C2,-S2); r = cmac(r,a[4],C1,-S1); b[1]=r;
  r = a[0]; r = cmac(r,a[1],C2, S2); r = cmac(r,a[2],C1,-S1); r = cmac(r,a[3],C1, S1); r = cmac(r,a[4],C2,-S2); b[2]=r;
  r = a[0]; r = cmac(r,a[1],C2,-S2); r = cmac(r,a[2],C1, S1); r = cmac(r,a[3],C1,-S1); r = cmac(r,a[4],C2, S2); b[3]=r;
  r = a[0]; r = cmac(r,a[1],C1,-S1); r = cmac(r,a[2],C2,-S2); r = cmac(r,a[3],C2, S2); r = cmac(r,a[4],C1, S1); b[4]=r;
}

// ---------------- W625 global LUT init ----------------
__global__ __launch_bounds__(256) void k_wlut(c2* __restrict__ W){
  int m = blockIdx.x*256 + threadIdx.x;
  if (m < 625) W[m] = cis(TWO_PI * (float)m * (1.0f/625.0f));
}

// ---------------- 256-point row FFT (x-chain only; single-wave blocks) ----------------
template<int S, int INMODE, int OUTMODE>
__global__ __launch_bounds__(64) void k_fft256(const void* __restrict__ inp, void* __restrict__ outp){
  __shared__ c2 lds[2][272];
  int g = blockIdx.x;
  int arr = g / NA, n1 = g - arr*NA;
  int j = threadIdx.x;
  c2 v[4];
  if (INMODE == 0){
    const c2* ip = (const c2*)inp + (size_t)arr*TLEN + (size_t)n1*NB;
    #pragma unroll
    for (int q=0;q<4;q++) v[q] = ip[j + 64*q];
  } else if (INMODE == 1){
    const float* ip = (const float*)inp + (size_t)arr*TLEN + (size_t)n1*NB;
    #pragma unroll
    for (int q=0;q<4;q++) v[q] = c2{ip[j + 64*q], 0.0f};
  } else {
    const float* ip = (const float*)inp + (size_t)arr*TLEN;
    #pragma unroll
    for (int q=0;q<4;q++) v[q] = c2{ip[n1 + NA*(j + 64*q)], 0.0f};
  }
  dft4<S>(v[0],v[1],v[2],v[3]);
  #pragma unroll
  for (int r=0;r<4;r++) lds[0][SW(4*j + r)] = v[r];
  wsync();
  { // L = 4
    int k = j & 3;
    c2 w = cis((float)S * TWO_PI * (float)k * (1.0f/16.0f));
    c2 w2 = cmul(w,w), w3 = cmul(w2,w);
    v[0] = lds[0][SW(j)];
    v[1] = cmul(lds[0][SW(j+64)], w);
    v[2] = cmul(lds[0][SW(j+128)], w2);
    v[3] = cmul(lds[0][SW(j+192)], w3);
    dft4<S>(v[0],v[1],v[2],v[3]);
    int base = 4*(j-k)+k;
    #pragma unroll
    for (int r=0;r<4;r++) lds[1][SW(base + 4*r)] = v[r];
  }
  wsync();
  { // L = 16
    int k = j & 15;
    c2 w = cis((float)S * TWO_PI * (float)k * (1.0f/64.0f));
    c2 w2 = cmul(w,w), w3 = cmul(w2,w);
    v[0] = lds[1][SW(j)];
    v[1] = cmul(lds[1][SW(j+64)], w);
    v[2] = cmul(lds[1][SW(j+128)], w2);
    v[3] = cmul(lds[1][SW(j+192)], w3);
    dft4<S>(v[0],v[1],v[2],v[3]);
    int base = 4*(j-k)+k;
    #pragma unroll
    for (int r=0;r<4;r++) lds[0][SW(base + 16*r)] = v[r];
  }
  wsync();
  { // L = 64
    c2 w = cis((float)S * TWO_PI * (float)j * (1.0f/256.0f));
    c2 w2 = cmul(w,w), w3 = cmul(w2,w);
    v[0] = lds[0][SW(j)];
    v[1] = cmul(lds[0][SW(j+64)], w);
    v[2] = cmul(lds[0][SW(j+128)], w2);
    v[3] = cmul(lds[0][SW(j+192)], w3);
    dft4<S>(v[0],v[1],v[2],v[3]);
    if (OUTMODE == 0){
      c2* op = (c2*)outp + (size_t)arr*TLEN + (size_t)n1*NB;
      #pragma unroll
      for (int r=0;r<4;r++){
        int kb = j + 64*r;
        c2 tw = cis((float)S * TWO_PI * (float)(n1*kb) * (1.0f/160000.0f));
        op[kb] = cmul(v[r], tw);
      }
    } else {
      float* op = (float*)outp + (size_t)arr*TLEN + (size_t)n1*NB;
      #pragma unroll
      for (int r=0;r<4;r++){
        c2 z = v[r];
        op[j + 64*r] = sqrtf(z.x*z.x + z.y*z.y) * (1.0f/160000.0f);
      }
    }
  }
}

// ---------------- fused gather + inverse 256-FFT + abs (+ optional forward 256-FFT -> B) --------
// PIN: input is packed bf16 (order-2 stream). WRITEB output B is packed bf16.
#define GCH     12
#define GNCH    53                        // ceil(625/12)
#define GTF     273                       // tile float-plane stride; 273 % 32 = 17
#define SCR     320                       // per-plane scratch floats
#define G_LDSB  ((2*GCH*GTF + 4*2*SCR)*4) // 36448 B dynamic
template<int WRITEB, int PIN>
__global__ __launch_bounds__(256) void k_fft256g(const void* __restrict__ inpv, float* __restrict__ outp,
                                                 unsigned* __restrict__ outB){
  extern __shared__ float smemg[];
  float* tr = smemg;                           // [GCH][GTF]
  float* ti = smemg + GCH*GTF;                 // [GCH][GTF]
  int g = blockIdx.x;
  int arr = g / GNCH, chunk = g - arr*GNCH;
  int n1_0 = chunk*GCH;
  int rows = NA - n1_0; if (rows > GCH) rows = GCH;
  const c2* ipc = (const c2*)inpv;
  const unsigned* ipu = (const unsigned*)inpv;
  size_t base = (size_t)arr*TLEN;
  if (rows == GCH){
    for (int e = threadIdx.x; e < 256*GCH; e += 256){
      int kb = e / GCH, i = e - kb*GCH;        // const divisor
      size_t idx = base + (size_t)kb*NA + n1_0 + i;
      c2 z = PIN ? unpack_bf(ipu[idx]) : ipc[idx];
      tr[i*GTF + kb] = z.x; ti[i*GTF + kb] = z.y;
    }
  } else {
    for (int e = threadIdx.x; e < 256*rows; e += 256){
      int kb = e / rows, i = e - kb*rows;
      size_t idx = base + (size_t)kb*NA + n1_0 + i;
      c2 z = PIN ? unpack_bf(ipu[idx]) : ipc[idx];
      tr[i*GTF + kb] = z.x; ti[i*GTF + kb] = z.y;
    }
  }
  __syncthreads();
  int gq = threadIdx.x >> 6, j = threadIdx.x & 63;
  float* sr = smemg + 2*GCH*GTF + gq*(2*SCR);
  float* si = sr + SCR;
  c2 w4  = cis(TWO_PI * (float)(j & 3)  * (1.0f/16.0f));
  c2 w4b = cmul(w4,w4),  w4c = cmul(w4b,w4);
  c2 w16 = cis(TWO_PI * (float)(j & 15) * (1.0f/64.0f));
  c2 w16b= cmul(w16,w16), w16c= cmul(w16b,w16);
  c2 w64 = cis(TWO_PI * (float)j * (1.0f/256.0f));
  c2 w64b= cmul(w64,w64), w64c= cmul(w64b,w64);
  int b4 = 4*(j-(j&3))+(j&3);
  int b16= 4*(j-(j&15))+(j&15);
  float* op0 = outp + (size_t)arr*TLEN;
  for (int t = 0; t < 3; t++){
    int n1i = gq + 4*t;
    if (n1i >= rows) break;
    int n1 = n1_0 + n1i;
    c2 v[4];
    #pragma unroll
    for (int q=0;q<4;q++) v[q] = c2{tr[n1i*GTF + j + 64*q], ti[n1i*GTF + j + 64*q]};
    dft4<1>(v[0],v[1],v[2],v[3]);
    #pragma unroll
    for (int r=0;r<4;r++){ sr[SW2(4*j + r)] = v[r].x; si[SW2(4*j + r)] = v[r].y; }
    wsync();
    { // L=4
      v[0] = c2{sr[SW2(j)],     si[SW2(j)]};
      v[1] = cmul(c2{sr[SW2(j+64)],  si[SW2(j+64)]},  w4);
      v[2] = cmul(c2{sr[SW2(j+128)], si[SW2(j+128)]}, w4b);
      v[3] = cmul(c2{sr[SW2(j+192)], si[SW2(j+192)]}, w4c);
      dft4<1>(v[0],v[1],v[2],v[3]);
      wsync();
      #pragma unroll
      for (int r=0;r<4;r++){ sr[SW2(b4 + 4*r)] = v[r].x; si[SW2(b4 + 4*r)] = v[r].y; }
    }
    wsync();
    { // L=16
      v[0] = c2{sr[SW2(j)],     si[SW2(j)]};
      v[1] = cmul(c2{sr[SW2(j+64)],  si[SW2(j+64)]},  w16);
      v[2] = cmul(c2{sr[SW2(j+128)], si[SW2(j+128)]}, w16b);
      v[3] = cmul(c2{sr[SW2(j+192)], si[SW2(j+192)]}, w16c);
      dft4<1>(v[0],v[1],v[2],v[3]);
      wsync();
      #pragma unroll
      for (int r=0;r<4;r++){ sr[SW2(b16 + 16*r)] = v[r].x; si[SW2(b16 + 16*r)] = v[r].y; }
    }
    wsync();
    float av[4];
    { // L=64 + abs
      v[0] = c2{sr[SW2(j)],     si[SW2(j)]};
      v[1] = cmul(c2{sr[SW2(j+64)],  si[SW2(j+64)]},  w64);
      v[2] = cmul(c2{sr[SW2(j+128)], si[SW2(j+128)]}, w64b);
      v[3] = cmul(c2{sr[SW2(j+192)], si[SW2(j+192)]}, w64c);
      dft4<1>(v[0],v[1],v[2],v[3]);
      float* op = op0 + (size_t)n1*NB;
      #pragma unroll
      for (int r=0;r<4;r++){
        c2 z = v[r];
        av[r] = sqrtf(z.x*z.x + z.y*z.y) * (1.0f/160000.0f);
        op[j + 64*r] = av[r];
      }
    }
    if (WRITEB){
      wsync();
      #pragma unroll
      for (int q=0;q<4;q++) v[q] = c2{av[q], 0.0f};
      dft4<-1>(v[0],v[1],v[2],v[3]);
      #pragma unroll
      for (int r=0;r<4;r++){ sr[SW2(4*j + r)] = v[r].x; si[SW2(4*j + r)] = v[r].y; }
      wsync();
      { // L=4
        v[0] = c2{sr[SW2(j)],     si[SW2(j)]};
        v[1] = cmulc(c2{sr[SW2(j+64)],  si[SW2(j+64)]},  w4);
        v[2] = cmulc(c2{sr[SW2(j+128)], si[SW2(j+128)]}, w4b);
        v[3] = cmulc(c2{sr[SW2(j+192)], si[SW2(j+192)]}, w4c);
        dft4<-1>(v[0],v[1],v[2],v[3]);
        wsync();
        #pragma unroll
        for (int r=0;r<4;r++){ sr[SW2(b4 + 4*r)] = v[r].x; si[SW2(b4 + 4*r)] = v[r].y; }
      }
      wsync();
      { // L=16
        v[0] = c2{sr[SW2(j)],     si[SW2(j)]};
        v[1] = cmulc(c2{sr[SW2(j+64)],  si[SW2(j+64)]},  w16);
        v[2] = cmulc(c2{sr[SW2(j+128)], si[SW2(j+128)]}, w16b);
        v[3] = cmulc(c2{sr[SW2(j+192)], si[SW2(j+192)]}, w16c);
        dft4<-1>(v[0],v[1],v[2],v[3]);
        wsync();
        #pragma unroll
        for (int r=0;r<4;r++){ sr[SW2(b16 + 16*r)] = v[r].x; si[SW2(b16 + 16*r)] = v[r].y; }
      }
      wsync();
      { // L=64 + row twiddle -> overwrite dead tile row (transposed store)
        v[0] = c2{sr[SW2(j)],     si[SW2(j)]};
        v[1] = cmulc(c2{sr[SW2(j+64)],  si[SW2(j+64)]},  w64);
        v[2] = cmulc(c2{sr[SW2(j+128)], si[SW2(j+128)]}, w64b);
        v[3] = cmulc(c2{sr[SW2(j+192)], si[SW2(j+192)]}, w64c);
        dft4<-1>(v[0],v[1],v[2],v[3]);
        #pragma unroll
        for (int r=0;r<4;r++){
          int kb = j + 64*r;
          c2 tw = cis(-TWO_PI * (float)(n1*kb) * (1.0f/160000.0f));
          c2 z = cmul(v[r], tw);
          tr[n1i*GTF + kb] = z.x;
          ti[n1i*GTF + kb] = z.y;
        }
      }
    }
    wsync();
  }
  if (WRITEB){
    __syncthreads();
    unsigned* op = outB + (size_t)arr*TLEN;
    if (rows == GCH){
      for (int e = threadIdx.x; e < 256*GCH; e += 256){
        int kb = e / GCH, i = e - kb*GCH;
        op[(size_t)kb*NA + n1_0 + i] = pack_bf(c2{tr[i*GTF + kb], ti[i*GTF + kb]});
      }
    } else {
      for (int e = threadIdx.x; e < 256*rows; e += 256){
        int kb = e / rows, i = e - kb*rows;
        op[(size_t)kb*NA + n1_0 + i] = pack_bf(c2{tr[i*GTF + kb], ti[i*GTF + kb]});
      }
    }
  }
}

// ---------------- 625-point row FFT (radix-5 Stockham), float-plane LDS + global W625 LUT --------
// FILT: 0 none, 1 psi1 (input Xf), 2 psi2 (input U1h). TW: output twiddle (incremental).
// PIN/POUT: packed-bf16 input/output (S2-only streams).
// Stage twiddles from global Wg (L1-resident 5 KB; stage-1/2 reads are <=25-distinct broadcasts,
// stage-3 uses one coalesced Wg[j] + cmul chain -> no strided LDS conflicts, no per-block sincos).
template<int S, int FILT, int TW, int PIN, int POUT>
__global__ __launch_bounds__(128) void k_fft625(const void* __restrict__ inpv, void* __restrict__ outpv,
                                                const c2* __restrict__ Wg,
                                                int cblk, int BLK, int nj2, int j2base, int scBase,
                                                int kamax){
  __shared__ float l0r[625], l0i[625], l1r[625], l1i[625];
  int g = blockIdx.x;
  int i = g / NB, kb = g - i*NB;
  int j = threadIdx.x;
  const c2* ipc = (const c2*)inpv;
  const unsigned* ipu = (const unsigned*)inpv;
  size_t ibase;
  int j1 = 0, j2 = 0;
  if (FILT == 0){
    ibase = (size_t)i*TLEN;
  } else if (FILT == 1){
    int bt = i / BLK; j1 = cblk*BLK + (i - bt*BLK);
    ibase = (size_t)bt*TLEN;
  } else {
    int g2 = scBase + i;
    int npb = BLK*nj2;
    int bt = g2 / npb, rr = g2 - bt*npb;
    int jloc = rr / nj2; j2 = j2base + (rr - jloc*nj2);
    ibase = (size_t)(bt*BLK + jloc)*TLEN;
  }
  ibase += (size_t)kb*NA;
  float xi = 0.0f, sig = 0.0f, inv2s = 0.0f;
  int klo = 0, khi = 0;
  if (FILT != 0){
    if (FILT == 1){ xi = 0.4f * exp2f(-(float)j1 * 0.0625f); sig = xi * 0.04427378243f; }
    else          { xi = 0.4f * exp2f(-(float)j2);           sig = 0.35f * xi; }
    inv2s = 0.5f / (sig*sig);
    klo = (int)((xi - 6.0f*sig) * (float)TLEN); if (klo < 0) klo = 0;
    khi = (int)((xi + 6.0f*sig) * (float)TLEN) + 1; if (khi > TLEN/2 - 1) khi = TLEN/2 - 1;
  }
  c2 a[5], b[5];
  if (j < 125){
    if (FILT == 0){
      #pragma unroll
      for (int q=0;q<5;q++){
        size_t idx = ibase + j + 125*q;
        a[q] = PIN ? unpack_bf(ipu[idx]) : ipc[idx];
      }
      dft5<S>(a, b);
    } else {
      bool any = false;
      #pragma unroll
      for (int q=0;q<5;q++){
        int ka = j + 125*q;
        int k = kb + 256*ka;
        c2 val = c2{0.0f, 0.0f};
        if (k >= klo && k <= khi){
          size_t idx = ibase + ka;
          val = PIN ? unpack_bf(ipu[idx]) : ipc[idx];
          float d = (float)k * (1.0f/(float)TLEN) - xi;
          float f = __expf(-d*d*inv2s);
          val.x *= f; val.y *= f;
          any = true;
        }
        a[q] = val;
      }
      if (any){
        dft5<S>(a, b);
      } else {
        #pragma unroll
        for (int r=0;r<5;r++) b[r] = c2{0.0f,0.0f};
      }
    }
    #pragma unroll
    for (int r=0;r<5;r++){ int s = 5*j + r; l0r[s] = b[r].x; l0i[s] = b[r].y; }
  }
  __syncthreads();
  if (j < 125){ // L = 5
    int k = j % 5;
    c2 w  = Wg[25*k];  if (S<0) w.y  = -w.y;
    c2 w2 = Wg[50*k];  if (S<0) w2.y = -w2.y;
    c2 w3 = Wg[75*k];  if (S<0) w3.y = -w3.y;
    c2 w4 = Wg[100*k]; if (S<0) w4.y = -w4.y;
    a[0] = c2{l0r[j],     l0i[j]};
    a[1] = cmul(c2{l0r[j+125], l0i[j+125]}, w);
    a[2] = cmul(c2{l0r[j+250], l0i[j+250]}, w2);
    a[3] = cmul(c2{l0r[j+375], l0i[j+375]}, w3);
    a[4] = cmul(c2{l0r[j+500], l0i[j+500]}, w4);
    dft5<S>(a, b);
    int base = 5*(j-k)+k;
    #pragma unroll
    for (int r=0;r<5;r++){ int s = base + 5*r; l1r[s] = b[r].x; l1i[s] = b[r].y; }
  }
  __syncthreads();
  if (j < 125){ // L = 25
    int k = j % 25;
    c2 w  = Wg[5*k];   if (S<0) w.y  = -w.y;
    c2 w2 = Wg[10*k];  if (S<0) w2.y = -w2.y;
    c2 w3 = Wg[15*k];  if (S<0) w3.y = -w3.y;
    c2 w4 = Wg[20*k];  if (S<0) w4.y = -w4.y;
    a[0] = c2{l1r[j],     l1i[j]};
    a[1] = cmul(c2{l1r[j+125], l1i[j+125]}, w);
    a[2] = cmul(c2{l1r[j+250], l1i[j+250]}, w2);
    a[3] = cmul(c2{l1r[j+375], l1i[j+375]}, w3);
    a[4] = cmul(c2{l1r[j+500], l1i[j+500]}, w4);
    dft5<S>(a, b);
    int base = 5*(j-k)+k;
    #pragma unroll
    for (int r=0;r<5;r++){ int s = base + 25*r; l0r[s] = b[r].x; l0i[s] = b[r].y; }
  }
  __syncthreads();
  if (j < 125){ // L = 125
    c2 w = Wg[j]; if (S<0) w.y = -w.y;
    c2 w2 = cmul(w,w), w3 = cmul(w2,w), w4 = cmul(w2,w2);
    a[0] = c2{l0r[j],     l0i[j]};
    a[1] = cmul(c2{l0r[j+125], l0i[j+125]}, w);
    a[2] = cmul(c2{l0r[j+250], l0i[j+250]}, w2);
    a[3] = cmul(c2{l0r[j+375], l0i[j+375]}, w3);
    a[4] = cmul(c2{l0r[j+500], l0i[j+500]}, w4);
    dft5<S>(a, b);
    size_t obase = (size_t)i*TLEN + (size_t)kb*NA;
    if (TW){
      c2 twb = cis((float)S * TWO_PI * (float)(j*kb)   * (1.0f/160000.0f));
      c2 tws = cis((float)S * TWO_PI * (float)(125*kb) * (1.0f/160000.0f));
      #pragma unroll
      for (int r=0;r<5;r++){
        int n1 = j + 125*r;
        c2 z = cmul(b[r], twb);
        if (POUT) ((unsigned*)outpv)[obase + n1] = pack_bf(z);
        else      ((c2*)outpv)[obase + n1] = z;
        twb = cmul(twb, tws);
      }
    } else {
      #pragma unroll
      for (int r=0;r<5;r++){
        int n1 = j + 125*r;
        if (n1 <= kamax){
          if (POUT) ((unsigned*)outpv)[obase + n1] = pack_bf(b[r]);
          else      ((c2*)outpv)[obase + n1] = b[r];
        }
      }
    }
  }
}

// ---------------- complex transpose (x-chain only) ----------------
__global__ __launch_bounds__(256) void k_transpose(const c2* __restrict__ in, c2* __restrict__ out,
                                                   int R, int C, int tilesR, int tilesC){
  __shared__ c2 tile[32][33];
  int bi = blockIdx.x;
  int arr = bi / (tilesR*tilesC);
  int tt = bi - arr*(tilesR*tilesC);
  int tr = tt / tilesC, tc = tt - tr*tilesC;
  const c2* ip = in + (size_t)arr*TLEN;
  c2* op = out + (size_t)arr*TLEN;
  int tx = threadIdx.x & 31, ty = threadIdx.x >> 5;
  #pragma unroll
  for (int i=0;i<4;i++){
    int r = tr*32 + ty + i*8, cc = tc*32 + tx;
    if (r < R && cc < C) tile[ty+i*8][tx] = ip[(size_t)r*C + cc];
  }
  __syncthreads();
  #pragma unroll
  for (int i=0;i<4;i++){
    int r = tc*32 + ty + i*8, cc = tr*32 + tx;
    if (r < C && cc < R) op[(size_t)r*R + cc] = tile[tx][ty+i*8];
  }
}

// ---------------- Gaussian lowpass + decimate-by-64, natural layout (S0 only) ----------------
__global__ __launch_bounds__(256) void k_conv(const float* __restrict__ inp, float* __restrict__ S){
  __shared__ float w[NTAP];
  for (int i=threadIdx.x; i<NTAP; i+=256){
    float d = (float)(i - KC);
    w[i] = 0.015666427f * __expf(-7.7106284e-4f * d * d);
  }
  __syncthreads();
  int g = blockIdx.x;
  int arr = g / 10;
  int t = (g - arr*10)*256 + threadIdx.x;
  if (t >= TD) return;
  int srow = arr * SROWS;
  const float* ip = inp + (size_t)arr*TLEN;
  float acc = 0.0f;
  int n = 64*t - KC; if (n < 0) n += TLEN;
  for (int m=0;m<NTAP;m++){
    acc += ip[n] * w[m];
    n++; if (n == TLEN) n = 0;
  }
  S[(size_t)srow*TD + t] = acc;
}

// ---------------- fused LDS stage + conv for scrambled-layout U (S1/S2 rows) ----------------
#define CONV_NCOL 27
#define CONV_NU   16875
#define CONV_USZ  17138
#define CONV_LDSB ((CONV_USZ + NTAP + 1)*4)
template<int MODE>
__global__ __launch_bounds__(256) void k_conv2(const float* __restrict__ inp, float* __restrict__ S,
                                               int cblk, int BLK, int nj2, int j2base, int scBase){
  extern __shared__ float smem[];
  float* u = smem;
  float* w = smem + CONV_USZ;
  for (int i=threadIdx.x; i<NTAP; i+=256){
    float d = (float)(i - KC);
    w[i] = 0.015666427f * __expf(-7.7106284e-4f * d * d);
  }
  int g = blockIdx.x;
  int arr = g / 10;
  int b = g - arr*10;
  int nlo = 16000*b - KC;
  int n2_0 = (nlo >= 0) ? (nlo/625) : -1;
  const float* ip = inp + (size_t)arr*TLEN;
  for (int e = threadIdx.x; e < CONV_NU; e += 256){
    int n1 = e / CONV_NCOL;
    int c  = e - n1*CONV_NCOL;
    int n2 = n2_0 + c;
    n2 &= 255;
    u[SW64(n1 + 625*c)] = ip[n1*NB + n2];
  }
  __syncthreads();
  int tl = threadIdx.x;
  if (tl >= 250) return;
  int t = 250*b + tl;
  int srow;
  if (MODE == 1){
    int a2 = arr / BLK; int j1 = cblk*BLK + (arr - a2*BLK);
    srow = a2*SROWS + 1 + j1;
  } else {
    int g2 = scBase + arr; int npb = BLK*nj2;
    int a2 = g2/npb, rr = g2 - a2*npb;
    int jloc = rr/nj2; int j2 = j2base + (rr - jloc*nj2);
    int j1 = cblk*BLK + jloc;
    int full = j1 >> 4;
    int cum = 16*(5*full - (full*(full-1))/2) + (j1 & 15)*(5 - full);
    int P = cum + j2 - full - 1;
    srow = a2*SROWS + 97 + P;
  }
  int base = 64*t - KC - 625*n2_0;
  float acc = 0.0f;
  #pragma unroll 4
  for (int m=0;m<NTAP;m++){
    acc += u[SW64(base + m)] * w[m];
  }
  S[(size_t)srow*TD + t] = acc;
}

// ---------------- global min/max + finalize ----------------
__global__ __launch_bounds__(256) void k_minmax1(const float* __restrict__ S, int n, float* pmn, float* pmx){
  __shared__ float smn[256], smx[256];
  float mn = 3.4028235e38f, mx = -3.4028235e38f;
  for (size_t i = (size_t)blockIdx.x*256 + threadIdx.x; i < (size_t)n; i += (size_t)gridDim.x*256){
    float v = S[i]; mn = fminf(mn,v); mx = fmaxf(mx,v);
  }
  smn[threadIdx.x]=mn; smx[threadIdx.x]=mx; __syncthreads();
  for (int s=128;s>0;s>>=1){
    if ((int)threadIdx.x < s){
      smn[threadIdx.x]=fminf(smn[threadIdx.x],smn[threadIdx.x+s]);
      smx[threadIdx.x]=fmaxf(smx[threadIdx.x],smx[threadIdx.x+s]);
    }
    __syncthreads();
  }
  if (threadIdx.x==0){ pmn[blockIdx.x]=smn[0]; pmx[blockIdx.x]=smx[0]; }
}
__global__ __launch_bounds__(256) void k_minmax2(const float* __restrict__ pmn, const float* __restrict__ pmx,
                                                 int nb, float* scal){
  __shared__ float smn[256], smx[256];
  float mn = 3.4028235e38f, mx = -3.4028235e38f;
  for (int i = threadIdx.x; i < nb; i += 256){ mn = fminf(mn,pmn[i]); mx = fmaxf(mx,pmx[i]); }
  smn[threadIdx.x]=mn; smx[threadIdx.x]=mx; __syncthreads();
  for (int s=128;s>0;s>>=1){
    if ((int)threadIdx.x < s){
      smn[threadIdx.x]=fminf(smn[threadIdx.x],smn[threadIdx.x+s]);
      smx[threadIdx.x]=fmaxf(smx[threadIdx.x],smx[threadIdx.x+s]);
    }
    __syncthreads();
  }
  if (threadIdx.x==0){ scal[0]=smn[0]; scal[1]=smx[0]; }
}
__global__ __launch_bounds__(256) void k_final(const float* __restrict__ S, const float* __restrict__ scal,
                                               float* __restrict__ out, int n){
  int i = blockIdx.x*256 + threadIdx.x;
  if (i >= n) return;
  float mn = scal[0];
  float r = scal[1] - mn;
  if (r == 0.0f) r = 1.0f;
  int half = SROWS*TD;
  int a = i / half; int rest = i - a*half;
  out[i] = (S[(size_t)(a & 1)*half + rest] - mn) / r;
}

extern "C" void kernel_launch(void* const* d_in, const int* in_sizes, int n_in,
                              void* d_out, int out_size, void* d_ws, size_t ws_size,
                              hipStream_t stream){
  (void)in_sizes; (void)n_in;
  const float* x = (const float*)d_in[0];

  int BLK = 16;
  while (BLK > 1){
    size_t CH = 2*(size_t)BLK;
    size_t needb = 2560000ULL + CH*TLEN*8ULL + CH*TLEN*4ULL + CH*TLEN*4ULL
                 + 3ULL*CH*TLEN*4ULL + 3ULL*CH*TLEN*4ULL + 6740000ULL + 16384ULL + 4096ULL;
    if (needb <= ws_size) break;
    BLK >>= 1;
  }
  {
    size_t CH = 2;
    size_t needmin = 2560000ULL + CH*TLEN*8ULL + CH*TLEN*4ULL + CH*TLEN*4ULL
                   + 3ULL*CH*TLEN*4ULL + 3ULL*CH*TLEN*4ULL + 6740000ULL + 16384ULL + 4096ULL;
    if (ws_size < needmin) return;
  }
  int CH = 2*BLK;

  char* p = (char*)d_ws;
  auto carve = [&](size_t bytes)->void*{ void* r = (void*)p; p += (bytes + 255) & ~(size_t)255; return r; };
  c2*       Xf  = (c2*)carve(2ULL*TLEN*sizeof(c2));
  c2*       A1  = (c2*)carve((size_t)CH*TLEN*sizeof(c2));       // order-1 intermediate (f32)
  unsigned* B   = (unsigned*)carve((size_t)CH*TLEN*4ULL);       // packed bf16 (S2 stream)
  unsigned* U1h = (unsigned*)carve((size_t)CH*TLEN*4ULL);       // packed bf16
  unsigned* A2  = (unsigned*)carve(3ULL*CH*TLEN*4ULL);          // packed bf16, 3 sc-slots
  float*    Ur  = (float*)carve(3ULL*CH*TLEN*sizeof(float));    // 3 sc-slots
  float*    Sb  = (float*)carve(2ULL*SROWS*TD*sizeof(float));
  c2*       Wg  = (c2*)carve(625*sizeof(c2));
  float*    pmn = (float*)carve(512*4);
  float*    pmx = (float*)carve(512*4);
  float*    scal = (float*)carve(256);

  // ---- W625 global LUT ----
  k_wlut<<<3, 256, 0, stream>>>(Wg);

  // ---- forward FFT of x -> Xf (f32 chain; U1h buffer reused as c2 scratch here) ----
  k_fft256<-1,2,0><<<2*NA, 64, 0, stream>>>((const void*)x, (void*)A1);
  k_transpose<<<2*20*8, 256, 0, stream>>>(A1, (c2*)U1h, NA, NB, 20, 8);
  k_fft625<-1,0,0,0,0><<<2*NB, 128, 0, stream>>>((const void*)U1h, (void*)Xf, Wg, 0,0,0,0,0, 314);
  // ---- S0 ----
  k_conv<<<2*10, 256, 0, stream>>>(x, Sb);

  int NCB = 96 / BLK;
  for (int c = 0; c < NCB; c++){
    int cq = (c*BLK)/16;
    int nj2 = 5 - cq;
    int j2base = cq + 1;
    float xi2 = 0.4f * exp2f(-(float)j2base);
    int khi2 = (int)(3.1f * xi2 * 160000.0f) + 1; if (khi2 > TLEN/2 - 1) khi2 = TLEN/2 - 1;
    int kamax = (khi2 >> 8) + 1; if (kamax > 624) kamax = 624;
    // ---- order 1 (f32 path) ----
    k_fft625<1,1,1,0,0><<<CH*NB, 128, 0, stream>>>((const void*)Xf, (void*)A1, Wg, c, BLK, 0,0,0, 624);
    if (nj2 > 0){
      k_fft256g<1,0><<<CH*GNCH, 256, G_LDSB, stream>>>((const void*)A1, Ur, B);   // |ifft|->Ur, fft->B(bf16)
      k_conv2<1><<<CH*10, 256, CONV_LDSB, stream>>>(Ur, Sb, c, BLK, 0,0,0);
      k_fft625<-1,0,0,1,1><<<CH*NB, 128, 0, stream>>>((const void*)B, (void*)U1h, Wg, 0,0,0,0,0, kamax);
      // ---- order 2 (bf16 stream), sc batched in triples ----
      for (int scStart = 0; scStart < nj2; scStart += 3){
        int nsc = nj2 - scStart; if (nsc > 3) nsc = 3;
        k_fft625<1,2,1,1,1><<<nsc*CH*NB, 128, 0, stream>>>((const void*)U1h, (void*)A2, Wg, c, BLK, nj2, j2base, scStart*CH, 624);
        k_fft256g<0,1><<<nsc*CH*GNCH, 256, G_LDSB, stream>>>((const void*)A2, Ur, (unsigned*)nullptr);
        k_conv2<2><<<nsc*CH*10, 256, CONV_LDSB, stream>>>(Ur, Sb, c, BLK, nj2, j2base, scStart*CH);
      }
    } else {
      k_fft256g<0,0><<<CH*GNCH, 256, G_LDSB, stream>>>((const void*)A1, Ur, (unsigned*)nullptr);
      k_conv2<1><<<CH*10, 256, CONV_LDSB, stream>>>(Ur, Sb, c, BLK, 0,0,0);
    }
  }

  // ---- global min-max normalize (standardize cancels) + tile(3,1,1) ----
  k_minmax1<<<512, 256, 0, stream>>>(Sb, 2*SROWS*TD, pmn, pmx);
  k_minmax2<<<1, 256, 0, stream>>>(pmn, pmx, 512, scal);
  k_final<<<(out_size+255)/256, 256, 0, stream>>>(Sb, scal, (float*)d_out, out_size);
}

// Round 15
// 1242.467 us; speedup vs baseline: 1.1220x; 1.0396x over previous
//
#include <hip/hip_runtime.h>
#include <math.h>

#define TLEN 160000
#define NA 625      // n1 (time rows) / ka (freq elements)
#define NB 256      // n2 (time elements) / kb (freq rows)
#define TD 2500
#define KC 128      // conv half width (~5 sigma_t, sigma_t = 25.46)
#define NTAP 257
#define SROWS 337
#define TWO_PI 6.283185307179586f

struct c2 { float x, y; };

__device__ __forceinline__ c2 cmul(c2 a, c2 b){ return c2{a.x*b.x - a.y*b.y, a.x*b.y + a.y*b.x}; }
__device__ __forceinline__ c2 cmulc(c2 a, c2 b){ return c2{a.x*b.x + a.y*b.y, a.y*b.x - a.x*b.y}; } // a*conj(b)
__device__ __forceinline__ c2 cadd(c2 a, c2 b){ return c2{a.x+b.x, a.y+b.y}; }
__device__ __forceinline__ c2 csub(c2 a, c2 b){ return c2{a.x-b.x, a.y-b.y}; }
__device__ __forceinline__ c2 cmac(c2 acc, c2 v, float wr, float wi){
  acc.x += v.x*wr - v.y*wi; acc.y += v.x*wi + v.y*wr; return acc;
}
__device__ __forceinline__ c2 cis(float ang){ c2 r; __sincosf(ang, &r.y, &r.x); return r; }
__device__ __forceinline__ int SW(int i){ return i + (i >> 4); }
__device__ __forceinline__ int SW2(int i){ return i + (i >> 2); }
__device__ __forceinline__ int SW64(int i){ return i + (i >> 6); }
// bf16-pair packing for magnitude-path intermediates (halves their HBM traffic)
__device__ __forceinline__ unsigned pack_bf(c2 z){
  unsigned xr = __float_as_uint(z.x), xi = __float_as_uint(z.y);
  xr += 0x8000u + ((xr >> 16) & 1u);
  xi += 0x8000u + ((xi >> 16) & 1u);
  return (xr >> 16) | (xi & 0xFFFF0000u);   // lo16 = re, hi16 = im
}
__device__ __forceinline__ c2 unpack_bf(unsigned p){
  return c2{ __uint_as_float(p << 16), __uint_as_float(p & 0xFFFF0000u) };
}
__device__ __forceinline__ unsigned short f2bf(float f){
  unsigned u = __float_as_uint(f);
  u += 0x8000u + ((u >> 16) & 1u);
  return (unsigned short)(u >> 16);
}
__device__ __forceinline__ float bf2f(unsigned short h){
  return __uint_as_float(((unsigned)h) << 16);
}
// wave-local "syncthreads" for wave-private LDS: LDS-only wait.
__device__ __forceinline__ void wsync(){
  __builtin_amdgcn_wave_barrier();
  asm volatile("s_waitcnt lgkmcnt(0)" ::: "memory");
  __builtin_amdgcn_sched_barrier(0);
  __builtin_amdgcn_wave_barrier();
}

template<int S>
__device__ __forceinline__ void dft4(c2& a0, c2& a1, c2& a2, c2& a3){
  c2 t0 = cadd(a0,a2), t1 = csub(a0,a2), t2 = cadd(a1,a3), t3 = csub(a1,a3);
  float fs = (float)S;
  a0 = cadd(t0,t2); a2 = csub(t0,t2);
  a1 = c2{t1.x - fs*t3.y, t1.y + fs*t3.x};
  a3 = c2{t1.x + fs*t3.y, t1.y - fs*t3.x};
}

template<int S>
__device__ __forceinline__ void dft5(const c2 a[5], c2 b[5]){
  const float C1 = 0.30901699437494742f, C2 = -0.80901699437494745f;
  const float S1 = 0.95105651629515353f * (float)S, S2 = 0.58778525229247314f * (float)S;
  b[0] = cadd(cadd(a[0],a[1]), cadd(cadd(a[2],a[3]),a[4]));
  c2 r;
  r = a[0]; r = cmac(r,a[1],C1, S1); r = cmac(r,a[2],C2, S2); r = cmac(r,a[3],C2,-S2); r = cmac(r,a[4],C1,-S1); b[1]=r;
  r = a[0]; r = cmac(r,a[1],C2, S2); r = cmac(r,a[2],C1,-S1); r = cmac(r,a[3],C1, S1); r = cmac(r,a[4],C2,-S2); b[2]=r;
  r = a[0]; r = cmac(r,a[1],C2,-S2); r = cmac(r,a[2],C1, S1); r = cmac(r,a[3],C1,-S1); r = cmac(r,a[4],C2, S2); b[3]=r;
  r = a[0]; r = cmac(r,a[1],C1,-S1); r = cmac(r,a[2],C2,-S2); r = cmac(r,a[3],C2, S2); r = cmac(r,a[4],C1, S1); b[4]=r;
}

// ---------------- W625 global LUT init ----------------
__global__ __launch_bounds__(256) void k_wlut(c2* __restrict__ W){
  int m = blockIdx.x*256 + threadIdx.x;
  if (m < 625) W[m] = cis(TWO_PI * (float)m * (1.0f/625.0f));
}

// ---------------- 256-point row FFT (x-chain only; single-wave blocks) ----------------
template<int S, int INMODE, int OUTMODE>
__global__ __launch_bounds__(64) void k_fft256(const void* __restrict__ inp, void* __restrict__ outp){
  __shared__ c2 lds[2][272];
  int g = blockIdx.x;
  int arr = g / NA, n1 = g - arr*NA;
  int j = threadIdx.x;
  c2 v[4];
  if (INMODE == 0){
    const c2* ip = (const c2*)inp + (size_t)arr*TLEN + (size_t)n1*NB;
    #pragma unroll
    for (int q=0;q<4;q++) v[q] = ip[j + 64*q];
  } else if (INMODE == 1){
    const float* ip = (const float*)inp + (size_t)arr*TLEN + (size_t)n1*NB;
    #pragma unroll
    for (int q=0;q<4;q++) v[q] = c2{ip[j + 64*q], 0.0f};
  } else {
    const float* ip = (const float*)inp + (size_t)arr*TLEN;
    #pragma unroll
    for (int q=0;q<4;q++) v[q] = c2{ip[n1 + NA*(j + 64*q)], 0.0f};
  }
  dft4<S>(v[0],v[1],v[2],v[3]);
  #pragma unroll
  for (int r=0;r<4;r++) lds[0][SW(4*j + r)] = v[r];
  wsync();
  { // L = 4
    int k = j & 3;
    c2 w = cis((float)S * TWO_PI * (float)k * (1.0f/16.0f));
    c2 w2 = cmul(w,w), w3 = cmul(w2,w);
    v[0] = lds[0][SW(j)];
    v[1] = cmul(lds[0][SW(j+64)], w);
    v[2] = cmul(lds[0][SW(j+128)], w2);
    v[3] = cmul(lds[0][SW(j+192)], w3);
    dft4<S>(v[0],v[1],v[2],v[3]);
    int base = 4*(j-k)+k;
    #pragma unroll
    for (int r=0;r<4;r++) lds[1][SW(base + 4*r)] = v[r];
  }
  wsync();
  { // L = 16
    int k = j & 15;
    c2 w = cis((float)S * TWO_PI * (float)k * (1.0f/64.0f));
    c2 w2 = cmul(w,w), w3 = cmul(w2,w);
    v[0] = lds[1][SW(j)];
    v[1] = cmul(lds[1][SW(j+64)], w);
    v[2] = cmul(lds[1][SW(j+128)], w2);
    v[3] = cmul(lds[1][SW(j+192)], w3);
    dft4<S>(v[0],v[1],v[2],v[3]);
    int base = 4*(j-k)+k;
    #pragma unroll
    for (int r=0;r<4;r++) lds[0][SW(base + 16*r)] = v[r];
  }
  wsync();
  { // L = 64
    c2 w = cis((float)S * TWO_PI * (float)j * (1.0f/256.0f));
    c2 w2 = cmul(w,w), w3 = cmul(w2,w);
    v[0] = lds[0][SW(j)];
    v[1] = cmul(lds[0][SW(j+64)], w);
    v[2] = cmul(lds[0][SW(j+128)], w2);
    v[3] = cmul(lds[0][SW(j+192)], w3);
    dft4<S>(v[0],v[1],v[2],v[3]);
    if (OUTMODE == 0){
      c2* op = (c2*)outp + (size_t)arr*TLEN + (size_t)n1*NB;
      #pragma unroll
      for (int r=0;r<4;r++){
        int kb = j + 64*r;
        c2 tw = cis((float)S * TWO_PI * (float)(n1*kb) * (1.0f/160000.0f));
        op[kb] = cmul(v[r], tw);
      }
    } else {
      float* op = (float*)outp + (size_t)arr*TLEN + (size_t)n1*NB;
      #pragma unroll
      for (int r=0;r<4;r++){
        c2 z = v[r];
        op[j + 64*r] = sqrtf(z.x*z.x + z.y*z.y) * (1.0f/160000.0f);
      }
    }
  }
}

// ---------------- fused gather + inverse 256-FFT + abs (+ optional forward 256-FFT -> B) --------
// PIN: input is packed bf16. Output Ur is scalar bf16 (ushort). WRITEB output B is packed bf16.
#define GCH     12
#define GNCH    53                        // ceil(625/12)
#define GTF     273                       // tile float-plane stride; 273 % 32 = 17
#define SCR     320                       // per-plane scratch floats
#define G_LDSB  ((2*GCH*GTF + 4*2*SCR)*4) // 36448 B dynamic
template<int WRITEB, int PIN>
__global__ __launch_bounds__(256) void k_fft256g(const void* __restrict__ inpv, unsigned short* __restrict__ outp,
                                                 unsigned* __restrict__ outB){
  extern __shared__ float smemg[];
  float* tr = smemg;                           // [GCH][GTF]
  float* ti = smemg + GCH*GTF;                 // [GCH][GTF]
  int g = blockIdx.x;
  int arr = g / GNCH, chunk = g - arr*GNCH;
  int n1_0 = chunk*GCH;
  int rows = NA - n1_0; if (rows > GCH) rows = GCH;
  const c2* ipc = (const c2*)inpv;
  const unsigned* ipu = (const unsigned*)inpv;
  size_t base = (size_t)arr*TLEN;
  if (rows == GCH){
    for (int e = threadIdx.x; e < 256*GCH; e += 256){
      int kb = e / GCH, i = e - kb*GCH;        // const divisor
      size_t idx = base + (size_t)kb*NA + n1_0 + i;
      c2 z = PIN ? unpack_bf(ipu[idx]) : ipc[idx];
      tr[i*GTF + kb] = z.x; ti[i*GTF + kb] = z.y;
    }
  } else {
    for (int e = threadIdx.x; e < 256*rows; e += 256){
      int kb = e / rows, i = e - kb*rows;
      size_t idx = base + (size_t)kb*NA + n1_0 + i;
      c2 z = PIN ? unpack_bf(ipu[idx]) : ipc[idx];
      tr[i*GTF + kb] = z.x; ti[i*GTF + kb] = z.y;
    }
  }
  __syncthreads();
  int gq = threadIdx.x >> 6, j = threadIdx.x & 63;
  float* sr = smemg + 2*GCH*GTF + gq*(2*SCR);
  float* si = sr + SCR;
  c2 w4  = cis(TWO_PI * (float)(j & 3)  * (1.0f/16.0f));
  c2 w4b = cmul(w4,w4),  w4c = cmul(w4b,w4);
  c2 w16 = cis(TWO_PI * (float)(j & 15) * (1.0f/64.0f));
  c2 w16b= cmul(w16,w16), w16c= cmul(w16b,w16);
  c2 w64 = cis(TWO_PI * (float)j * (1.0f/256.0f));
  c2 w64b= cmul(w64,w64), w64c= cmul(w64b,w64);
  int b4 = 4*(j-(j&3))+(j&3);
  int b16= 4*(j-(j&15))+(j&15);
  unsigned short* op0 = outp + (size_t)arr*TLEN;
  for (int t = 0; t < 3; t++){
    int n1i = gq + 4*t;
    if (n1i >= rows) break;
    int n1 = n1_0 + n1i;
    c2 v[4];
    #pragma unroll
    for (int q=0;q<4;q++) v[q] = c2{tr[n1i*GTF + j + 64*q], ti[n1i*GTF + j + 64*q]};
    dft4<1>(v[0],v[1],v[2],v[3]);
    #pragma unroll
    for (int r=0;r<4;r++){ sr[SW2(4*j + r)] = v[r].x; si[SW2(4*j + r)] = v[r].y; }
    wsync();
    { // L=4
      v[0] = c2{sr[SW2(j)],     si[SW2(j)]};
      v[1] = cmul(c2{sr[SW2(j+64)],  si[SW2(j+64)]},  w4);
      v[2] = cmul(c2{sr[SW2(j+128)], si[SW2(j+128)]}, w4b);
      v[3] = cmul(c2{sr[SW2(j+192)], si[SW2(j+192)]}, w4c);
      dft4<1>(v[0],v[1],v[2],v[3]);
      wsync();
      #pragma unroll
      for (int r=0;r<4;r++){ sr[SW2(b4 + 4*r)] = v[r].x; si[SW2(b4 + 4*r)] = v[r].y; }
    }
    wsync();
    { // L=16
      v[0] = c2{sr[SW2(j)],     si[SW2(j)]};
      v[1] = cmul(c2{sr[SW2(j+64)],  si[SW2(j+64)]},  w16);
      v[2] = cmul(c2{sr[SW2(j+128)], si[SW2(j+128)]}, w16b);
      v[3] = cmul(c2{sr[SW2(j+192)], si[SW2(j+192)]}, w16c);
      dft4<1>(v[0],v[1],v[2],v[3]);
      wsync();
      #pragma unroll
      for (int r=0;r<4;r++){ sr[SW2(b16 + 16*r)] = v[r].x; si[SW2(b16 + 16*r)] = v[r].y; }
    }
    wsync();
    float av[4];
    { // L=64 + abs
      v[0] = c2{sr[SW2(j)],     si[SW2(j)]};
      v[1] = cmul(c2{sr[SW2(j+64)],  si[SW2(j+64)]},  w64);
      v[2] = cmul(c2{sr[SW2(j+128)], si[SW2(j+128)]}, w64b);
      v[3] = cmul(c2{sr[SW2(j+192)], si[SW2(j+192)]}, w64c);
      dft4<1>(v[0],v[1],v[2],v[3]);
      unsigned short* op = op0 + (size_t)n1*NB;
      #pragma unroll
      for (int r=0;r<4;r++){
        c2 z = v[r];
        av[r] = sqrtf(z.x*z.x + z.y*z.y) * (1.0f/160000.0f);
        op[j + 64*r] = f2bf(av[r]);
      }
    }
    if (WRITEB){
      wsync();
      #pragma unroll
      for (int q=0;q<4;q++) v[q] = c2{av[q], 0.0f};
      dft4<-1>(v[0],v[1],v[2],v[3]);
      #pragma unroll
      for (int r=0;r<4;r++){ sr[SW2(4*j + r)] = v[r].x; si[SW2(4*j + r)] = v[r].y; }
      wsync();
      { // L=4
        v[0] = c2{sr[SW2(j)],     si[SW2(j)]};
        v[1] = cmulc(c2{sr[SW2(j+64)],  si[SW2(j+64)]},  w4);
        v[2] = cmulc(c2{sr[SW2(j+128)], si[SW2(j+128)]}, w4b);
        v[3] = cmulc(c2{sr[SW2(j+192)], si[SW2(j+192)]}, w4c);
        dft4<-1>(v[0],v[1],v[2],v[3]);
        wsync();
        #pragma unroll
        for (int r=0;r<4;r++){ sr[SW2(b4 + 4*r)] = v[r].x; si[SW2(b4 + 4*r)] = v[r].y; }
      }
      wsync();
      { // L=16
        v[0] = c2{sr[SW2(j)],     si[SW2(j)]};
        v[1] = cmulc(c2{sr[SW2(j+64)],  si[SW2(j+64)]},  w16);
        v[2] = cmulc(c2{sr[SW2(j+128)], si[SW2(j+128)]}, w16b);
        v[3] = cmulc(c2{sr[SW2(j+192)], si[SW2(j+192)]}, w16c);
        dft4<-1>(v[0],v[1],v[2],v[3]);
        wsync();
        #pragma unroll
        for (int r=0;r<4;r++){ sr[SW2(b16 + 16*r)] = v[r].x; si[SW2(b16 + 16*r)] = v[r].y; }
      }
      wsync();
      { // L=64 + row twiddle -> overwrite dead tile row (transposed store)
        v[0] = c2{sr[SW2(j)],     si[SW2(j)]};
        v[1] = cmulc(c2{sr[SW2(j+64)],  si[SW2(j+64)]},  w64);
        v[2] = cmulc(c2{sr[SW2(j+128)], si[SW2(j+128)]}, w64b);
        v[3] = cmulc(c2{sr[SW2(j+192)], si[SW2(j+192)]}, w64c);
        dft4<-1>(v[0],v[1],v[2],v[3]);
        #pragma unroll
        for (int r=0;r<4;r++){
          int kb = j + 64*r;
          c2 tw = cis(-TWO_PI * (float)(n1*kb) * (1.0f/160000.0f));
          c2 z = cmul(v[r], tw);
          tr[n1i*GTF + kb] = z.x;
          ti[n1i*GTF + kb] = z.y;
        }
      }
    }
    wsync();
  }
  if (WRITEB){
    __syncthreads();
    unsigned* op = outB + (size_t)arr*TLEN;
    if (rows == GCH){
      for (int e = threadIdx.x; e < 256*GCH; e += 256){
        int kb = e / GCH, i = e - kb*GCH;
        op[(size_t)kb*NA + n1_0 + i] = pack_bf(c2{tr[i*GTF + kb], ti[i*GTF + kb]});
      }
    } else {
      for (int e = threadIdx.x; e < 256*rows; e += 256){
        int kb = e / rows, i = e - kb*rows;
        op[(size_t)kb*NA + n1_0 + i] = pack_bf(c2{tr[i*GTF + kb], ti[i*GTF + kb]});
      }
    }
  }
}

// ---------------- 625-point row FFT (radix-5 Stockham), float-plane LDS + global W625 LUT --------
// FILT: 0 none, 1 psi1 (input Xf), 2 psi2 (input U1h). TW: output twiddle (incremental).
// PIN/POUT: packed-bf16 input/output.
template<int S, int FILT, int TW, int PIN, int POUT>
__global__ __launch_bounds__(128) void k_fft625(const void* __restrict__ inpv, void* __restrict__ outpv,
                                                const c2* __restrict__ Wg,
                                                int cblk, int BLK, int nj2, int j2base, int scBase,
                                                int kamax){
  __shared__ float l0r[625], l0i[625], l1r[625], l1i[625];
  int g = blockIdx.x;
  int i = g / NB, kb = g - i*NB;
  int j = threadIdx.x;
  const c2* ipc = (const c2*)inpv;
  const unsigned* ipu = (const unsigned*)inpv;
  size_t ibase;
  int j1 = 0, j2 = 0;
  if (FILT == 0){
    ibase = (size_t)i*TLEN;
  } else if (FILT == 1){
    int bt = i / BLK; j1 = cblk*BLK + (i - bt*BLK);
    ibase = (size_t)bt*TLEN;
  } else {
    int g2 = scBase + i;
    int npb = BLK*nj2;
    int bt = g2 / npb, rr = g2 - bt*npb;
    int jloc = rr / nj2; j2 = j2base + (rr - jloc*nj2);
    ibase = (size_t)(bt*BLK + jloc)*TLEN;
  }
  ibase += (size_t)kb*NA;
  float xi = 0.0f, sig = 0.0f, inv2s = 0.0f;
  int klo = 0, khi = 0;
  if (FILT != 0){
    if (FILT == 1){ xi = 0.4f * exp2f(-(float)j1 * 0.0625f); sig = xi * 0.04427378243f; }
    else          { xi = 0.4f * exp2f(-(float)j2);           sig = 0.35f * xi; }
    inv2s = 0.5f / (sig*sig);
    klo = (int)((xi - 6.0f*sig) * (float)TLEN); if (klo < 0) klo = 0;
    khi = (int)((xi + 6.0f*sig) * (float)TLEN) + 1; if (khi > TLEN/2 - 1) khi = TLEN/2 - 1;
  }
  c2 a[5], b[5];
  if (j < 125){
    if (FILT == 0){
      #pragma unroll
      for (int q=0;q<5;q++){
        size_t idx = ibase + j + 125*q;
        a[q] = PIN ? unpack_bf(ipu[idx]) : ipc[idx];
      }
      dft5<S>(a, b);
    } else {
      bool any = false;
      #pragma unroll
      for (int q=0;q<5;q++){
        int ka = j + 125*q;
        int k = kb + 256*ka;
        c2 val = c2{0.0f, 0.0f};
        if (k >= klo && k <= khi){
          size_t idx = ibase + ka;
          val = PIN ? unpack_bf(ipu[idx]) : ipc[idx];
          float d = (float)k * (1.0f/(float)TLEN) - xi;
          float f = __expf(-d*d*inv2s);
          val.x *= f; val.y *= f;
          any = true;
        }
        a[q] = val;
      }
      if (any){
        dft5<S>(a, b);
      } else {
        #pragma unroll
        for (int r=0;r<5;r++) b[r] = c2{0.0f,0.0f};
      }
    }
    #pragma unroll
    for (int r=0;r<5;r++){ int s = 5*j + r; l0r[s] = b[r].x; l0i[s] = b[r].y; }
  }
  __syncthreads();
  if (j < 125){ // L = 5
    int k = j % 5;
    c2 w  = Wg[25*k];  if (S<0) w.y  = -w.y;
    c2 w2 = Wg[50*k];  if (S<0) w2.y = -w2.y;
    c2 w3 = Wg[75*k];  if (S<0) w3.y = -w3.y;
    c2 w4 = Wg[100*k]; if (S<0) w4.y = -w4.y;
    a[0] = c2{l0r[j],     l0i[j]};
    a[1] = cmul(c2{l0r[j+125], l0i[j+125]}, w);
    a[2] = cmul(c2{l0r[j+250], l0i[j+250]}, w2);
    a[3] = cmul(c2{l0r[j+375], l0i[j+375]}, w3);
    a[4] = cmul(c2{l0r[j+500], l0i[j+500]}, w4);
    dft5<S>(a, b);
    int base = 5*(j-k)+k;
    #pragma unroll
    for (int r=0;r<5;r++){ int s = base + 5*r; l1r[s] = b[r].x; l1i[s] = b[r].y; }
  }
  __syncthreads();
  if (j < 125){ // L = 25
    int k = j % 25;
    c2 w  = Wg[5*k];   if (S<0) w.y  = -w.y;
    c2 w2 = Wg[10*k];  if (S<0) w2.y = -w2.y;
    c2 w3 = Wg[15*k];  if (S<0) w3.y = -w3.y;
    c2 w4 = Wg[20*k];  if (S<0) w4.y = -w4.y;
    a[0] = c2{l1r[j],     l1i[j]};
    a[1] = cmul(c2{l1r[j+125], l1i[j+125]}, w);
    a[2] = cmul(c2{l1r[j+250], l1i[j+250]}, w2);
    a[3] = cmul(c2{l1r[j+375], l1i[j+375]}, w3);
    a[4] = cmul(c2{l1r[j+500], l1i[j+500]}, w4);
    dft5<S>(a, b);
    int base = 5*(j-k)+k;
    #pragma unroll
    for (int r=0;r<5;r++){ int s = base + 25*r; l0r[s] = b[r].x; l0i[s] = b[r].y; }
  }
  __syncthreads();
  if (j < 125){ // L = 125
    c2 w = Wg[j]; if (S<0) w.y = -w.y;
    c2 w2 = cmul(w,w), w3 = cmul(w2,w), w4 = cmul(w2,w2);
    a[0] = c2{l0r[j],     l0i[j]};
    a[1] = cmul(c2{l0r[j+125], l0i[j+125]}, w);
    a[2] = cmul(c2{l0r[j+250], l0i[j+250]}, w2);
    a[3] = cmul(c2{l0r[j+375], l0i[j+375]}, w3);
    a[4] = cmul(c2{l0r[j+500], l0i[j+500]}, w4);
    dft5<S>(a, b);
    size_t obase = (size_t)i*TLEN + (size_t)kb*NA;
    if (TW){
      c2 twb = cis((float)S * TWO_PI * (float)(j*kb)   * (1.0f/160000.0f));
      c2 tws = cis((float)S * TWO_PI * (float)(125*kb) * (1.0f/160000.0f));
      #pragma unroll
      for (int r=0;r<5;r++){
        int n1 = j + 125*r;
        c2 z = cmul(b[r], twb);
        if (POUT) ((unsigned*)outpv)[obase + n1] = pack_bf(z);
        else      ((c2*)outpv)[obase + n1] = z;
        twb = cmul(twb, tws);
      }
    } else {
      #pragma unroll
      for (int r=0;r<5;r++){
        int n1 = j + 125*r;
        if (n1 <= kamax){
          if (POUT) ((unsigned*)outpv)[obase + n1] = pack_bf(b[r]);
          else      ((c2*)outpv)[obase + n1] = b[r];
        }
      }
    }
  }
}

// ---------------- complex transpose (x-chain only) ----------------
__global__ __launch_bounds__(256) void k_transpose(const c2* __restrict__ in, c2* __restrict__ out,
                                                   int R, int C, int tilesR, int tilesC){
  __shared__ c2 tile[32][33];
  int bi = blockIdx.x;
  int arr = bi / (tilesR*tilesC);
  int tt = bi - arr*(tilesR*tilesC);
  int tr = tt / tilesC, tc = tt - tr*tilesC;
  const c2* ip = in + (size_t)arr*TLEN;
  c2* op = out + (size_t)arr*TLEN;
  int tx = threadIdx.x & 31, ty = threadIdx.x >> 5;
  #pragma unroll
  for (int i=0;i<4;i++){
    int r = tr*32 + ty + i*8, cc = tc*32 + tx;
    if (r < R && cc < C) tile[ty+i*8][tx] = ip[(size_t)r*C + cc];
  }
  __syncthreads();
  #pragma unroll
  for (int i=0;i<4;i++){
    int r = tc*32 + ty + i*8, cc = tr*32 + tx;
    if (r < C && cc < R) op[(size_t)r*R + cc] = tile[tx][ty+i*8];
  }
}

// ---------------- Gaussian lowpass + decimate-by-64, natural layout (S0 only) ----------------
__global__ __launch_bounds__(256) void k_conv(const float* __restrict__ inp, float* __restrict__ S){
  __shared__ float w[NTAP];
  for (int i=threadIdx.x; i<NTAP; i+=256){
    float d = (float)(i - KC);
    w[i] = 0.015666427f * __expf(-7.7106284e-4f * d * d);
  }
  __syncthreads();
  int g = blockIdx.x;
  int arr = g / 10;
  int t = (g - arr*10)*256 + threadIdx.x;
  if (t >= TD) return;
  int srow = arr * SROWS;
  const float* ip = inp + (size_t)arr*TLEN;
  float acc = 0.0f;
  int n = 64*t - KC; if (n < 0) n += TLEN;
  for (int m=0;m<NTAP;m++){
    acc += ip[n] * w[m];
    n++; if (n == TLEN) n = 0;
  }
  S[(size_t)srow*TD + t] = acc;
}

// ---------------- fused LDS stage + conv for scrambled-layout U (bf16 input; S1/S2 rows) --------
#define CONV_NCOL 27
#define CONV_NU   16875
#define CONV_USZ  17138
#define CONV_LDSB ((CONV_USZ + NTAP + 1)*4)
template<int MODE>
__global__ __launch_bounds__(256) void k_conv2(const unsigned short* __restrict__ inp, float* __restrict__ S,
                                               int cblk, int BLK, int nj2, int j2base, int scBase){
  extern __shared__ float smem[];
  float* u = smem;
  float* w = smem + CONV_USZ;
  for (int i=threadIdx.x; i<NTAP; i+=256){
    float d = (float)(i - KC);
    w[i] = 0.015666427f * __expf(-7.7106284e-4f * d * d);
  }
  int g = blockIdx.x;
  int arr = g / 10;
  int b = g - arr*10;
  int nlo = 16000*b - KC;
  int n2_0 = (nlo >= 0) ? (nlo/625) : -1;
  const unsigned short* ip = inp + (size_t)arr*TLEN;
  for (int e = threadIdx.x; e < CONV_NU; e += 256){
    int n1 = e / CONV_NCOL;
    int c  = e - n1*CONV_NCOL;
    int n2 = n2_0 + c;
    n2 &= 255;
    u[SW64(n1 + 625*c)] = bf2f(ip[n1*NB + n2]);
  }
  __syncthreads();
  int tl = threadIdx.x;
  if (tl >= 250) return;
  int t = 250*b + tl;
  int srow;
  if (MODE == 1){
    int a2 = arr / BLK; int j1 = cblk*BLK + (arr - a2*BLK);
    srow = a2*SROWS + 1 + j1;
  } else {
    int g2 = scBase + arr; int npb = BLK*nj2;
    int a2 = g2/npb, rr = g2 - a2*npb;
    int jloc = rr/nj2; int j2 = j2base + (rr - jloc*nj2);
    int j1 = cblk*BLK + jloc;
    int full = j1 >> 4;
    int cum = 16*(5*full - (full*(full-1))/2) + (j1 & 15)*(5 - full);
    int P = cum + j2 - full - 1;
    srow = a2*SROWS + 97 + P;
  }
  int base = 64*t - KC - 625*n2_0;
  float acc = 0.0f;
  #pragma unroll 4
  for (int m=0;m<NTAP;m++){
    acc += u[SW64(base + m)] * w[m];
  }
  S[(size_t)srow*TD + t] = acc;
}

// ---------------- global min/max + finalize ----------------
__global__ __launch_bounds__(256) void k_minmax1(const float* __restrict__ S, int n, float* pmn, float* pmx){
  __shared__ float smn[256], smx[256];
  float mn = 3.4028235e38f, mx = -3.4028235e38f;
  for (size_t i = (size_t)blockIdx.x*256 + threadIdx.x; i < (size_t)n; i += (size_t)gridDim.x*256){
    float v = S[i]; mn = fminf(mn,v); mx = fmaxf(mx,v);
  }
  smn[threadIdx.x]=mn; smx[threadIdx.x]=mx; __syncthreads();
  for (int s=128;s>0;s>>=1){
    if ((int)threadIdx.x < s){
      smn[threadIdx.x]=fminf(smn[threadIdx.x],smn[threadIdx.x+s]);
      smx[threadIdx.x]=fmaxf(smx[threadIdx.x],smx[threadIdx.x+s]);
    }
    __syncthreads();
  }
  if (threadIdx.x==0){ pmn[blockIdx.x]=smn[0]; pmx[blockIdx.x]=smx[0]; }
}
__global__ __launch_bounds__(256) void k_minmax2(const float* __restrict__ pmn, const float* __restrict__ pmx,
                                                 int nb, float* scal){
  __shared__ float smn[256], smx[256];
  float mn = 3.4028235e38f, mx = -3.4028235e38f;
  for (int i = threadIdx.x; i < nb; i += 256){ mn = fminf(mn,pmn[i]); mx = fmaxf(mx,pmx[i]); }
  smn[threadIdx.x]=mn; smx[threadIdx.x]=mx; __syncthreads();
  for (int s=128;s>0;s>>=1){
    if ((int)threadIdx.x < s){
      smn[threadIdx.x]=fminf(smn[threadIdx.x],smn[threadIdx.x+s]);
      smx[threadIdx.x]=fmaxf(smx[threadIdx.x],smx[threadIdx.x+s]);
    }
    __syncthreads();
  }
  if (threadIdx.x==0){ scal[0]=smn[0]; scal[1]=smx[0]; }
}
__global__ __launch_bounds__(256) void k_final(const float* __restrict__ S, const float* __restrict__ scal,
                                               float* __restrict__ out, int n){
  int i = blockIdx.x*256 + threadIdx.x;
  if (i >= n) return;
  float mn = scal[0];
  float r = scal[1] - mn;
  if (r == 0.0f) r = 1.0f;
  int half = SROWS*TD;
  int a = i / half; int rest = i - a*half;
  out[i] = (S[(size_t)(a & 1)*half + rest] - mn) / r;
}

extern "C" void kernel_launch(void* const* d_in, const int* in_sizes, int n_in,
                              void* d_out, int out_size, void* d_ws, size_t ws_size,
                              hipStream_t stream){
  (void)in_sizes; (void)n_in;
  const float* x = (const float*)d_in[0];

  int BLK = 16;
  while (BLK > 1){
    size_t CH = 2*(size_t)BLK;
    // Xf(f32) + A1(u32 bf-pairs) + B(u32) + U1h(u32) + A2(3,u32) + Ur(3,u16) + Sb + misc
    size_t needb = 2560000ULL + CH*TLEN*4ULL + CH*TLEN*4ULL + CH*TLEN*4ULL
                 + 3ULL*CH*TLEN*4ULL + 3ULL*CH*TLEN*2ULL + 6740000ULL + 16384ULL + 4096ULL;
    if (needb <= ws_size) break;
    BLK >>= 1;
  }
  {
    size_t CH = 2;
    size_t needmin = 2560000ULL + CH*TLEN*4ULL + CH*TLEN*4ULL + CH*TLEN*4ULL
                   + 3ULL*CH*TLEN*4ULL + 3ULL*CH*TLEN*2ULL + 6740000ULL + 16384ULL + 4096ULL;
    if (ws_size < needmin) return;
  }
  int CH = 2*BLK;

  char* p = (char*)d_ws;
  auto carve = [&](size_t bytes)->void*{ void* r = (void*)p; p += (bytes + 255) & ~(size_t)255; return r; };
  c2*             Xf  = (c2*)carve(2ULL*TLEN*sizeof(c2));
  unsigned*       A1  = (unsigned*)carve((size_t)CH*TLEN*4ULL);   // packed bf16 (order-1 spectrum)
  unsigned*       B   = (unsigned*)carve((size_t)CH*TLEN*4ULL);   // packed bf16 (S2 stream)
  unsigned*       U1h = (unsigned*)carve((size_t)CH*TLEN*4ULL);   // packed bf16
  unsigned*       A2  = (unsigned*)carve(3ULL*CH*TLEN*4ULL);      // packed bf16, 3 sc-slots
  unsigned short* Ur  = (unsigned short*)carve(3ULL*CH*TLEN*2ULL);// scalar bf16, 3 sc-slots
  float*          Sb  = (float*)carve(2ULL*SROWS*TD*sizeof(float));
  c2*             Wg  = (c2*)carve(625*sizeof(c2));
  float*          pmn = (float*)carve(512*4);
  float*          pmx = (float*)carve(512*4);
  float*          scal = (float*)carve(256);

  // ---- W625 global LUT ----
  k_wlut<<<3, 256, 0, stream>>>(Wg);

  // ---- forward FFT of x -> Xf (f32 chain; A2 buffer reused as c2 scratch here) ----
  k_fft256<-1,2,0><<<2*NA, 64, 0, stream>>>((const void*)x, (void*)A2);
  k_transpose<<<2*20*8, 256, 0, stream>>>((c2*)A2, (c2*)U1h, NA, NB, 20, 8);
  k_fft625<-1,0,0,0,0><<<2*NB, 128, 0, stream>>>((const void*)U1h, (void*)Xf, Wg, 0,0,0,0,0, 314);
  // ---- S0 ----
  k_conv<<<2*10, 256, 0, stream>>>(x, Sb);

  int NCB = 96 / BLK;
  for (int c = 0; c < NCB; c++){
    int cq = (c*BLK)/16;
    int nj2 = 5 - cq;
    int j2base = cq + 1;
    float xi2 = 0.4f * exp2f(-(float)j2base);
    int khi2 = (int)(3.1f * xi2 * 160000.0f) + 1; if (khi2 > TLEN/2 - 1) khi2 = TLEN/2 - 1;
    int kamax = (khi2 >> 8) + 1; if (kamax > 624) kamax = 624;
    // ---- order 1 (bf16 A1) ----
    k_fft625<1,1,1,0,1><<<CH*NB, 128, 0, stream>>>((const void*)Xf, (void*)A1, Wg, c, BLK, 0,0,0, 624);
    if (nj2 > 0){
      k_fft256g<1,1><<<CH*GNCH, 256, G_LDSB, stream>>>((const void*)A1, Ur, B);   // |ifft|->Ur(bf16), fft->B(bf16)
      k_conv2<1><<<CH*10, 256, CONV_LDSB, stream>>>(Ur, Sb, c, BLK, 0,0,0);
      k_fft625<-1,0,0,1,1><<<CH*NB, 128, 0, stream>>>((const void*)B, (void*)U1h, Wg, 0,0,0,0,0, kamax);
      // ---- order 2 (bf16 stream), sc batched in triples ----
      for (int scStart = 0; scStart < nj2; scStart += 3){
        int nsc = nj2 - scStart; if (nsc > 3) nsc = 3;
        k_fft625<1,2,1,1,1><<<nsc*CH*NB, 128, 0, stream>>>((const void*)U1h, (void*)A2, Wg, c, BLK, nj2, j2base, scStart*CH, 624);
        k_fft256g<0,1><<<nsc*CH*GNCH, 256, G_LDSB, stream>>>((const void*)A2, Ur, (unsigned*)nullptr);
        k_conv2<2><<<nsc*CH*10, 256, CONV_LDSB, stream>>>(Ur, Sb, c, BLK, nj2, j2base, scStart*CH);
      }
    } else {
      k_fft256g<0,1><<<CH*GNCH, 256, G_LDSB, stream>>>((const void*)A1, Ur, (unsigned*)nullptr);
      k_conv2<1><<<CH*10, 256, CONV_LDSB, stream>>>(Ur, Sb, c, BLK, 0,0,0);
    }
  }

  // ---- global min-max normalize (standardize cancels) + tile(3,1,1) ----
  k_minmax1<<<512, 256, 0, stream>>>(Sb, 2*SROWS*TD, pmn, pmx);
  k_minmax2<<<1, 256, 0, stream>>>(pmn, pmx, 512, scal);
  k_final<<<(out_size+255)/256, 256, 0, stream>>>(Sb, scal, (float*)d_out, out_size);
}

// Round 16
// 1239.678 us; speedup vs baseline: 1.1245x; 1.0023x over previous
//
#include <hip/hip_runtime.h>
#include <math.h>

#define TLEN 160000
#define NA 625      // n1 (time rows) / ka (freq elements)
#define NB 256      // n2 (time elements) / kb (freq rows)
#define TD 2500
#define KC 128      // conv half width (~5 sigma_t, sigma_t = 25.46)
#define NTAP 257
#define SROWS 337
#define TWO_PI 6.283185307179586f

struct c2 { float x, y; };

__device__ __forceinline__ c2 cmul(c2 a, c2 b){ return c2{a.x*b.x - a.y*b.y, a.x*b.y + a.y*b.x}; }
__device__ __forceinline__ c2 cmulc(c2 a, c2 b){ return c2{a.x*b.x + a.y*b.y, a.y*b.x - a.x*b.y}; } // a*conj(b)
__device__ __forceinline__ c2 cadd(c2 a, c2 b){ return c2{a.x+b.x, a.y+b.y}; }
__device__ __forceinline__ c2 csub(c2 a, c2 b){ return c2{a.x-b.x, a.y-b.y}; }
__device__ __forceinline__ c2 cmac(c2 acc, c2 v, float wr, float wi){
  acc.x += v.x*wr - v.y*wi; acc.y += v.x*wi + v.y*wr; return acc;
}
__device__ __forceinline__ c2 cis(float ang){ c2 r; __sincosf(ang, &r.y, &r.x); return r; }
__device__ __forceinline__ int SW(int i){ return i + (i >> 4); }
__device__ __forceinline__ int SW2(int i){ return i + (i >> 2); }
__device__ __forceinline__ int SW64(int i){ return i + (i >> 6); }
// bf16-pair packing for magnitude-path intermediates (halves their HBM traffic)
__device__ __forceinline__ unsigned pack_bf(c2 z){
  unsigned xr = __float_as_uint(z.x), xi = __float_as_uint(z.y);
  xr += 0x8000u + ((xr >> 16) & 1u);
  xi += 0x8000u + ((xi >> 16) & 1u);
  return (xr >> 16) | (xi & 0xFFFF0000u);   // lo16 = re, hi16 = im
}
__device__ __forceinline__ c2 unpack_bf(unsigned p){
  return c2{ __uint_as_float(p << 16), __uint_as_float(p & 0xFFFF0000u) };
}
__device__ __forceinline__ unsigned short f2bf(float f){
  unsigned u = __float_as_uint(f);
  u += 0x8000u + ((u >> 16) & 1u);
  return (unsigned short)(u >> 16);
}
__device__ __forceinline__ float bf2f(unsigned short h){
  return __uint_as_float(((unsigned)h) << 16);
}
// wave-local "syncthreads" for wave-private LDS: LDS-only wait.
// The "memory" clobber is a compiler-level memory fence (orders the ds_read/ds_write
// around it); consumers are memory ops, so NO sched_barrier is needed (rule-18's
// hazard applies to register-only consumers like MFMA). Leaving scheduling free lets
// twiddle/address VALU overlap the LDS latency.
__device__ __forceinline__ void wsync(){
  __builtin_amdgcn_wave_barrier();
  asm volatile("s_waitcnt lgkmcnt(0)" ::: "memory");
  __builtin_amdgcn_wave_barrier();
}

template<int S>
__device__ __forceinline__ void dft4(c2& a0, c2& a1, c2& a2, c2& a3){
  c2 t0 = cadd(a0,a2), t1 = csub(a0,a2), t2 = cadd(a1,a3), t3 = csub(a1,a3);
  float fs = (float)S;
  a0 = cadd(t0,t2); a2 = csub(t0,t2);
  a1 = c2{t1.x - fs*t3.y, t1.y + fs*t3.x};
  a3 = c2{t1.x + fs*t3.y, t1.y - fs*t3.x};
}

template<int S>
__device__ __forceinline__ void dft5(const c2 a[5], c2 b[5]){
  const float C1 = 0.30901699437494742f, C2 = -0.80901699437494745f;
  const float S1 = 0.95105651629515353f * (float)S, S2 = 0.58778525229247314f * (float)S;
  b[0] = cadd(cadd(a[0],a[1]), cadd(cadd(a[2],a[3]),a[4]));
  c2 r;
  r = a[0]; r = cmac(r,a[1],C1, S1); r = cmac(r,a[2],C2, S2); r = cmac(r,a[3],C2,-S2); r = cmac(r,a[4],C1,-S1); b[1]=r;
  r = a[0]; r = cmac(r,a[1],C2, S2); r = cmac(r,a[2],C1,-S1); r = cmac(r,a[3],C1, S1); r = cmac(r,a[4],C2,-S2); b[2]=r;
  r = a[0]; r = cmac(r,a[1],C2,-S2); r = cmac(r,a[2],C1, S1); r = cmac(r,a[3],C1,-S1); r = cmac(r,a[4],C2, S2); b[3]=r;
  r = a[0]; r = cmac(r,a[1],C1,-S1); r = cmac(r,a[2],C2,-S2); r = cmac(r,a[3],C2, S2); r = cmac(r,a[4],C1, S1); b[4]=r;
}

// ---------------- W625 global LUT init ----------------
__global__ __launch_bounds__(256) void k_wlut(c2* __restrict__ W){
  int m = blockIdx.x*256 + threadIdx.x;
  if (m < 625) W[m] = cis(TWO_PI * (float)m * (1.0f/625.0f));
}

// ---------------- 256-point row FFT (x-chain only; single-wave blocks) ----------------
template<int S, int INMODE, int OUTMODE>
__global__ __launch_bounds__(64) void k_fft256(const void* __restrict__ inp, void* __restrict__ outp){
  __shared__ c2 lds[2][272];
  int g = blockIdx.x;
  int arr = g / NA, n1 = g - arr*NA;
  int j = threadIdx.x;
  c2 v[4];
  if (INMODE == 0){
    const c2* ip = (const c2*)inp + (size_t)arr*TLEN + (size_t)n1*NB;
    #pragma unroll
    for (int q=0;q<4;q++) v[q] = ip[j + 64*q];
  } else if (INMODE == 1){
    const float* ip = (const float*)inp + (size_t)arr*TLEN + (size_t)n1*NB;
    #pragma unroll
    for (int q=0;q<4;q++) v[q] = c2{ip[j + 64*q], 0.0f};
  } else {
    const float* ip = (const float*)inp + (size_t)arr*TLEN;
    #pragma unroll
    for (int q=0;q<4;q++) v[q] = c2{ip[n1 + NA*(j + 64*q)], 0.0f};
  }
  dft4<S>(v[0],v[1],v[2],v[3]);
  #pragma unroll
  for (int r=0;r<4;r++) lds[0][SW(4*j + r)] = v[r];
  wsync();
  { // L = 4
    int k = j & 3;
    c2 w = cis((float)S * TWO_PI * (float)k * (1.0f/16.0f));
    c2 w2 = cmul(w,w), w3 = cmul(w2,w);
    v[0] = lds[0][SW(j)];
    v[1] = cmul(lds[0][SW(j+64)], w);
    v[2] = cmul(lds[0][SW(j+128)], w2);
    v[3] = cmul(lds[0][SW(j+192)], w3);
    dft4<S>(v[0],v[1],v[2],v[3]);
    int base = 4*(j-k)+k;
    #pragma unroll
    for (int r=0;r<4;r++) lds[1][SW(base + 4*r)] = v[r];
  }
  wsync();
  { // L = 16
    int k = j & 15;
    c2 w = cis((float)S * TWO_PI * (float)k * (1.0f/64.0f));
    c2 w2 = cmul(w,w), w3 = cmul(w2,w);
    v[0] = lds[1][SW(j)];
    v[1] = cmul(lds[1][SW(j+64)], w);
    v[2] = cmul(lds[1][SW(j+128)], w2);
    v[3] = cmul(lds[1][SW(j+192)], w3);
    dft4<S>(v[0],v[1],v[2],v[3]);
    int base = 4*(j-k)+k;
    #pragma unroll
    for (int r=0;r<4;r++) lds[0][SW(base + 16*r)] = v[r];
  }
  wsync();
  { // L = 64
    c2 w = cis((float)S * TWO_PI * (float)j * (1.0f/256.0f));
    c2 w2 = cmul(w,w), w3 = cmul(w2,w);
    v[0] = lds[0][SW(j)];
    v[1] = cmul(lds[0][SW(j+64)], w);
    v[2] = cmul(lds[0][SW(j+128)], w2);
    v[3] = cmul(lds[0][SW(j+192)], w3);
    dft4<S>(v[0],v[1],v[2],v[3]);
    if (OUTMODE == 0){
      c2* op = (c2*)outp + (size_t)arr*TLEN + (size_t)n1*NB;
      #pragma unroll
      for (int r=0;r<4;r++){
        int kb = j + 64*r;
        c2 tw = cis((float)S * TWO_PI * (float)(n1*kb) * (1.0f/160000.0f));
        op[kb] = cmul(v[r], tw);
      }
    } else {
      float* op = (float*)outp + (size_t)arr*TLEN + (size_t)n1*NB;
      #pragma unroll
      for (int r=0;r<4;r++){
        c2 z = v[r];
        op[j + 64*r] = sqrtf(z.x*z.x + z.y*z.y) * (1.0f/160000.0f);
      }
    }
  }
}

// ---------------- fused gather + inverse 256-FFT + abs (+ optional forward 256-FFT -> B) --------
// PIN: input is packed bf16. Output Ur is scalar bf16 (ushort). WRITEB output B is packed bf16.
#define GCH     12
#define GNCH    53                        // ceil(625/12)
#define GTF     273                       // tile float-plane stride; 273 % 32 = 17
#define SCR     320                       // per-plane scratch floats
#define G_LDSB  ((2*GCH*GTF + 4*2*SCR)*4) // 36448 B dynamic
template<int WRITEB, int PIN>
__global__ __launch_bounds__(256) void k_fft256g(const void* __restrict__ inpv, unsigned short* __restrict__ outp,
                                                 unsigned* __restrict__ outB){
  extern __shared__ float smemg[];
  float* tr = smemg;                           // [GCH][GTF]
  float* ti = smemg + GCH*GTF;                 // [GCH][GTF]
  int g = blockIdx.x;
  int arr = g / GNCH, chunk = g - arr*GNCH;
  int n1_0 = chunk*GCH;
  int rows = NA - n1_0; if (rows > GCH) rows = GCH;
  const c2* ipc = (const c2*)inpv;
  const unsigned* ipu = (const unsigned*)inpv;
  size_t base = (size_t)arr*TLEN;
  if (rows == GCH){
    for (int e = threadIdx.x; e < 256*GCH; e += 256){
      int kb = e / GCH, i = e - kb*GCH;        // const divisor
      size_t idx = base + (size_t)kb*NA + n1_0 + i;
      c2 z = PIN ? unpack_bf(ipu[idx]) : ipc[idx];
      tr[i*GTF + kb] = z.x; ti[i*GTF + kb] = z.y;
    }
  } else {
    for (int e = threadIdx.x; e < 256*rows; e += 256){
      int kb = e / rows, i = e - kb*rows;
      size_t idx = base + (size_t)kb*NA + n1_0 + i;
      c2 z = PIN ? unpack_bf(ipu[idx]) : ipc[idx];
      tr[i*GTF + kb] = z.x; ti[i*GTF + kb] = z.y;
    }
  }
  __syncthreads();
  int gq = threadIdx.x >> 6, j = threadIdx.x & 63;
  float* sr = smemg + 2*GCH*GTF + gq*(2*SCR);
  float* si = sr + SCR;
  c2 w4  = cis(TWO_PI * (float)(j & 3)  * (1.0f/16.0f));
  c2 w4b = cmul(w4,w4),  w4c = cmul(w4b,w4);
  c2 w16 = cis(TWO_PI * (float)(j & 15) * (1.0f/64.0f));
  c2 w16b= cmul(w16,w16), w16c= cmul(w16b,w16);
  c2 w64 = cis(TWO_PI * (float)j * (1.0f/256.0f));
  c2 w64b= cmul(w64,w64), w64c= cmul(w64b,w64);
  int b4 = 4*(j-(j&3))+(j&3);
  int b16= 4*(j-(j&15))+(j&15);
  unsigned short* op0 = outp + (size_t)arr*TLEN;
  for (int t = 0; t < 3; t++){
    int n1i = gq + 4*t;
    if (n1i >= rows) break;
    int n1 = n1_0 + n1i;
    c2 v[4];
    #pragma unroll
    for (int q=0;q<4;q++) v[q] = c2{tr[n1i*GTF + j + 64*q], ti[n1i*GTF + j + 64*q]};
    dft4<1>(v[0],v[1],v[2],v[3]);
    #pragma unroll
    for (int r=0;r<4;r++){ sr[SW2(4*j + r)] = v[r].x; si[SW2(4*j + r)] = v[r].y; }
    wsync();
    { // L=4
      v[0] = c2{sr[SW2(j)],     si[SW2(j)]};
      v[1] = cmul(c2{sr[SW2(j+64)],  si[SW2(j+64)]},  w4);
      v[2] = cmul(c2{sr[SW2(j+128)], si[SW2(j+128)]}, w4b);
      v[3] = cmul(c2{sr[SW2(j+192)], si[SW2(j+192)]}, w4c);
      dft4<1>(v[0],v[1],v[2],v[3]);
      wsync();
      #pragma unroll
      for (int r=0;r<4;r++){ sr[SW2(b4 + 4*r)] = v[r].x; si[SW2(b4 + 4*r)] = v[r].y; }
    }
    wsync();
    { // L=16
      v[0] = c2{sr[SW2(j)],     si[SW2(j)]};
      v[1] = cmul(c2{sr[SW2(j+64)],  si[SW2(j+64)]},  w16);
      v[2] = cmul(c2{sr[SW2(j+128)], si[SW2(j+128)]}, w16b);
      v[3] = cmul(c2{sr[SW2(j+192)], si[SW2(j+192)]}, w16c);
      dft4<1>(v[0],v[1],v[2],v[3]);
      wsync();
      #pragma unroll
      for (int r=0;r<4;r++){ sr[SW2(b16 + 16*r)] = v[r].x; si[SW2(b16 + 16*r)] = v[r].y; }
    }
    wsync();
    float av[4];
    { // L=64 + abs
      v[0] = c2{sr[SW2(j)],     si[SW2(j)]};
      v[1] = cmul(c2{sr[SW2(j+64)],  si[SW2(j+64)]},  w64);
      v[2] = cmul(c2{sr[SW2(j+128)], si[SW2(j+128)]}, w64b);
      v[3] = cmul(c2{sr[SW2(j+192)], si[SW2(j+192)]}, w64c);
      dft4<1>(v[0],v[1],v[2],v[3]);
      unsigned short* op = op0 + (size_t)n1*NB;
      #pragma unroll
      for (int r=0;r<4;r++){
        c2 z = v[r];
        av[r] = sqrtf(z.x*z.x + z.y*z.y) * (1.0f/160000.0f);
        op[j + 64*r] = f2bf(av[r]);
      }
    }
    if (WRITEB){
      wsync();
      #pragma unroll
      for (int q=0;q<4;q++) v[q] = c2{av[q], 0.0f};
      dft4<-1>(v[0],v[1],v[2],v[3]);
      #pragma unroll
      for (int r=0;r<4;r++){ sr[SW2(4*j + r)] = v[r].x; si[SW2(4*j + r)] = v[r].y; }
      wsync();
      { // L=4
        v[0] = c2{sr[SW2(j)],     si[SW2(j)]};
        v[1] = cmulc(c2{sr[SW2(j+64)],  si[SW2(j+64)]},  w4);
        v[2] = cmulc(c2{sr[SW2(j+128)], si[SW2(j+128)]}, w4b);
        v[3] = cmulc(c2{sr[SW2(j+192)], si[SW2(j+192)]}, w4c);
        dft4<-1>(v[0],v[1],v[2],v[3]);
        wsync();
        #pragma unroll
        for (int r=0;r<4;r++){ sr[SW2(b4 + 4*r)] = v[r].x; si[SW2(b4 + 4*r)] = v[r].y; }
      }
      wsync();
      { // L=16
        v[0] = c2{sr[SW2(j)],     si[SW2(j)]};
        v[1] = cmulc(c2{sr[SW2(j+64)],  si[SW2(j+64)]},  w16);
        v[2] = cmulc(c2{sr[SW2(j+128)], si[SW2(j+128)]}, w16b);
        v[3] = cmulc(c2{sr[SW2(j+192)], si[SW2(j+192)]}, w16c);
        dft4<-1>(v[0],v[1],v[2],v[3]);
        wsync();
        #pragma unroll
        for (int r=0;r<4;r++){ sr[SW2(b16 + 16*r)] = v[r].x; si[SW2(b16 + 16*r)] = v[r].y; }
      }
      wsync();
      { // L=64 + row twiddle -> overwrite dead tile row (transposed store)
        v[0] = c2{sr[SW2(j)],     si[SW2(j)]};
        v[1] = cmulc(c2{sr[SW2(j+64)],  si[SW2(j+64)]},  w64);
        v[2] = cmulc(c2{sr[SW2(j+128)], si[SW2(j+128)]}, w64b);
        v[3] = cmulc(c2{sr[SW2(j+192)], si[SW2(j+192)]}, w64c);
        dft4<-1>(v[0],v[1],v[2],v[3]);
        #pragma unroll
        for (int r=0;r<4;r++){
          int kb = j + 64*r;
          c2 tw = cis(-TWO_PI * (float)(n1*kb) * (1.0f/160000.0f));
          c2 z = cmul(v[r], tw);
          tr[n1i*GTF + kb] = z.x;
          ti[n1i*GTF + kb] = z.y;
        }
      }
    }
    wsync();
  }
  if (WRITEB){
    __syncthreads();
    unsigned* op = outB + (size_t)arr*TLEN;
    if (rows == GCH){
      for (int e = threadIdx.x; e < 256*GCH; e += 256){
        int kb = e / GCH, i = e - kb*GCH;
        op[(size_t)kb*NA + n1_0 + i] = pack_bf(c2{tr[i*GTF + kb], ti[i*GTF + kb]});
      }
    } else {
      for (int e = threadIdx.x; e < 256*rows; e += 256){
        int kb = e / rows, i = e - kb*rows;
        op[(size_t)kb*NA + n1_0 + i] = pack_bf(c2{tr[i*GTF + kb], ti[i*GTF + kb]});
      }
    }
  }
}

// ---------------- 625-point row FFT (radix-5 Stockham), float-plane LDS + global W625 LUT --------
// FILT: 0 none, 1 psi1 (input Xf), 2 psi2 (input U1h). TW: output twiddle (incremental).
// PIN/POUT: packed-bf16 input/output.
template<int S, int FILT, int TW, int PIN, int POUT>
__global__ __launch_bounds__(128) void k_fft625(const void* __restrict__ inpv, void* __restrict__ outpv,
                                                const c2* __restrict__ Wg,
                                                int cblk, int BLK, int nj2, int j2base, int scBase,
                                                int kamax){
  __shared__ float l0r[625], l0i[625], l1r[625], l1i[625];
  int g = blockIdx.x;
  int i = g / NB, kb = g - i*NB;
  int j = threadIdx.x;
  const c2* ipc = (const c2*)inpv;
  const unsigned* ipu = (const unsigned*)inpv;
  size_t ibase;
  int j1 = 0, j2 = 0;
  if (FILT == 0){
    ibase = (size_t)i*TLEN;
  } else if (FILT == 1){
    int bt = i / BLK; j1 = cblk*BLK + (i - bt*BLK);
    ibase = (size_t)bt*TLEN;
  } else {
    int g2 = scBase + i;
    int npb = BLK*nj2;
    int bt = g2 / npb, rr = g2 - bt*npb;
    int jloc = rr / nj2; j2 = j2base + (rr - jloc*nj2);
    ibase = (size_t)(bt*BLK + jloc)*TLEN;
  }
  ibase += (size_t)kb*NA;
  float xi = 0.0f, sig = 0.0f, inv2s = 0.0f;
  int klo = 0, khi = 0;
  if (FILT != 0){
    if (FILT == 1){ xi = 0.4f * exp2f(-(float)j1 * 0.0625f); sig = xi * 0.04427378243f; }
    else          { xi = 0.4f * exp2f(-(float)j2);           sig = 0.35f * xi; }
    inv2s = 0.5f / (sig*sig);
    klo = (int)((xi - 6.0f*sig) * (float)TLEN); if (klo < 0) klo = 0;
    khi = (int)((xi + 6.0f*sig) * (float)TLEN) + 1; if (khi > TLEN/2 - 1) khi = TLEN/2 - 1;
  }
  c2 a[5], b[5];
  if (j < 125){
    if (FILT == 0){
      #pragma unroll
      for (int q=0;q<5;q++){
        size_t idx = ibase + j + 125*q;
        a[q] = PIN ? unpack_bf(ipu[idx]) : ipc[idx];
      }
      dft5<S>(a, b);
    } else {
      bool any = false;
      #pragma unroll
      for (int q=0;q<5;q++){
        int ka = j + 125*q;
        int k = kb + 256*ka;
        c2 val = c2{0.0f, 0.0f};
        if (k >= klo && k <= khi){
          size_t idx = ibase + ka;
          val = PIN ? unpack_bf(ipu[idx]) : ipc[idx];
          float d = (float)k * (1.0f/(float)TLEN) - xi;
          float f = __expf(-d*d*inv2s);
          val.x *= f; val.y *= f;
          any = true;
        }
        a[q] = val;
      }
      if (any){
        dft5<S>(a, b);
      } else {
        #pragma unroll
        for (int r=0;r<5;r++) b[r] = c2{0.0f,0.0f};
      }
    }
    #pragma unroll
    for (int r=0;r<5;r++){ int s = 5*j + r; l0r[s] = b[r].x; l0i[s] = b[r].y; }
  }
  __syncthreads();
  if (j < 125){ // L = 5
    int k = j % 5;
    c2 w  = Wg[25*k];  if (S<0) w.y  = -w.y;
    c2 w2 = Wg[50*k];  if (S<0) w2.y = -w2.y;
    c2 w3 = Wg[75*k];  if (S<0) w3.y = -w3.y;
    c2 w4 = Wg[100*k]; if (S<0) w4.y = -w4.y;
    a[0] = c2{l0r[j],     l0i[j]};
    a[1] = cmul(c2{l0r[j+125], l0i[j+125]}, w);
    a[2] = cmul(c2{l0r[j+250], l0i[j+250]}, w2);
    a[3] = cmul(c2{l0r[j+375], l0i[j+375]}, w3);
    a[4] = cmul(c2{l0r[j+500], l0i[j+500]}, w4);
    dft5<S>(a, b);
    int base = 5*(j-k)+k;
    #pragma unroll
    for (int r=0;r<5;r++){ int s = base + 5*r; l1r[s] = b[r].x; l1i[s] = b[r].y; }
  }
  __syncthreads();
  if (j < 125){ // L = 25
    int k = j % 25;
    c2 w  = Wg[5*k];   if (S<0) w.y  = -w.y;
    c2 w2 = Wg[10*k];  if (S<0) w2.y = -w2.y;
    c2 w3 = Wg[15*k];  if (S<0) w3.y = -w3.y;
    c2 w4 = Wg[20*k];  if (S<0) w4.y = -w4.y;
    a[0] = c2{l1r[j],     l1i[j]};
    a[1] = cmul(c2{l1r[j+125], l1i[j+125]}, w);
    a[2] = cmul(c2{l1r[j+250], l1i[j+250]}, w2);
    a[3] = cmul(c2{l1r[j+375], l1i[j+375]}, w3);
    a[4] = cmul(c2{l1r[j+500], l1i[j+500]}, w4);
    dft5<S>(a, b);
    int base = 5*(j-k)+k;
    #pragma unroll
    for (int r=0;r<5;r++){ int s = base + 25*r; l0r[s] = b[r].x; l0i[s] = b[r].y; }
  }
  __syncthreads();
  if (j < 125){ // L = 125
    c2 w = Wg[j]; if (S<0) w.y = -w.y;
    c2 w2 = cmul(w,w), w3 = cmul(w2,w), w4 = cmul(w2,w2);
    a[0] = c2{l0r[j],     l0i[j]};
    a[1] = cmul(c2{l0r[j+125], l0i[j+125]}, w);
    a[2] = cmul(c2{l0r[j+250], l0i[j+250]}, w2);
    a[3] = cmul(c2{l0r[j+375], l0i[j+375]}, w3);
    a[4] = cmul(c2{l0r[j+500], l0i[j+500]}, w4);
    dft5<S>(a, b);
    size_t obase = (size_t)i*TLEN + (size_t)kb*NA;
    if (TW){
      c2 twb = cis((float)S * TWO_PI * (float)(j*kb)   * (1.0f/160000.0f));
      c2 tws = cis((float)S * TWO_PI * (float)(125*kb) * (1.0f/160000.0f));
      #pragma unroll
      for (int r=0;r<5;r++){
        int n1 = j + 125*r;
        c2 z = cmul(b[r], twb);
        if (POUT) ((unsigned*)outpv)[obase + n1] = pack_bf(z);
        else      ((c2*)outpv)[obase + n1] = z;
        twb = cmul(twb, tws);
      }
    } else {
      #pragma unroll
      for (int r=0;r<5;r++){
        int n1 = j + 125*r;
        if (n1 <= kamax){
          if (POUT) ((unsigned*)outpv)[obase + n1] = pack_bf(b[r]);
          else      ((c2*)outpv)[obase + n1] = b[r];
        }
      }
    }
  }
}

// ---------------- complex transpose (x-chain only) ----------------
__global__ __launch_bounds__(256) void k_transpose(const c2* __restrict__ in, c2* __restrict__ out,
                                                   int R, int C, int tilesR, int tilesC){
  __shared__ c2 tile[32][33];
  int bi = blockIdx.x;
  int arr = bi / (tilesR*tilesC);
  int tt = bi - arr*(tilesR*tilesC);
  int tr = tt / tilesC, tc = tt - tr*tilesC;
  const c2* ip = in + (size_t)arr*TLEN;
  c2* op = out + (size_t)arr*TLEN;
  int tx = threadIdx.x & 31, ty = threadIdx.x >> 5;
  #pragma unroll
  for (int i=0;i<4;i++){
    int r = tr*32 + ty + i*8, cc = tc*32 + tx;
    if (r < R && cc < C) tile[ty+i*8][tx] = ip[(size_t)r*C + cc];
  }
  __syncthreads();
  #pragma unroll
  for (int i=0;i<4;i++){
    int r = tc*32 + ty + i*8, cc = tr*32 + tx;
    if (r < C && cc < R) op[(size_t)r*R + cc] = tile[tx][ty+i*8];
  }
}

// ---------------- Gaussian lowpass + decimate-by-64, natural layout (S0 only) ----------------
__global__ __launch_bounds__(256) void k_conv(const float* __restrict__ inp, float* __restrict__ S){
  __shared__ float w[NTAP];
  for (int i=threadIdx.x; i<NTAP; i+=256){
    float d = (float)(i - KC);
    w[i] = 0.015666427f * __expf(-7.7106284e-4f * d * d);
  }
  __syncthreads();
  int g = blockIdx.x;
  int arr = g / 10;
  int t = (g - arr*10)*256 + threadIdx.x;
  if (t >= TD) return;
  int srow = arr * SROWS;
  const float* ip = inp + (size_t)arr*TLEN;
  float acc = 0.0f;
  int n = 64*t - KC; if (n < 0) n += TLEN;
  for (int m=0;m<NTAP;m++){
    acc += ip[n] * w[m];
    n++; if (n == TLEN) n = 0;
  }
  S[(size_t)srow*TD + t] = acc;
}

// ---------------- fused LDS stage + conv for scrambled-layout U (bf16 input; S1/S2 rows) --------
#define CONV_NCOL 27
#define CONV_NU   16875
#define CONV_USZ  17138
#define CONV_LDSB ((CONV_USZ + NTAP + 1)*4)
template<int MODE>
__global__ __launch_bounds__(256) void k_conv2(const unsigned short* __restrict__ inp, float* __restrict__ S,
                                               int cblk, int BLK, int nj2, int j2base, int scBase){
  extern __shared__ float smem[];
  float* u = smem;
  float* w = smem + CONV_USZ;
  for (int i=threadIdx.x; i<NTAP; i+=256){
    float d = (float)(i - KC);
    w[i] = 0.015666427f * __expf(-7.7106284e-4f * d * d);
  }
  int g = blockIdx.x;
  int arr = g / 10;
  int b = g - arr*10;
  int nlo = 16000*b - KC;
  int n2_0 = (nlo >= 0) ? (nlo/625) : -1;
  const unsigned short* ip = inp + (size_t)arr*TLEN;
  for (int e = threadIdx.x; e < CONV_NU; e += 256){
    int n1 = e / CONV_NCOL;
    int c  = e - n1*CONV_NCOL;
    int n2 = n2_0 + c;
    n2 &= 255;
    u[SW64(n1 + 625*c)] = bf2f(ip[n1*NB + n2]);
  }
  __syncthreads();
  int tl = threadIdx.x;
  if (tl >= 250) return;
  int t = 250*b + tl;
  int srow;
  if (MODE == 1){
    int a2 = arr / BLK; int j1 = cblk*BLK + (arr - a2*BLK);
    srow = a2*SROWS + 1 + j1;
  } else {
    int g2 = scBase + arr; int npb = BLK*nj2;
    int a2 = g2/npb, rr = g2 - a2*npb;
    int jloc = rr/nj2; int j2 = j2base + (rr - jloc*nj2);
    int j1 = cblk*BLK + jloc;
    int full = j1 >> 4;
    int cum = 16*(5*full - (full*(full-1))/2) + (j1 & 15)*(5 - full);
    int P = cum + j2 - full - 1;
    srow = a2*SROWS + 97 + P;
  }
  int base = 64*t - KC - 625*n2_0;
  float acc = 0.0f;
  #pragma unroll 4
  for (int m=0;m<NTAP;m++){
    acc += u[SW64(base + m)] * w[m];
  }
  S[(size_t)srow*TD + t] = acc;
}

// ---------------- global min/max + finalize ----------------
__global__ __launch_bounds__(256) void k_minmax1(const float* __restrict__ S, int n, float* pmn, float* pmx){
  __shared__ float smn[256], smx[256];
  float mn = 3.4028235e38f, mx = -3.4028235e38f;
  for (size_t i = (size_t)blockIdx.x*256 + threadIdx.x; i < (size_t)n; i += (size_t)gridDim.x*256){
    float v = S[i]; mn = fminf(mn,v); mx = fmaxf(mx,v);
  }
  smn[threadIdx.x]=mn; smx[threadIdx.x]=mx; __syncthreads();
  for (int s=128;s>0;s>>=1){
    if ((int)threadIdx.x < s){
      smn[threadIdx.x]=fminf(smn[threadIdx.x],smn[threadIdx.x+s]);
      smx[threadIdx.x]=fmaxf(smx[threadIdx.x],smx[threadIdx.x+s]);
    }
    __syncthreads();
  }
  if (threadIdx.x==0){ pmn[blockIdx.x]=smn[0]; pmx[blockIdx.x]=smx[0]; }
}
__global__ __launch_bounds__(256) void k_minmax2(const float* __restrict__ pmn, const float* __restrict__ pmx,
                                                 int nb, float* scal){
  __shared__ float smn[256], smx[256];
  float mn = 3.4028235e38f, mx = -3.4028235e38f;
  for (int i = threadIdx.x; i < nb; i += 256){ mn = fminf(mn,pmn[i]); mx = fmaxf(mx,pmx[i]); }
  smn[threadIdx.x]=mn; smx[threadIdx.x]=mx; __syncthreads();
  for (int s=128;s>0;s>>=1){
    if ((int)threadIdx.x < s){
      smn[threadIdx.x]=fminf(smn[threadIdx.x],smn[threadIdx.x+s]);
      smx[threadIdx.x]=fmaxf(smx[threadIdx.x],smx[threadIdx.x+s]);
    }
    __syncthreads();
  }
  if (threadIdx.x==0){ scal[0]=smn[0]; scal[1]=smx[0]; }
}
__global__ __launch_bounds__(256) void k_final(const float* __restrict__ S, const float* __restrict__ scal,
                                               float* __restrict__ out, int n){
  int i = blockIdx.x*256 + threadIdx.x;
  if (i >= n) return;
  float mn = scal[0];
  float r = scal[1] - mn;
  if (r == 0.0f) r = 1.0f;
  int half = SROWS*TD;
  int a = i / half; int rest = i - a*half;
  out[i] = (S[(size_t)(a & 1)*half + rest] - mn) / r;
}

extern "C" void kernel_launch(void* const* d_in, const int* in_sizes, int n_in,
                              void* d_out, int out_size, void* d_ws, size_t ws_size,
                              hipStream_t stream){
  (void)in_sizes; (void)n_in;
  const float* x = (const float*)d_in[0];

  int BLK = 16;
  while (BLK > 1){
    size_t CH = 2*(size_t)BLK;
    size_t needb = 2560000ULL + CH*TLEN*4ULL + CH*TLEN*4ULL + CH*TLEN*4ULL
                 + 3ULL*CH*TLEN*4ULL + 3ULL*CH*TLEN*2ULL + 6740000ULL + 16384ULL + 4096ULL;
    if (needb <= ws_size) break;
    BLK >>= 1;
  }
  {
    size_t CH = 2;
    size_t needmin = 2560000ULL + CH*TLEN*4ULL + CH*TLEN*4ULL + CH*TLEN*4ULL
                   + 3ULL*CH*TLEN*4ULL + 3ULL*CH*TLEN*2ULL + 6740000ULL + 16384ULL + 4096ULL;
    if (ws_size < needmin) return;
  }
  int CH = 2*BLK;

  char* p = (char*)d_ws;
  auto carve = [&](size_t bytes)->void*{ void* r = (void*)p; p += (bytes + 255) & ~(size_t)255; return r; };
  c2*             Xf  = (c2*)carve(2ULL*TLEN*sizeof(c2));
  unsigned*       A1  = (unsigned*)carve((size_t)CH*TLEN*4ULL);   // packed bf16 (order-1 spectrum)
  unsigned*       B   = (unsigned*)carve((size_t)CH*TLEN*4ULL);   // packed bf16 (S2 stream)
  unsigned*       U1h = (unsigned*)carve((size_t)CH*TLEN*4ULL);   // packed bf16
  unsigned*       A2  = (unsigned*)carve(3ULL*CH*TLEN*4ULL);      // packed bf16, 3 sc-slots
  unsigned short* Ur  = (unsigned short*)carve(3ULL*CH*TLEN*2ULL);// scalar bf16, 3 sc-slots
  float*          Sb  = (float*)carve(2ULL*SROWS*TD*sizeof(float));
  c2*             Wg  = (c2*)carve(625*sizeof(c2));
  float*          pmn = (float*)carve(512*4);
  float*          pmx = (float*)carve(512*4);
  float*          scal = (float*)carve(256);

  // ---- W625 global LUT ----
  k_wlut<<<3, 256, 0, stream>>>(Wg);

  // ---- forward FFT of x -> Xf (f32 chain; A2 buffer reused as c2 scratch here) ----
  k_fft256<-1,2,0><<<2*NA, 64, 0, stream>>>((const void*)x, (void*)A2);
  k_transpose<<<2*20*8, 256, 0, stream>>>((c2*)A2, (c2*)U1h, NA, NB, 20, 8);
  k_fft625<-1,0,0,0,0><<<2*NB, 128, 0, stream>>>((const void*)U1h, (void*)Xf, Wg, 0,0,0,0,0, 314);
  // ---- S0 ----
  k_conv<<<2*10, 256, 0, stream>>>(x, Sb);

  int NCB = 96 / BLK;
  for (int c = 0; c < NCB; c++){
    int cq = (c*BLK)/16;
    int nj2 = 5 - cq;
    int j2base = cq + 1;
    float xi2 = 0.4f * exp2f(-(float)j2base);
    int khi2 = (int)(3.1f * xi2 * 160000.0f) + 1; if (khi2 > TLEN/2 - 1) khi2 = TLEN/2 - 1;
    int kamax = (khi2 >> 8) + 1; if (kamax > 624) kamax = 624;
    // ---- order 1 (bf16 A1) ----
    k_fft625<1,1,1,0,1><<<CH*NB, 128, 0, stream>>>((const void*)Xf, (void*)A1, Wg, c, BLK, 0,0,0, 624);
    if (nj2 > 0){
      k_fft256g<1,1><<<CH*GNCH, 256, G_LDSB, stream>>>((const void*)A1, Ur, B);   // |ifft|->Ur(bf16), fft->B(bf16)
      k_conv2<1><<<CH*10, 256, CONV_LDSB, stream>>>(Ur, Sb, c, BLK, 0,0,0);
      k_fft625<-1,0,0,1,1><<<CH*NB, 128, 0, stream>>>((const void*)B, (void*)U1h, Wg, 0,0,0,0,0, kamax);
      // ---- order 2 (bf16 stream), sc batched in triples ----
      for (int scStart = 0; scStart < nj2; scStart += 3){
        int nsc = nj2 - scStart; if (nsc > 3) nsc = 3;
        k_fft625<1,2,1,1,1><<<nsc*CH*NB, 128, 0, stream>>>((const void*)U1h, (void*)A2, Wg, c, BLK, nj2, j2base, scStart*CH, 624);
        k_fft256g<0,1><<<nsc*CH*GNCH, 256, G_LDSB, stream>>>((const void*)A2, Ur, (unsigned*)nullptr);
        k_conv2<2><<<nsc*CH*10, 256, CONV_LDSB, stream>>>(Ur, Sb, c, BLK, nj2, j2base, scStart*CH);
      }
    } else {
      k_fft256g<0,1><<<CH*GNCH, 256, G_LDSB, stream>>>((const void*)A1, Ur, (unsigned*)nullptr);
      k_conv2<1><<<CH*10, 256, CONV_LDSB, stream>>>(Ur, Sb, c, BLK, 0,0,0);
    }
  }

  // ---- global min-max normalize (standardize cancels) + tile(3,1,1) ----
  k_minmax1<<<512, 256, 0, stream>>>(Sb, 2*SROWS*TD, pmn, pmx);
  k_minmax2<<<1, 256, 0, stream>>>(pmn, pmx, 512, scal);
  k_final<<<(out_size+255)/256, 256, 0, stream>>>(Sb, scal, (float*)d_out, out_size);
}

// Round 17
// 875.288 us; speedup vs baseline: 1.5927x; 1.4163x over previous
//
#include <hip/hip_runtime.h>
#include <math.h>

#define TLEN 160000
#define NA 625      // n1 (time rows) / ka (freq elements)
#define NB 256      // n2 (time elements) / kb (freq rows)
#define TD 2500
#define KC 128      // conv half width (~5 sigma_t, sigma_t = 25.46)
#define NTAP 257
#define SROWS 337
#define TWO_PI 6.283185307179586f

struct c2 { float x, y; };

__device__ __forceinline__ c2 cmul(c2 a, c2 b){ return c2{a.x*b.x - a.y*b.y, a.x*b.y + a.y*b.x}; }
__device__ __forceinline__ c2 cmulc(c2 a, c2 b){ return c2{a.x*b.x + a.y*b.y, a.y*b.x - a.x*b.y}; } // a*conj(b)
__device__ __forceinline__ c2 cadd(c2 a, c2 b){ return c2{a.x+b.x, a.y+b.y}; }
__device__ __forceinline__ c2 csub(c2 a, c2 b){ return c2{a.x-b.x, a.y-b.y}; }
__device__ __forceinline__ c2 cmac(c2 acc, c2 v, float wr, float wi){
  acc.x += v.x*wr - v.y*wi; acc.y += v.x*wi + v.y*wr; return acc;
}
__device__ __forceinline__ c2 cis(float ang){ c2 r; __sincosf(ang, &r.y, &r.x); return r; }
__device__ __forceinline__ int SW(int i){ return i + (i >> 4); }
__device__ __forceinline__ int SW2(int i){ return i + (i >> 2); }
__device__ __forceinline__ int SW16(int i){ return i + (i >> 4); }
__device__ __forceinline__ int SW64(int i){ return i + (i >> 6); }
// bf16-pair packing for magnitude-path intermediates (halves their HBM traffic)
__device__ __forceinline__ unsigned pack_bf(c2 z){
  unsigned xr = __float_as_uint(z.x), xi = __float_as_uint(z.y);
  xr += 0x8000u + ((xr >> 16) & 1u);
  xi += 0x8000u + ((xi >> 16) & 1u);
  return (xr >> 16) | (xi & 0xFFFF0000u);   // lo16 = re, hi16 = im
}
__device__ __forceinline__ c2 unpack_bf(unsigned p){
  return c2{ __uint_as_float(p << 16), __uint_as_float(p & 0xFFFF0000u) };
}
__device__ __forceinline__ unsigned short f2bf(float f){
  unsigned u = __float_as_uint(f);
  u += 0x8000u + ((u >> 16) & 1u);
  return (unsigned short)(u >> 16);
}
__device__ __forceinline__ float bf2f(unsigned short h){
  return __uint_as_float(((unsigned)h) << 16);
}
// wave-local "syncthreads" for wave-private LDS: LDS-only wait.
__device__ __forceinline__ void wsync(){
  __builtin_amdgcn_wave_barrier();
  asm volatile("s_waitcnt lgkmcnt(0)" ::: "memory");
  __builtin_amdgcn_wave_barrier();
}

template<int S>
__device__ __forceinline__ void dft4(c2& a0, c2& a1, c2& a2, c2& a3){
  c2 t0 = cadd(a0,a2), t1 = csub(a0,a2), t2 = cadd(a1,a3), t3 = csub(a1,a3);
  float fs = (float)S;
  a0 = cadd(t0,t2); a2 = csub(t0,t2);
  a1 = c2{t1.x - fs*t3.y, t1.y + fs*t3.x};
  a3 = c2{t1.x + fs*t3.y, t1.y - fs*t3.x};
}

template<int S>
__device__ __forceinline__ void dft5(const c2 a[5], c2 b[5]){
  const float C1 = 0.30901699437494742f, C2 = -0.80901699437494745f;
  const float S1 = 0.95105651629515353f * (float)S, S2 = 0.58778525229247314f * (float)S;
  b[0] = cadd(cadd(a[0],a[1]), cadd(cadd(a[2],a[3]),a[4]));
  c2 r;
  r = a[0]; r = cmac(r,a[1],C1, S1); r = cmac(r,a[2],C2, S2); r = cmac(r,a[3],C2,-S2); r = cmac(r,a[4],C1,-S1); b[1]=r;
  r = a[0]; r = cmac(r,a[1],C2, S2); r = cmac(r,a[2],C1,-S1); r = cmac(r,a[3],C1, S1); r = cmac(r,a[4],C2,-S2); b[2]=r;
  r = a[0]; r = cmac(r,a[1],C2,-S2); r = cmac(r,a[2],C1, S1); r = cmac(r,a[3],C1,-S1); r = cmac(r,a[4],C2, S2); b[3]=r;
  r = a[0]; r = cmac(r,a[1],C1,-S1); r = cmac(r,a[2],C2,-S2); r = cmac(r,a[3],C2, S2); r = cmac(r,a[4],C1, S1); b[4]=r;
}

// ---------------- W625 global LUT init ----------------
__global__ __launch_bounds__(256) void k_wlut(c2* __restrict__ W){
  int m = blockIdx.x*256 + threadIdx.x;
  if (m < 625) W[m] = cis(TWO_PI * (float)m * (1.0f/625.0f));
}

// ---------------- 256-point row FFT (x-chain only; single-wave blocks) ----------------
template<int S, int INMODE, int OUTMODE>
__global__ __launch_bounds__(64) void k_fft256(const void* __restrict__ inp, void* __restrict__ outp){
  __shared__ c2 lds[2][272];
  int g = blockIdx.x;
  int arr = g / NA, n1 = g - arr*NA;
  int j = threadIdx.x;
  c2 v[4];
  if (INMODE == 0){
    const c2* ip = (const c2*)inp + (size_t)arr*TLEN + (size_t)n1*NB;
    #pragma unroll
    for (int q=0;q<4;q++) v[q] = ip[j + 64*q];
  } else if (INMODE == 1){
    const float* ip = (const float*)inp + (size_t)arr*TLEN + (size_t)n1*NB;
    #pragma unroll
    for (int q=0;q<4;q++) v[q] = c2{ip[j + 64*q], 0.0f};
  } else {
    const float* ip = (const float*)inp + (size_t)arr*TLEN;
    #pragma unroll
    for (int q=0;q<4;q++) v[q] = c2{ip[n1 + NA*(j + 64*q)], 0.0f};
  }
  dft4<S>(v[0],v[1],v[2],v[3]);
  #pragma unroll
  for (int r=0;r<4;r++) lds[0][SW(4*j + r)] = v[r];
  wsync();
  { // L = 4
    int k = j & 3;
    c2 w = cis((float)S * TWO_PI * (float)k * (1.0f/16.0f));
    c2 w2 = cmul(w,w), w3 = cmul(w2,w);
    v[0] = lds[0][SW(j)];
    v[1] = cmul(lds[0][SW(j+64)], w);
    v[2] = cmul(lds[0][SW(j+128)], w2);
    v[3] = cmul(lds[0][SW(j+192)], w3);
    dft4<S>(v[0],v[1],v[2],v[3]);
    int base = 4*(j-k)+k;
    #pragma unroll
    for (int r=0;r<4;r++) lds[1][SW(base + 4*r)] = v[r];
  }
  wsync();
  { // L = 16
    int k = j & 15;
    c2 w = cis((float)S * TWO_PI * (float)k * (1.0f/64.0f));
    c2 w2 = cmul(w,w), w3 = cmul(w2,w);
    v[0] = lds[1][SW(j)];
    v[1] = cmul(lds[1][SW(j+64)], w);
    v[2] = cmul(lds[1][SW(j+128)], w2);
    v[3] = cmul(lds[1][SW(j+192)], w3);
    dft4<S>(v[0],v[1],v[2],v[3]);
    int base = 4*(j-k)+k;
    #pragma unroll
    for (int r=0;r<4;r++) lds[0][SW(base + 16*r)] = v[r];
  }
  wsync();
  { // L = 64
    c2 w = cis((float)S * TWO_PI * (float)j * (1.0f/256.0f));
    c2 w2 = cmul(w,w), w3 = cmul(w2,w);
    v[0] = lds[0][SW(j)];
    v[1] = cmul(lds[0][SW(j+64)], w);
    v[2] = cmul(lds[0][SW(j+128)], w2);
    v[3] = cmul(lds[0][SW(j+192)], w3);
    dft4<S>(v[0],v[1],v[2],v[3]);
    if (OUTMODE == 0){
      c2* op = (c2*)outp + (size_t)arr*TLEN + (size_t)n1*NB;
      #pragma unroll
      for (int r=0;r<4;r++){
        int kb = j + 64*r;
        c2 tw = cis((float)S * TWO_PI * (float)(n1*kb) * (1.0f/160000.0f));
        op[kb] = cmul(v[r], tw);
      }
    } else {
      float* op = (float*)outp + (size_t)arr*TLEN + (size_t)n1*NB;
      #pragma unroll
      for (int r=0;r<4;r++){
        c2 z = v[r];
        op[j + 64*r] = sqrtf(z.x*z.x + z.y*z.y) * (1.0f/160000.0f);
      }
    }
  }
}

// ---------------- fused gather + inverse 256-FFT + abs (+ optional forward 256-FFT -> B) --------
// PIN: input is packed bf16. Output Ur is scalar bf16 (ushort). WRITEB output B is packed bf16.
#define GCH     12
#define GNCH    53                        // ceil(625/12)
#define GTF     273                       // tile float-plane stride; 273 % 32 = 17
#define SCR     320                       // per-plane scratch floats
#define G_LDSB  ((2*GCH*GTF + 4*2*SCR)*4) // 36448 B dynamic
template<int WRITEB, int PIN>
__global__ __launch_bounds__(256) void k_fft256g(const void* __restrict__ inpv, unsigned short* __restrict__ outp,
                                                 unsigned* __restrict__ outB){
  extern __shared__ float smemg[];
  float* tr = smemg;                           // [GCH][GTF]
  float* ti = smemg + GCH*GTF;                 // [GCH][GTF]
  int g = blockIdx.x;
  int arr = g / GNCH, chunk = g - arr*GNCH;
  int n1_0 = chunk*GCH;
  int rows = NA - n1_0; if (rows > GCH) rows = GCH;
  const c2* ipc = (const c2*)inpv;
  const unsigned* ipu = (const unsigned*)inpv;
  size_t base = (size_t)arr*TLEN;
  if (rows == GCH){
    for (int e = threadIdx.x; e < 256*GCH; e += 256){
      int kb = e / GCH, i = e - kb*GCH;        // const divisor
      size_t idx = base + (size_t)kb*NA + n1_0 + i;
      c2 z = PIN ? unpack_bf(ipu[idx]) : ipc[idx];
      tr[i*GTF + kb] = z.x; ti[i*GTF + kb] = z.y;
    }
  } else {
    for (int e = threadIdx.x; e < 256*rows; e += 256){
      int kb = e / rows, i = e - kb*rows;
      size_t idx = base + (size_t)kb*NA + n1_0 + i;
      c2 z = PIN ? unpack_bf(ipu[idx]) : ipc[idx];
      tr[i*GTF + kb] = z.x; ti[i*GTF + kb] = z.y;
    }
  }
  __syncthreads();
  int gq = threadIdx.x >> 6, j = threadIdx.x & 63;
  float* sr = smemg + 2*GCH*GTF + gq*(2*SCR);
  float* si = sr + SCR;
  c2 w4  = cis(TWO_PI * (float)(j & 3)  * (1.0f/16.0f));
  c2 w4b = cmul(w4,w4),  w4c = cmul(w4b,w4);
  c2 w16 = cis(TWO_PI * (float)(j & 15) * (1.0f/64.0f));
  c2 w16b= cmul(w16,w16), w16c= cmul(w16b,w16);
  c2 w64 = cis(TWO_PI * (float)j * (1.0f/256.0f));
  c2 w64b= cmul(w64,w64), w64c= cmul(w64b,w64);
  int b4 = 4*(j-(j&3))+(j&3);
  int b16= 4*(j-(j&15))+(j&15);
  unsigned short* op0 = outp + (size_t)arr*TLEN;
  for (int t = 0; t < 3; t++){
    int n1i = gq + 4*t;
    if (n1i >= rows) break;
    int n1 = n1_0 + n1i;
    c2 v[4];
    #pragma unroll
    for (int q=0;q<4;q++) v[q] = c2{tr[n1i*GTF + j + 64*q], ti[n1i*GTF + j + 64*q]};
    dft4<1>(v[0],v[1],v[2],v[3]);
    #pragma unroll
    for (int r=0;r<4;r++){ sr[SW2(4*j + r)] = v[r].x; si[SW2(4*j + r)] = v[r].y; }
    wsync();
    { // L=4
      v[0] = c2{sr[SW2(j)],     si[SW2(j)]};
      v[1] = cmul(c2{sr[SW2(j+64)],  si[SW2(j+64)]},  w4);
      v[2] = cmul(c2{sr[SW2(j+128)], si[SW2(j+128)]}, w4b);
      v[3] = cmul(c2{sr[SW2(j+192)], si[SW2(j+192)]}, w4c);
      dft4<1>(v[0],v[1],v[2],v[3]);
      wsync();
      #pragma unroll
      for (int r=0;r<4;r++){ sr[SW2(b4 + 4*r)] = v[r].x; si[SW2(b4 + 4*r)] = v[r].y; }
    }
    wsync();
    { // L=16
      v[0] = c2{sr[SW2(j)],     si[SW2(j)]};
      v[1] = cmul(c2{sr[SW2(j+64)],  si[SW2(j+64)]},  w16);
      v[2] = cmul(c2{sr[SW2(j+128)], si[SW2(j+128)]}, w16b);
      v[3] = cmul(c2{sr[SW2(j+192)], si[SW2(j+192)]}, w16c);
      dft4<1>(v[0],v[1],v[2],v[3]);
      wsync();
      #pragma unroll
      for (int r=0;r<4;r++){ sr[SW2(b16 + 16*r)] = v[r].x; si[SW2(b16 + 16*r)] = v[r].y; }
    }
    wsync();
    float av[4];
    { // L=64 + abs
      v[0] = c2{sr[SW2(j)],     si[SW2(j)]};
      v[1] = cmul(c2{sr[SW2(j+64)],  si[SW2(j+64)]},  w64);
      v[2] = cmul(c2{sr[SW2(j+128)], si[SW2(j+128)]}, w64b);
      v[3] = cmul(c2{sr[SW2(j+192)], si[SW2(j+192)]}, w64c);
      dft4<1>(v[0],v[1],v[2],v[3]);
      unsigned short* op = op0 + (size_t)n1*NB;
      #pragma unroll
      for (int r=0;r<4;r++){
        c2 z = v[r];
        av[r] = sqrtf(z.x*z.x + z.y*z.y) * (1.0f/160000.0f);
        op[j + 64*r] = f2bf(av[r]);
      }
    }
    if (WRITEB){
      wsync();
      #pragma unroll
      for (int q=0;q<4;q++) v[q] = c2{av[q], 0.0f};
      dft4<-1>(v[0],v[1],v[2],v[3]);
      #pragma unroll
      for (int r=0;r<4;r++){ sr[SW2(4*j + r)] = v[r].x; si[SW2(4*j + r)] = v[r].y; }
      wsync();
      { // L=4
        v[0] = c2{sr[SW2(j)],     si[SW2(j)]};
        v[1] = cmulc(c2{sr[SW2(j+64)],  si[SW2(j+64)]},  w4);
        v[2] = cmulc(c2{sr[SW2(j+128)], si[SW2(j+128)]}, w4b);
        v[3] = cmulc(c2{sr[SW2(j+192)], si[SW2(j+192)]}, w4c);
        dft4<-1>(v[0],v[1],v[2],v[3]);
        wsync();
        #pragma unroll
        for (int r=0;r<4;r++){ sr[SW2(b4 + 4*r)] = v[r].x; si[SW2(b4 + 4*r)] = v[r].y; }
      }
      wsync();
      { // L=16
        v[0] = c2{sr[SW2(j)],     si[SW2(j)]};
        v[1] = cmulc(c2{sr[SW2(j+64)],  si[SW2(j+64)]},  w16);
        v[2] = cmulc(c2{sr[SW2(j+128)], si[SW2(j+128)]}, w16b);
        v[3] = cmulc(c2{sr[SW2(j+192)], si[SW2(j+192)]}, w16c);
        dft4<-1>(v[0],v[1],v[2],v[3]);
        wsync();
        #pragma unroll
        for (int r=0;r<4;r++){ sr[SW2(b16 + 16*r)] = v[r].x; si[SW2(b16 + 16*r)] = v[r].y; }
      }
      wsync();
      { // L=64 + row twiddle -> overwrite dead tile row (transposed store)
        v[0] = c2{sr[SW2(j)],     si[SW2(j)]};
        v[1] = cmulc(c2{sr[SW2(j+64)],  si[SW2(j+64)]},  w64);
        v[2] = cmulc(c2{sr[SW2(j+128)], si[SW2(j+128)]}, w64b);
        v[3] = cmulc(c2{sr[SW2(j+192)], si[SW2(j+192)]}, w64c);
        dft4<-1>(v[0],v[1],v[2],v[3]);
        #pragma unroll
        for (int r=0;r<4;r++){
          int kb = j + 64*r;
          c2 tw = cis(-TWO_PI * (float)(n1*kb) * (1.0f/160000.0f));
          c2 z = cmul(v[r], tw);
          tr[n1i*GTF + kb] = z.x;
          ti[n1i*GTF + kb] = z.y;
        }
      }
    }
    wsync();
  }
  if (WRITEB){
    __syncthreads();
    unsigned* op = outB + (size_t)arr*TLEN;
    if (rows == GCH){
      for (int e = threadIdx.x; e < 256*GCH; e += 256){
        int kb = e / GCH, i = e - kb*GCH;
        op[(size_t)kb*NA + n1_0 + i] = pack_bf(c2{tr[i*GTF + kb], ti[i*GTF + kb]});
      }
    } else {
      for (int e = threadIdx.x; e < 256*rows; e += 256){
        int kb = e / rows, i = e - kb*rows;
        op[(size_t)kb*NA + n1_0 + i] = pack_bf(c2{tr[i*GTF + kb], ti[i*GTF + kb]});
      }
    }
  }
}

// ---------------- fused gather + inverse 64-FFT + abs (decimated order-2, M = 625*64) ----------
// Input A2d[task][kb<64][n1<625] packed bf16; output Ur_dec[task][n1<625][n2<64] scalar bf16.
// 16 lanes per row, 16 rows per 256-thread block, 3 radix-4 stages.
#define G2CH  16
#define G2N   40      // ceil(625/16)
#define G2TF  73      // tile float-plane row stride
#define G2RS  328     // per-row scratch stride (4 planes of 80: SW2(63)=78<80)
__global__ __launch_bounds__(256) void k_fft64g(const unsigned* __restrict__ inp, unsigned short* __restrict__ outp){
  __shared__ float smem[2*G2CH*G2TF + G2CH*G2RS];
  float* tr = smem;
  float* ti = smem + G2CH*G2TF;
  float* scr = smem + 2*G2CH*G2TF;
  int g = blockIdx.x;
  int arr = g / G2N, chunk = g - arr*G2N;
  int n1_0 = chunk*G2CH;
  int rows = 625 - n1_0; if (rows > G2CH) rows = G2CH;
  const unsigned* ip = inp + (size_t)arr*40000;
  if (rows == G2CH){
    for (int e = threadIdx.x; e < 64*G2CH; e += 256){
      int kb = e >> 4, i = e & 15;
      c2 z = unpack_bf(ip[kb*625 + n1_0 + i]);
      tr[i*G2TF + kb] = z.x; ti[i*G2TF + kb] = z.y;
    }
  } else {
    for (int e = threadIdx.x; e < 64*rows; e += 256){
      int kb = e / rows, i = e - kb*rows;
      c2 z = unpack_bf(ip[kb*625 + n1_0 + i]);
      tr[i*G2TF + kb] = z.x; ti[i*G2TF + kb] = z.y;
    }
  }
  __syncthreads();
  int row = threadIdx.x >> 4;
  int j   = threadIdx.x & 15;
  bool act = row < rows;
  float* s = scr + row*G2RS;       // planes: [0]=re0 [80]=im0 [160]=re1 [240]=im1
  if (act){
    c2 v[4];
    #pragma unroll
    for (int q=0;q<4;q++) v[q] = c2{tr[row*G2TF + j + 16*q], ti[row*G2TF + j + 16*q]};
    dft4<1>(v[0],v[1],v[2],v[3]);
    #pragma unroll
    for (int r=0;r<4;r++){ int p = SW2(4*j+r); s[p] = v[r].x; s[80+p] = v[r].y; }
  }
  wsync();
  if (act){ // L = 4
    int k = j & 3;
    c2 w = cis(TWO_PI * (float)k * (1.0f/16.0f));
    c2 w2 = cmul(w,w), w3 = cmul(w2,w);
    c2 v[4];
    v[0] = c2{s[SW2(j)],    s[80+SW2(j)]};
    v[1] = cmul(c2{s[SW2(j+16)], s[80+SW2(j+16)]}, w);
    v[2] = cmul(c2{s[SW2(j+32)], s[80+SW2(j+32)]}, w2);
    v[3] = cmul(c2{s[SW2(j+48)], s[80+SW2(j+48)]}, w3);
    dft4<1>(v[0],v[1],v[2],v[3]);
    int base = 4*(j-k)+k;
    #pragma unroll
    for (int r=0;r<4;r++){ int p = SW2(base+4*r); s[160+p] = v[r].x; s[240+p] = v[r].y; }
  }
  wsync();
  if (act){ // L = 16 + abs
    c2 w = cis(TWO_PI * (float)j * (1.0f/64.0f));
    c2 w2 = cmul(w,w), w3 = cmul(w2,w);
    c2 v[4];
    v[0] = c2{s[160+SW2(j)],    s[240+SW2(j)]};
    v[1] = cmul(c2{s[160+SW2(j+16)], s[240+SW2(j+16)]}, w);
    v[2] = cmul(c2{s[160+SW2(j+32)], s[240+SW2(j+32)]}, w2);
    v[3] = cmul(c2{s[160+SW2(j+48)], s[240+SW2(j+48)]}, w3);
    dft4<1>(v[0],v[1],v[2],v[3]);
    unsigned short* op = outp + (size_t)arr*40000 + (size_t)(n1_0+row)*64;
    #pragma unroll
    for (int r=0;r<4;r++){
      c2 z = v[r];
      op[j + 16*r] = f2bf(sqrtf(z.x*z.x + z.y*z.y) * (1.0f/160000.0f));
    }
  }
}

// ---------------- 625-point row FFT (radix-5 Stockham), float-plane LDS + global W625 LUT --------
// FILT: 0 none, 1 psi1 (input Xf), 2 psi2 (input U1h). TW: output twiddle (incremental).
// PIN/POUT: packed-bf16 input/output. NB2: second-stage length (256 full, 64 decimated).
// For NB2 != 256 (FILT2 only), input U1h is addressed via k = kb + NB2*ka -> (k&255, k>>8).
template<int S, int FILT, int TW, int PIN, int POUT, int NB2>
__global__ __launch_bounds__(128) void k_fft625(const void* __restrict__ inpv, void* __restrict__ outpv,
                                                const c2* __restrict__ Wg,
                                                int cblk, int BLK, int nj2, int j2base, int scBase,
                                                int kamax){
  __shared__ float l0r[625], l0i[625], l1r[625], l1i[625];
  int g = blockIdx.x;
  int i = g / NB2, kb = g - i*NB2;
  int j = threadIdx.x;
  const c2* ipc = (const c2*)inpv;
  const unsigned* ipu = (const unsigned*)inpv;
  size_t ibase;
  int j1 = 0, j2 = 0;
  if (FILT == 0){
    ibase = (size_t)i*TLEN;
  } else if (FILT == 1){
    int bt = i / BLK; j1 = cblk*BLK + (i - bt*BLK);
    ibase = (size_t)bt*TLEN;
  } else {
    int g2 = scBase + i;
    int npb = BLK*nj2;
    int bt = g2 / npb, rr = g2 - bt*npb;
    int jloc = rr / nj2; j2 = j2base + (rr - jloc*nj2);
    ibase = (size_t)(bt*BLK + jloc)*TLEN;
  }
  if (NB2 == 256) ibase += (size_t)kb*NA;
  float xi = 0.0f, sig = 0.0f, inv2s = 0.0f;
  int klo = 0, khi = 0;
  if (FILT != 0){
    if (FILT == 1){ xi = 0.4f * exp2f(-(float)j1 * 0.0625f); sig = xi * 0.04427378243f; }
    else          { xi = 0.4f * exp2f(-(float)j2);           sig = 0.35f * xi; }
    inv2s = 0.5f / (sig*sig);
    klo = (int)((xi - 6.0f*sig) * (float)TLEN); if (klo < 0) klo = 0;
    khi = (int)((xi + 6.0f*sig) * (float)TLEN) + 1; if (khi > TLEN/2 - 1) khi = TLEN/2 - 1;
  }
  c2 a[5], b[5];
  if (j < 125){
    if (FILT == 0){
      #pragma unroll
      for (int q=0;q<5;q++){
        size_t idx = ibase + j + 125*q;
        a[q] = PIN ? unpack_bf(ipu[idx]) : ipc[idx];
      }
      dft5<S>(a, b);
    } else {
      bool any = false;
      #pragma unroll
      for (int q=0;q<5;q++){
        int ka = j + 125*q;
        int k = kb + NB2*ka;
        c2 val = c2{0.0f, 0.0f};
        if (k >= klo && k <= khi){
          size_t idx = (NB2 == 256) ? (ibase + ka)
                                    : (ibase + (size_t)(k & 255)*NA + (k >> 8));
          val = PIN ? unpack_bf(ipu[idx]) : ipc[idx];
          float d = (float)k * (1.0f/(float)TLEN) - xi;
          float f = __expf(-d*d*inv2s);
          val.x *= f; val.y *= f;
          any = true;
        }
        a[q] = val;
      }
      if (any){
        dft5<S>(a, b);
      } else {
        #pragma unroll
        for (int r=0;r<5;r++) b[r] = c2{0.0f,0.0f};
      }
    }
    #pragma unroll
    for (int r=0;r<5;r++){ int s = 5*j + r; l0r[s] = b[r].x; l0i[s] = b[r].y; }
  }
  __syncthreads();
  if (j < 125){ // L = 5
    int k = j % 5;
    c2 w  = Wg[25*k];  if (S<0) w.y  = -w.y;
    c2 w2 = Wg[50*k];  if (S<0) w2.y = -w2.y;
    c2 w3 = Wg[75*k];  if (S<0) w3.y = -w3.y;
    c2 w4 = Wg[100*k]; if (S<0) w4.y = -w4.y;
    a[0] = c2{l0r[j],     l0i[j]};
    a[1] = cmul(c2{l0r[j+125], l0i[j+125]}, w);
    a[2] = cmul(c2{l0r[j+250], l0i[j+250]}, w2);
    a[3] = cmul(c2{l0r[j+375], l0i[j+375]}, w3);
    a[4] = cmul(c2{l0r[j+500], l0i[j+500]}, w4);
    dft5<S>(a, b);
    int base = 5*(j-k)+k;
    #pragma unroll
    for (int r=0;r<5;r++){ int s = base + 5*r; l1r[s] = b[r].x; l1i[s] = b[r].y; }
  }
  __syncthreads();
  if (j < 125){ // L = 25
    int k = j % 25;
    c2 w  = Wg[5*k];   if (S<0) w.y  = -w.y;
    c2 w2 = Wg[10*k];  if (S<0) w2.y = -w2.y;
    c2 w3 = Wg[15*k];  if (S<0) w3.y = -w3.y;
    c2 w4 = Wg[20*k];  if (S<0) w4.y = -w4.y;
    a[0] = c2{l1r[j],     l1i[j]};
    a[1] = cmul(c2{l1r[j+125], l1i[j+125]}, w);
    a[2] = cmul(c2{l1r[j+250], l1i[j+250]}, w2);
    a[3] = cmul(c2{l1r[j+375], l1i[j+375]}, w3);
    a[4] = cmul(c2{l1r[j+500], l1i[j+500]}, w4);
    dft5<S>(a, b);
    int base = 5*(j-k)+k;
    #pragma unroll
    for (int r=0;r<5;r++){ int s = base + 25*r; l0r[s] = b[r].x; l0i[s] = b[r].y; }
  }
  __syncthreads();
  if (j < 125){ // L = 125
    c2 w = Wg[j]; if (S<0) w.y = -w.y;
    c2 w2 = cmul(w,w), w3 = cmul(w2,w), w4 = cmul(w2,w2);
    a[0] = c2{l0r[j],     l0i[j]};
    a[1] = cmul(c2{l0r[j+125], l0i[j+125]}, w);
    a[2] = cmul(c2{l0r[j+250], l0i[j+250]}, w2);
    a[3] = cmul(c2{l0r[j+375], l0i[j+375]}, w3);
    a[4] = cmul(c2{l0r[j+500], l0i[j+500]}, w4);
    dft5<S>(a, b);
    size_t obase = (size_t)i*(625ULL*(size_t)NB2) + (size_t)kb*NA;
    if (TW){
      const float invM = 1.0f/(625.0f*(float)NB2);
      c2 twb = cis((float)S * TWO_PI * (float)(j*kb)   * invM);
      c2 tws = cis((float)S * TWO_PI * (float)(125*kb) * invM);
      #pragma unroll
      for (int r=0;r<5;r++){
        int n1 = j + 125*r;
        c2 z = cmul(b[r], twb);
        if (POUT) ((unsigned*)outpv)[obase + n1] = pack_bf(z);
        else      ((c2*)outpv)[obase + n1] = z;
        twb = cmul(twb, tws);
      }
    } else {
      #pragma unroll
      for (int r=0;r<5;r++){
        int n1 = j + 125*r;
        if (n1 <= kamax){
          if (POUT) ((unsigned*)outpv)[obase + n1] = pack_bf(b[r]);
          else      ((c2*)outpv)[obase + n1] = b[r];
        }
      }
    }
  }
}

// ---------------- complex transpose (x-chain only) ----------------
__global__ __launch_bounds__(256) void k_transpose(const c2* __restrict__ in, c2* __restrict__ out,
                                                   int R, int C, int tilesR, int tilesC){
  __shared__ c2 tile[32][33];
  int bi = blockIdx.x;
  int arr = bi / (tilesR*tilesC);
  int tt = bi - arr*(tilesR*tilesC);
  int tr = tt / tilesC, tc = tt - tr*tilesC;
  const c2* ip = in + (size_t)arr*TLEN;
  c2* op = out + (size_t)arr*TLEN;
  int tx = threadIdx.x & 31, ty = threadIdx.x >> 5;
  #pragma unroll
  for (int i=0;i<4;i++){
    int r = tr*32 + ty + i*8, cc = tc*32 + tx;
    if (r < R && cc < C) tile[ty+i*8][tx] = ip[(size_t)r*C + cc];
  }
  __syncthreads();
  #pragma unroll
  for (int i=0;i<4;i++){
    int r = tc*32 + ty + i*8, cc = tr*32 + tx;
    if (r < C && cc < R) op[(size_t)r*R + cc] = tile[tx][ty+i*8];
  }
}

// ---------------- Gaussian lowpass + decimate-by-64, natural layout (S0 only) ----------------
__global__ __launch_bounds__(256) void k_conv(const float* __restrict__ inp, float* __restrict__ S){
  __shared__ float w[NTAP];
  for (int i=threadIdx.x; i<NTAP; i+=256){
    float d = (float)(i - KC);
    w[i] = 0.015666427f * __expf(-7.7106284e-4f * d * d);
  }
  __syncthreads();
  int g = blockIdx.x;
  int arr = g / 10;
  int t = (g - arr*10)*256 + threadIdx.x;
  if (t >= TD) return;
  int srow = arr * SROWS;
  const float* ip = inp + (size_t)arr*TLEN;
  float acc = 0.0f;
  int n = 64*t - KC; if (n < 0) n += TLEN;
  for (int m=0;m<NTAP;m++){
    acc += ip[n] * w[m];
    n++; if (n == TLEN) n = 0;
  }
  S[(size_t)srow*TD + t] = acc;
}

// ---------------- fused LDS stage + conv for scrambled-layout U (bf16 input; S1/S2 rows) --------
#define CONV_NCOL 27
#define CONV_NU   16875
#define CONV_USZ  17138
#define CONV_LDSB ((CONV_USZ + NTAP + 1)*4)
template<int MODE>
__global__ __launch_bounds__(256) void k_conv2(const unsigned short* __restrict__ inp, float* __restrict__ S,
                                               int cblk, int BLK, int nj2, int j2base, int scBase){
  extern __shared__ float smem[];
  float* u = smem;
  float* w = smem + CONV_USZ;
  for (int i=threadIdx.x; i<NTAP; i+=256){
    float d = (float)(i - KC);
    w[i] = 0.015666427f * __expf(-7.7106284e-4f * d * d);
  }
  int g = blockIdx.x;
  int arr = g / 10;
  int b = g - arr*10;
  int nlo = 16000*b - KC;
  int n2_0 = (nlo >= 0) ? (nlo/625) : -1;
  const unsigned short* ip = inp + (size_t)arr*TLEN;
  for (int e = threadIdx.x; e < CONV_NU; e += 256){
    int n1 = e / CONV_NCOL;
    int c  = e - n1*CONV_NCOL;
    int n2 = n2_0 + c;
    n2 &= 255;
    u[SW64(n1 + 625*c)] = bf2f(ip[n1*NB + n2]);
  }
  __syncthreads();
  int tl = threadIdx.x;
  if (tl >= 250) return;
  int t = 250*b + tl;
  int srow;
  if (MODE == 1){
    int a2 = arr / BLK; int j1 = cblk*BLK + (arr - a2*BLK);
    srow = a2*SROWS + 1 + j1;
  } else {
    int g2 = scBase + arr; int npb = BLK*nj2;
    int a2 = g2/npb, rr = g2 - a2*npb;
    int jloc = rr/nj2; int j2 = j2base + (rr - jloc*nj2);
    int j1 = cblk*BLK + jloc;
    int full = j1 >> 4;
    int cum = 16*(5*full - (full*(full-1))/2) + (j1 & 15)*(5 - full);
    int P = cum + j2 - full - 1;
    srow = a2*SROWS + 97 + P;
  }
  int base = 64*t - KC - 625*n2_0;
  float acc = 0.0f;
  #pragma unroll 4
  for (int m=0;m<NTAP;m++){
    acc += u[SW64(base + m)] * w[m];
  }
  S[(size_t)srow*TD + t] = acc;
}

// ---------------- decimated conv (D=4): input Ur_dec[n1<625][n2<64], M=40000 (S2 rows) ----------
#define C2NU  5000    // 8 cols * 625
#define C2USZ 5312    // SW16(4999)+1
__global__ __launch_bounds__(256) void k_conv2d(const unsigned short* __restrict__ inp, float* __restrict__ S,
                                                int cblk, int BLK, int nj2, int j2base, int scBase){
  __shared__ float u[C2USZ];
  __shared__ float w[72];
  if (threadIdx.x < 65){
    float d = 4.0f * (float)((int)threadIdx.x - 32);
    w[threadIdx.x] = 0.062665708f * __expf(-7.7106284e-4f * d * d);  // 4x weight (rectangle rule)
  }
  int g = blockIdx.x;
  int arr = g / 10;
  int b = g - arr*10;
  int mlo = 4000*b - 32;
  int n2_0 = (mlo >= 0) ? (mlo/625) : -1;
  const unsigned short* ip = inp + (size_t)arr*40000;
  for (int e = threadIdx.x; e < C2NU; e += 256){
    int n1 = e >> 3, c = e & 7;
    int n2 = (n2_0 + c) & 63;
    u[SW16(n1 + 625*c)] = bf2f(ip[n1*64 + n2]);
  }
  __syncthreads();
  int tl = threadIdx.x;
  if (tl >= 250) return;
  int t = 250*b + tl;
  // srow decode (MODE 2)
  int g2 = scBase + arr; int npb = BLK*nj2;
  int a2 = g2/npb, rr = g2 - a2*npb;
  int jloc = rr/nj2; int j2 = j2base + (rr - jloc*nj2);
  int j1 = cblk*BLK + jloc;
  int full = j1 >> 4;
  int cum = 16*(5*full - (full*(full-1))/2) + (j1 & 15)*(5 - full);
  int P = cum + j2 - full - 1;
  int srow = a2*SROWS + 97 + P;
  int base = (4000*b - 32 - 625*n2_0) + 16*tl;
  float acc = 0.0f;
  #pragma unroll 5
  for (int m=0;m<65;m++){
    acc += u[SW16(base + m)] * w[m];
  }
  S[(size_t)srow*TD + t] = acc;
}

// ---------------- global min/max + finalize ----------------
__global__ __launch_bounds__(256) void k_minmax1(const float* __restrict__ S, int n, float* pmn, float* pmx){
  __shared__ float smn[256], smx[256];
  float mn = 3.4028235e38f, mx = -3.4028235e38f;
  for (size_t i = (size_t)blockIdx.x*256 + threadIdx.x; i < (size_t)n; i += (size_t)gridDim.x*256){
    float v = S[i]; mn = fminf(mn,v); mx = fmaxf(mx,v);
  }
  smn[threadIdx.x]=mn; smx[threadIdx.x]=mx; __syncthreads();
  for (int s=128;s>0;s>>=1){
    if ((int)threadIdx.x < s){
      smn[threadIdx.x]=fminf(smn[threadIdx.x],smn[threadIdx.x+s]);
      smx[threadIdx.x]=fmaxf(smx[threadIdx.x],smx[threadIdx.x+s]);
    }
    __syncthreads();
  }
  if (threadIdx.x==0){ pmn[blockIdx.x]=smn[0]; pmx[blockIdx.x]=smx[0]; }
}
__global__ __launch_bounds__(256) void k_minmax2(const float* __restrict__ pmn, const float* __restrict__ pmx,
                                                 int nb, float* scal){
  __shared__ float smn[256], smx[256];
  float mn = 3.4028235e38f, mx = -3.4028235e38f;
  for (int i = threadIdx.x; i < nb; i += 256){ mn = fminf(mn,pmn[i]); mx = fmaxf(mx,pmx[i]); }
  smn[threadIdx.x]=mn; smx[threadIdx.x]=mx; __syncthreads();
  for (int s=128;s>0;s>>=1){
    if ((int)threadIdx.x < s){
      smn[threadIdx.x]=fminf(smn[threadIdx.x],smn[threadIdx.x+s]);
      smx[threadIdx.x]=fmaxf(smx[threadIdx.x],smx[threadIdx.x+s]);
    }
    __syncthreads();
  }
  if (threadIdx.x==0){ scal[0]=smn[0]; scal[1]=smx[0]; }
}
__global__ __launch_bounds__(256) void k_final(const float* __restrict__ S, const float* __restrict__ scal,
                                               float* __restrict__ out, int n){
  int i = blockIdx.x*256 + threadIdx.x;
  if (i >= n) return;
  float mn = scal[0];
  float r = scal[1] - mn;
  if (r == 0.0f) r = 1.0f;
  int half = SROWS*TD;
  int a = i / half; int rest = i - a*half;
  out[i] = (S[(size_t)(a & 1)*half + rest] - mn) / r;
}

extern "C" void kernel_launch(void* const* d_in, const int* in_sizes, int n_in,
                              void* d_out, int out_size, void* d_ws, size_t ws_size,
                              hipStream_t stream){
  (void)in_sizes; (void)n_in;
  const float* x = (const float*)d_in[0];

  int BLK = 16;
  while (BLK > 1){
    size_t CH = 2*(size_t)BLK;
    size_t needb = 2560000ULL + CH*TLEN*4ULL + CH*TLEN*4ULL + CH*TLEN*4ULL
                 + 3ULL*CH*TLEN*4ULL + 3ULL*CH*TLEN*2ULL + 6740000ULL + 16384ULL + 4096ULL;
    if (needb <= ws_size) break;
    BLK >>= 1;
  }
  {
    size_t CH = 2;
    size_t needmin = 2560000ULL + CH*TLEN*4ULL + CH*TLEN*4ULL + CH*TLEN*4ULL
                   + 3ULL*CH*TLEN*4ULL + 3ULL*CH*TLEN*2ULL + 6740000ULL + 16384ULL + 4096ULL;
    if (ws_size < needmin) return;
  }
  int CH = 2*BLK;

  char* p = (char*)d_ws;
  auto carve = [&](size_t bytes)->void*{ void* r = (void*)p; p += (bytes + 255) & ~(size_t)255; return r; };
  c2*             Xf  = (c2*)carve(2ULL*TLEN*sizeof(c2));
  unsigned*       A1  = (unsigned*)carve((size_t)CH*TLEN*4ULL);   // packed bf16 (order-1 spectrum)
  unsigned*       B   = (unsigned*)carve((size_t)CH*TLEN*4ULL);   // packed bf16 (S2 stream)
  unsigned*       U1h = (unsigned*)carve((size_t)CH*TLEN*4ULL);   // packed bf16
  unsigned*       A2  = (unsigned*)carve(3ULL*CH*TLEN*4ULL);      // packed bf16, full + decimated (aliased)
  unsigned short* Ur  = (unsigned short*)carve(3ULL*CH*TLEN*2ULL);// scalar bf16, full + decimated (aliased)
  float*          Sb  = (float*)carve(2ULL*SROWS*TD*sizeof(float));
  c2*             Wg  = (c2*)carve(625*sizeof(c2));
  float*          pmn = (float*)carve(512*4);
  float*          pmx = (float*)carve(512*4);
  float*          scal = (float*)carve(256);

  // ---- W625 global LUT ----
  k_wlut<<<3, 256, 0, stream>>>(Wg);

  // ---- forward FFT of x -> Xf (f32 chain; A2 buffer reused as c2 scratch here) ----
  k_fft256<-1,2,0><<<2*NA, 64, 0, stream>>>((const void*)x, (void*)A2);
  k_transpose<<<2*20*8, 256, 0, stream>>>((c2*)A2, (c2*)U1h, NA, NB, 20, 8);
  k_fft625<-1,0,0,0,0,256><<<2*NB, 128, 0, stream>>>((const void*)U1h, (void*)Xf, Wg, 0,0,0,0,0, 314);
  // ---- S0 ----
  k_conv<<<2*10, 256, 0, stream>>>(x, Sb);

  int NCB = 96 / BLK;
  for (int c = 0; c < NCB; c++){
    int cq = (c*BLK)/16;
    int nj2 = 5 - cq;
    int j2base = cq + 1;
    float xi2 = 0.4f * exp2f(-(float)j2base);
    int khi2 = (int)(3.1f * xi2 * 160000.0f) + 1; if (khi2 > TLEN/2 - 1) khi2 = TLEN/2 - 1;
    int kamax = (khi2 >> 8) + 1; if (kamax > 624) kamax = 624;
    // ---- order 1 (bf16 A1) ----
    k_fft625<1,1,1,0,1,256><<<CH*NB, 128, 0, stream>>>((const void*)Xf, (void*)A1, Wg, c, BLK, 0,0,0, 624);
    if (nj2 > 0){
      k_fft256g<1,1><<<CH*GNCH, 256, G_LDSB, stream>>>((const void*)A1, Ur, B);   // |ifft|->Ur(bf16), fft->B(bf16)
      k_conv2<1><<<CH*10, 256, CONV_LDSB, stream>>>(Ur, Sb, c, BLK, 0,0,0);
      k_fft625<-1,0,0,1,1,256><<<CH*NB, 128, 0, stream>>>((const void*)B, (void*)U1h, Wg, 0,0,0,0,0, kamax);
      // ---- order 2 split: full-rate j2 <= 2, decimated (D=4) j2 >= 3 ----
      int nf = 3 - j2base; if (nf < 0) nf = 0; if (nf > nj2) nf = nj2;
      int j2d = (j2base > 3) ? j2base : 3;
      int nd = 6 - j2d; if (nd < 0) nd = 0;
      if (nf > 0){
        k_fft625<1,2,1,1,1,256><<<nf*CH*NB, 128, 0, stream>>>((const void*)U1h, (void*)A2, Wg, c, BLK, nf, j2base, 0, 624);
        k_fft256g<0,1><<<nf*CH*GNCH, 256, G_LDSB, stream>>>((const void*)A2, Ur, (unsigned*)nullptr);
        k_conv2<2><<<nf*CH*10, 256, CONV_LDSB, stream>>>(Ur, Sb, c, BLK, nf, j2base, 0);
      }
      if (nd > 0){
        k_fft625<1,2,1,1,1,64><<<nd*CH*64, 128, 0, stream>>>((const void*)U1h, (void*)A2, Wg, c, BLK, nd, j2d, 0, 624);
        k_fft64g<<<nd*CH*G2N, 256, 0, stream>>>(A2, Ur);
        k_conv2d<<<nd*CH*10, 256, 0, stream>>>(Ur, Sb, c, BLK, nd, j2d, 0);
      }
    } else {
      k_fft256g<0,1><<<CH*GNCH, 256, G_LDSB, stream>>>((const void*)A1, Ur, (unsigned*)nullptr);
      k_conv2<1><<<CH*10, 256, CONV_LDSB, stream>>>(Ur, Sb, c, BLK, 0,0,0);
    }
  }

  // ---- global min-max normalize (standardize cancels) + tile(3,1,1) ----
  k_minmax1<<<512, 256, 0, stream>>>(Sb, 2*SROWS*TD, pmn, pmx);
  k_minmax2<<<1, 256, 0, stream>>>(pmn, pmx, 512, scal);
  k_final<<<(out_size+255)/256, 256, 0, stream>>>(Sb, scal, (float*)d_out, out_size);
}

// Round 18
// 587.169 us; speedup vs baseline: 2.3742x; 1.4907x over previous
//
#include <hip/hip_runtime.h>
#include <math.h>

#define TLEN 160000
#define NA 625
#define NB 256
#define TD 2500
#define KC 128
#define NTAP 257
#define SROWS 337
#define TWO_PI 6.283185307179586f

struct c2 { float x, y; };

__device__ __forceinline__ c2 cmul(c2 a, c2 b){ return c2{a.x*b.x - a.y*b.y, a.x*b.y + a.y*b.x}; }
__device__ __forceinline__ c2 cmulc(c2 a, c2 b){ return c2{a.x*b.x + a.y*b.y, a.y*b.x - a.x*b.y}; }
__device__ __forceinline__ c2 cadd(c2 a, c2 b){ return c2{a.x+b.x, a.y+b.y}; }
__device__ __forceinline__ c2 csub(c2 a, c2 b){ return c2{a.x-b.x, a.y-b.y}; }
__device__ __forceinline__ c2 cmac(c2 acc, c2 v, float wr, float wi){
  acc.x += v.x*wr - v.y*wi; acc.y += v.x*wi + v.y*wr; return acc;
}
__device__ __forceinline__ c2 cis(float ang){ c2 r; __sincosf(ang, &r.y, &r.x); return r; }
__device__ __forceinline__ int SW(int i){ return i + (i >> 4); }
__device__ __forceinline__ int SW2(int i){ return i + (i >> 2); }
__device__ __forceinline__ int SW16(int i){ return i + (i >> 4); }
__device__ __forceinline__ int SW64(int i){ return i + (i >> 6); }
__device__ __forceinline__ unsigned pack_bf(c2 z){
  unsigned xr = __float_as_uint(z.x), xi = __float_as_uint(z.y);
  xr += 0x8000u + ((xr >> 16) & 1u);
  xi += 0x8000u + ((xi >> 16) & 1u);
  return (xr >> 16) | (xi & 0xFFFF0000u);
}
__device__ __forceinline__ c2 unpack_bf(unsigned p){
  return c2{ __uint_as_float(p << 16), __uint_as_float(p & 0xFFFF0000u) };
}
__device__ __forceinline__ unsigned short f2bf(float f){
  unsigned u = __float_as_uint(f);
  u += 0x8000u + ((u >> 16) & 1u);
  return (unsigned short)(u >> 16);
}
__device__ __forceinline__ float bf2f(unsigned short h){
  return __uint_as_float(((unsigned)h) << 16);
}
__device__ __forceinline__ void wsync(){
  __builtin_amdgcn_wave_barrier();
  asm volatile("s_waitcnt lgkmcnt(0)" ::: "memory");
  __builtin_amdgcn_wave_barrier();
}

template<int S>
__device__ __forceinline__ void dft4(c2& a0, c2& a1, c2& a2, c2& a3){
  c2 t0 = cadd(a0,a2), t1 = csub(a0,a2), t2 = cadd(a1,a3), t3 = csub(a1,a3);
  float fs = (float)S;
  a0 = cadd(t0,t2); a2 = csub(t0,t2);
  a1 = c2{t1.x - fs*t3.y, t1.y + fs*t3.x};
  a3 = c2{t1.x + fs*t3.y, t1.y - fs*t3.x};
}

template<int S>
__device__ __forceinline__ void dft5(const c2 a[5], c2 b[5]){
  const float C1 = 0.30901699437494742f, C2 = -0.80901699437494745f;
  const float S1 = 0.95105651629515353f * (float)S, S2 = 0.58778525229247314f * (float)S;
  b[0] = cadd(cadd(a[0],a[1]), cadd(cadd(a[2],a[3]),a[4]));
  c2 r;
  r = a[0]; r = cmac(r,a[1],C1, S1); r = cmac(r,a[2],C2, S2); r = cmac(r,a[3],C2,-S2); r = cmac(r,a[4],C1,-S1); b[1]=r;
  r = a[0]; r = cmac(r,a[1],C2, S2); r = cmac(r,a[2],C1,-S1); r = cmac(r,a[3],C1, S1); r = cmac(r,a[4],C2,-S2); b[2]=r;
  r = a[0]; r = cmac(r,a[1],C2,-S2); r = cmac(r,a[2],C1, S1); r = cmac(r,a[3],C1,-S1); r = cmac(r,a[4],C2, S2); b[3]=r;
  r = a[0]; r = cmac(r,a[1],C1,-S1); r = cmac(r,a[2],C2,-S2); r = cmac(r,a[3],C2, S2); r = cmac(r,a[4],C1, S1); b[4]=r;
}

// ---------------- W625 global LUT init ----------------
__global__ __launch_bounds__(256) void k_wlut(c2* __restrict__ W){
  int m = blockIdx.x*256 + threadIdx.x;
  if (m < 625) W[m] = cis(TWO_PI * (float)m * (1.0f/625.0f));
}

// ---------------- 256-point row FFT (x-chain only) ----------------
template<int S, int INMODE, int OUTMODE>
__global__ __launch_bounds__(64) void k_fft256(const void* __restrict__ inp, void* __restrict__ outp){
  __shared__ c2 lds[2][272];
  int g = blockIdx.x;
  int arr = g / NA, n1 = g - arr*NA;
  int j = threadIdx.x;
  c2 v[4];
  if (INMODE == 0){
    const c2* ip = (const c2*)inp + (size_t)arr*TLEN + (size_t)n1*NB;
    #pragma unroll
    for (int q=0;q<4;q++) v[q] = ip[j + 64*q];
  } else if (INMODE == 1){
    const float* ip = (const float*)inp + (size_t)arr*TLEN + (size_t)n1*NB;
    #pragma unroll
    for (int q=0;q<4;q++) v[q] = c2{ip[j + 64*q], 0.0f};
  } else {
    const float* ip = (const float*)inp + (size_t)arr*TLEN;
    #pragma unroll
    for (int q=0;q<4;q++) v[q] = c2{ip[n1 + NA*(j + 64*q)], 0.0f};
  }
  dft4<S>(v[0],v[1],v[2],v[3]);
  #pragma unroll
  for (int r=0;r<4;r++) lds[0][SW(4*j + r)] = v[r];
  wsync();
  { // L = 4
    int k = j & 3;
    c2 w = cis((float)S * TWO_PI * (float)k * (1.0f/16.0f));
    c2 w2 = cmul(w,w), w3 = cmul(w2,w);
    v[0] = lds[0][SW(j)];
    v[1] = cmul(lds[0][SW(j+64)], w);
    v[2] = cmul(lds[0][SW(j+128)], w2);
    v[3] = cmul(lds[0][SW(j+192)], w3);
    dft4<S>(v[0],v[1],v[2],v[3]);
    int base = 4*(j-k)+k;
    #pragma unroll
    for (int r=0;r<4;r++) lds[1][SW(base + 4*r)] = v[r];
  }
  wsync();
  { // L = 16
    int k = j & 15;
    c2 w = cis((float)S * TWO_PI * (float)k * (1.0f/64.0f));
    c2 w2 = cmul(w,w), w3 = cmul(w2,w);
    v[0] = lds[1][SW(j)];
    v[1] = cmul(lds[1][SW(j+64)], w);
    v[2] = cmul(lds[1][SW(j+128)], w2);
    v[3] = cmul(lds[1][SW(j+192)], w3);
    dft4<S>(v[0],v[1],v[2],v[3]);
    int base = 4*(j-k)+k;
    #pragma unroll
    for (int r=0;r<4;r++) lds[0][SW(base + 16*r)] = v[r];
  }
  wsync();
  { // L = 64
    c2 w = cis((float)S * TWO_PI * (float)j * (1.0f/256.0f));
    c2 w2 = cmul(w,w), w3 = cmul(w2,w);
    v[0] = lds[0][SW(j)];
    v[1] = cmul(lds[0][SW(j+64)], w);
    v[2] = cmul(lds[0][SW(j+128)], w2);
    v[3] = cmul(lds[0][SW(j+192)], w3);
    dft4<S>(v[0],v[1],v[2],v[3]);
    if (OUTMODE == 0){
      c2* op = (c2*)outp + (size_t)arr*TLEN + (size_t)n1*NB;
      #pragma unroll
      for (int r=0;r<4;r++){
        int kb = j + 64*r;
        c2 tw = cis((float)S * TWO_PI * (float)(n1*kb) * (1.0f/160000.0f));
        op[kb] = cmul(v[r], tw);
      }
    } else {
      float* op = (float*)outp + (size_t)arr*TLEN + (size_t)n1*NB;
      #pragma unroll
      for (int r=0;r<4;r++){
        c2 z = v[r];
        op[j + 64*r] = sqrtf(z.x*z.x + z.y*z.y) * (1.0f/160000.0f);
      }
    }
  }
}

// ---------------- fused gather + inverse 256-FFT + abs (+ optional forward -> B) ---------------
#define GCH     12
#define GNCH    53
#define GTF     273
#define SCR     320
#define G_LDSB  ((2*GCH*GTF + 4*2*SCR)*4)
template<int WRITEB, int PIN>
__global__ __launch_bounds__(256) void k_fft256g(const void* __restrict__ inpv, unsigned short* __restrict__ outp,
                                                 unsigned* __restrict__ outB){
  extern __shared__ float smemg[];
  float* tr = smemg;
  float* ti = smemg + GCH*GTF;
  int g = blockIdx.x;
  int arr = g / GNCH, chunk = g - arr*GNCH;
  int n1_0 = chunk*GCH;
  int rows = NA - n1_0; if (rows > GCH) rows = GCH;
  const c2* ipc = (const c2*)inpv;
  const unsigned* ipu = (const unsigned*)inpv;
  size_t base = (size_t)arr*TLEN;
  if (rows == GCH){
    for (int e = threadIdx.x; e < 256*GCH; e += 256){
      int kb = e / GCH, i = e - kb*GCH;
      size_t idx = base + (size_t)kb*NA + n1_0 + i;
      c2 z = PIN ? unpack_bf(ipu[idx]) : ipc[idx];
      tr[i*GTF + kb] = z.x; ti[i*GTF + kb] = z.y;
    }
  } else {
    for (int e = threadIdx.x; e < 256*rows; e += 256){
      int kb = e / rows, i = e - kb*rows;
      size_t idx = base + (size_t)kb*NA + n1_0 + i;
      c2 z = PIN ? unpack_bf(ipu[idx]) : ipc[idx];
      tr[i*GTF + kb] = z.x; ti[i*GTF + kb] = z.y;
    }
  }
  __syncthreads();
  int gq = threadIdx.x >> 6, j = threadIdx.x & 63;
  float* sr = smemg + 2*GCH*GTF + gq*(2*SCR);
  float* si = sr + SCR;
  c2 w4  = cis(TWO_PI * (float)(j & 3)  * (1.0f/16.0f));
  c2 w4b = cmul(w4,w4),  w4c = cmul(w4b,w4);
  c2 w16 = cis(TWO_PI * (float)(j & 15) * (1.0f/64.0f));
  c2 w16b= cmul(w16,w16), w16c= cmul(w16b,w16);
  c2 w64 = cis(TWO_PI * (float)j * (1.0f/256.0f));
  c2 w64b= cmul(w64,w64), w64c= cmul(w64b,w64);
  int b4 = 4*(j-(j&3))+(j&3);
  int b16= 4*(j-(j&15))+(j&15);
  unsigned short* op0 = outp + (size_t)arr*TLEN;
  for (int t = 0; t < 3; t++){
    int n1i = gq + 4*t;
    if (n1i >= rows) break;
    int n1 = n1_0 + n1i;
    c2 v[4];
    #pragma unroll
    for (int q=0;q<4;q++) v[q] = c2{tr[n1i*GTF + j + 64*q], ti[n1i*GTF + j + 64*q]};
    dft4<1>(v[0],v[1],v[2],v[3]);
    #pragma unroll
    for (int r=0;r<4;r++){ sr[SW2(4*j + r)] = v[r].x; si[SW2(4*j + r)] = v[r].y; }
    wsync();
    {
      v[0] = c2{sr[SW2(j)],     si[SW2(j)]};
      v[1] = cmul(c2{sr[SW2(j+64)],  si[SW2(j+64)]},  w4);
      v[2] = cmul(c2{sr[SW2(j+128)], si[SW2(j+128)]}, w4b);
      v[3] = cmul(c2{sr[SW2(j+192)], si[SW2(j+192)]}, w4c);
      dft4<1>(v[0],v[1],v[2],v[3]);
      wsync();
      #pragma unroll
      for (int r=0;r<4;r++){ sr[SW2(b4 + 4*r)] = v[r].x; si[SW2(b4 + 4*r)] = v[r].y; }
    }
    wsync();
    {
      v[0] = c2{sr[SW2(j)],     si[SW2(j)]};
      v[1] = cmul(c2{sr[SW2(j+64)],  si[SW2(j+64)]},  w16);
      v[2] = cmul(c2{sr[SW2(j+128)], si[SW2(j+128)]}, w16b);
      v[3] = cmul(c2{sr[SW2(j+192)], si[SW2(j+192)]}, w16c);
      dft4<1>(v[0],v[1],v[2],v[3]);
      wsync();
      #pragma unroll
      for (int r=0;r<4;r++){ sr[SW2(b16 + 16*r)] = v[r].x; si[SW2(b16 + 16*r)] = v[r].y; }
    }
    wsync();
    float av[4];
    {
      v[0] = c2{sr[SW2(j)],     si[SW2(j)]};
      v[1] = cmul(c2{sr[SW2(j+64)],  si[SW2(j+64)]},  w64);
      v[2] = cmul(c2{sr[SW2(j+128)], si[SW2(j+128)]}, w64b);
      v[3] = cmul(c2{sr[SW2(j+192)], si[SW2(j+192)]}, w64c);
      dft4<1>(v[0],v[1],v[2],v[3]);
      unsigned short* op = op0 + (size_t)n1*NB;
      #pragma unroll
      for (int r=0;r<4;r++){
        c2 z = v[r];
        av[r] = sqrtf(z.x*z.x + z.y*z.y) * (1.0f/160000.0f);
        op[j + 64*r] = f2bf(av[r]);
      }
    }
    if (WRITEB){
      wsync();
      #pragma unroll
      for (int q=0;q<4;q++) v[q] = c2{av[q], 0.0f};
      dft4<-1>(v[0],v[1],v[2],v[3]);
      #pragma unroll
      for (int r=0;r<4;r++){ sr[SW2(4*j + r)] = v[r].x; si[SW2(4*j + r)] = v[r].y; }
      wsync();
      {
        v[0] = c2{sr[SW2(j)],     si[SW2(j)]};
        v[1] = cmulc(c2{sr[SW2(j+64)],  si[SW2(j+64)]},  w4);
        v[2] = cmulc(c2{sr[SW2(j+128)], si[SW2(j+128)]}, w4b);
        v[3] = cmulc(c2{sr[SW2(j+192)], si[SW2(j+192)]}, w4c);
        dft4<-1>(v[0],v[1],v[2],v[3]);
        wsync();
        #pragma unroll
        for (int r=0;r<4;r++){ sr[SW2(b4 + 4*r)] = v[r].x; si[SW2(b4 + 4*r)] = v[r].y; }
      }
      wsync();
      {
        v[0] = c2{sr[SW2(j)],     si[SW2(j)]};
        v[1] = cmulc(c2{sr[SW2(j+64)],  si[SW2(j+64)]},  w16);
        v[2] = cmulc(c2{sr[SW2(j+128)], si[SW2(j+128)]}, w16b);
        v[3] = cmulc(c2{sr[SW2(j+192)], si[SW2(j+192)]}, w16c);
        dft4<-1>(v[0],v[1],v[2],v[3]);
        wsync();
        #pragma unroll
        for (int r=0;r<4;r++){ sr[SW2(b16 + 16*r)] = v[r].x; si[SW2(b16 + 16*r)] = v[r].y; }
      }
      wsync();
      {
        v[0] = c2{sr[SW2(j)],     si[SW2(j)]};
        v[1] = cmulc(c2{sr[SW2(j+64)],  si[SW2(j+64)]},  w64);
        v[2] = cmulc(c2{sr[SW2(j+128)], si[SW2(j+128)]}, w64b);
        v[3] = cmulc(c2{sr[SW2(j+192)], si[SW2(j+192)]}, w64c);
        dft4<-1>(v[0],v[1],v[2],v[3]);
        #pragma unroll
        for (int r=0;r<4;r++){
          int kb = j + 64*r;
          c2 tw = cis(-TWO_PI * (float)(n1*kb) * (1.0f/160000.0f));
          c2 z = cmul(v[r], tw);
          tr[n1i*GTF + kb] = z.x;
          ti[n1i*GTF + kb] = z.y;
        }
      }
    }
    wsync();
  }
  if (WRITEB){
    __syncthreads();
    unsigned* op = outB + (size_t)arr*TLEN;
    if (rows == GCH){
      for (int e = threadIdx.x; e < 256*GCH; e += 256){
        int kb = e / GCH, i = e - kb*GCH;
        op[(size_t)kb*NA + n1_0 + i] = pack_bf(c2{tr[i*GTF + kb], ti[i*GTF + kb]});
      }
    } else {
      for (int e = threadIdx.x; e < 256*rows; e += 256){
        int kb = e / rows, i = e - kb*rows;
        op[(size_t)kb*NA + n1_0 + i] = pack_bf(c2{tr[i*GTF + kb], ti[i*GTF + kb]});
      }
    }
  }
}

// ---------------- fused gather + inverse 64-FFT + abs (+ optional forward 64-FFT -> Bdec) ------
// M = 625*64 = 40000 grid. Input [kb<64][n1<625] packed bf16; output Ur[n1<625][n2<64] bf16.
#define G2CH  16
#define G2N   40
#define G2TF  73
#define G2RS  328
template<int WRITEB>
__global__ __launch_bounds__(256) void k_fft64g(const unsigned* __restrict__ inp, unsigned short* __restrict__ outp,
                                                unsigned* __restrict__ outB){
  __shared__ float smem[2*G2CH*G2TF + G2CH*G2RS];
  float* tr = smem;
  float* ti = smem + G2CH*G2TF;
  float* scr = smem + 2*G2CH*G2TF;
  int g = blockIdx.x;
  int arr = g / G2N, chunk = g - arr*G2N;
  int n1_0 = chunk*G2CH;
  int rows = 625 - n1_0; if (rows > G2CH) rows = G2CH;
  const unsigned* ip = inp + (size_t)arr*40000;
  if (rows == G2CH){
    for (int e = threadIdx.x; e < 64*G2CH; e += 256){
      int kb = e >> 4, i = e & 15;
      c2 z = unpack_bf(ip[kb*625 + n1_0 + i]);
      tr[i*G2TF + kb] = z.x; ti[i*G2TF + kb] = z.y;
    }
  } else {
    for (int e = threadIdx.x; e < 64*rows; e += 256){
      int kb = e / rows, i = e - kb*rows;
      c2 z = unpack_bf(ip[kb*625 + n1_0 + i]);
      tr[i*G2TF + kb] = z.x; ti[i*G2TF + kb] = z.y;
    }
  }
  __syncthreads();
  int row = threadIdx.x >> 4;
  int j   = threadIdx.x & 15;
  bool act = row < rows;
  int n1 = n1_0 + row;
  float* s = scr + row*G2RS;       // planes: [0]=re0 [80]=im0 [160]=re1 [240]=im1
  c2 w4  = cis(TWO_PI * (float)(j & 3) * (1.0f/16.0f));
  c2 w4b = cmul(w4,w4), w4c = cmul(w4b,w4);
  c2 w16 = cis(TWO_PI * (float)j * (1.0f/64.0f));
  c2 w16b= cmul(w16,w16), w16c= cmul(w16b,w16);
  int b4 = 4*(j-(j&3))+(j&3);
  float av[4];
  if (act){
    c2 v[4];
    #pragma unroll
    for (int q=0;q<4;q++) v[q] = c2{tr[row*G2TF + j + 16*q], ti[row*G2TF + j + 16*q]};
    dft4<1>(v[0],v[1],v[2],v[3]);
    #pragma unroll
    for (int r=0;r<4;r++){ int p = SW2(4*j+r); s[p] = v[r].x; s[80+p] = v[r].y; }
  }
  wsync();
  if (act){ // L = 4
    c2 v[4];
    v[0] = c2{s[SW2(j)],    s[80+SW2(j)]};
    v[1] = cmul(c2{s[SW2(j+16)], s[80+SW2(j+16)]}, w4);
    v[2] = cmul(c2{s[SW2(j+32)], s[80+SW2(j+32)]}, w4b);
    v[3] = cmul(c2{s[SW2(j+48)], s[80+SW2(j+48)]}, w4c);
    dft4<1>(v[0],v[1],v[2],v[3]);
    #pragma unroll
    for (int r=0;r<4;r++){ int p = SW2(b4+4*r); s[160+p] = v[r].x; s[240+p] = v[r].y; }
  }
  wsync();
  if (act){ // L = 16 + abs
    c2 v[4];
    v[0] = c2{s[160+SW2(j)],    s[240+SW2(j)]};
    v[1] = cmul(c2{s[160+SW2(j+16)], s[240+SW2(j+16)]}, w16);
    v[2] = cmul(c2{s[160+SW2(j+32)], s[240+SW2(j+32)]}, w16b);
    v[3] = cmul(c2{s[160+SW2(j+48)], s[240+SW2(j+48)]}, w16c);
    dft4<1>(v[0],v[1],v[2],v[3]);
    unsigned short* op = outp + (size_t)arr*40000 + (size_t)n1*64;
    #pragma unroll
    for (int r=0;r<4;r++){
      c2 z = v[r];
      av[r] = sqrtf(z.x*z.x + z.y*z.y) * (1.0f/160000.0f);
      op[j + 16*r] = f2bf(av[r]);
    }
  }
  if (WRITEB){
    wsync();
    if (act){
      c2 v[4];
      #pragma unroll
      for (int q=0;q<4;q++) v[q] = c2{av[q], 0.0f};
      dft4<-1>(v[0],v[1],v[2],v[3]);
      #pragma unroll
      for (int r=0;r<4;r++){ int p = SW2(4*j+r); s[p] = v[r].x; s[80+p] = v[r].y; }
    }
    wsync();
    if (act){ // L = 4 (conjugate twiddles)
      c2 v[4];
      v[0] = c2{s[SW2(j)],    s[80+SW2(j)]};
      v[1] = cmulc(c2{s[SW2(j+16)], s[80+SW2(j+16)]}, w4);
      v[2] = cmulc(c2{s[SW2(j+32)], s[80+SW2(j+32)]}, w4b);
      v[3] = cmulc(c2{s[SW2(j+48)], s[80+SW2(j+48)]}, w4c);
      dft4<-1>(v[0],v[1],v[2],v[3]);
      #pragma unroll
      for (int r=0;r<4;r++){ int p = SW2(b4+4*r); s[160+p] = v[r].x; s[240+p] = v[r].y; }
    }
    wsync();
    if (act){ // L = 16 + row twiddle -> tile
      c2 v[4];
      v[0] = c2{s[160+SW2(j)],    s[240+SW2(j)]};
      v[1] = cmulc(c2{s[160+SW2(j+16)], s[240+SW2(j+16)]}, w16);
      v[2] = cmulc(c2{s[160+SW2(j+32)], s[240+SW2(j+32)]}, w16b);
      v[3] = cmulc(c2{s[160+SW2(j+48)], s[240+SW2(j+48)]}, w16c);
      dft4<-1>(v[0],v[1],v[2],v[3]);
      #pragma unroll
      for (int r=0;r<4;r++){
        int kb = j + 16*r;
        c2 tw = cis(-TWO_PI * (float)(n1*kb) * (1.0f/40000.0f));
        c2 z = cmul(v[r], tw);
        tr[row*G2TF + kb] = z.x;
        ti[row*G2TF + kb] = z.y;
      }
    }
    __syncthreads();
    unsigned* op = outB + (size_t)arr*40000;
    if (rows == G2CH){
      for (int e = threadIdx.x; e < 64*G2CH; e += 256){
        int kb = e >> 4, i = e & 15;
        op[kb*625 + n1_0 + i] = pack_bf(c2{tr[i*G2TF + kb], ti[i*G2TF + kb]});
      }
    } else {
      for (int e = threadIdx.x; e < 64*rows; e += 256){
        int kb = e / rows, i = e - kb*rows;
        op[kb*625 + n1_0 + i] = pack_bf(c2{tr[i*G2TF + kb], ti[i*G2TF + kb]});
      }
    }
  }
}

// ---------------- 625-point row FFT (radix-5 Stockham) ----------------
// NB2: output second-stage length (M = 625*NB2). NBI: input grid second-dim (256 full, 64 dec).
// FILT>=1 input addressing: k = kb + NB2*ka -> idx = (k % NBI)*NA + k/NBI (input grid NA*NBI).
// khi clamped to M-1 (output support). fscale=4 compensates decimated-forward 1/4 (FILT2, NBI=64).
template<int S, int FILT, int TW, int PIN, int POUT, int NB2, int NBI>
__global__ __launch_bounds__(128) void k_fft625(const void* __restrict__ inpv, void* __restrict__ outpv,
                                                const c2* __restrict__ Wg,
                                                int cblk, int BLK, int nj2, int j2base, int scBase,
                                                int kamax){
  __shared__ float l0r[625], l0i[625], l1r[625], l1i[625];
  int g = blockIdx.x;
  int i = g / NB2, kb = g - i*NB2;
  int j = threadIdx.x;
  const c2* ipc = (const c2*)inpv;
  const unsigned* ipu = (const unsigned*)inpv;
  size_t ibase;
  int j1 = 0, j2 = 0;
  if (FILT == 0){
    ibase = (size_t)i*(625ULL*(size_t)NB2) + (size_t)kb*NA;
  } else if (FILT == 1){
    int bt = i / BLK; j1 = cblk*BLK + (i - bt*BLK);
    ibase = (size_t)bt*(625ULL*(size_t)NBI);
  } else {
    int g2 = scBase + i;
    int npb = BLK*nj2;
    int bt = g2 / npb, rr = g2 - bt*npb;
    int jloc = rr / nj2; j2 = j2base + (rr - jloc*nj2);
    ibase = (size_t)(bt*BLK + jloc)*(625ULL*(size_t)NBI);
  }
  float xi = 0.0f, sig = 0.0f, inv2s = 0.0f;
  int klo = 0, khi = 0;
  const float fscale = (FILT == 2 && NBI == 64) ? 4.0f : 1.0f;
  if (FILT != 0){
    if (FILT == 1){ xi = 0.4f * exp2f(-(float)j1 * 0.0625f); sig = xi * 0.04427378243f; }
    else          { xi = 0.4f * exp2f(-(float)j2);           sig = 0.35f * xi; }
    inv2s = 0.5f / (sig*sig);
    klo = (int)((xi - 6.0f*sig) * (float)TLEN); if (klo < 0) klo = 0;
    khi = (int)((xi + 6.0f*sig) * (float)TLEN) + 1; if (khi > TLEN/2 - 1) khi = TLEN/2 - 1;
    if (khi > 625*NB2 - 1) khi = 625*NB2 - 1;   // output grid support
  }
  c2 a[5], b[5];
  if (j < 125){
    if (FILT == 0){
      #pragma unroll
      for (int q=0;q<5;q++){
        size_t idx = ibase + j + 125*q;
        a[q] = PIN ? unpack_bf(ipu[idx]) : ipc[idx];
      }
      dft5<S>(a, b);
    } else {
      bool any = false;
      #pragma unroll
      for (int q=0;q<5;q++){
        int ka = j + 125*q;
        int k = kb + NB2*ka;
        c2 val = c2{0.0f, 0.0f};
        if (k >= klo && k <= khi){
          size_t idx = ibase + (size_t)(k % NBI)*NA + (size_t)(k / NBI);
          val = PIN ? unpack_bf(ipu[idx]) : ipc[idx];
          float d = (float)k * (1.0f/(float)TLEN) - xi;
          float f = fscale * __expf(-d*d*inv2s);
          val.x *= f; val.y *= f;
          any = true;
        }
        a[q] = val;
      }
      if (any){
        dft5<S>(a, b);
      } else {
        #pragma unroll
        for (int r=0;r<5;r++) b[r] = c2{0.0f,0.0f};
      }
    }
    #pragma unroll
    for (int r=0;r<5;r++){ int s = 5*j + r; l0r[s] = b[r].x; l0i[s] = b[r].y; }
  }
  __syncthreads();
  if (j < 125){ // L = 5
    int k = j % 5;
    c2 w  = Wg[25*k];  if (S<0) w.y  = -w.y;
    c2 w2 = Wg[50*k];  if (S<0) w2.y = -w2.y;
    c2 w3 = Wg[75*k];  if (S<0) w3.y = -w3.y;
    c2 w4 = Wg[100*k]; if (S<0) w4.y = -w4.y;
    a[0] = c2{l0r[j],     l0i[j]};
    a[1] = cmul(c2{l0r[j+125], l0i[j+125]}, w);
    a[2] = cmul(c2{l0r[j+250], l0i[j+250]}, w2);
    a[3] = cmul(c2{l0r[j+375], l0i[j+375]}, w3);
    a[4] = cmul(c2{l0r[j+500], l0i[j+500]}, w4);
    dft5<S>(a, b);
    int base = 5*(j-k)+k;
    #pragma unroll
    for (int r=0;r<5;r++){ int s = base + 5*r; l1r[s] = b[r].x; l1i[s] = b[r].y; }
  }
  __syncthreads();
  if (j < 125){ // L = 25
    int k = j % 25;
    c2 w  = Wg[5*k];   if (S<0) w.y  = -w.y;
    c2 w2 = Wg[10*k];  if (S<0) w2.y = -w2.y;
    c2 w3 = Wg[15*k];  if (S<0) w3.y = -w3.y;
    c2 w4 = Wg[20*k];  if (S<0) w4.y = -w4.y;
    a[0] = c2{l1r[j],     l1i[j]};
    a[1] = cmul(c2{l1r[j+125], l1i[j+125]}, w);
    a[2] = cmul(c2{l1r[j+250], l1i[j+250]}, w2);
    a[3] = cmul(c2{l1r[j+375], l1i[j+375]}, w3);
    a[4] = cmul(c2{l1r[j+500], l1i[j+500]}, w4);
    dft5<S>(a, b);
    int base = 5*(j-k)+k;
    #pragma unroll
    for (int r=0;r<5;r++){ int s = base + 25*r; l0r[s] = b[r].x; l0i[s] = b[r].y; }
  }
  __syncthreads();
  if (j < 125){ // L = 125
    c2 w = Wg[j]; if (S<0) w.y = -w.y;
    c2 w2 = cmul(w,w), w3 = cmul(w2,w), w4 = cmul(w2,w2);
    a[0] = c2{l0r[j],     l0i[j]};
    a[1] = cmul(c2{l0r[j+125], l0i[j+125]}, w);
    a[2] = cmul(c2{l0r[j+250], l0i[j+250]}, w2);
    a[3] = cmul(c2{l0r[j+375], l0i[j+375]}, w3);
    a[4] = cmul(c2{l0r[j+500], l0i[j+500]}, w4);
    dft5<S>(a, b);
    size_t obase = (size_t)i*(625ULL*(size_t)NB2) + (size_t)kb*NA;
    if (TW){
      const float invM = 1.0f/(625.0f*(float)NB2);
      c2 twb = cis((float)S * TWO_PI * (float)(j*kb)   * invM);
      c2 tws = cis((float)S * TWO_PI * (float)(125*kb) * invM);
      #pragma unroll
      for (int r=0;r<5;r++){
        int n1 = j + 125*r;
        c2 z = cmul(b[r], twb);
        if (POUT) ((unsigned*)outpv)[obase + n1] = pack_bf(z);
        else      ((c2*)outpv)[obase + n1] = z;
        twb = cmul(twb, tws);
      }
    } else {
      #pragma unroll
      for (int r=0;r<5;r++){
        int n1 = j + 125*r;
        if (n1 <= kamax){
          if (POUT) ((unsigned*)outpv)[obase + n1] = pack_bf(b[r]);
          else      ((c2*)outpv)[obase + n1] = b[r];
        }
      }
    }
  }
}

// ---------------- complex transpose (x-chain only) ----------------
__global__ __launch_bounds__(256) void k_transpose(const c2* __restrict__ in, c2* __restrict__ out,
                                                   int R, int C, int tilesR, int tilesC){
  __shared__ c2 tile[32][33];
  int bi = blockIdx.x;
  int arr = bi / (tilesR*tilesC);
  int tt = bi - arr*(tilesR*tilesC);
  int tr = tt / tilesC, tc = tt - tr*tilesC;
  const c2* ip = in + (size_t)arr*TLEN;
  c2* op = out + (size_t)arr*TLEN;
  int tx = threadIdx.x & 31, ty = threadIdx.x >> 5;
  #pragma unroll
  for (int i=0;i<4;i++){
    int r = tr*32 + ty + i*8, cc = tc*32 + tx;
    if (r < R && cc < C) tile[ty+i*8][tx] = ip[(size_t)r*C + cc];
  }
  __syncthreads();
  #pragma unroll
  for (int i=0;i<4;i++){
    int r = tc*32 + ty + i*8, cc = tr*32 + tx;
    if (r < C && cc < R) op[(size_t)r*R + cc] = tile[tx][ty+i*8];
  }
}

// ---------------- Gaussian lowpass + decimate-by-64, natural layout (S0 only) ----------------
__global__ __launch_bounds__(256) void k_conv(const float* __restrict__ inp, float* __restrict__ S){
  __shared__ float w[NTAP];
  for (int i=threadIdx.x; i<NTAP; i+=256){
    float d = (float)(i - KC);
    w[i] = 0.015666427f * __expf(-7.7106284e-4f * d * d);
  }
  __syncthreads();
  int g = blockIdx.x;
  int arr = g / 10;
  int t = (g - arr*10)*256 + threadIdx.x;
  if (t >= TD) return;
  int srow = arr * SROWS;
  const float* ip = inp + (size_t)arr*TLEN;
  float acc = 0.0f;
  int n = 64*t - KC; if (n < 0) n += TLEN;
  for (int m=0;m<NTAP;m++){
    acc += ip[n] * w[m];
    n++; if (n == TLEN) n = 0;
  }
  S[(size_t)srow*TD + t] = acc;
}

// ---------------- fused LDS stage + conv, full-rate scrambled U (bf16 input) ----------------
#define CONV_NCOL 27
#define CONV_NU   16875
#define CONV_USZ  17138
#define CONV_LDSB ((CONV_USZ + NTAP + 1)*4)
template<int MODE>
__global__ __launch_bounds__(256) void k_conv2(const unsigned short* __restrict__ inp, float* __restrict__ S,
                                               int cblk, int BLK, int nj2, int j2base, int scBase){
  extern __shared__ float smem[];
  float* u = smem;
  float* w = smem + CONV_USZ;
  for (int i=threadIdx.x; i<NTAP; i+=256){
    float d = (float)(i - KC);
    w[i] = 0.015666427f * __expf(-7.7106284e-4f * d * d);
  }
  int g = blockIdx.x;
  int arr = g / 10;
  int b = g - arr*10;
  int nlo = 16000*b - KC;
  int n2_0 = (nlo >= 0) ? (nlo/625) : -1;
  const unsigned short* ip = inp + (size_t)arr*TLEN;
  for (int e = threadIdx.x; e < CONV_NU; e += 256){
    int n1 = e / CONV_NCOL;
    int c  = e - n1*CONV_NCOL;
    int n2 = n2_0 + c;
    n2 &= 255;
    u[SW64(n1 + 625*c)] = bf2f(ip[n1*NB + n2]);
  }
  __syncthreads();
  int tl = threadIdx.x;
  if (tl >= 250) return;
  int t = 250*b + tl;
  int srow;
  if (MODE == 1){
    int a2 = arr / BLK; int j1 = cblk*BLK + (arr - a2*BLK);
    srow = a2*SROWS + 1 + j1;
  } else {
    int g2 = scBase + arr; int npb = BLK*nj2;
    int a2 = g2/npb, rr = g2 - a2*npb;
    int jloc = rr/nj2; int j2 = j2base + (rr - jloc*nj2);
    int j1 = cblk*BLK + jloc;
    int full = j1 >> 4;
    int cum = 16*(5*full - (full*(full-1))/2) + (j1 & 15)*(5 - full);
    int P = cum + j2 - full - 1;
    srow = a2*SROWS + 97 + P;
  }
  int base = 64*t - KC - 625*n2_0;
  float acc = 0.0f;
  #pragma unroll 4
  for (int m=0;m<NTAP;m++){
    acc += u[SW64(base + m)] * w[m];
  }
  S[(size_t)srow*TD + t] = acc;
}

// ---------------- decimated conv (D=4): input Ur_dec[n1<625][n2<64], M=40000 ----------------
#define C2NU  5000
#define C2USZ 5312
template<int MODE>
__global__ __launch_bounds__(256) void k_conv2d(const unsigned short* __restrict__ inp, float* __restrict__ S,
                                                int cblk, int BLK, int nj2, int j2base, int scBase){
  __shared__ float u[C2USZ];
  __shared__ float w[72];
  if (threadIdx.x < 65){
    float d = 4.0f * (float)((int)threadIdx.x - 32);
    w[threadIdx.x] = 0.062665708f * __expf(-7.7106284e-4f * d * d);  // 4x weight (rectangle rule)
  }
  int g = blockIdx.x;
  int arr = g / 10;
  int b = g - arr*10;
  int mlo = 4000*b - 32;
  int n2_0 = (mlo >= 0) ? (mlo/625) : -1;
  const unsigned short* ip = inp + (size_t)arr*40000;
  for (int e = threadIdx.x; e < C2NU; e += 256){
    int n1 = e >> 3, c = e & 7;
    int n2 = (n2_0 + c) & 63;
    u[SW16(n1 + 625*c)] = bf2f(ip[n1*64 + n2]);
  }
  __syncthreads();
  int tl = threadIdx.x;
  if (tl >= 250) return;
  int t = 250*b + tl;
  int srow;
  if (MODE == 1){
    int a2 = arr / BLK; int j1 = cblk*BLK + (arr - a2*BLK);
    srow = a2*SROWS + 1 + j1;
  } else {
    int g2 = scBase + arr; int npb = BLK*nj2;
    int a2 = g2/npb, rr = g2 - a2*npb;
    int jloc = rr/nj2; int j2 = j2base + (rr - jloc*nj2);
    int j1 = cblk*BLK + jloc;
    int full = j1 >> 4;
    int cum = 16*(5*full - (full*(full-1))/2) + (j1 & 15)*(5 - full);
    int P = cum + j2 - full - 1;
    srow = a2*SROWS + 97 + P;
  }
  int base = (4000*b - 32 - 625*n2_0) + 16*tl;
  float acc = 0.0f;
  #pragma unroll 5
  for (int m=0;m<65;m++){
    acc += u[SW16(base + m)] * w[m];
  }
  S[(size_t)srow*TD + t] = acc;
}

// ---------------- global min/max + finalize ----------------
__global__ __launch_bounds__(256) void k_minmax1(const float* __restrict__ S, int n, float* pmn, float* pmx){
  __shared__ float smn[256], smx[256];
  float mn = 3.4028235e38f, mx = -3.4028235e38f;
  for (size_t i = (size_t)blockIdx.x*256 + threadIdx.x; i < (size_t)n; i += (size_t)gridDim.x*256){
    float v = S[i]; mn = fminf(mn,v); mx = fmaxf(mx,v);
  }
  smn[threadIdx.x]=mn; smx[threadIdx.x]=mx; __syncthreads();
  for (int s=128;s>0;s>>=1){
    if ((int)threadIdx.x < s){
      smn[threadIdx.x]=fminf(smn[threadIdx.x],smn[threadIdx.x+s]);
      smx[threadIdx.x]=fmaxf(smx[threadIdx.x],smx[threadIdx.x+s]);
    }
    __syncthreads();
  }
  if (threadIdx.x==0){ pmn[blockIdx.x]=smn[0]; pmx[blockIdx.x]=smx[0]; }
}
__global__ __launch_bounds__(256) void k_minmax2(const float* __restrict__ pmn, const float* __restrict__ pmx,
                                                 int nb, float* scal){
  __shared__ float smn[256], smx[256];
  float mn = 3.4028235e38f, mx = -3.4028235e38f;
  for (int i = threadIdx.x; i < nb; i += 256){ mn = fminf(mn,pmn[i]); mx = fmaxf(mx,pmx[i]); }
  smn[threadIdx.x]=mn; smx[threadIdx.x]=mx; __syncthreads();
  for (int s=128;s>0;s>>=1){
    if ((int)threadIdx.x < s){
      smn[threadIdx.x]=fminf(smn[threadIdx.x],smn[threadIdx.x+s]);
      smx[threadIdx.x]=fmaxf(smx[threadIdx.x],smx[threadIdx.x+s]);
    }
    __syncthreads();
  }
  if (threadIdx.x==0){ scal[0]=smn[0]; scal[1]=smx[0]; }
}
__global__ __launch_bounds__(256) void k_final(const float* __restrict__ S, const float* __restrict__ scal,
                                               float* __restrict__ out, int n){
  int i = blockIdx.x*256 + threadIdx.x;
  if (i >= n) return;
  float mn = scal[0];
  float r = scal[1] - mn;
  if (r == 0.0f) r = 1.0f;
  int half = SROWS*TD;
  int a = i / half; int rest = i - a*half;
  out[i] = (S[(size_t)(a & 1)*half + rest] - mn) / r;
}

extern "C" void kernel_launch(void* const* d_in, const int* in_sizes, int n_in,
                              void* d_out, int out_size, void* d_ws, size_t ws_size,
                              hipStream_t stream){
  (void)in_sizes; (void)n_in;
  const float* x = (const float*)d_in[0];

  int BLK = 16;
  while (BLK > 1){
    size_t CH = 2*(size_t)BLK;
    size_t needb = 2560000ULL + CH*TLEN*4ULL + CH*TLEN*4ULL + CH*TLEN*4ULL
                 + 3ULL*CH*TLEN*4ULL + 3ULL*CH*TLEN*2ULL + 6740000ULL + 16384ULL + 4096ULL;
    if (needb <= ws_size) break;
    BLK >>= 1;
  }
  {
    size_t CH = 2;
    size_t needmin = 2560000ULL + CH*TLEN*4ULL + CH*TLEN*4ULL + CH*TLEN*4ULL
                   + 3ULL*CH*TLEN*4ULL + 3ULL*CH*TLEN*2ULL + 6740000ULL + 16384ULL + 4096ULL;
    if (ws_size < needmin) return;
  }
  int CH = 2*BLK;

  char* p = (char*)d_ws;
  auto carve = [&](size_t bytes)->void*{ void* r = (void*)p; p += (bytes + 255) & ~(size_t)255; return r; };
  c2*             Xf  = (c2*)carve(2ULL*TLEN*sizeof(c2));
  unsigned*       A1  = (unsigned*)carve((size_t)CH*TLEN*4ULL);
  unsigned*       B   = (unsigned*)carve((size_t)CH*TLEN*4ULL);
  unsigned*       U1h = (unsigned*)carve((size_t)CH*TLEN*4ULL);
  unsigned*       A2  = (unsigned*)carve(3ULL*CH*TLEN*4ULL);
  unsigned short* Ur  = (unsigned short*)carve(3ULL*CH*TLEN*2ULL);
  float*          Sb  = (float*)carve(2ULL*SROWS*TD*sizeof(float));
  c2*             Wg  = (c2*)carve(625*sizeof(c2));
  float*          pmn = (float*)carve(512*4);
  float*          pmx = (float*)carve(512*4);
  float*          scal = (float*)carve(256);

  // ---- W625 global LUT ----
  k_wlut<<<3, 256, 0, stream>>>(Wg);

  // ---- forward FFT of x -> Xf (f32 chain; A2 buffer reused as c2 scratch here) ----
  k_fft256<-1,2,0><<<2*NA, 64, 0, stream>>>((const void*)x, (void*)A2);
  k_transpose<<<2*20*8, 256, 0, stream>>>((c2*)A2, (c2*)U1h, NA, NB, 20, 8);
  k_fft625<-1,0,0,0,0,256,256><<<2*NB, 128, 0, stream>>>((const void*)U1h, (void*)Xf, Wg, 0,0,0,0,0, 314);
  // ---- S0 ----
  k_conv<<<2*10, 256, 0, stream>>>(x, Sb);

  int NCB = 96 / BLK;
  for (int c = 0; c < NCB; c++){
    int cq = (c*BLK)/16;
    int nj2 = 5 - cq;
    int j2base = cq + 1;
    float xi2 = 0.4f * exp2f(-(float)j2base);
    int khi2 = (int)(3.1f * xi2 * 160000.0f) + 1; if (khi2 > TLEN/2 - 1) khi2 = TLEN/2 - 1;
    if (j2base >= 2){
      // ---- fully decimated cascade (all j1 >= 16 in this block) ----
      int khi2c = khi2 > 39999 ? 39999 : khi2;
      int kamaxd = (khi2c >> 6) + 1; if (kamaxd > 624) kamaxd = 624;
      k_fft625<1,1,1,0,1,64,256><<<CH*64, 128, 0, stream>>>((const void*)Xf, (void*)A1, Wg, c, BLK, 0,0,0, 624);
      k_fft64g<1><<<CH*G2N, 256, 0, stream>>>(A1, Ur, B);
      k_conv2d<1><<<CH*10, 256, 0, stream>>>(Ur, Sb, c, BLK, 0,0,0);
      k_fft625<-1,0,0,1,1,64,64><<<CH*64, 128, 0, stream>>>((const void*)B, (void*)U1h, Wg, 0,0,0,0,0, kamaxd);
      k_fft625<1,2,1,1,1,64,64><<<nj2*CH*64, 128, 0, stream>>>((const void*)U1h, (void*)A2, Wg, c, BLK, nj2, j2base, 0, 624);
      k_fft64g<0><<<nj2*CH*G2N, 256, 0, stream>>>(A2, Ur, (unsigned*)nullptr);
      k_conv2d<2><<<nj2*CH*10, 256, 0, stream>>>(Ur, Sb, c, BLK, nj2, j2base, 0);
    } else {
      // ---- full-rate order-1 (j1 < 16); j2=1,2 full-rate, j2>=3 decimated from full U1h ----
      int kamax = (khi2 >> 8) + 1; if (kamax > 624) kamax = 624;
      k_fft625<1,1,1,0,1,256,256><<<CH*NB, 128, 0, stream>>>((const void*)Xf, (void*)A1, Wg, c, BLK, 0,0,0, 624);
      k_fft256g<1,1><<<CH*GNCH, 256, G_LDSB, stream>>>((const void*)A1, Ur, B);
      k_conv2<1><<<CH*10, 256, CONV_LDSB, stream>>>(Ur, Sb, c, BLK, 0,0,0);
      k_fft625<-1,0,0,1,1,256,256><<<CH*NB, 128, 0, stream>>>((const void*)B, (void*)U1h, Wg, 0,0,0,0,0, kamax);
      int nf = 3 - j2base; if (nf < 0) nf = 0; if (nf > nj2) nf = nj2;
      if (nf > 0){
        k_fft625<1,2,1,1,1,256,256><<<nf*CH*NB, 128, 0, stream>>>((const void*)U1h, (void*)A2, Wg, c, BLK, nf, j2base, 0, 624);
        k_fft256g<0,1><<<nf*CH*GNCH, 256, G_LDSB, stream>>>((const void*)A2, Ur, (unsigned*)nullptr);
        k_conv2<2><<<nf*CH*10, 256, CONV_LDSB, stream>>>(Ur, Sb, c, BLK, nf, j2base, 0);
      }
      int j2d = 3;
      int nd = 6 - j2d; if (j2d < j2base){ j2d = j2base; nd = 6 - j2d; }
      if (nd > 0){
        k_fft625<1,2,1,1,1,64,256><<<nd*CH*64, 128, 0, stream>>>((const void*)U1h, (void*)A2, Wg, c, BLK, nd, j2d, 0, 624);
        k_fft64g<0><<<nd*CH*G2N, 256, 0, stream>>>(A2, Ur, (unsigned*)nullptr);
        k_conv2d<2><<<nd*CH*10, 256, 0, stream>>>(Ur, Sb, c, BLK, nd, j2d, 0);
      }
    }
  }

  // ---- global min-max normalize (standardize cancels) + tile(3,1,1) ----
  k_minmax1<<<512, 256, 0, stream>>>(Sb, 2*SROWS*TD, pmn, pmx);
  k_minmax2<<<1, 256, 0, stream>>>(pmn, pmx, 512, scal);
  k_final<<<(out_size+255)/256, 256, 0, stream>>>(Sb, scal, (float*)d_out, out_size);
}

// Round 19
// 497.901 us; speedup vs baseline: 2.7999x; 1.1793x over previous
//
#include <hip/hip_runtime.h>
#include <math.h>

#define TLEN 160000
#define NA 625
#define NB 256
#define TD 2500
#define KC 128
#define NTAP 257
#define SROWS 337
#define TWO_PI 6.283185307179586f

struct c2 { float x, y; };

__device__ __forceinline__ c2 cmul(c2 a, c2 b){ return c2{a.x*b.x - a.y*b.y, a.x*b.y + a.y*b.x}; }
__device__ __forceinline__ c2 cmulc(c2 a, c2 b){ return c2{a.x*b.x + a.y*b.y, a.y*b.x - a.x*b.y}; }
__device__ __forceinline__ c2 cadd(c2 a, c2 b){ return c2{a.x+b.x, a.y+b.y}; }
__device__ __forceinline__ c2 csub(c2 a, c2 b){ return c2{a.x-b.x, a.y-b.y}; }
__device__ __forceinline__ c2 cmac(c2 acc, c2 v, float wr, float wi){
  acc.x += v.x*wr - v.y*wi; acc.y += v.x*wi + v.y*wr; return acc;
}
__device__ __forceinline__ c2 cis(float ang){ c2 r; __sincosf(ang, &r.y, &r.x); return r; }
__device__ __forceinline__ int SW(int i){ return i + (i >> 4); }
__device__ __forceinline__ int SW2(int i){ return i + (i >> 2); }
__device__ __forceinline__ int SW16(int i){ return i + (i >> 4); }
__device__ __forceinline__ int SW64(int i){ return i + (i >> 6); }
__device__ __forceinline__ unsigned pack_bf(c2 z){
  unsigned xr = __float_as_uint(z.x), xi = __float_as_uint(z.y);
  xr += 0x8000u + ((xr >> 16) & 1u);
  xi += 0x8000u + ((xi >> 16) & 1u);
  return (xr >> 16) | (xi & 0xFFFF0000u);
}
__device__ __forceinline__ c2 unpack_bf(unsigned p){
  return c2{ __uint_as_float(p << 16), __uint_as_float(p & 0xFFFF0000u) };
}
__device__ __forceinline__ unsigned short f2bf(float f){
  unsigned u = __float_as_uint(f);
  u += 0x8000u + ((u >> 16) & 1u);
  return (unsigned short)(u >> 16);
}
__device__ __forceinline__ float bf2f(unsigned short h){
  return __uint_as_float(((unsigned)h) << 16);
}
__device__ __forceinline__ void wsync(){
  __builtin_amdgcn_wave_barrier();
  asm volatile("s_waitcnt lgkmcnt(0)" ::: "memory");
  __builtin_amdgcn_wave_barrier();
}

template<int S>
__device__ __forceinline__ void dft4(c2& a0, c2& a1, c2& a2, c2& a3){
  c2 t0 = cadd(a0,a2), t1 = csub(a0,a2), t2 = cadd(a1,a3), t3 = csub(a1,a3);
  float fs = (float)S;
  a0 = cadd(t0,t2); a2 = csub(t0,t2);
  a1 = c2{t1.x - fs*t3.y, t1.y + fs*t3.x};
  a3 = c2{t1.x + fs*t3.y, t1.y - fs*t3.x};
}

template<int S>
__device__ __forceinline__ void dft5(const c2 a[5], c2 b[5]){
  const float C1 = 0.30901699437494742f, C2 = -0.80901699437494745f;
  const float S1 = 0.95105651629515353f * (float)S, S2 = 0.58778525229247314f * (float)S;
  b[0] = cadd(cadd(a[0],a[1]), cadd(cadd(a[2],a[3]),a[4]));
  c2 r;
  r = a[0]; r = cmac(r,a[1],C1, S1); r = cmac(r,a[2],C2, S2); r = cmac(r,a[3],C2,-S2); r = cmac(r,a[4],C1,-S1); b[1]=r;
  r = a[0]; r = cmac(r,a[1],C2, S2); r = cmac(r,a[2],C1,-S1); r = cmac(r,a[3],C1, S1); r = cmac(r,a[4],C2,-S2); b[2]=r;
  r = a[0]; r = cmac(r,a[1],C2,-S2); r = cmac(r,a[2],C1, S1); r = cmac(r,a[3],C1,-S1); r = cmac(r,a[4],C2, S2); b[3]=r;
  r = a[0]; r = cmac(r,a[1],C1,-S1); r = cmac(r,a[2],C2,-S2); r = cmac(r,a[3],C2, S2); r = cmac(r,a[4],C1, S1); b[4]=r;
}

// ---------------- W625 global LUT init ----------------
__global__ __launch_bounds__(256) void k_wlut(c2* __restrict__ W){
  int m = blockIdx.x*256 + threadIdx.x;
  if (m < 625) W[m] = cis(TWO_PI * (float)m * (1.0f/625.0f));
}

// ---------------- srow table for the 416 S2 paths ----------------
// p<320: batched paths (j1 in [16,96), grouped c=1..4); p>=320: c0 j2>=3 paths.
__global__ __launch_bounds__(256) void k_ptab(int* __restrict__ tab){
  int p = blockIdx.x*256 + threadIdx.x;
  if (p >= 416) return;
  int arr, j1, j2;
  if (p < 320){
    int c = 1, base = 0;
    while (c < 4 && p >= base + 32*(5-c)){ base += 32*(5-c); c++; }
    int loc = p - base;
    int nj2 = 5 - c;
    int npb = 16*nj2;
    arr = loc / npb;
    int rr = loc - arr*npb;
    int jloc = rr / nj2;
    j2 = (c+1) + (rr - jloc*nj2);
    j1 = 16*c + jloc;
  } else {
    int q = p - 320;
    arr = q / 48;
    int rr = q - arr*48;
    int jloc = rr / 3;
    j2 = 3 + (rr - jloc*3);
    j1 = jloc;
  }
  int full = j1 >> 4;
  int cum = 16*(5*full - (full*(full-1))/2) + (j1 & 15)*(5 - full);
  int P = cum + j2 - full - 1;
  tab[p] = arr*SROWS + 97 + P;
}

// ---------------- 256-point row FFT (x-chain only) ----------------
template<int S, int INMODE, int OUTMODE>
__global__ __launch_bounds__(64) void k_fft256(const void* __restrict__ inp, void* __restrict__ outp){
  __shared__ c2 lds[2][272];
  int g = blockIdx.x;
  int arr = g / NA, n1 = g - arr*NA;
  int j = threadIdx.x;
  c2 v[4];
  if (INMODE == 0){
    const c2* ip = (const c2*)inp + (size_t)arr*TLEN + (size_t)n1*NB;
    #pragma unroll
    for (int q=0;q<4;q++) v[q] = ip[j + 64*q];
  } else if (INMODE == 1){
    const float* ip = (const float*)inp + (size_t)arr*TLEN + (size_t)n1*NB;
    #pragma unroll
    for (int q=0;q<4;q++) v[q] = c2{ip[j + 64*q], 0.0f};
  } else {
    const float* ip = (const float*)inp + (size_t)arr*TLEN;
    #pragma unroll
    for (int q=0;q<4;q++) v[q] = c2{ip[n1 + NA*(j + 64*q)], 0.0f};
  }
  dft4<S>(v[0],v[1],v[2],v[3]);
  #pragma unroll
  for (int r=0;r<4;r++) lds[0][SW(4*j + r)] = v[r];
  wsync();
  { // L = 4
    int k = j & 3;
    c2 w = cis((float)S * TWO_PI * (float)k * (1.0f/16.0f));
    c2 w2 = cmul(w,w), w3 = cmul(w2,w);
    v[0] = lds[0][SW(j)];
    v[1] = cmul(lds[0][SW(j+64)], w);
    v[2] = cmul(lds[0][SW(j+128)], w2);
    v[3] = cmul(lds[0][SW(j+192)], w3);
    dft4<S>(v[0],v[1],v[2],v[3]);
    int base = 4*(j-k)+k;
    #pragma unroll
    for (int r=0;r<4;r++) lds[1][SW(base + 4*r)] = v[r];
  }
  wsync();
  { // L = 16
    int k = j & 15;
    c2 w = cis((float)S * TWO_PI * (float)k * (1.0f/64.0f));
    c2 w2 = cmul(w,w), w3 = cmul(w2,w);
    v[0] = lds[1][SW(j)];
    v[1] = cmul(lds[1][SW(j+64)], w);
    v[2] = cmul(lds[1][SW(j+128)], w2);
    v[3] = cmul(lds[1][SW(j+192)], w3);
    dft4<S>(v[0],v[1],v[2],v[3]);
    int base = 4*(j-k)+k;
    #pragma unroll
    for (int r=0;r<4;r++) lds[0][SW(base + 16*r)] = v[r];
  }
  wsync();
  { // L = 64
    c2 w = cis((float)S * TWO_PI * (float)j * (1.0f/256.0f));
    c2 w2 = cmul(w,w), w3 = cmul(w2,w);
    v[0] = lds[0][SW(j)];
    v[1] = cmul(lds[0][SW(j+64)], w);
    v[2] = cmul(lds[0][SW(j+128)], w2);
    v[3] = cmul(lds[0][SW(j+192)], w3);
    dft4<S>(v[0],v[1],v[2],v[3]);
    if (OUTMODE == 0){
      c2* op = (c2*)outp + (size_t)arr*TLEN + (size_t)n1*NB;
      #pragma unroll
      for (int r=0;r<4;r++){
        int kb = j + 64*r;
        c2 tw = cis((float)S * TWO_PI * (float)(n1*kb) * (1.0f/160000.0f));
        op[kb] = cmul(v[r], tw);
      }
    } else {
      float* op = (float*)outp + (size_t)arr*TLEN + (size_t)n1*NB;
      #pragma unroll
      for (int r=0;r<4;r++){
        c2 z = v[r];
        op[j + 64*r] = sqrtf(z.x*z.x + z.y*z.y) * (1.0f/160000.0f);
      }
    }
  }
}

// ---------------- fused gather + inverse 256-FFT + abs (+ optional forward -> B) ---------------
#define GCH     12
#define GNCH    53
#define GTF     273
#define SCR     320
#define G_LDSB  ((2*GCH*GTF + 4*2*SCR)*4)
template<int WRITEB, int PIN>
__global__ __launch_bounds__(256) void k_fft256g(const void* __restrict__ inpv, unsigned short* __restrict__ outp,
                                                 unsigned* __restrict__ outB){
  extern __shared__ float smemg[];
  float* tr = smemg;
  float* ti = smemg + GCH*GTF;
  int g = blockIdx.x;
  int arr = g / GNCH, chunk = g - arr*GNCH;
  int n1_0 = chunk*GCH;
  int rows = NA - n1_0; if (rows > GCH) rows = GCH;
  const c2* ipc = (const c2*)inpv;
  const unsigned* ipu = (const unsigned*)inpv;
  size_t base = (size_t)arr*TLEN;
  if (rows == GCH){
    for (int e = threadIdx.x; e < 256*GCH; e += 256){
      int kb = e / GCH, i = e - kb*GCH;
      size_t idx = base + (size_t)kb*NA + n1_0 + i;
      c2 z = PIN ? unpack_bf(ipu[idx]) : ipc[idx];
      tr[i*GTF + kb] = z.x; ti[i*GTF + kb] = z.y;
    }
  } else {
    for (int e = threadIdx.x; e < 256*rows; e += 256){
      int kb = e / rows, i = e - kb*rows;
      size_t idx = base + (size_t)kb*NA + n1_0 + i;
      c2 z = PIN ? unpack_bf(ipu[idx]) : ipc[idx];
      tr[i*GTF + kb] = z.x; ti[i*GTF + kb] = z.y;
    }
  }
  __syncthreads();
  int gq = threadIdx.x >> 6, j = threadIdx.x & 63;
  float* sr = smemg + 2*GCH*GTF + gq*(2*SCR);
  float* si = sr + SCR;
  c2 w4  = cis(TWO_PI * (float)(j & 3)  * (1.0f/16.0f));
  c2 w4b = cmul(w4,w4),  w4c = cmul(w4b,w4);
  c2 w16 = cis(TWO_PI * (float)(j & 15) * (1.0f/64.0f));
  c2 w16b= cmul(w16,w16), w16c= cmul(w16b,w16);
  c2 w64 = cis(TWO_PI * (float)j * (1.0f/256.0f));
  c2 w64b= cmul(w64,w64), w64c= cmul(w64b,w64);
  int b4 = 4*(j-(j&3))+(j&3);
  int b16= 4*(j-(j&15))+(j&15);
  unsigned short* op0 = outp + (size_t)arr*TLEN;
  for (int t = 0; t < 3; t++){
    int n1i = gq + 4*t;
    if (n1i >= rows) break;
    int n1 = n1_0 + n1i;
    c2 v[4];
    #pragma unroll
    for (int q=0;q<4;q++) v[q] = c2{tr[n1i*GTF + j + 64*q], ti[n1i*GTF + j + 64*q]};
    dft4<1>(v[0],v[1],v[2],v[3]);
    #pragma unroll
    for (int r=0;r<4;r++){ sr[SW2(4*j + r)] = v[r].x; si[SW2(4*j + r)] = v[r].y; }
    wsync();
    {
      v[0] = c2{sr[SW2(j)],     si[SW2(j)]};
      v[1] = cmul(c2{sr[SW2(j+64)],  si[SW2(j+64)]},  w4);
      v[2] = cmul(c2{sr[SW2(j+128)], si[SW2(j+128)]}, w4b);
      v[3] = cmul(c2{sr[SW2(j+192)], si[SW2(j+192)]}, w4c);
      dft4<1>(v[0],v[1],v[2],v[3]);
      wsync();
      #pragma unroll
      for (int r=0;r<4;r++){ sr[SW2(b4 + 4*r)] = v[r].x; si[SW2(b4 + 4*r)] = v[r].y; }
    }
    wsync();
    {
      v[0] = c2{sr[SW2(j)],     si[SW2(j)]};
      v[1] = cmul(c2{sr[SW2(j+64)],  si[SW2(j+64)]},  w16);
      v[2] = cmul(c2{sr[SW2(j+128)], si[SW2(j+128)]}, w16b);
      v[3] = cmul(c2{sr[SW2(j+192)], si[SW2(j+192)]}, w16c);
      dft4<1>(v[0],v[1],v[2],v[3]);
      wsync();
      #pragma unroll
      for (int r=0;r<4;r++){ sr[SW2(b16 + 16*r)] = v[r].x; si[SW2(b16 + 16*r)] = v[r].y; }
    }
    wsync();
    float av[4];
    {
      v[0] = c2{sr[SW2(j)],     si[SW2(j)]};
      v[1] = cmul(c2{sr[SW2(j+64)],  si[SW2(j+64)]},  w64);
      v[2] = cmul(c2{sr[SW2(j+128)], si[SW2(j+128)]}, w64b);
      v[3] = cmul(c2{sr[SW2(j+192)], si[SW2(j+192)]}, w64c);
      dft4<1>(v[0],v[1],v[2],v[3]);
      unsigned short* op = op0 + (size_t)n1*NB;
      #pragma unroll
      for (int r=0;r<4;r++){
        c2 z = v[r];
        av[r] = sqrtf(z.x*z.x + z.y*z.y) * (1.0f/160000.0f);
        op[j + 64*r] = f2bf(av[r]);
      }
    }
    if (WRITEB){
      wsync();
      #pragma unroll
      for (int q=0;q<4;q++) v[q] = c2{av[q], 0.0f};
      dft4<-1>(v[0],v[1],v[2],v[3]);
      #pragma unroll
      for (int r=0;r<4;r++){ sr[SW2(4*j + r)] = v[r].x; si[SW2(4*j + r)] = v[r].y; }
      wsync();
      {
        v[0] = c2{sr[SW2(j)],     si[SW2(j)]};
        v[1] = cmulc(c2{sr[SW2(j+64)],  si[SW2(j+64)]},  w4);
        v[2] = cmulc(c2{sr[SW2(j+128)], si[SW2(j+128)]}, w4b);
        v[3] = cmulc(c2{sr[SW2(j+192)], si[SW2(j+192)]}, w4c);
        dft4<-1>(v[0],v[1],v[2],v[3]);
        wsync();
        #pragma unroll
        for (int r=0;r<4;r++){ sr[SW2(b4 + 4*r)] = v[r].x; si[SW2(b4 + 4*r)] = v[r].y; }
      }
      wsync();
      {
        v[0] = c2{sr[SW2(j)],     si[SW2(j)]};
        v[1] = cmulc(c2{sr[SW2(j+64)],  si[SW2(j+64)]},  w16);
        v[2] = cmulc(c2{sr[SW2(j+128)], si[SW2(j+128)]}, w16b);
        v[3] = cmulc(c2{sr[SW2(j+192)], si[SW2(j+192)]}, w16c);
        dft4<-1>(v[0],v[1],v[2],v[3]);
        wsync();
        #pragma unroll
        for (int r=0;r<4;r++){ sr[SW2(b16 + 16*r)] = v[r].x; si[SW2(b16 + 16*r)] = v[r].y; }
      }
      wsync();
      {
        v[0] = c2{sr[SW2(j)],     si[SW2(j)]};
        v[1] = cmulc(c2{sr[SW2(j+64)],  si[SW2(j+64)]},  w64);
        v[2] = cmulc(c2{sr[SW2(j+128)], si[SW2(j+128)]}, w64b);
        v[3] = cmulc(c2{sr[SW2(j+192)], si[SW2(j+192)]}, w64c);
        dft4<-1>(v[0],v[1],v[2],v[3]);
        #pragma unroll
        for (int r=0;r<4;r++){
          int kb = j + 64*r;
          c2 tw = cis(-TWO_PI * (float)(n1*kb) * (1.0f/160000.0f));
          c2 z = cmul(v[r], tw);
          tr[n1i*GTF + kb] = z.x;
          ti[n1i*GTF + kb] = z.y;
        }
      }
    }
    wsync();
  }
  if (WRITEB){
    __syncthreads();
    unsigned* op = outB + (size_t)arr*TLEN;
    if (rows == GCH){
      for (int e = threadIdx.x; e < 256*GCH; e += 256){
        int kb = e / GCH, i = e - kb*GCH;
        op[(size_t)kb*NA + n1_0 + i] = pack_bf(c2{tr[i*GTF + kb], ti[i*GTF + kb]});
      }
    } else {
      for (int e = threadIdx.x; e < 256*rows; e += 256){
        int kb = e / rows, i = e - kb*rows;
        op[(size_t)kb*NA + n1_0 + i] = pack_bf(c2{tr[i*GTF + kb], ti[i*GTF + kb]});
      }
    }
  }
}

// ---------------- fused gather + inverse 64-FFT + abs (+ optional forward 64-FFT -> Bdec) ------
#define G2CH  16
#define G2N   40
#define G2TF  73
#define G2RS  328
template<int WRITEB>
__global__ __launch_bounds__(256) void k_fft64g(const unsigned* __restrict__ inp, unsigned short* __restrict__ outp,
                                                unsigned* __restrict__ outB){
  __shared__ float smem[2*G2CH*G2TF + G2CH*G2RS];
  float* tr = smem;
  float* ti = smem + G2CH*G2TF;
  float* scr = smem + 2*G2CH*G2TF;
  int g = blockIdx.x;
  int arr = g / G2N, chunk = g - arr*G2N;
  int n1_0 = chunk*G2CH;
  int rows = 625 - n1_0; if (rows > G2CH) rows = G2CH;
  const unsigned* ip = inp + (size_t)arr*40000;
  if (rows == G2CH){
    for (int e = threadIdx.x; e < 64*G2CH; e += 256){
      int kb = e >> 4, i = e & 15;
      c2 z = unpack_bf(ip[kb*625 + n1_0 + i]);
      tr[i*G2TF + kb] = z.x; ti[i*G2TF + kb] = z.y;
    }
  } else {
    for (int e = threadIdx.x; e < 64*rows; e += 256){
      int kb = e / rows, i = e - kb*rows;
      c2 z = unpack_bf(ip[kb*625 + n1_0 + i]);
      tr[i*G2TF + kb] = z.x; ti[i*G2TF + kb] = z.y;
    }
  }
  __syncthreads();
  int row = threadIdx.x >> 4;
  int j   = threadIdx.x & 15;
  bool act = row < rows;
  int n1 = n1_0 + row;
  float* s = scr + row*G2RS;
  c2 w4  = cis(TWO_PI * (float)(j & 3) * (1.0f/16.0f));
  c2 w4b = cmul(w4,w4), w4c = cmul(w4b,w4);
  c2 w16 = cis(TWO_PI * (float)j * (1.0f/64.0f));
  c2 w16b= cmul(w16,w16), w16c= cmul(w16b,w16);
  int b4 = 4*(j-(j&3))+(j&3);
  float av[4];
  if (act){
    c2 v[4];
    #pragma unroll
    for (int q=0;q<4;q++) v[q] = c2{tr[row*G2TF + j + 16*q], ti[row*G2TF + j + 16*q]};
    dft4<1>(v[0],v[1],v[2],v[3]);
    #pragma unroll
    for (int r=0;r<4;r++){ int p = SW2(4*j+r); s[p] = v[r].x; s[80+p] = v[r].y; }
  }
  wsync();
  if (act){ // L = 4
    c2 v[4];
    v[0] = c2{s[SW2(j)],    s[80+SW2(j)]};
    v[1] = cmul(c2{s[SW2(j+16)], s[80+SW2(j+16)]}, w4);
    v[2] = cmul(c2{s[SW2(j+32)], s[80+SW2(j+32)]}, w4b);
    v[3] = cmul(c2{s[SW2(j+48)], s[80+SW2(j+48)]}, w4c);
    dft4<1>(v[0],v[1],v[2],v[3]);
    #pragma unroll
    for (int r=0;r<4;r++){ int p = SW2(b4+4*r); s[160+p] = v[r].x; s[240+p] = v[r].y; }
  }
  wsync();
  if (act){ // L = 16 + abs
    c2 v[4];
    v[0] = c2{s[160+SW2(j)],    s[240+SW2(j)]};
    v[1] = cmul(c2{s[160+SW2(j+16)], s[240+SW2(j+16)]}, w16);
    v[2] = cmul(c2{s[160+SW2(j+32)], s[240+SW2(j+32)]}, w16b);
    v[3] = cmul(c2{s[160+SW2(j+48)], s[240+SW2(j+48)]}, w16c);
    dft4<1>(v[0],v[1],v[2],v[3]);
    unsigned short* op = outp + (size_t)arr*40000 + (size_t)n1*64;
    #pragma unroll
    for (int r=0;r<4;r++){
      c2 z = v[r];
      av[r] = sqrtf(z.x*z.x + z.y*z.y) * (1.0f/160000.0f);
      op[j + 16*r] = f2bf(av[r]);
    }
  }
  if (WRITEB){
    wsync();
    if (act){
      c2 v[4];
      #pragma unroll
      for (int q=0;q<4;q++) v[q] = c2{av[q], 0.0f};
      dft4<-1>(v[0],v[1],v[2],v[3]);
      #pragma unroll
      for (int r=0;r<4;r++){ int p = SW2(4*j+r); s[p] = v[r].x; s[80+p] = v[r].y; }
    }
    wsync();
    if (act){
      c2 v[4];
      v[0] = c2{s[SW2(j)],    s[80+SW2(j)]};
      v[1] = cmulc(c2{s[SW2(j+16)], s[80+SW2(j+16)]}, w4);
      v[2] = cmulc(c2{s[SW2(j+32)], s[80+SW2(j+32)]}, w4b);
      v[3] = cmulc(c2{s[SW2(j+48)], s[80+SW2(j+48)]}, w4c);
      dft4<-1>(v[0],v[1],v[2],v[3]);
      #pragma unroll
      for (int r=0;r<4;r++){ int p = SW2(b4+4*r); s[160+p] = v[r].x; s[240+p] = v[r].y; }
    }
    wsync();
    if (act){
      c2 v[4];
      v[0] = c2{s[160+SW2(j)],    s[240+SW2(j)]};
      v[1] = cmulc(c2{s[160+SW2(j+16)], s[240+SW2(j+16)]}, w16);
      v[2] = cmulc(c2{s[160+SW2(j+32)], s[240+SW2(j+32)]}, w16b);
      v[3] = cmulc(c2{s[160+SW2(j+48)], s[240+SW2(j+48)]}, w16c);
      dft4<-1>(v[0],v[1],v[2],v[3]);
      #pragma unroll
      for (int r=0;r<4;r++){
        int kb = j + 16*r;
        c2 tw = cis(-TWO_PI * (float)(n1*kb) * (1.0f/40000.0f));
        c2 z = cmul(v[r], tw);
        tr[row*G2TF + kb] = z.x;
        ti[row*G2TF + kb] = z.y;
      }
    }
    __syncthreads();
    unsigned* op = outB + (size_t)arr*40000;
    if (rows == G2CH){
      for (int e = threadIdx.x; e < 64*G2CH; e += 256){
        int kb = e >> 4, i = e & 15;
        op[kb*625 + n1_0 + i] = pack_bf(c2{tr[i*G2TF + kb], ti[i*G2TF + kb]});
      }
    } else {
      for (int e = threadIdx.x; e < 64*rows; e += 256){
        int kb = e / rows, i = e - kb*rows;
        op[kb*625 + n1_0 + i] = pack_bf(c2{tr[i*G2TF + kb], ti[i*G2TF + kb]});
      }
    }
  }
}

// ---------------- 625-point row FFT (radix-5 Stockham) ----------------
// j1off: raw j1 offset. BLK: per-arr j1 count in this launch. istr: input task stride per arr
// (FILT2). scBase: output slot offset. Input task for FILT2: bt*istr + j1off + jloc.
template<int S, int FILT, int TW, int PIN, int POUT, int NB2, int NBI>
__global__ __launch_bounds__(128) void k_fft625(const void* __restrict__ inpv, void* __restrict__ outpv,
                                                const c2* __restrict__ Wg,
                                                int j1off, int BLK, int nj2, int j2base, int istr,
                                                int scBase, int kamax){
  __shared__ float l0r[625], l0i[625], l1r[625], l1i[625];
  int g = blockIdx.x;
  int i = g / NB2, kb = g - i*NB2;
  int j = threadIdx.x;
  const c2* ipc = (const c2*)inpv;
  const unsigned* ipu = (const unsigned*)inpv;
  size_t ibase;
  int j1 = 0, j2 = 0;
  if (FILT == 0){
    ibase = (size_t)i*(625ULL*(size_t)NB2) + (size_t)kb*NA;
  } else if (FILT == 1){
    int bt = i / BLK; j1 = j1off + (i - bt*BLK);
    ibase = (size_t)bt*(625ULL*(size_t)NBI);
  } else {
    int npb = BLK*nj2;
    int bt = i / npb, rr = i - bt*npb;
    int jloc = rr / nj2; j2 = j2base + (rr - jloc*nj2);
    int islot = bt*istr + j1off + jloc;
    ibase = (size_t)islot*(625ULL*(size_t)NBI);
  }
  float xi = 0.0f, sig = 0.0f, inv2s = 0.0f;
  int klo = 0, khi = 0;
  const float fscale = (FILT == 2 && NBI == 64) ? 4.0f : 1.0f;
  if (FILT != 0){
    if (FILT == 1){ xi = 0.4f * exp2f(-(float)j1 * 0.0625f); sig = xi * 0.04427378243f; }
    else          { xi = 0.4f * exp2f(-(float)j2);           sig = 0.35f * xi; }
    inv2s = 0.5f / (sig*sig);
    klo = (int)((xi - 6.0f*sig) * (float)TLEN); if (klo < 0) klo = 0;
    khi = (int)((xi + 6.0f*sig) * (float)TLEN) + 1; if (khi > TLEN/2 - 1) khi = TLEN/2 - 1;
    if (khi > 625*NB2 - 1) khi = 625*NB2 - 1;
  }
  c2 a[5], b[5];
  if (j < 125){
    if (FILT == 0){
      #pragma unroll
      for (int q=0;q<5;q++){
        size_t idx = ibase + j + 125*q;
        a[q] = PIN ? unpack_bf(ipu[idx]) : ipc[idx];
      }
      dft5<S>(a, b);
    } else {
      bool any = false;
      #pragma unroll
      for (int q=0;q<5;q++){
        int ka = j + 125*q;
        int k = kb + NB2*ka;
        c2 val = c2{0.0f, 0.0f};
        if (k >= klo && k <= khi){
          size_t idx = ibase + (size_t)(k % NBI)*NA + (size_t)(k / NBI);
          val = PIN ? unpack_bf(ipu[idx]) : ipc[idx];
          float d = (float)k * (1.0f/(float)TLEN) - xi;
          float f = fscale * __expf(-d*d*inv2s);
          val.x *= f; val.y *= f;
          any = true;
        }
        a[q] = val;
      }
      if (any){
        dft5<S>(a, b);
      } else {
        #pragma unroll
        for (int r=0;r<5;r++) b[r] = c2{0.0f,0.0f};
      }
    }
    #pragma unroll
    for (int r=0;r<5;r++){ int s = 5*j + r; l0r[s] = b[r].x; l0i[s] = b[r].y; }
  }
  __syncthreads();
  if (j < 125){ // L = 5
    int k = j % 5;
    c2 w  = Wg[25*k];  if (S<0) w.y  = -w.y;
    c2 w2 = Wg[50*k];  if (S<0) w2.y = -w2.y;
    c2 w3 = Wg[75*k];  if (S<0) w3.y = -w3.y;
    c2 w4 = Wg[100*k]; if (S<0) w4.y = -w4.y;
    a[0] = c2{l0r[j],     l0i[j]};
    a[1] = cmul(c2{l0r[j+125], l0i[j+125]}, w);
    a[2] = cmul(c2{l0r[j+250], l0i[j+250]}, w2);
    a[3] = cmul(c2{l0r[j+375], l0i[j+375]}, w3);
    a[4] = cmul(c2{l0r[j+500], l0i[j+500]}, w4);
    dft5<S>(a, b);
    int base = 5*(j-k)+k;
    #pragma unroll
    for (int r=0;r<5;r++){ int s = base + 5*r; l1r[s] = b[r].x; l1i[s] = b[r].y; }
  }
  __syncthreads();
  if (j < 125){ // L = 25
    int k = j % 25;
    c2 w  = Wg[5*k];   if (S<0) w.y  = -w.y;
    c2 w2 = Wg[10*k];  if (S<0) w2.y = -w2.y;
    c2 w3 = Wg[15*k];  if (S<0) w3.y = -w3.y;
    c2 w4 = Wg[20*k];  if (S<0) w4.y = -w4.y;
    a[0] = c2{l1r[j],     l1i[j]};
    a[1] = cmul(c2{l1r[j+125], l1i[j+125]}, w);
    a[2] = cmul(c2{l1r[j+250], l1i[j+250]}, w2);
    a[3] = cmul(c2{l1r[j+375], l1i[j+375]}, w3);
    a[4] = cmul(c2{l1r[j+500], l1i[j+500]}, w4);
    dft5<S>(a, b);
    int base = 5*(j-k)+k;
    #pragma unroll
    for (int r=0;r<5;r++){ int s = base + 25*r; l0r[s] = b[r].x; l0i[s] = b[r].y; }
  }
  __syncthreads();
  if (j < 125){ // L = 125
    c2 w = Wg[j]; if (S<0) w.y = -w.y;
    c2 w2 = cmul(w,w), w3 = cmul(w2,w), w4 = cmul(w2,w2);
    a[0] = c2{l0r[j],     l0i[j]};
    a[1] = cmul(c2{l0r[j+125], l0i[j+125]}, w);
    a[2] = cmul(c2{l0r[j+250], l0i[j+250]}, w2);
    a[3] = cmul(c2{l0r[j+375], l0i[j+375]}, w3);
    a[4] = cmul(c2{l0r[j+500], l0i[j+500]}, w4);
    dft5<S>(a, b);
    size_t obase = (size_t)(scBase + i)*(625ULL*(size_t)NB2) + (size_t)kb*NA;
    if (TW){
      const float invM = 1.0f/(625.0f*(float)NB2);
      c2 twb = cis((float)S * TWO_PI * (float)(j*kb)   * invM);
      c2 tws = cis((float)S * TWO_PI * (float)(125*kb) * invM);
      #pragma unroll
      for (int r=0;r<5;r++){
        int n1 = j + 125*r;
        c2 z = cmul(b[r], twb);
        if (POUT) ((unsigned*)outpv)[obase + n1] = pack_bf(z);
        else      ((c2*)outpv)[obase + n1] = z;
        twb = cmul(twb, tws);
      }
    } else {
      #pragma unroll
      for (int r=0;r<5;r++){
        int n1 = j + 125*r;
        if (n1 <= kamax){
          if (POUT) ((unsigned*)outpv)[obase + n1] = pack_bf(b[r]);
          else      ((c2*)outpv)[obase + n1] = b[r];
        }
      }
    }
  }
}

// ---------------- complex transpose (x-chain only) ----------------
__global__ __launch_bounds__(256) void k_transpose(const c2* __restrict__ in, c2* __restrict__ out,
                                                   int R, int C, int tilesR, int tilesC){
  __shared__ c2 tile[32][33];
  int bi = blockIdx.x;
  int arr = bi / (tilesR*tilesC);
  int tt = bi - arr*(tilesR*tilesC);
  int tr = tt / tilesC, tc = tt - tr*tilesC;
  const c2* ip = in + (size_t)arr*TLEN;
  c2* op = out + (size_t)arr*TLEN;
  int tx = threadIdx.x & 31, ty = threadIdx.x >> 5;
  #pragma unroll
  for (int i=0;i<4;i++){
    int r = tr*32 + ty + i*8, cc = tc*32 + tx;
    if (r < R && cc < C) tile[ty+i*8][tx] = ip[(size_t)r*C + cc];
  }
  __syncthreads();
  #pragma unroll
  for (int i=0;i<4;i++){
    int r = tc*32 + ty + i*8, cc = tr*32 + tx;
    if (r < C && cc < R) op[(size_t)r*R + cc] = tile[tx][ty+i*8];
  }
}

// ---------------- Gaussian lowpass + decimate-by-64, natural layout (S0 only) ----------------
__global__ __launch_bounds__(256) void k_conv(const float* __restrict__ inp, float* __restrict__ S){
  __shared__ float w[NTAP];
  for (int i=threadIdx.x; i<NTAP; i+=256){
    float d = (float)(i - KC);
    w[i] = 0.015666427f * __expf(-7.7106284e-4f * d * d);
  }
  __syncthreads();
  int g = blockIdx.x;
  int arr = g / 10;
  int t = (g - arr*10)*256 + threadIdx.x;
  if (t >= TD) return;
  int srow = arr * SROWS;
  const float* ip = inp + (size_t)arr*TLEN;
  float acc = 0.0f;
  int n = 64*t - KC; if (n < 0) n += TLEN;
  for (int m=0;m<NTAP;m++){
    acc += ip[n] * w[m];
    n++; if (n == TLEN) n = 0;
  }
  S[(size_t)srow*TD + t] = acc;
}

// ---------------- fused LDS stage + conv, full-rate scrambled U (bf16 input) ----------------
#define CONV_NCOL 27
#define CONV_NU   16875
#define CONV_USZ  17138
#define CONV_LDSB ((CONV_USZ + NTAP + 1)*4)
template<int MODE>
__global__ __launch_bounds__(256) void k_conv2(const unsigned short* __restrict__ inp, float* __restrict__ S,
                                               int j1off, int BLK, int nj2, int j2base, int scBase){
  extern __shared__ float smem[];
  float* u = smem;
  float* w = smem + CONV_USZ;
  for (int i=threadIdx.x; i<NTAP; i+=256){
    float d = (float)(i - KC);
    w[i] = 0.015666427f * __expf(-7.7106284e-4f * d * d);
  }
  int g = blockIdx.x;
  int arr = g / 10;
  int b = g - arr*10;
  int nlo = 16000*b - KC;
  int n2_0 = (nlo >= 0) ? (nlo/625) : -1;
  const unsigned short* ip = inp + (size_t)arr*TLEN;
  for (int e = threadIdx.x; e < CONV_NU; e += 256){
    int n1 = e / CONV_NCOL;
    int c  = e - n1*CONV_NCOL;
    int n2 = n2_0 + c;
    n2 &= 255;
    u[SW64(n1 + 625*c)] = bf2f(ip[n1*NB + n2]);
  }
  __syncthreads();
  int tl = threadIdx.x;
  if (tl >= 250) return;
  int t = 250*b + tl;
  int srow;
  if (MODE == 1){
    int a2 = arr / BLK; int j1 = j1off + (arr - a2*BLK);
    srow = a2*SROWS + 1 + j1;
  } else {
    int g2 = scBase + arr; int npb = BLK*nj2;
    int a2 = g2/npb, rr = g2 - a2*npb;
    int jloc = rr/nj2; int j2 = j2base + (rr - jloc*nj2);
    int j1 = j1off + jloc;
    int full = j1 >> 4;
    int cum = 16*(5*full - (full*(full-1))/2) + (j1 & 15)*(5 - full);
    int P = cum + j2 - full - 1;
    srow = a2*SROWS + 97 + P;
  }
  int base = 64*t - KC - 625*n2_0;
  float acc = 0.0f;
  #pragma unroll 4
  for (int m=0;m<NTAP;m++){
    acc += u[SW64(base + m)] * w[m];
  }
  S[(size_t)srow*TD + t] = acc;
}

// ---------------- decimated conv (D=4): input Ur_dec[n1<625][n2<64], M=40000 ----------------
// MODE 1: S1 rows (j1 = j1off + t%BLK, arr = t/BLK). MODE 3: srow from table[path].
#define C2NU  5000
#define C2USZ 5312
template<int MODE>
__global__ __launch_bounds__(256) void k_conv2d(const unsigned short* __restrict__ inp, float* __restrict__ S,
                                                int j1off, int BLK, const int* __restrict__ srowTab){
  __shared__ float u[C2USZ];
  __shared__ float w[72];
  if (threadIdx.x < 65){
    float d = 4.0f * (float)((int)threadIdx.x - 32);
    w[threadIdx.x] = 0.062665708f * __expf(-7.7106284e-4f * d * d);
  }
  int g = blockIdx.x;
  int arr = g / 10;
  int b = g - arr*10;
  int mlo = 4000*b - 32;
  int n2_0 = (mlo >= 0) ? (mlo/625) : -1;
  const unsigned short* ip = inp + (size_t)arr*40000;
  for (int e = threadIdx.x; e < C2NU; e += 256){
    int n1 = e >> 3, c = e & 7;
    int n2 = (n2_0 + c) & 63;
    u[SW16(n1 + 625*c)] = bf2f(ip[n1*64 + n2]);
  }
  __syncthreads();
  int tl = threadIdx.x;
  if (tl >= 250) return;
  int t = 250*b + tl;
  int srow;
  if (MODE == 1){
    int a2 = arr / BLK; int j1 = j1off + (arr - a2*BLK);
    srow = a2*SROWS + 1 + j1;
  } else {
    srow = srowTab[arr];
  }
  int base = (4000*b - 32 - 625*n2_0) + 16*tl;
  float acc = 0.0f;
  #pragma unroll 5
  for (int m=0;m<65;m++){
    acc += u[SW16(base + m)] * w[m];
  }
  S[(size_t)srow*TD + t] = acc;
}

// ---------------- global min/max + finalize ----------------
__global__ __launch_bounds__(256) void k_minmax1(const float* __restrict__ S, int n, float* pmn, float* pmx){
  __shared__ float smn[256], smx[256];
  float mn = 3.4028235e38f, mx = -3.4028235e38f;
  for (size_t i = (size_t)blockIdx.x*256 + threadIdx.x; i < (size_t)n; i += (size_t)gridDim.x*256){
    float v = S[i]; mn = fminf(mn,v); mx = fmaxf(mx,v);
  }
  smn[threadIdx.x]=mn; smx[threadIdx.x]=mx; __syncthreads();
  for (int s=128;s>0;s>>=1){
    if ((int)threadIdx.x < s){
      smn[threadIdx.x]=fminf(smn[threadIdx.x],smn[threadIdx.x+s]);
      smx[threadIdx.x]=fmaxf(smx[threadIdx.x],smx[threadIdx.x+s]);
    }
    __syncthreads();
  }
  if (threadIdx.x==0){ pmn[blockIdx.x]=smn[0]; pmx[blockIdx.x]=smx[0]; }
}
__global__ __launch_bounds__(256) void k_minmax2(const float* __restrict__ pmn, const float* __restrict__ pmx,
                                                 int nb, float* scal){
  __shared__ float smn[256], smx[256];
  float mn = 3.4028235e38f, mx = -3.4028235e38f;
  for (int i = threadIdx.x; i < nb; i += 256){ mn = fminf(mn,pmn[i]); mx = fmaxf(mx,pmx[i]); }
  smn[threadIdx.x]=mn; smx[threadIdx.x]=mx; __syncthreads();
  for (int s=128;s>0;s>>=1){
    if ((int)threadIdx.x < s){
      smn[threadIdx.x]=fminf(smn[threadIdx.x],smn[threadIdx.x+s]);
      smx[threadIdx.x]=fmaxf(smx[threadIdx.x],smx[threadIdx.x+s]);
    }
    __syncthreads();
  }
  if (threadIdx.x==0){ scal[0]=smn[0]; scal[1]=smx[0]; }
}
__global__ __launch_bounds__(256) void k_final(const float* __restrict__ S, const float* __restrict__ scal,
                                               float* __restrict__ out, int n){
  int i = blockIdx.x*256 + threadIdx.x;
  if (i >= n) return;
  float mn = scal[0];
  float r = scal[1] - mn;
  if (r == 0.0f) r = 1.0f;
  int half = SROWS*TD;
  int a = i / half; int rest = i - a*half;
  out[i] = (S[(size_t)(a & 1)*half + rest] - mn) / r;
}

extern "C" void kernel_launch(void* const* d_in, const int* in_sizes, int n_in,
                              void* d_out, int out_size, void* d_ws, size_t ws_size,
                              hipStream_t stream){
  (void)in_sizes; (void)n_in;
  const float* x = (const float*)d_in[0];

  // workspace budget (fixed structure): ~189 MB
  {
    size_t need = 2560000ULL + 3ULL*25600000ULL + 66560000ULL + 33280000ULL
                + 6740000ULL + 16384ULL + 8192ULL;
    if (ws_size < need) return;
  }

  char* p = (char*)d_ws;
  auto carve = [&](size_t bytes)->void*{ void* r = (void*)p; p += (bytes + 255) & ~(size_t)255; return r; };
  c2*             Xf  = (c2*)carve(2ULL*TLEN*sizeof(c2));
  unsigned*       A1  = (unsigned*)carve(160ULL*40000*4);     // dec slots (>= c0 full 32*160000*4? no: 25.6MB > 20.5MB OK)
  unsigned*       B   = (unsigned*)carve(160ULL*40000*4);
  unsigned*       U1h = (unsigned*)carve(160ULL*40000*4);
  unsigned*       A2  = (unsigned*)carve(416ULL*40000*4);     // >= c0 full-rate 64*160000*4
  unsigned short* Ur  = (unsigned short*)carve(416ULL*40000*2);
  float*          Sb  = (float*)carve(2ULL*SROWS*TD*sizeof(float));
  c2*             Wg  = (c2*)carve(625*sizeof(c2));
  int*            ptab = (int*)carve(416*4);
  float*          pmn = (float*)carve(512*4);
  float*          pmx = (float*)carve(512*4);
  float*          scal = (float*)carve(256);

  k_wlut<<<3, 256, 0, stream>>>(Wg);
  k_ptab<<<2, 256, 0, stream>>>(ptab);

  // ---- forward FFT of x -> Xf (A2 reused as c2 scratch) ----
  k_fft256<-1,2,0><<<2*NA, 64, 0, stream>>>((const void*)x, (void*)A2);
  k_transpose<<<2*20*8, 256, 0, stream>>>((c2*)A2, (c2*)U1h, NA, NB, 20, 8);
  k_fft625<-1,0,0,0,0,256,256><<<2*NB, 128, 0, stream>>>((const void*)U1h, (void*)Xf, Wg, 0,0,0,0,0,0, 314);
  // ---- S0 ----
  k_conv<<<2*10, 256, 0, stream>>>(x, Sb);

  // ================= c-block 0 (j1 0..15): full-rate =================
  {
    int khi1 = (int)(3.1f * 0.2f * 160000.0f) + 1;          // widest psi2 (j2=1)
    int kamax0 = (khi1 >> 8) + 1; if (kamax0 > 624) kamax0 = 624;
    k_fft625<1,1,1,0,1,256,256><<<32*256, 128, 0, stream>>>((const void*)Xf, (void*)A1, Wg, 0, 16, 0,0,0,0, 624);
    k_fft256g<1,1><<<32*GNCH, 256, G_LDSB, stream>>>((const void*)A1, Ur, B);
    k_conv2<1><<<32*10, 256, CONV_LDSB, stream>>>(Ur, Sb, 0, 16, 0,0,0);
    k_fft625<-1,0,0,1,1,256,256><<<32*256, 128, 0, stream>>>((const void*)B, (void*)U1h, Wg, 0,0,0,0,0,0, kamax0);
    // j2 = 1,2 full-rate
    k_fft625<1,2,1,1,1,256,256><<<2*32*256, 128, 0, stream>>>((const void*)U1h, (void*)A2, Wg, 0, 16, 2, 1, 16, 0, 624);
    k_fft256g<0,1><<<2*32*GNCH, 256, G_LDSB, stream>>>((const void*)A2, Ur, (unsigned*)nullptr);
    k_conv2<2><<<2*32*10, 256, CONV_LDSB, stream>>>(Ur, Sb, 0, 16, 2, 1, 0);
    // j2 = 3,4,5 decimated -> A2 path slots [320,416)
    k_fft625<1,2,1,1,1,64,256><<<3*32*64, 128, 0, stream>>>((const void*)U1h, (void*)A2, Wg, 0, 16, 3, 3, 16, 320, 624);
  }

  // ================= batched decimated cascade (j1 16..95) =================
  k_fft625<1,1,1,0,1,64,256><<<160*64, 128, 0, stream>>>((const void*)Xf, (void*)A1, Wg, 16, 80, 0,0,0,0, 624);
  k_fft64g<1><<<160*G2N, 256, 0, stream>>>(A1, Ur, B);
  k_conv2d<1><<<160*10, 256, 0, stream>>>(Ur, Sb, 16, 80, (const int*)nullptr);
  k_fft625<-1,0,0,1,1,64,64><<<160*64, 128, 0, stream>>>((const void*)B, (void*)U1h, Wg, 0,0,0,0,0,0, 624);
  // FILT2 per c-block (uniform nj2), output flat path slots
  {
    int base = 0;
    for (int c = 1; c <= 4; c++){
      int nj2 = 5 - c;
      k_fft625<1,2,1,1,1,64,64><<<nj2*32*64, 128, 0, stream>>>((const void*)U1h, (void*)A2, Wg,
                                                               16*(c-1), 16, nj2, c+1, 80, base, 624);
      base += 32*nj2;
    }
  }
  // ---- all 416 decimated S2 paths: ifft64+abs, then conv ----
  k_fft64g<0><<<416*G2N, 256, 0, stream>>>(A2, Ur, (unsigned*)nullptr);
  k_conv2d<3><<<416*10, 256, 0, stream>>>(Ur, Sb, 0, 0, ptab);

  // ---- global min-max normalize (standardize cancels) + tile(3,1,1) ----
  k_minmax1<<<512, 256, 0, stream>>>(Sb, 2*SROWS*TD, pmn, pmx);
  k_minmax2<<<1, 256, 0, stream>>>(pmn, pmx, 512, scal);
  k_final<<<(out_size+255)/256, 256, 0, stream>>>(Sb, scal, (float*)d_out, out_size);
}

// Round 22
// 395.861 us; speedup vs baseline: 3.5216x; 1.2578x over previous
//
#include <hip/hip_runtime.h>
#include <math.h>

#define TLEN 160000
#define NA 625
#define NB 256
#define TD 2500
#define KC 128
#define NTAP 257
#define SROWS 337
#define TWO_PI 6.283185307179586f

struct c2 { float x, y; };

__device__ __forceinline__ c2 cmul(c2 a, c2 b){ return c2{a.x*b.x - a.y*b.y, a.x*b.y + a.y*b.x}; }
__device__ __forceinline__ c2 cmulc(c2 a, c2 b){ return c2{a.x*b.x + a.y*b.y, a.y*b.x - a.x*b.y}; }
__device__ __forceinline__ c2 cadd(c2 a, c2 b){ return c2{a.x+b.x, a.y+b.y}; }
__device__ __forceinline__ c2 csub(c2 a, c2 b){ return c2{a.x-b.x, a.y-b.y}; }
__device__ __forceinline__ c2 cmac(c2 acc, c2 v, float wr, float wi){
  acc.x += v.x*wr - v.y*wi; acc.y += v.x*wi + v.y*wr; return acc;
}
__device__ __forceinline__ c2 cis(float ang){ c2 r; __sincosf(ang, &r.y, &r.x); return r; }
__device__ __forceinline__ int SW(int i){ return i + (i >> 4); }
__device__ __forceinline__ int SW2(int i){ return i + (i >> 2); }
__device__ __forceinline__ int SW16(int i){ return i + (i >> 4); }
__device__ __forceinline__ int SW64(int i){ return i + (i >> 6); }
__device__ __forceinline__ unsigned pack_bf(c2 z){
  unsigned xr = __float_as_uint(z.x), xi = __float_as_uint(z.y);
  xr += 0x8000u + ((xr >> 16) & 1u);
  xi += 0x8000u + ((xi >> 16) & 1u);
  return (xr >> 16) | (xi & 0xFFFF0000u);
}
__device__ __forceinline__ c2 unpack_bf(unsigned p){
  return c2{ __uint_as_float(p << 16), __uint_as_float(p & 0xFFFF0000u) };
}
__device__ __forceinline__ unsigned short f2bf(float f){
  unsigned u = __float_as_uint(f);
  u += 0x8000u + ((u >> 16) & 1u);
  return (unsigned short)(u >> 16);
}
__device__ __forceinline__ float bf2f(unsigned short h){
  return __uint_as_float(((unsigned)h) << 16);
}
__device__ __forceinline__ void wsync(){
  __builtin_amdgcn_wave_barrier();
  asm volatile("s_waitcnt lgkmcnt(0)" ::: "memory");
  __builtin_amdgcn_wave_barrier();
}

template<int S>
__device__ __forceinline__ void dft4(c2& a0, c2& a1, c2& a2, c2& a3){
  c2 t0 = cadd(a0,a2), t1 = csub(a0,a2), t2 = cadd(a1,a3), t3 = csub(a1,a3);
  float fs = (float)S;
  a0 = cadd(t0,t2); a2 = csub(t0,t2);
  a1 = c2{t1.x - fs*t3.y, t1.y + fs*t3.x};
  a3 = c2{t1.x + fs*t3.y, t1.y - fs*t3.x};
}

template<int S>
__device__ __forceinline__ void dft5(const c2 a[5], c2 b[5]){
  const float C1 = 0.30901699437494742f, C2 = -0.80901699437494745f;
  const float S1 = 0.95105651629515353f * (float)S, S2 = 0.58778525229247314f * (float)S;
  b[0] = cadd(cadd(a[0],a[1]), cadd(cadd(a[2],a[3]),a[4]));
  c2 r;
  r = a[0]; r = cmac(r,a[1],C1, S1); r = cmac(r,a[2],C2, S2); r = cmac(r,a[3],C2,-S2); r = cmac(r,a[4],C1,-S1); b[1]=r;
  r = a[0]; r = cmac(r,a[1],C2, S2); r = cmac(r,a[2],C1,-S1); r = cmac(r,a[3],C1, S1); r = cmac(r,a[4],C2,-S2); b[2]=r;
  r = a[0]; r = cmac(r,a[1],C2,-S2); r = cmac(r,a[2],C1, S1); r = cmac(r,a[3],C1,-S1); r = cmac(r,a[4],C2, S2); b[3]=r;
  r = a[0]; r = cmac(r,a[1],C1,-S1); r = cmac(r,a[2],C2,-S2); r = cmac(r,a[3],C2, S2); r = cmac(r,a[4],C1, S1); b[4]=r;
}

// ---------------- W625 global LUT init ----------------
__global__ __launch_bounds__(256) void k_wlut(c2* __restrict__ W){
  int m = blockIdx.x*256 + threadIdx.x;
  if (m < 625) W[m] = cis(TWO_PI * (float)m * (1.0f/625.0f));
}

// ---------------- srow table for the 448 S2 conv2d<3> paths ----------------
__global__ __launch_bounds__(256) void k_ptab(int* __restrict__ tab){
  int p = blockIdx.x*256 + threadIdx.x;
  if (p >= 448) return;
  int arr, j1, j2;
  if (p < 128){
    arr = p / 64;
    int rr = p - arr*64;
    j1 = rr >> 2;
    j2 = 2 + (rr & 3);
  } else {
    int q = p - 128;
    int c = 1, base = 0;
    while (c < 4 && q >= base + 32*(5-c)){ base += 32*(5-c); c++; }
    int loc = q - base;
    int nj2 = 5 - c;
    int npb = 16*nj2;
    arr = loc / npb;
    int rr = loc - arr*npb;
    int jloc = rr / nj2;
    j2 = (c+1) + (rr - jloc*nj2);
    j1 = 16*c + jloc;
  }
  int full = j1 >> 4;
  int cum = 16*(5*full - (full*(full-1))/2) + (j1 & 15)*(5 - full);
  int P = cum + j2 - full - 1;
  tab[p] = arr*SROWS + 97 + P;
}

// ---------------- 256-point row FFT (x-chain only) ----------------
template<int S, int INMODE, int OUTMODE>
__global__ __launch_bounds__(64) void k_fft256(const void* __restrict__ inp, void* __restrict__ outp){
  __shared__ c2 lds[2][272];
  int g = blockIdx.x;
  int arr = g / NA, n1 = g - arr*NA;
  int j = threadIdx.x;
  c2 v[4];
  if (INMODE == 0){
    const c2* ip = (const c2*)inp + (size_t)arr*TLEN + (size_t)n1*NB;
    #pragma unroll
    for (int q=0;q<4;q++) v[q] = ip[j + 64*q];
  } else if (INMODE == 1){
    const float* ip = (const float*)inp + (size_t)arr*TLEN + (size_t)n1*NB;
    #pragma unroll
    for (int q=0;q<4;q++) v[q] = c2{ip[j + 64*q], 0.0f};
  } else {
    const float* ip = (const float*)inp + (size_t)arr*TLEN;
    #pragma unroll
    for (int q=0;q<4;q++) v[q] = c2{ip[n1 + NA*(j + 64*q)], 0.0f};
  }
  dft4<S>(v[0],v[1],v[2],v[3]);
  #pragma unroll
  for (int r=0;r<4;r++) lds[0][SW(4*j + r)] = v[r];
  wsync();
  { // L = 4
    int k = j & 3;
    c2 w = cis((float)S * TWO_PI * (float)k * (1.0f/16.0f));
    c2 w2 = cmul(w,w), w3 = cmul(w2,w);
    v[0] = lds[0][SW(j)];
    v[1] = cmul(lds[0][SW(j+64)], w);
    v[2] = cmul(lds[0][SW(j+128)], w2);
    v[3] = cmul(lds[0][SW(j+192)], w3);
    dft4<S>(v[0],v[1],v[2],v[3]);
    int base = 4*(j-k)+k;
    #pragma unroll
    for (int r=0;r<4;r++) lds[1][SW(base + 4*r)] = v[r];
  }
  wsync();
  { // L = 16
    int k = j & 15;
    c2 w = cis((float)S * TWO_PI * (float)k * (1.0f/64.0f));
    c2 w2 = cmul(w,w), w3 = cmul(w2,w);
    v[0] = lds[1][SW(j)];
    v[1] = cmul(lds[1][SW(j+64)], w);
    v[2] = cmul(lds[1][SW(j+128)], w2);
    v[3] = cmul(lds[1][SW(j+192)], w3);
    dft4<S>(v[0],v[1],v[2],v[3]);
    int base = 4*(j-k)+k;
    #pragma unroll
    for (int r=0;r<4;r++) lds[0][SW(base + 16*r)] = v[r];
  }
  wsync();
  { // L = 64
    c2 w = cis((float)S * TWO_PI * (float)j * (1.0f/256.0f));
    c2 w2 = cmul(w,w), w3 = cmul(w2,w);
    v[0] = lds[0][SW(j)];
    v[1] = cmul(lds[0][SW(j+64)], w);
    v[2] = cmul(lds[0][SW(j+128)], w2);
    v[3] = cmul(lds[0][SW(j+192)], w3);
    dft4<S>(v[0],v[1],v[2],v[3]);
    if (OUTMODE == 0){
      c2* op = (c2*)outp + (size_t)arr*TLEN + (size_t)n1*NB;
      #pragma unroll
      for (int r=0;r<4;r++){
        int kb = j + 64*r;
        c2 tw = cis((float)S * TWO_PI * (float)(n1*kb) * (1.0f/160000.0f));
        op[kb] = cmul(v[r], tw);
      }
    } else {
      float* op = (float*)outp + (size_t)arr*TLEN + (size_t)n1*NB;
      #pragma unroll
      for (int r=0;r<4;r++){
        c2 z = v[r];
        op[j + 64*r] = sqrtf(z.x*z.x + z.y*z.y) * (1.0f/160000.0f);
      }
    }
  }
}

// ---------------- fused gather + inverse 64-FFT + abs (+ optional forward 64-FFT -> B) ------
#define G2CH  16
#define G2N   40
#define G2TF  73
#define G2RS  328
template<int WRITEB>
__global__ __launch_bounds__(256) void k_fft64g(const unsigned* __restrict__ inp, unsigned short* __restrict__ outp,
                                                unsigned* __restrict__ outB){
  __shared__ float smem[2*G2CH*G2TF + G2CH*G2RS];
  float* tr = smem;
  float* ti = smem + G2CH*G2TF;
  float* scr = smem + 2*G2CH*G2TF;
  int g = blockIdx.x;
  int arr = g / G2N, chunk = g - arr*G2N;
  int n1_0 = chunk*G2CH;
  int rows = 625 - n1_0; if (rows > G2CH) rows = G2CH;
  const unsigned* ip = inp + (size_t)arr*40000;
  if (rows == G2CH){
    for (int e = threadIdx.x; e < 64*G2CH; e += 256){
      int kb = e >> 4, i = e & 15;
      c2 z = unpack_bf(ip[kb*625 + n1_0 + i]);
      tr[i*G2TF + kb] = z.x; ti[i*G2TF + kb] = z.y;
    }
  } else {
    for (int e = threadIdx.x; e < 64*rows; e += 256){
      int kb = e / rows, i = e - kb*rows;
      c2 z = unpack_bf(ip[kb*625 + n1_0 + i]);
      tr[i*G2TF + kb] = z.x; ti[i*G2TF + kb] = z.y;
    }
  }
  __syncthreads();
  int row = threadIdx.x >> 4;
  int j   = threadIdx.x & 15;
  bool act = row < rows;
  int n1 = n1_0 + row;
  float* s = scr + row*G2RS;
  c2 w4  = cis(TWO_PI * (float)(j & 3) * (1.0f/16.0f));
  c2 w4b = cmul(w4,w4), w4c = cmul(w4b,w4);
  c2 w16 = cis(TWO_PI * (float)j * (1.0f/64.0f));
  c2 w16b= cmul(w16,w16), w16c= cmul(w16b,w16);
  int b4 = 4*(j-(j&3))+(j&3);
  float av[4];
  if (act){
    c2 v[4];
    #pragma unroll
    for (int q=0;q<4;q++) v[q] = c2{tr[row*G2TF + j + 16*q], ti[row*G2TF + j + 16*q]};
    dft4<1>(v[0],v[1],v[2],v[3]);
    #pragma unroll
    for (int r=0;r<4;r++){ int p = SW2(4*j+r); s[p] = v[r].x; s[80+p] = v[r].y; }
  }
  wsync();
  if (act){ // L = 4
    c2 v[4];
    v[0] = c2{s[SW2(j)],    s[80+SW2(j)]};
    v[1] = cmul(c2{s[SW2(j+16)], s[80+SW2(j+16)]}, w4);
    v[2] = cmul(c2{s[SW2(j+32)], s[80+SW2(j+32)]}, w4b);
    v[3] = cmul(c2{s[SW2(j+48)], s[80+SW2(j+48)]}, w4c);
    dft4<1>(v[0],v[1],v[2],v[3]);
    #pragma unroll
    for (int r=0;r<4;r++){ int p = SW2(b4+4*r); s[160+p] = v[r].x; s[240+p] = v[r].y; }
  }
  wsync();
  if (act){ // L = 16 + abs
    c2 v[4];
    v[0] = c2{s[160+SW2(j)],    s[240+SW2(j)]};
    v[1] = cmul(c2{s[160+SW2(j+16)], s[240+SW2(j+16)]}, w16);
    v[2] = cmul(c2{s[160+SW2(j+32)], s[240+SW2(j+32)]}, w16b);
    v[3] = cmul(c2{s[160+SW2(j+48)], s[240+SW2(j+48)]}, w16c);
    dft4<1>(v[0],v[1],v[2],v[3]);
    unsigned short* op = outp + (size_t)arr*40000 + (size_t)n1*64;
    #pragma unroll
    for (int r=0;r<4;r++){
      c2 z = v[r];
      av[r] = sqrtf(z.x*z.x + z.y*z.y) * (1.0f/160000.0f);
      op[j + 16*r] = f2bf(av[r]);
    }
  }
  if (WRITEB){
    wsync();
    if (act){
      c2 v[4];
      #pragma unroll
      for (int q=0;q<4;q++) v[q] = c2{av[q], 0.0f};
      dft4<-1>(v[0],v[1],v[2],v[3]);
      #pragma unroll
      for (int r=0;r<4;r++){ int p = SW2(4*j+r); s[p] = v[r].x; s[80+p] = v[r].y; }
    }
    wsync();
    if (act){
      c2 v[4];
      v[0] = c2{s[SW2(j)],    s[80+SW2(j)]};
      v[1] = cmulc(c2{s[SW2(j+16)], s[80+SW2(j+16)]}, w4);
      v[2] = cmulc(c2{s[SW2(j+32)], s[80+SW2(j+32)]}, w4b);
      v[3] = cmulc(c2{s[SW2(j+48)], s[80+SW2(j+48)]}, w4c);
      dft4<-1>(v[0],v[1],v[2],v[3]);
      #pragma unroll
      for (int r=0;r<4;r++){ int p = SW2(b4+4*r); s[160+p] = v[r].x; s[240+p] = v[r].y; }
    }
    wsync();
    if (act){
      c2 v[4];
      v[0] = c2{s[160+SW2(j)],    s[240+SW2(j)]};
      v[1] = cmulc(c2{s[160+SW2(j+16)], s[240+SW2(j+16)]}, w16);
      v[2] = cmulc(c2{s[160+SW2(j+32)], s[240+SW2(j+32)]}, w16b);
      v[3] = cmulc(c2{s[160+SW2(j+48)], s[240+SW2(j+48)]}, w16c);
      dft4<-1>(v[0],v[1],v[2],v[3]);
      #pragma unroll
      for (int r=0;r<4;r++){
        int kb = j + 16*r;
        c2 tw = cis(-TWO_PI * (float)(n1*kb) * (1.0f/40000.0f));
        c2 z = cmul(v[r], tw);
        tr[row*G2TF + kb] = z.x;
        ti[row*G2TF + kb] = z.y;
      }
    }
    __syncthreads();
    unsigned* op = outB + (size_t)arr*40000;
    if (rows == G2CH){
      for (int e = threadIdx.x; e < 64*G2CH; e += 256){
        int kb = e >> 4, i = e & 15;
        op[kb*625 + n1_0 + i] = pack_bf(c2{tr[i*G2TF + kb], ti[i*G2TF + kb]});
      }
    } else {
      for (int e = threadIdx.x; e < 64*rows; e += 256){
        int kb = e / rows, i = e - kb*rows;
        op[kb*625 + n1_0 + i] = pack_bf(c2{tr[i*G2TF + kb], ti[i*G2TF + kb]});
      }
    }
  }
}

// ---------------- 625-point row FFT (radix-5 Stockham) ----------------
// FILT: 0 none, 1 psi1 (FOLD: +ψX[k+40000], QPH: odd-phase twist),
//       2 psi2 from U1h (NBI grid), 3 psi2 from completed 2-phase spectra F0/F2 (c0).
// FILT3 input layout: completed 40000-pt spectra, idx(k) = (k%64)*625 + k/64;
//       F0 at slot (arr*16+j1), F2 at +32 slots (=+1280000 elems).
template<int S, int FILT, int TW, int PIN, int POUT, int NB2, int NBI, int FOLD, int QPH>
__global__ __launch_bounds__(128) void k_fft625(const void* __restrict__ inpv, void* __restrict__ outpv,
                                                const c2* __restrict__ Wg,
                                                int j1off, int BLK, int nj2, int j2base, int istr,
                                                int scBase, int kamax){
  __shared__ float l0r[625], l0i[625], l1r[625], l1i[625];
  int g = blockIdx.x;
  int i = g / NB2, kb = g - i*NB2;
  int j = threadIdx.x;
  const c2* ipc = (const c2*)inpv;
  const unsigned* ipu = (const unsigned*)inpv;
  size_t ibase;
  int j1 = 0, j2 = 0;
  if (FILT == 0){
    ibase = (size_t)i*(625ULL*(size_t)NB2) + (size_t)kb*NA;
  } else if (FILT == 1){
    int bt = i / BLK; j1 = j1off + (i - bt*BLK);
    ibase = (size_t)bt*(625ULL*(size_t)NBI);
  } else if (FILT == 2){
    int npb = BLK*nj2;
    int bt = i / npb, rr = i - bt*npb;
    int jloc = rr / nj2; j2 = j2base + (rr - jloc*nj2);
    int islot = bt*istr + j1off + jloc;
    ibase = (size_t)islot*(625ULL*(size_t)NBI);
  } else { // FILT 3: completed-spectrum slot space (40000 each)
    int npb = BLK*nj2;
    int bt = i / npb, rr = i - bt*npb;
    int jloc = rr / nj2; j2 = j2base + (rr - jloc*nj2);
    int islot = bt*BLK + jloc;
    ibase = (size_t)islot*40000ULL;
  }
  float xi = 0.0f, sig = 0.0f, inv2s = 0.0f;
  int klo = 0, khi = 0;
  const float fscale = (FILT == 2 && NBI == 64) ? 4.0f : 1.0f;
  if (FILT != 0){
    if (FILT == 1){ xi = 0.4f * exp2f(-(float)j1 * 0.0625f); sig = xi * 0.04427378243f; }
    else          { xi = 0.4f * exp2f(-(float)j2);           sig = 0.35f * xi; }
    inv2s = 0.5f / (sig*sig);
    klo = (int)((xi - 6.0f*sig) * (float)TLEN); if (klo < 0) klo = 0;
    khi = (int)((xi + 6.0f*sig) * (float)TLEN) + 1; if (khi > TLEN/2 - 1) khi = TLEN/2 - 1;
    if (FILT != 3 && !FOLD){
      if (khi > 625*NB2 - 1) khi = 625*NB2 - 1;
    }
  }
  c2 a[5], b[5];
  if (j < 125){
    if (FILT == 0){
      #pragma unroll
      for (int q=0;q<5;q++){
        size_t idx = ibase + j + 125*q;
        a[q] = PIN ? unpack_bf(ipu[idx]) : ipc[idx];
      }
      dft5<S>(a, b);
    } else if (FILT == 3){
      bool any = false;
      #pragma unroll
      for (int q=0;q<5;q++){
        int ka = j + 125*q;
        int k = kb + NB2*ka;    // NB2==64, k < 40000
        float p0 = 0.0f, p1 = 0.0f;
        if (k >= klo && k <= khi){
          float d = (float)k * (1.0f/(float)TLEN) - xi;
          p0 = __expf(-d*d*inv2s); any = true;
        }
        int k1 = k + 40000;
        if (k1 >= klo && k1 <= khi){
          float d = (float)k1 * (1.0f/(float)TLEN) - xi;
          p1 = __expf(-d*d*inv2s); any = true;
        }
        c2 val = c2{0.0f, 0.0f};
        if (p0 != 0.0f || p1 != 0.0f){
          size_t kidx = (size_t)(k & 63)*625 + (size_t)(k >> 6);
          c2 B0 = unpack_bf(ipu[ibase + kidx]);
          c2 B2 = unpack_bf(ipu[ibase + 1280000ULL + kidx]);
          c2 tw = cis(-TWO_PI * (float)k * (1.0f/80000.0f));
          c2 twB2 = cmul(tw, B2);
          // exact: H[k] = 2(F0 + tw*F2)   (H3 cancels in this combination)
          c2 Hk = c2{2.0f*(B0.x + twB2.x), 2.0f*(B0.y + twB2.y)};
          // H[k+40000] = 2(F0 - tw*F2) - conj(H[40000-k])
          c2 Hb = c2{2.0f*(B0.x - twB2.x), 2.0f*(B0.y - twB2.y)};
          if (p1 != 0.0f && k > 0){
            int qi = 40000 - k;
            size_t qidx = (size_t)(qi & 63)*625 + (size_t)(qi >> 6);
            c2 C0 = unpack_bf(ipu[ibase + qidx]);
            c2 C2 = unpack_bf(ipu[ibase + 1280000ULL + qidx]);
            c2 ctwC2 = cmulc(C2, tw);   // C2 * conj(tw)
            c2 Hq = c2{2.0f*(C0.x - ctwC2.x), 2.0f*(C0.y - ctwC2.y)};
            Hb.x -= Hq.x;  Hb.y += Hq.y;   // Hb -= conj(Hq)
          }
          if (QPH == 0){
            val = c2{p0*Hk.x + p1*Hb.x, p0*Hk.y + p1*Hb.y};
          } else {
            c2 t2 = c2{p0*Hk.x - p1*Hb.x, p0*Hk.y - p1*Hb.y};
            val = cmulc(t2, tw);   // t2 * e^{+2*pi*i*k/80000}
          }
        }
        a[q] = val;
      }
      if (any){
        dft5<S>(a, b);
      } else {
        #pragma unroll
        for (int r=0;r<5;r++) b[r] = c2{0.0f,0.0f};
      }
    } else {  // FILT 1 or 2
      bool any = false;
      #pragma unroll
      for (int q=0;q<5;q++){
        int ka = j + 125*q;
        int k = kb + NB2*ka;
        c2 val = c2{0.0f, 0.0f};
        if (k >= klo && k <= khi){
          size_t idx = ibase + (size_t)(k % NBI)*NA + (size_t)(k / NBI);
          val = PIN ? unpack_bf(ipu[idx]) : ipc[idx];
          float d = (float)k * (1.0f/(float)TLEN) - xi;
          float f = fscale * __expf(-d*d*inv2s);
          val.x *= f; val.y *= f;
          any = true;
        }
        if (FILT == 1 && FOLD){
          int k1 = k + 40000;
          if (k1 >= klo && k1 <= khi){
            size_t idx1 = ibase + (size_t)(k1 % NBI)*NA + (size_t)(k1 / NBI);
            c2 v1 = PIN ? unpack_bf(ipu[idx1]) : ipc[idx1];
            float d = (float)k1 * (1.0f/(float)TLEN) - xi;
            float f1 = __expf(-d*d*inv2s);
            v1.x *= f1; v1.y *= f1;
            val = QPH ? csub(val, v1) : cadd(val, v1);
            any = true;
          }
        }
        if (FILT == 1 && FOLD && QPH){
          c2 tww = cis(TWO_PI * (float)k * (1.0f/80000.0f));
          val = cmul(tww, val);
        }
        a[q] = val;
      }
      if (any){
        dft5<S>(a, b);
      } else {
        #pragma unroll
        for (int r=0;r<5;r++) b[r] = c2{0.0f,0.0f};
      }
    }
    #pragma unroll
    for (int r=0;r<5;r++){ int s = 5*j + r; l0r[s] = b[r].x; l0i[s] = b[r].y; }
  }
  __syncthreads();
  if (j < 125){ // L = 5
    int k = j % 5;
    c2 w  = Wg[25*k];  if (S<0) w.y  = -w.y;
    c2 w2 = Wg[50*k];  if (S<0) w2.y = -w2.y;
    c2 w3 = Wg[75*k];  if (S<0) w3.y = -w3.y;
    c2 w4 = Wg[100*k]; if (S<0) w4.y = -w4.y;
    a[0] = c2{l0r[j],     l0i[j]};
    a[1] = cmul(c2{l0r[j+125], l0i[j+125]}, w);
    a[2] = cmul(c2{l0r[j+250], l0i[j+250]}, w2);
    a[3] = cmul(c2{l0r[j+375], l0i[j+375]}, w3);
    a[4] = cmul(c2{l0r[j+500], l0i[j+500]}, w4);
    dft5<S>(a, b);
    int base = 5*(j-k)+k;
    #pragma unroll
    for (int r=0;r<5;r++){ int s = base + 5*r; l1r[s] = b[r].x; l1i[s] = b[r].y; }
  }
  __syncthreads();
  if (j < 125){ // L = 25
    int k = j % 25;
    c2 w  = Wg[5*k];   if (S<0) w.y  = -w.y;
    c2 w2 = Wg[10*k];  if (S<0) w2.y = -w2.y;
    c2 w3 = Wg[15*k];  if (S<0) w3.y = -w3.y;
    c2 w4 = Wg[20*k];  if (S<0) w4.y = -w4.y;
    a[0] = c2{l1r[j],     l1i[j]};
    a[1] = cmul(c2{l1r[j+125], l1i[j+125]}, w);
    a[2] = cmul(c2{l1r[j+250], l1i[j+250]}, w2);
    a[3] = cmul(c2{l1r[j+375], l1i[j+375]}, w3);
    a[4] = cmul(c2{l1r[j+500], l1i[j+500]}, w4);
    dft5<S>(a, b);
    int base = 5*(j-k)+k;
    #pragma unroll
    for (int r=0;r<5;r++){ int s = base + 25*r; l0r[s] = b[r].x; l0i[s] = b[r].y; }
  }
  __syncthreads();
  if (j < 125){ // L = 125
    c2 w = Wg[j]; if (S<0) w.y = -w.y;
    c2 w2 = cmul(w,w), w3 = cmul(w2,w), w4 = cmul(w2,w2);
    a[0] = c2{l0r[j],     l0i[j]};
    a[1] = cmul(c2{l0r[j+125], l0i[j+125]}, w);
    a[2] = cmul(c2{l0r[j+250], l0i[j+250]}, w2);
    a[3] = cmul(c2{l0r[j+375], l0i[j+375]}, w3);
    a[4] = cmul(c2{l0r[j+500], l0i[j+500]}, w4);
    dft5<S>(a, b);
    size_t obase = (size_t)(scBase + i)*(625ULL*(size_t)NB2) + (size_t)kb*NA;
    if (TW){
      const float invM = 1.0f/(625.0f*(float)NB2);
      c2 twb = cis((float)S * TWO_PI * (float)(j*kb)   * invM);
      c2 tws = cis((float)S * TWO_PI * (float)(125*kb) * invM);
      #pragma unroll
      for (int r=0;r<5;r++){
        int n1 = j + 125*r;
        c2 z = cmul(b[r], twb);
        if (POUT) ((unsigned*)outpv)[obase + n1] = pack_bf(z);
        else      ((c2*)outpv)[obase + n1] = z;
        twb = cmul(twb, tws);
      }
    } else {
      #pragma unroll
      for (int r=0;r<5;r++){
        int n1 = j + 125*r;
        if (n1 <= kamax){
          if (POUT) ((unsigned*)outpv)[obase + n1] = pack_bf(b[r]);
          else      ((c2*)outpv)[obase + n1] = b[r];
        }
      }
    }
  }
}

// ---------------- complex transpose (x-chain only) ----------------
__global__ __launch_bounds__(256) void k_transpose(const c2* __restrict__ in, c2* __restrict__ out,
                                                   int R, int C, int tilesR, int tilesC){
  __shared__ c2 tile[32][33];
  int bi = blockIdx.x;
  int arr = bi / (tilesR*tilesC);
  int tt = bi - arr*(tilesR*tilesC);
  int tr = tt / tilesC, tc = tt - tr*tilesC;
  const c2* ip = in + (size_t)arr*TLEN;
  c2* op = out + (size_t)arr*TLEN;
  int tx = threadIdx.x & 31, ty = threadIdx.x >> 5;
  #pragma unroll
  for (int i=0;i<4;i++){
    int r = tr*32 + ty + i*8, cc = tc*32 + tx;
    if (r < R && cc < C) tile[ty+i*8][tx] = ip[(size_t)r*C + cc];
  }
  __syncthreads();
  #pragma unroll
  for (int i=0;i<4;i++){
    int r = tc*32 + ty + i*8, cc = tr*32 + tx;
    if (r < C && cc < R) op[(size_t)r*R + cc] = tile[tx][ty+i*8];
  }
}

// ---------------- Gaussian lowpass + decimate-by-64, natural layout (S0 only) ----------------
__global__ __launch_bounds__(256) void k_conv(const float* __restrict__ inp, float* __restrict__ S){
  __shared__ float w[NTAP];
  for (int i=threadIdx.x; i<NTAP; i+=256){
    float d = (float)(i - KC);
    w[i] = 0.015666427f * __expf(-7.7106284e-4f * d * d);
  }
  __syncthreads();
  int g = blockIdx.x;
  int arr = g / 10;
  int t = (g - arr*10)*256 + threadIdx.x;
  if (t >= TD) return;
  int srow = arr * SROWS;
  const float* ip = inp + (size_t)arr*TLEN;
  float acc = 0.0f;
  int n = 64*t - KC; if (n < 0) n += TLEN;
  for (int m=0;m<NTAP;m++){
    acc += ip[n] * w[m];
    n++; if (n == TLEN) n = 0;
  }
  S[(size_t)srow*TD + t] = acc;
}

// ---------------- decimated conv (D=4): input Ur_dec[n1<625][n2<64], M=40000 ----------------
#define C2NU  5000
#define C2USZ 5312
template<int MODE>
__global__ __launch_bounds__(256) void k_conv2d(const unsigned short* __restrict__ inp, float* __restrict__ S,
                                                int j1off, int BLK, const int* __restrict__ srowTab){
  __shared__ float u[C2USZ];
  __shared__ float w[72];
  if (threadIdx.x < 65){
    float d = 4.0f * (float)((int)threadIdx.x - 32);
    w[threadIdx.x] = 0.062665708f * __expf(-7.7106284e-4f * d * d);
  }
  int g = blockIdx.x;
  int arr = g / 10;
  int b = g - arr*10;
  int mlo = 4000*b - 32;
  int n2_0 = (mlo >= 0) ? (mlo/625) : -1;
  const unsigned short* ip = inp + (size_t)arr*40000;
  for (int e = threadIdx.x; e < C2NU; e += 256){
    int n1 = e >> 3, c = e & 7;
    int n2 = (n2_0 + c) & 63;
    u[SW16(n1 + 625*c)] = bf2f(ip[n1*64 + n2]);
  }
  __syncthreads();
  int tl = threadIdx.x;
  if (tl >= 250) return;
  int t = 250*b + tl;
  int srow;
  if (MODE == 1){
    int a2 = arr / BLK; int j1 = j1off + (arr - a2*BLK);
    srow = a2*SROWS + 1 + j1;
  } else {
    srow = srowTab[arr];
  }
  int base = (4000*b - 32 - 625*n2_0) + 16*tl;
  float acc = 0.0f;
  #pragma unroll 5
  for (int m=0;m<65;m++){
    acc += u[SW16(base + m)] * w[m];
  }
  S[(size_t)srow*TD + t] = acc;
}

// ---------------- 2-phase decimated conv (D=2) for c0 j2=1 paths ----------------
__global__ __launch_bounds__(256) void k_conv2e(const unsigned short* __restrict__ Ue,
                                                const unsigned short* __restrict__ Uo,
                                                float* __restrict__ S){
  __shared__ float ue[C2USZ], uo[C2USZ];
  __shared__ float we[72], wo[72];
  if (threadIdx.x < 65){
    float d = 4.0f*(float)((int)threadIdx.x) - 128.0f;
    we[threadIdx.x] = 0.031332854f * __expf(-7.7106284e-4f * d * d);
  }
  if (threadIdx.x >= 128 && threadIdx.x < 192){
    int h = (int)threadIdx.x - 128;
    float d = 4.0f*(float)h - 126.0f;
    wo[h] = 0.031332854f * __expf(-7.7106284e-4f * d * d);
  }
  int g = blockIdx.x;
  int path = g / 10;
  int b = g - path*10;
  int mlo = 4000*b - 32;
  int n2_0 = (mlo >= 0) ? (mlo/625) : -1;
  const unsigned short* ipe = Ue + (size_t)path*40000;
  const unsigned short* ipo = Uo + (size_t)path*40000;
  for (int e = threadIdx.x; e < C2NU; e += 256){
    int n1 = e >> 3, c = e & 7;
    int n2 = (n2_0 + c) & 63;
    ue[SW16(n1 + 625*c)] = bf2f(ipe[n1*64 + n2]);
    uo[SW16(n1 + 625*c)] = bf2f(ipo[n1*64 + n2]);
  }
  __syncthreads();
  int tl = threadIdx.x;
  if (tl >= 250) return;
  int t = 250*b + tl;
  int arr = path >> 4;
  int j1  = path & 15;
  int srow = arr*SROWS + 97 + 5*j1;   // j2=1, j1<16: P = 5*j1
  int base = (4000*b - 32 - 625*n2_0) + 16*tl;
  float acc = 0.0f;
  #pragma unroll 5
  for (int m=0;m<65;m++){
    acc += ue[SW16(base + m)] * we[m];
  }
  #pragma unroll 4
  for (int m=0;m<64;m++){
    acc += uo[SW16(base + m)] * wo[m];
  }
  S[(size_t)srow*TD + t] = acc;
}

// ---------------- global min/max + finalize ----------------
__global__ __launch_bounds__(256) void k_minmax1(const float* __restrict__ S, int n, float* pmn, float* pmx){
  __shared__ float smn[256], smx[256];
  float mn = 3.4028235e38f, mx = -3.4028235e38f;
  for (size_t i = (size_t)blockIdx.x*256 + threadIdx.x; i < (size_t)n; i += (size_t)gridDim.x*256){
    float v = S[i]; mn = fminf(mn,v); mx = fmaxf(mx,v);
  }
  smn[threadIdx.x]=mn; smx[threadIdx.x]=mx; __syncthreads();
  for (int s=128;s>0;s>>=1){
    if ((int)threadIdx.x < s){
      smn[threadIdx.x]=fminf(smn[threadIdx.x],smn[threadIdx.x+s]);
      smx[threadIdx.x]=fmaxf(smx[threadIdx.x],smx[threadIdx.x+s]);
    }
    __syncthreads();
  }
  if (threadIdx.x==0){ pmn[blockIdx.x]=smn[0]; pmx[blockIdx.x]=smx[0]; }
}
__global__ __launch_bounds__(256) void k_minmax2(const float* __restrict__ pmn, const float* __restrict__ pmx,
                                                 int nb, float* scal){
  __shared__ float smn[256], smx[256];
  float mn = 3.4028235e38f, mx = -3.4028235e38f;
  for (int i = threadIdx.x; i < nb; i += 256){ mn = fminf(mn,pmn[i]); mx = fmaxf(mx,pmx[i]); }
  smn[threadIdx.x]=mn; smx[threadIdx.x]=mx; __syncthreads();
  for (int s=128;s>0;s>>=1){
    if ((int)threadIdx.x < s){
      smn[threadIdx.x]=fminf(smn[threadIdx.x],smn[threadIdx.x+s]);
      smx[threadIdx.x]=fmaxf(smx[threadIdx.x],smx[threadIdx.x+s]);
    }
    __syncthreads();
  }
  if (threadIdx.x==0){ scal[0]=smn[0]; scal[1]=smx[0]; }
}
__global__ __launch_bounds__(256) void k_final(const float* __restrict__ S, const float* __restrict__ scal,
                                               float* __restrict__ out, int n){
  int i = blockIdx.x*256 + threadIdx.x;
  if (i >= n) return;
  float mn = scal[0];
  float r = scal[1] - mn;
  if (r == 0.0f) r = 1.0f;
  int half = SROWS*TD;
  int a = i / half; int rest = i - a*half;
  out[i] = (S[(size_t)(a & 1)*half + rest] - mn) / r;
}

extern "C" void kernel_launch(void* const* d_in, const int* in_sizes, int n_in,
                              void* d_out, int out_size, void* d_ws, size_t ws_size,
                              hipStream_t stream){
  (void)in_sizes; (void)n_in;
  const float* x = (const float*)d_in[0];

  {
    size_t need = 2560000ULL + 35840000ULL + 35840000ULL + 35840000ULL
                + 81920000ULL + 40960000ULL + 6740000ULL + 65536ULL;
    if (ws_size < need) return;
  }

  char* p = (char*)d_ws;
  auto carve = [&](size_t bytes)->void*{ void* r = (void*)p; p += (bytes + 255) & ~(size_t)255; return r; };
  c2*             Xf  = (c2*)carve(2ULL*TLEN*sizeof(c2));
  unsigned*       A1  = (unsigned*)carve(224ULL*40000*4);   // 0-31 c0e, 32-63 c0o, 64-223 dec
  unsigned*       B   = (unsigned*)carve(224ULL*40000*4);   // first-stage fwd, same slot map
  unsigned*       U1h = (unsigned*)carve(224ULL*40000*4);   // COMPLETED spectra, same slot map
  unsigned*       A2  = (unsigned*)carve(512ULL*40000*4);   // 0-63 j2=1 phases, 64-191 c0 j2>=2, 192-511 dec
  unsigned short* Ur  = (unsigned short*)carve(512ULL*40000*2);
  float*          Sb  = (float*)carve(2ULL*SROWS*TD*sizeof(float));
  c2*             Wg  = (c2*)carve(625*sizeof(c2));
  int*            ptab = (int*)carve(448*4);
  float*          pmn = (float*)carve(512*4);
  float*          pmx = (float*)carve(512*4);
  float*          scal = (float*)carve(256);

  k_wlut<<<3, 256, 0, stream>>>(Wg);
  k_ptab<<<2, 256, 0, stream>>>(ptab);

  // ---- forward FFT of x -> Xf (A2 reused as c2 scratch; U1h as c2 scratch) ----
  k_fft256<-1,2,0><<<2*NA, 64, 0, stream>>>((const void*)x, (void*)A2);
  k_transpose<<<2*20*8, 256, 0, stream>>>((c2*)A2, (c2*)U1h, NA, NB, 20, 8);
  k_fft625<-1,0,0,0,0,256,256,0,0><<<2*NB, 128, 0, stream>>>((const void*)U1h, (void*)Xf, Wg, 0,0,0,0,0,0, 314);
  // ---- S0 ----
  k_conv<<<2*10, 256, 0, stream>>>(x, Sb);

  // ================= order-1 (all decimated) =================
  k_fft625<1,1,1,0,1,64,256,1,0><<<32*64, 128, 0, stream>>>((const void*)Xf, (void*)A1, Wg, 0,16,0,0,0,0, 624);
  k_fft625<1,1,1,0,1,64,256,1,1><<<32*64, 128, 0, stream>>>((const void*)Xf, (void*)A1, Wg, 0,16,0,0,0,32, 624);
  k_fft625<1,1,1,0,1,64,256,0,0><<<160*64, 128, 0, stream>>>((const void*)Xf, (void*)A1, Wg, 16,80,0,0,0,64, 624);
  k_fft64g<1><<<224*G2N, 256, 0, stream>>>(A1, Ur, B);
  k_conv2d<1><<<32*10, 256, 0, stream>>>(Ur, Sb, 0, 16, (const int*)nullptr);
  k_conv2d<1><<<160*10, 256, 0, stream>>>(Ur + 64ULL*40000, Sb, 16, 80, (const int*)nullptr);
  // second stage forward over ALL 224 slots -> completed spectra in U1h (same slot map)
  k_fft625<-1,0,0,1,1,64,64,0,0><<<224*64, 128, 0, stream>>>((const void*)B, (void*)U1h, Wg, 0,0,0,0,0,0, 624);

  // ================= order-2 =================
  // dec (j1>=16): FILT2 per c-block, reading U1h slots 64-223 via pointer offset
  {
    int base = 0;
    for (int c = 1; c <= 4; c++){
      int nj2 = 5 - c;
      k_fft625<1,2,1,1,1,64,64,0,0><<<nj2*32*64, 128, 0, stream>>>((const void*)(U1h + 64ULL*40000), (void*)A2, Wg,
                                                                   16*(c-1), 16, nj2, c+1, 80, 192+base, 624);
      base += 32*nj2;
    }
  }
  // c0 j2>=2 (assembled from completed F0/F2 spectra) -> slots 64-191
  k_fft625<1,3,1,1,1,64,64,0,0><<<128*64, 128, 0, stream>>>((const void*)U1h, (void*)A2, Wg, 0,16,4,2,16, 64, 624);
  // c0 j2=1, two output phases -> slots 0-31 (even), 32-63 (odd)
  k_fft625<1,3,1,1,1,64,64,0,0><<<32*64, 128, 0, stream>>>((const void*)U1h, (void*)A2, Wg, 0,16,1,1,16, 0, 624);
  k_fft625<1,3,1,1,1,64,64,0,1><<<32*64, 128, 0, stream>>>((const void*)U1h, (void*)A2, Wg, 0,16,1,1,16, 32, 624);
  k_fft64g<0><<<512*G2N, 256, 0, stream>>>(A2, Ur, (unsigned*)nullptr);
  k_conv2e<<<32*10, 256, 0, stream>>>(Ur, Ur + 32ULL*40000, Sb);
  k_conv2d<3><<<448*10, 256, 0, stream>>>(Ur + 64ULL*40000, Sb, 0, 0, ptab);

  // ---- global min-max normalize (standardize cancels) + tile(3,1,1) ----
  k_minmax1<<<512, 256, 0, stream>>>(Sb, 2*SROWS*TD, pmn, pmx);
  k_minmax2<<<1, 256, 0, stream>>>(pmn, pmx, 512, scal);
  k_final<<<(out_size+255)/256, 256, 0, stream>>>(Sb, scal, (float*)d_out, out_size);
}

// Round 23
// 344.074 us; speedup vs baseline: 4.0516x; 1.1505x over previous
//
#include <hip/hip_runtime.h>
#include <math.h>

#define TLEN 160000
#define NA 625
#define NB 256
#define TD 2500
#define KC 128
#define NTAP 257
#define SROWS 337
#define TWO_PI 6.283185307179586f

struct c2 { float x, y; };

__device__ __forceinline__ c2 cmul(c2 a, c2 b){ return c2{a.x*b.x - a.y*b.y, a.x*b.y + a.y*b.x}; }
__device__ __forceinline__ c2 cmulc(c2 a, c2 b){ return c2{a.x*b.x + a.y*b.y, a.y*b.x - a.x*b.y}; }
__device__ __forceinline__ c2 cadd(c2 a, c2 b){ return c2{a.x+b.x, a.y+b.y}; }
__device__ __forceinline__ c2 csub(c2 a, c2 b){ return c2{a.x-b.x, a.y-b.y}; }
__device__ __forceinline__ c2 cmac(c2 acc, c2 v, float wr, float wi){
  acc.x += v.x*wr - v.y*wi; acc.y += v.x*wi + v.y*wr; return acc;
}
__device__ __forceinline__ c2 cis(float ang){ c2 r; __sincosf(ang, &r.y, &r.x); return r; }
__device__ __forceinline__ int SW(int i){ return i + (i >> 4); }
__device__ __forceinline__ int SW2(int i){ return i + (i >> 2); }
__device__ __forceinline__ int SW16(int i){ return i + (i >> 4); }
__device__ __forceinline__ int SW64(int i){ return i + (i >> 6); }
__device__ __forceinline__ unsigned pack_bf(c2 z){
  unsigned xr = __float_as_uint(z.x), xi = __float_as_uint(z.y);
  xr += 0x8000u + ((xr >> 16) & 1u);
  xi += 0x8000u + ((xi >> 16) & 1u);
  return (xr >> 16) | (xi & 0xFFFF0000u);
}
__device__ __forceinline__ c2 unpack_bf(unsigned p){
  return c2{ __uint_as_float(p << 16), __uint_as_float(p & 0xFFFF0000u) };
}
__device__ __forceinline__ unsigned short f2bf(float f){
  unsigned u = __float_as_uint(f);
  u += 0x8000u + ((u >> 16) & 1u);
  return (unsigned short)(u >> 16);
}
__device__ __forceinline__ float bf2f(unsigned short h){
  return __uint_as_float(((unsigned)h) << 16);
}
__device__ __forceinline__ void wsync(){
  __builtin_amdgcn_wave_barrier();
  asm volatile("s_waitcnt lgkmcnt(0)" ::: "memory");
  __builtin_amdgcn_wave_barrier();
}

template<int S>
__device__ __forceinline__ void dft4(c2& a0, c2& a1, c2& a2, c2& a3){
  c2 t0 = cadd(a0,a2), t1 = csub(a0,a2), t2 = cadd(a1,a3), t3 = csub(a1,a3);
  float fs = (float)S;
  a0 = cadd(t0,t2); a2 = csub(t0,t2);
  a1 = c2{t1.x - fs*t3.y, t1.y + fs*t3.x};
  a3 = c2{t1.x + fs*t3.y, t1.y - fs*t3.x};
}

template<int S>
__device__ __forceinline__ void dft5(const c2 a[5], c2 b[5]){
  const float C1 = 0.30901699437494742f, C2 = -0.80901699437494745f;
  const float S1 = 0.95105651629515353f * (float)S, S2 = 0.58778525229247314f * (float)S;
  b[0] = cadd(cadd(a[0],a[1]), cadd(cadd(a[2],a[3]),a[4]));
  c2 r;
  r = a[0]; r = cmac(r,a[1],C1, S1); r = cmac(r,a[2],C2, S2); r = cmac(r,a[3],C2,-S2); r = cmac(r,a[4],C1,-S1); b[1]=r;
  r = a[0]; r = cmac(r,a[1],C2, S2); r = cmac(r,a[2],C1,-S1); r = cmac(r,a[3],C1, S1); r = cmac(r,a[4],C2,-S2); b[2]=r;
  r = a[0]; r = cmac(r,a[1],C2,-S2); r = cmac(r,a[2],C1, S1); r = cmac(r,a[3],C1,-S1); r = cmac(r,a[4],C2, S2); b[3]=r;
  r = a[0]; r = cmac(r,a[1],C1,-S1); r = cmac(r,a[2],C2,-S2); r = cmac(r,a[3],C2, S2); r = cmac(r,a[4],C1, S1); b[4]=r;
}

// ---------------- W625 global LUT init ----------------
__global__ __launch_bounds__(256) void k_wlut(c2* __restrict__ W){
  int m = blockIdx.x*256 + threadIdx.x;
  if (m < 625) W[m] = cis(TWO_PI * (float)m * (1.0f/625.0f));
}

// ---------------- tables ----------------
// tab[0..159]   stab40 : srow for M=40k conv paths (slots 64-223 of A2_40k)
// tab[160..447] stab10 : srow for M=10k conv paths (288 slots)
// tab[448..543] ftab40 : (islot | j2<<16) for dec j2<=3 FILT4 launch (96)
// tab[544..767] ftab10 : (islot | j2<<16) for dec j2>=4 FILT4 launch (224)
__device__ __forceinline__ int srowOf(int arr, int j1, int j2){
  int full = j1 >> 4;
  int cum = 16*(5*full - (full*(full-1))/2) + (j1 & 15)*(5 - full);
  int P = cum + j2 - full - 1;
  return arr*SROWS + 97 + P;
}
__global__ __launch_bounds__(256) void k_ptab(int* __restrict__ tab){
  int p = blockIdx.x*256 + threadIdx.x;
  if (p >= 768) return;
  if (p < 160){           // stab40
    int s = p, arr, j1, j2;
    if (s < 64){ arr = s>>5; int rr = s&31; j1 = rr>>1; j2 = 2 + (rr&1); }
    else {
      int q = s - 64;
      if (q < 64){ arr = q>>5; int rr = q&31; int jl = rr>>1; j2 = 2 + (rr&1); j1 = 16 + jl; }
      else { int q2 = q - 64; arr = q2>>4; int jl = q2&15; j2 = 3; j1 = 32 + jl; }
    }
    tab[p] = srowOf(arr, j1, j2);
  } else if (p < 448){    // stab10
    int s = p - 160, arr, j1, j2;
    if (s < 64){ arr = s>>5; int rr = s&31; j1 = rr>>1; j2 = 4 + (rr&1); }
    else {
      int q = s - 64;
      if (q < 192){ int c = 1 + q/64; int qq = q - (c-1)*64; arr = qq>>5; int rr = qq&31; int jl = rr>>1; j2 = 4 + (rr&1); j1 = 16*c + jl; }
      else { int q2 = q - 192; arr = q2>>4; int jl = q2&15; j2 = 5; j1 = 64 + jl; }
    }
    tab[p] = srowOf(arr, j1, j2);
  } else if (p < 544){    // ftab40
    int q = p - 448, arr, jl, j2, c;
    if (q < 64){ c = 1; arr = q>>5; int rr = q&31; jl = rr>>1; j2 = 2 + (rr&1); }
    else { int q2 = q - 64; c = 2; arr = q2>>4; jl = q2&15; j2 = 3; }
    int islot = arr*80 + 16*(c-1) + jl;
    tab[p] = islot | (j2<<16);
  } else {                // ftab10
    int q = p - 544, arr, jl, j2, c;
    if (q < 192){ c = 1 + q/64; int qq = q - (c-1)*64; arr = qq>>5; int rr = qq&31; jl = rr>>1; j2 = 4 + (rr&1); }
    else { int q2 = q - 192; c = 4; arr = q2>>4; jl = q2&15; j2 = 5; }
    int islot = arr*80 + 16*(c-1) + jl;
    tab[p] = islot | (j2<<16);
  }
}

// ---------------- 256-point row FFT (x-chain only) ----------------
template<int S, int INMODE, int OUTMODE>
__global__ __launch_bounds__(64) void k_fft256(const void* __restrict__ inp, void* __restrict__ outp){
  __shared__ c2 lds[2][272];
  int g = blockIdx.x;
  int arr = g / NA, n1 = g - arr*NA;
  int j = threadIdx.x;
  c2 v[4];
  if (INMODE == 0){
    const c2* ip = (const c2*)inp + (size_t)arr*TLEN + (size_t)n1*NB;
    #pragma unroll
    for (int q=0;q<4;q++) v[q] = ip[j + 64*q];
  } else if (INMODE == 1){
    const float* ip = (const float*)inp + (size_t)arr*TLEN + (size_t)n1*NB;
    #pragma unroll
    for (int q=0;q<4;q++) v[q] = c2{ip[j + 64*q], 0.0f};
  } else {
    const float* ip = (const float*)inp + (size_t)arr*TLEN;
    #pragma unroll
    for (int q=0;q<4;q++) v[q] = c2{ip[n1 + NA*(j + 64*q)], 0.0f};
  }
  dft4<S>(v[0],v[1],v[2],v[3]);
  #pragma unroll
  for (int r=0;r<4;r++) lds[0][SW(4*j + r)] = v[r];
  wsync();
  { // L = 4
    int k = j & 3;
    c2 w = cis((float)S * TWO_PI * (float)k * (1.0f/16.0f));
    c2 w2 = cmul(w,w), w3 = cmul(w2,w);
    v[0] = lds[0][SW(j)];
    v[1] = cmul(lds[0][SW(j+64)], w);
    v[2] = cmul(lds[0][SW(j+128)], w2);
    v[3] = cmul(lds[0][SW(j+192)], w3);
    dft4<S>(v[0],v[1],v[2],v[3]);
    int base = 4*(j-k)+k;
    #pragma unroll
    for (int r=0;r<4;r++) lds[1][SW(base + 4*r)] = v[r];
  }
  wsync();
  { // L = 16
    int k = j & 15;
    c2 w = cis((float)S * TWO_PI * (float)k * (1.0f/64.0f));
    c2 w2 = cmul(w,w), w3 = cmul(w2,w);
    v[0] = lds[1][SW(j)];
    v[1] = cmul(lds[1][SW(j+64)], w);
    v[2] = cmul(lds[1][SW(j+128)], w2);
    v[3] = cmul(lds[1][SW(j+192)], w3);
    dft4<S>(v[0],v[1],v[2],v[3]);
    int base = 4*(j-k)+k;
    #pragma unroll
    for (int r=0;r<4;r++) lds[0][SW(base + 16*r)] = v[r];
  }
  wsync();
  { // L = 64
    c2 w = cis((float)S * TWO_PI * (float)j * (1.0f/256.0f));
    c2 w2 = cmul(w,w), w3 = cmul(w2,w);
    v[0] = lds[0][SW(j)];
    v[1] = cmul(lds[0][SW(j+64)], w);
    v[2] = cmul(lds[0][SW(j+128)], w2);
    v[3] = cmul(lds[0][SW(j+192)], w3);
    dft4<S>(v[0],v[1],v[2],v[3]);
    if (OUTMODE == 0){
      c2* op = (c2*)outp + (size_t)arr*TLEN + (size_t)n1*NB;
      #pragma unroll
      for (int r=0;r<4;r++){
        int kb = j + 64*r;
        c2 tw = cis((float)S * TWO_PI * (float)(n1*kb) * (1.0f/160000.0f));
        op[kb] = cmul(v[r], tw);
      }
    } else {
      float* op = (float*)outp + (size_t)arr*TLEN + (size_t)n1*NB;
      #pragma unroll
      for (int r=0;r<4;r++){
        c2 z = v[r];
        op[j + 64*r] = sqrtf(z.x*z.x + z.y*z.y) * (1.0f/160000.0f);
      }
    }
  }
}

// ---------------- fused gather + inverse 64-FFT + abs (+ optional forward 64-FFT -> B) ------
#define G2CH  16
#define G2N   40
#define G2TF  73
#define G2RS  328
template<int WRITEB>
__global__ __launch_bounds__(256) void k_fft64g(const unsigned* __restrict__ inp, unsigned short* __restrict__ outp,
                                                unsigned* __restrict__ outB){
  __shared__ float smem[2*G2CH*G2TF + G2CH*G2RS];
  float* tr = smem;
  float* ti = smem + G2CH*G2TF;
  float* scr = smem + 2*G2CH*G2TF;
  int g = blockIdx.x;
  int arr = g / G2N, chunk = g - arr*G2N;
  int n1_0 = chunk*G2CH;
  int rows = 625 - n1_0; if (rows > G2CH) rows = G2CH;
  const unsigned* ip = inp + (size_t)arr*40000;
  if (rows == G2CH){
    for (int e = threadIdx.x; e < 64*G2CH; e += 256){
      int kb = e >> 4, i = e & 15;
      c2 z = unpack_bf(ip[kb*625 + n1_0 + i]);
      tr[i*G2TF + kb] = z.x; ti[i*G2TF + kb] = z.y;
    }
  } else {
    for (int e = threadIdx.x; e < 64*rows; e += 256){
      int kb = e / rows, i = e - kb*rows;
      c2 z = unpack_bf(ip[kb*625 + n1_0 + i]);
      tr[i*G2TF + kb] = z.x; ti[i*G2TF + kb] = z.y;
    }
  }
  __syncthreads();
  int row = threadIdx.x >> 4;
  int j   = threadIdx.x & 15;
  bool act = row < rows;
  int n1 = n1_0 + row;
  float* s = scr + row*G2RS;
  c2 w4  = cis(TWO_PI * (float)(j & 3) * (1.0f/16.0f));
  c2 w4b = cmul(w4,w4), w4c = cmul(w4b,w4);
  c2 w16 = cis(TWO_PI * (float)j * (1.0f/64.0f));
  c2 w16b= cmul(w16,w16), w16c= cmul(w16b,w16);
  int b4 = 4*(j-(j&3))+(j&3);
  float av[4];
  if (act){
    c2 v[4];
    #pragma unroll
    for (int q=0;q<4;q++) v[q] = c2{tr[row*G2TF + j + 16*q], ti[row*G2TF + j + 16*q]};
    dft4<1>(v[0],v[1],v[2],v[3]);
    #pragma unroll
    for (int r=0;r<4;r++){ int p = SW2(4*j+r); s[p] = v[r].x; s[80+p] = v[r].y; }
  }
  wsync();
  if (act){ // L = 4
    c2 v[4];
    v[0] = c2{s[SW2(j)],    s[80+SW2(j)]};
    v[1] = cmul(c2{s[SW2(j+16)], s[80+SW2(j+16)]}, w4);
    v[2] = cmul(c2{s[SW2(j+32)], s[80+SW2(j+32)]}, w4b);
    v[3] = cmul(c2{s[SW2(j+48)], s[80+SW2(j+48)]}, w4c);
    dft4<1>(v[0],v[1],v[2],v[3]);
    #pragma unroll
    for (int r=0;r<4;r++){ int p = SW2(b4+4*r); s[160+p] = v[r].x; s[240+p] = v[r].y; }
  }
  wsync();
  if (act){ // L = 16 + abs
    c2 v[4];
    v[0] = c2{s[160+SW2(j)],    s[240+SW2(j)]};
    v[1] = cmul(c2{s[160+SW2(j+16)], s[240+SW2(j+16)]}, w16);
    v[2] = cmul(c2{s[160+SW2(j+32)], s[240+SW2(j+32)]}, w16b);
    v[3] = cmul(c2{s[160+SW2(j+48)], s[240+SW2(j+48)]}, w16c);
    dft4<1>(v[0],v[1],v[2],v[3]);
    unsigned short* op = outp + (size_t)arr*40000 + (size_t)n1*64;
    #pragma unroll
    for (int r=0;r<4;r++){
      c2 z = v[r];
      av[r] = sqrtf(z.x*z.x + z.y*z.y) * (1.0f/160000.0f);
      op[j + 16*r] = f2bf(av[r]);
    }
  }
  if (WRITEB){
    wsync();
    if (act){
      c2 v[4];
      #pragma unroll
      for (int q=0;q<4;q++) v[q] = c2{av[q], 0.0f};
      dft4<-1>(v[0],v[1],v[2],v[3]);
      #pragma unroll
      for (int r=0;r<4;r++){ int p = SW2(4*j+r); s[p] = v[r].x; s[80+p] = v[r].y; }
    }
    wsync();
    if (act){
      c2 v[4];
      v[0] = c2{s[SW2(j)],    s[80+SW2(j)]};
      v[1] = cmulc(c2{s[SW2(j+16)], s[80+SW2(j+16)]}, w4);
      v[2] = cmulc(c2{s[SW2(j+32)], s[80+SW2(j+32)]}, w4b);
      v[3] = cmulc(c2{s[SW2(j+48)], s[80+SW2(j+48)]}, w4c);
      dft4<-1>(v[0],v[1],v[2],v[3]);
      #pragma unroll
      for (int r=0;r<4;r++){ int p = SW2(b4+4*r); s[160+p] = v[r].x; s[240+p] = v[r].y; }
    }
    wsync();
    if (act){
      c2 v[4];
      v[0] = c2{s[160+SW2(j)],    s[240+SW2(j)]};
      v[1] = cmulc(c2{s[160+SW2(j+16)], s[240+SW2(j+16)]}, w16);
      v[2] = cmulc(c2{s[160+SW2(j+32)], s[240+SW2(j+32)]}, w16b);
      v[3] = cmulc(c2{s[160+SW2(j+48)], s[240+SW2(j+48)]}, w16c);
      dft4<-1>(v[0],v[1],v[2],v[3]);
      #pragma unroll
      for (int r=0;r<4;r++){
        int kb = j + 16*r;
        c2 tw = cis(-TWO_PI * (float)(n1*kb) * (1.0f/40000.0f));
        c2 z = cmul(v[r], tw);
        tr[row*G2TF + kb] = z.x;
        ti[row*G2TF + kb] = z.y;
      }
    }
    __syncthreads();
    unsigned* op = outB + (size_t)arr*40000;
    if (rows == G2CH){
      for (int e = threadIdx.x; e < 64*G2CH; e += 256){
        int kb = e >> 4, i = e & 15;
        op[kb*625 + n1_0 + i] = pack_bf(c2{tr[i*G2TF + kb], ti[i*G2TF + kb]});
      }
    } else {
      for (int e = threadIdx.x; e < 64*rows; e += 256){
        int kb = e / rows, i = e - kb*rows;
        op[kb*625 + n1_0 + i] = pack_bf(c2{tr[i*G2TF + kb], ti[i*G2TF + kb]});
      }
    }
  }
}

// ---------------- per-thread inverse 16-FFT + abs (M = 10000 tier) ----------------
// Input [slot][kb<16][n1<625] packed bf16; output Ur[slot][n1<625][n2<16] scalar bf16.
__global__ __launch_bounds__(256) void k_fft16g(const unsigned* __restrict__ inp, unsigned short* __restrict__ outp){
  int gid = blockIdx.x*256 + threadIdx.x;
  int s = gid / 625, n1 = gid - s*625;
  if (s >= 288) return;
  const unsigned* ip = inp + (size_t)s*10000 + n1;
  c2 A[4][4];
  #pragma unroll
  for (int k1=0;k1<4;k1++){
    c2 a0 = unpack_bf(ip[(k1   )*625]);
    c2 a1 = unpack_bf(ip[(k1+ 4)*625]);
    c2 a2 = unpack_bf(ip[(k1+ 8)*625]);
    c2 a3 = unpack_bf(ip[(k1+12)*625]);
    dft4<1>(a0,a1,a2,a3);
    A[k1][0]=a0; A[k1][1]=a1; A[k1][2]=a2; A[k1][3]=a3;
  }
  unsigned short ov[16];
  #pragma unroll
  for (int n0=0;n0<4;n0++){
    c2 w1 = cis(TWO_PI * (float)n0 * (1.0f/16.0f));
    c2 w2 = cmul(w1,w1), w3 = cmul(w2,w1);
    c2 b0 = A[0][n0];
    c2 b1 = cmul(A[1][n0], w1);
    c2 b2 = cmul(A[2][n0], w2);
    c2 b3 = cmul(A[3][n0], w3);
    dft4<1>(b0,b1,b2,b3);
    ov[n0   ] = f2bf(sqrtf(b0.x*b0.x+b0.y*b0.y)*(1.0f/160000.0f));
    ov[n0+ 4] = f2bf(sqrtf(b1.x*b1.x+b1.y*b1.y)*(1.0f/160000.0f));
    ov[n0+ 8] = f2bf(sqrtf(b2.x*b2.x+b2.y*b2.y)*(1.0f/160000.0f));
    ov[n0+12] = f2bf(sqrtf(b3.x*b3.x+b3.y*b3.y)*(1.0f/160000.0f));
  }
  unsigned short* op = outp + (size_t)s*10000 + (size_t)n1*16;
  #pragma unroll
  for (int n=0;n<16;n++) op[n] = ov[n];
}

// ---------------- 625-point row FFT (radix-5 Stockham) ----------------
// FILT: 0 none, 1 psi1 (FOLD/QPH phases), 2 psi2 (decode via launch params),
//       3 psi2 from completed 2-phase spectra (c0), 4 psi2 table-driven (dec).
template<int S, int FILT, int TW, int PIN, int POUT, int NB2, int NBI, int FOLD, int QPH>
__global__ __launch_bounds__(128) void k_fft625(const void* __restrict__ inpv, void* __restrict__ outpv,
                                                const c2* __restrict__ Wg,
                                                int j1off, int BLK, int nj2, int j2base, int istr,
                                                int scBase, int kamax, const int* __restrict__ ftab){
  __shared__ float l0r[625], l0i[625], l1r[625], l1i[625];
  int g = blockIdx.x;
  int i = g / NB2, kb = g - i*NB2;
  int j = threadIdx.x;
  const c2* ipc = (const c2*)inpv;
  const unsigned* ipu = (const unsigned*)inpv;
  size_t ibase;
  int j1 = 0, j2 = 0;
  if (FILT == 0){
    ibase = (size_t)i*(625ULL*(size_t)NB2) + (size_t)kb*NA;
  } else if (FILT == 1){
    int bt = i / BLK; j1 = j1off + (i - bt*BLK);
    ibase = (size_t)bt*(625ULL*(size_t)NBI);
  } else if (FILT == 2){
    int npb = BLK*nj2;
    int bt = i / npb, rr = i - bt*npb;
    int jloc = rr / nj2; j2 = j2base + (rr - jloc*nj2);
    int islot = bt*istr + j1off + jloc;
    ibase = (size_t)islot*(625ULL*(size_t)NBI);
  } else if (FILT == 4){
    int v = ftab[i];
    int islot = v & 0xFFFF;
    j2 = v >> 16;
    ibase = (size_t)islot*(625ULL*(size_t)NBI);
  } else { // FILT 3: completed-spectrum slot space (40000 each)
    int npb = BLK*nj2;
    int bt = i / npb, rr = i - bt*npb;
    int jloc = rr / nj2; j2 = j2base + (rr - jloc*nj2);
    int islot = bt*BLK + jloc;
    ibase = (size_t)islot*40000ULL;
  }
  float xi = 0.0f, sig = 0.0f, inv2s = 0.0f;
  int klo = 0, khi = 0;
  const float fscale = ((FILT == 2 || FILT == 4) && NBI == 64) ? 4.0f : 1.0f;
  if (FILT != 0){
    if (FILT == 1){ xi = 0.4f * exp2f(-(float)j1 * 0.0625f); sig = xi * 0.04427378243f; }
    else          { xi = 0.4f * exp2f(-(float)j2);           sig = 0.35f * xi; }
    inv2s = 0.5f / (sig*sig);
    klo = (int)((xi - 6.0f*sig) * (float)TLEN); if (klo < 0) klo = 0;
    khi = (int)((xi + 6.0f*sig) * (float)TLEN) + 1; if (khi > TLEN/2 - 1) khi = TLEN/2 - 1;
    if (FILT != 3 && !FOLD){
      if (khi > 625*NB2 - 1) khi = 625*NB2 - 1;
    }
  }
  c2 a[5], b[5];
  if (j < 125){
    if (FILT == 0){
      #pragma unroll
      for (int q=0;q<5;q++){
        size_t idx = ibase + j + 125*q;
        a[q] = PIN ? unpack_bf(ipu[idx]) : ipc[idx];
      }
      dft5<S>(a, b);
    } else if (FILT == 3){
      bool any = false;
      #pragma unroll
      for (int q=0;q<5;q++){
        int ka = j + 125*q;
        int k = kb + NB2*ka;
        float p0 = 0.0f, p1 = 0.0f;
        if (k >= klo && k <= khi){
          float d = (float)k * (1.0f/(float)TLEN) - xi;
          p0 = __expf(-d*d*inv2s); any = true;
        }
        int k1 = k + 40000;
        if (k1 >= klo && k1 <= khi){
          float d = (float)k1 * (1.0f/(float)TLEN) - xi;
          p1 = __expf(-d*d*inv2s); any = true;
        }
        c2 val = c2{0.0f, 0.0f};
        if (p0 != 0.0f || p1 != 0.0f){
          size_t kidx = (size_t)(k & 63)*625 + (size_t)(k >> 6);
          c2 B0 = unpack_bf(ipu[ibase + kidx]);
          c2 B2 = unpack_bf(ipu[ibase + 1280000ULL + kidx]);
          c2 tw = cis(-TWO_PI * (float)k * (1.0f/80000.0f));
          c2 twB2 = cmul(tw, B2);
          c2 Hk = c2{2.0f*(B0.x + twB2.x), 2.0f*(B0.y + twB2.y)};
          c2 Hb = c2{2.0f*(B0.x - twB2.x), 2.0f*(B0.y - twB2.y)};
          if (p1 != 0.0f && k > 0){
            int qi = 40000 - k;
            size_t qidx = (size_t)(qi & 63)*625 + (size_t)(qi >> 6);
            c2 C0 = unpack_bf(ipu[ibase + qidx]);
            c2 C2 = unpack_bf(ipu[ibase + 1280000ULL + qidx]);
            c2 ctwC2 = cmulc(C2, tw);
            c2 Hq = c2{2.0f*(C0.x - ctwC2.x), 2.0f*(C0.y - ctwC2.y)};
            Hb.x -= Hq.x;  Hb.y += Hq.y;
          }
          if (QPH == 0){
            val = c2{p0*Hk.x + p1*Hb.x, p0*Hk.y + p1*Hb.y};
          } else {
            c2 t2 = c2{p0*Hk.x - p1*Hb.x, p0*Hk.y - p1*Hb.y};
            val = cmulc(t2, tw);
          }
        }
        a[q] = val;
      }
      if (any){
        dft5<S>(a, b);
      } else {
        #pragma unroll
        for (int r=0;r<5;r++) b[r] = c2{0.0f,0.0f};
      }
    } else {  // FILT 1, 2 or 4
      bool any = false;
      #pragma unroll
      for (int q=0;q<5;q++){
        int ka = j + 125*q;
        int k = kb + NB2*ka;
        c2 val = c2{0.0f, 0.0f};
        if (k >= klo && k <= khi){
          size_t idx = ibase + (size_t)(k % NBI)*NA + (size_t)(k / NBI);
          val = PIN ? unpack_bf(ipu[idx]) : ipc[idx];
          float d = (float)k * (1.0f/(float)TLEN) - xi;
          float f = fscale * __expf(-d*d*inv2s);
          val.x *= f; val.y *= f;
          any = true;
        }
        if (FILT == 1 && FOLD){
          int k1 = k + 40000;
          if (k1 >= klo && k1 <= khi){
            size_t idx1 = ibase + (size_t)(k1 % NBI)*NA + (size_t)(k1 / NBI);
            c2 v1 = PIN ? unpack_bf(ipu[idx1]) : ipc[idx1];
            float d = (float)k1 * (1.0f/(float)TLEN) - xi;
            float f1 = __expf(-d*d*inv2s);
            v1.x *= f1; v1.y *= f1;
            val = QPH ? csub(val, v1) : cadd(val, v1);
            any = true;
          }
        }
        if (FILT == 1 && FOLD && QPH){
          c2 tww = cis(TWO_PI * (float)k * (1.0f/80000.0f));
          val = cmul(tww, val);
        }
        a[q] = val;
      }
      if (any){
        dft5<S>(a, b);
      } else {
        #pragma unroll
        for (int r=0;r<5;r++) b[r] = c2{0.0f,0.0f};
      }
    }
    #pragma unroll
    for (int r=0;r<5;r++){ int s = 5*j + r; l0r[s] = b[r].x; l0i[s] = b[r].y; }
  }
  __syncthreads();
  if (j < 125){ // L = 5
    int k = j % 5;
    c2 w  = Wg[25*k];  if (S<0) w.y  = -w.y;
    c2 w2 = Wg[50*k];  if (S<0) w2.y = -w2.y;
    c2 w3 = Wg[75*k];  if (S<0) w3.y = -w3.y;
    c2 w4 = Wg[100*k]; if (S<0) w4.y = -w4.y;
    a[0] = c2{l0r[j],     l0i[j]};
    a[1] = cmul(c2{l0r[j+125], l0i[j+125]}, w);
    a[2] = cmul(c2{l0r[j+250], l0i[j+250]}, w2);
    a[3] = cmul(c2{l0r[j+375], l0i[j+375]}, w3);
    a[4] = cmul(c2{l0r[j+500], l0i[j+500]}, w4);
    dft5<S>(a, b);
    int base = 5*(j-k)+k;
    #pragma unroll
    for (int r=0;r<5;r++){ int s = base + 5*r; l1r[s] = b[r].x; l1i[s] = b[r].y; }
  }
  __syncthreads();
  if (j < 125){ // L = 25
    int k = j % 25;
    c2 w  = Wg[5*k];   if (S<0) w.y  = -w.y;
    c2 w2 = Wg[10*k];  if (S<0) w2.y = -w2.y;
    c2 w3 = Wg[15*k];  if (S<0) w3.y = -w3.y;
    c2 w4 = Wg[20*k];  if (S<0) w4.y = -w4.y;
    a[0] = c2{l1r[j],     l1i[j]};
    a[1] = cmul(c2{l1r[j+125], l1i[j+125]}, w);
    a[2] = cmul(c2{l1r[j+250], l1i[j+250]}, w2);
    a[3] = cmul(c2{l1r[j+375], l1i[j+375]}, w3);
    a[4] = cmul(c2{l1r[j+500], l1i[j+500]}, w4);
    dft5<S>(a, b);
    int base = 5*(j-k)+k;
    #pragma unroll
    for (int r=0;r<5;r++){ int s = base + 25*r; l0r[s] = b[r].x; l0i[s] = b[r].y; }
  }
  __syncthreads();
  if (j < 125){ // L = 125
    c2 w = Wg[j]; if (S<0) w.y = -w.y;
    c2 w2 = cmul(w,w), w3 = cmul(w2,w), w4 = cmul(w2,w2);
    a[0] = c2{l0r[j],     l0i[j]};
    a[1] = cmul(c2{l0r[j+125], l0i[j+125]}, w);
    a[2] = cmul(c2{l0r[j+250], l0i[j+250]}, w2);
    a[3] = cmul(c2{l0r[j+375], l0i[j+375]}, w3);
    a[4] = cmul(c2{l0r[j+500], l0i[j+500]}, w4);
    dft5<S>(a, b);
    size_t obase = (size_t)(scBase + i)*(625ULL*(size_t)NB2) + (size_t)kb*NA;
    if (TW){
      const float invM = 1.0f/(625.0f*(float)NB2);
      c2 twb = cis((float)S * TWO_PI * (float)(j*kb)   * invM);
      c2 tws = cis((float)S * TWO_PI * (float)(125*kb) * invM);
      #pragma unroll
      for (int r=0;r<5;r++){
        int n1 = j + 125*r;
        c2 z = cmul(b[r], twb);
        if (POUT) ((unsigned*)outpv)[obase + n1] = pack_bf(z);
        else      ((c2*)outpv)[obase + n1] = z;
        twb = cmul(twb, tws);
      }
    } else {
      #pragma unroll
      for (int r=0;r<5;r++){
        int n1 = j + 125*r;
        if (n1 <= kamax){
          if (POUT) ((unsigned*)outpv)[obase + n1] = pack_bf(b[r]);
          else      ((c2*)outpv)[obase + n1] = b[r];
        }
      }
    }
  }
}

// ---------------- complex transpose (x-chain only) ----------------
__global__ __launch_bounds__(256) void k_transpose(const c2* __restrict__ in, c2* __restrict__ out,
                                                   int R, int C, int tilesR, int tilesC){
  __shared__ c2 tile[32][33];
  int bi = blockIdx.x;
  int arr = bi / (tilesR*tilesC);
  int tt = bi - arr*(tilesR*tilesC);
  int tr = tt / tilesC, tc = tt - tr*tilesC;
  const c2* ip = in + (size_t)arr*TLEN;
  c2* op = out + (size_t)arr*TLEN;
  int tx = threadIdx.x & 31, ty = threadIdx.x >> 5;
  #pragma unroll
  for (int i=0;i<4;i++){
    int r = tr*32 + ty + i*8, cc = tc*32 + tx;
    if (r < R && cc < C) tile[ty+i*8][tx] = ip[(size_t)r*C + cc];
  }
  __syncthreads();
  #pragma unroll
  for (int i=0;i<4;i++){
    int r = tc*32 + ty + i*8, cc = tr*32 + tx;
    if (r < C && cc < R) op[(size_t)r*R + cc] = tile[tx][ty+i*8];
  }
}

// ---------------- Gaussian lowpass + decimate-by-64, natural layout (S0 only) ----------------
__global__ __launch_bounds__(256) void k_conv(const float* __restrict__ inp, float* __restrict__ S){
  __shared__ float w[NTAP];
  for (int i=threadIdx.x; i<NTAP; i+=256){
    float d = (float)(i - KC);
    w[i] = 0.015666427f * __expf(-7.7106284e-4f * d * d);
  }
  __syncthreads();
  int g = blockIdx.x;
  int arr = g / 10;
  int t = (g - arr*10)*256 + threadIdx.x;
  if (t >= TD) return;
  int srow = arr * SROWS;
  const float* ip = inp + (size_t)arr*TLEN;
  float acc = 0.0f;
  int n = 64*t - KC; if (n < 0) n += TLEN;
  for (int m=0;m<NTAP;m++){
    acc += ip[n] * w[m];
    n++; if (n == TLEN) n = 0;
  }
  S[(size_t)srow*TD + t] = acc;
}

// ---------------- decimated conv (D=4): input Ur_dec[n1<625][n2<64], M=40000 ----------------
#define C2NU  5000
#define C2USZ 5312
template<int MODE>
__global__ __launch_bounds__(256) void k_conv2d(const unsigned short* __restrict__ inp, float* __restrict__ S,
                                                int j1off, int BLK, const int* __restrict__ srowTab){
  __shared__ float u[C2USZ];
  __shared__ float w[72];
  if (threadIdx.x < 65){
    float d = 4.0f * (float)((int)threadIdx.x - 32);
    w[threadIdx.x] = 0.062665708f * __expf(-7.7106284e-4f * d * d);
  }
  int g = blockIdx.x;
  int arr = g / 10;
  int b = g - arr*10;
  int mlo = 4000*b - 32;
  int n2_0 = (mlo >= 0) ? (mlo/625) : -1;
  const unsigned short* ip = inp + (size_t)arr*40000;
  for (int e = threadIdx.x; e < C2NU; e += 256){
    int n1 = e >> 3, c = e & 7;
    int n2 = (n2_0 + c) & 63;
    u[SW16(n1 + 625*c)] = bf2f(ip[n1*64 + n2]);
  }
  __syncthreads();
  int tl = threadIdx.x;
  if (tl >= 250) return;
  int t = 250*b + tl;
  int srow;
  if (MODE == 1){
    int a2 = arr / BLK; int j1 = j1off + (arr - a2*BLK);
    srow = a2*SROWS + 1 + j1;
  } else {
    srow = srowTab[arr];
  }
  int base = (4000*b - 32 - 625*n2_0) + 16*tl;
  float acc = 0.0f;
  #pragma unroll 5
  for (int m=0;m<65;m++){
    acc += u[SW16(base + m)] * w[m];
  }
  S[(size_t)srow*TD + t] = acc;
}

// ---------------- decimated conv (D=16): input Ur10k[n1<625][n2<16], M=10000 ----------------
#define CQ_USZ 2344
__global__ __launch_bounds__(256) void k_conv2q(const unsigned short* __restrict__ inp, float* __restrict__ S,
                                                const int* __restrict__ srowTab){
  __shared__ float u[CQ_USZ];
  __shared__ float w[20];
  if (threadIdx.x < 17){
    float d = 16.0f * (float)((int)threadIdx.x - 8);
    w[threadIdx.x] = 0.25066283f * __expf(-7.7106284e-4f * d * d);
  }
  int g = blockIdx.x;
  int slot = g / 10;
  int b = g - slot*10;
  int mlo = 1000*b - 8;
  int n2_0 = (mlo >= 0) ? (mlo/625) : -1;
  const unsigned short* ip = inp + (size_t)slot*10000;
  for (int e = threadIdx.x; e < 1875; e += 256){
    int c = e / 625, n1 = e - c*625;
    int n2 = (n2_0 + c) & 15;
    u[SW2(n1 + 625*c)] = bf2f(ip[n1*16 + n2]);
  }
  __syncthreads();
  int tl = threadIdx.x;
  if (tl >= 250) return;
  int t = 250*b + tl;
  int srow = srowTab[slot];
  int base = (1000*b - 8 - 625*n2_0) + 4*tl;
  float acc = 0.0f;
  #pragma unroll
  for (int m=0;m<17;m++){
    acc += u[SW2(base + m)] * w[m];
  }
  S[(size_t)srow*TD + t] = acc;
}

// ---------------- 2-phase decimated conv (D=2) for c0 j2=1 paths ----------------
__global__ __launch_bounds__(256) void k_conv2e(const unsigned short* __restrict__ Ue,
                                                const unsigned short* __restrict__ Uo,
                                                float* __restrict__ S){
  __shared__ float ue[C2USZ], uo[C2USZ];
  __shared__ float we[72], wo[72];
  if (threadIdx.x < 65){
    float d = 4.0f*(float)((int)threadIdx.x) - 128.0f;
    we[threadIdx.x] = 0.031332854f * __expf(-7.7106284e-4f * d * d);
  }
  if (threadIdx.x >= 128 && threadIdx.x < 192){
    int h = (int)threadIdx.x - 128;
    float d = 4.0f*(float)h - 126.0f;
    wo[h] = 0.031332854f * __expf(-7.7106284e-4f * d * d);
  }
  int g = blockIdx.x;
  int path = g / 10;
  int b = g - path*10;
  int mlo = 4000*b - 32;
  int n2_0 = (mlo >= 0) ? (mlo/625) : -1;
  const unsigned short* ipe = Ue + (size_t)path*40000;
  const unsigned short* ipo = Uo + (size_t)path*40000;
  for (int e = threadIdx.x; e < C2NU; e += 256){
    int n1 = e >> 3, c = e & 7;
    int n2 = (n2_0 + c) & 63;
    ue[SW16(n1 + 625*c)] = bf2f(ipe[n1*64 + n2]);
    uo[SW16(n1 + 625*c)] = bf2f(ipo[n1*64 + n2]);
  }
  __syncthreads();
  int tl = threadIdx.x;
  if (tl >= 250) return;
  int t = 250*b + tl;
  int arr = path >> 4;
  int j1  = path & 15;
  int srow = arr*SROWS + 97 + 5*j1;
  int base = (4000*b - 32 - 625*n2_0) + 16*tl;
  float acc = 0.0f;
  #pragma unroll 5
  for (int m=0;m<65;m++){
    acc += ue[SW16(base + m)] * we[m];
  }
  #pragma unroll 4
  for (int m=0;m<64;m++){
    acc += uo[SW16(base + m)] * wo[m];
  }
  S[(size_t)srow*TD + t] = acc;
}

// ---------------- global min/max + finalize ----------------
__global__ __launch_bounds__(256) void k_minmax1(const float* __restrict__ S, int n, float* pmn, float* pmx){
  __shared__ float smn[256], smx[256];
  float mn = 3.4028235e38f, mx = -3.4028235e38f;
  for (size_t i = (size_t)blockIdx.x*256 + threadIdx.x; i < (size_t)n; i += (size_t)gridDim.x*256){
    float v = S[i]; mn = fminf(mn,v); mx = fmaxf(mx,v);
  }
  smn[threadIdx.x]=mn; smx[threadIdx.x]=mx; __syncthreads();
  for (int s=128;s>0;s>>=1){
    if ((int)threadIdx.x < s){
      smn[threadIdx.x]=fminf(smn[threadIdx.x],smn[threadIdx.x+s]);
      smx[threadIdx.x]=fmaxf(smx[threadIdx.x],smx[threadIdx.x+s]);
    }
    __syncthreads();
  }
  if (threadIdx.x==0){ pmn[blockIdx.x]=smn[0]; pmx[blockIdx.x]=smx[0]; }
}
__global__ __launch_bounds__(256) void k_minmax2(const float* __restrict__ pmn, const float* __restrict__ pmx,
                                                 int nb, float* scal){
  __shared__ float smn[256], smx[256];
  float mn = 3.4028235e38f, mx = -3.4028235e38f;
  for (int i = threadIdx.x; i < nb; i += 256){ mn = fminf(mn,pmn[i]); mx = fmaxf(mx,pmx[i]); }
  smn[threadIdx.x]=mn; smx[threadIdx.x]=mx; __syncthreads();
  for (int s=128;s>0;s>>=1){
    if ((int)threadIdx.x < s){
      smn[threadIdx.x]=fminf(smn[threadIdx.x],smn[threadIdx.x+s]);
      smx[threadIdx.x]=fmaxf(smx[threadIdx.x],smx[threadIdx.x+s]);
    }
    __syncthreads();
  }
  if (threadIdx.x==0){ scal[0]=smn[0]; scal[1]=smx[0]; }
}
__global__ __launch_bounds__(256) void k_final(const float* __restrict__ S, const float* __restrict__ scal,
                                               float* __restrict__ out, int n){
  int i = blockIdx.x*256 + threadIdx.x;
  if (i >= n) return;
  float mn = scal[0];
  float r = scal[1] - mn;
  if (r == 0.0f) r = 1.0f;
  int half = SROWS*TD;
  int a = i / half; int rest = i - a*half;
  out[i] = (S[(size_t)(a & 1)*half + rest] - mn) / r;
}

extern "C" void kernel_launch(void* const* d_in, const int* in_sizes, int n_in,
                              void* d_out, int out_size, void* d_ws, size_t ws_size,
                              hipStream_t stream){
  (void)in_sizes; (void)n_in;
  const float* x = (const float*)d_in[0];

  // Xf 2.56 + A1 35.84 + B 35.84 + U1h 35.84 + A2 47.36 + Ur 23.68 + Sb 6.74 + misc
  {
    size_t need = 2560000ULL + 35840000ULL + 35840000ULL + 35840000ULL
                + 47360000ULL + 23680000ULL + 6740000ULL + 65536ULL;
    if (ws_size < need) return;
  }

  char* p = (char*)d_ws;
  auto carve = [&](size_t bytes)->void*{ void* r = (void*)p; p += (bytes + 255) & ~(size_t)255; return r; };
  c2*             Xf  = (c2*)carve(2ULL*TLEN*sizeof(c2));
  unsigned*       A1  = (unsigned*)carve(224ULL*40000*4);    // 0-31 c0e, 32-63 c0o, 64-223 dec
  unsigned*       B   = (unsigned*)carve(224ULL*40000*4);    // first-stage fwd, same slot map
  unsigned*       U1h = (unsigned*)carve(224ULL*40000*4);    // completed spectra, same slot map
  unsigned*       A2  = (unsigned*)carve(224ULL*40000*4 + 288ULL*10000*4); // 40k tier + 10k tier
  unsigned short* Ur  = (unsigned short*)carve(224ULL*40000*2 + 288ULL*10000*2);
  float*          Sb  = (float*)carve(2ULL*SROWS*TD*sizeof(float));
  c2*             Wg  = (c2*)carve(625*sizeof(c2));
  int*            tab = (int*)carve(768*4);
  float*          pmn = (float*)carve(512*4);
  float*          pmx = (float*)carve(512*4);
  float*          scal = (float*)carve(256);

  unsigned*       A2t = A2 + 224ULL*40000;        // 10k tier spectra
  unsigned short* Urt = Ur + 224ULL*40000;        // 10k tier magnitudes

  k_wlut<<<3, 256, 0, stream>>>(Wg);
  k_ptab<<<3, 256, 0, stream>>>(tab);

  // ---- forward FFT of x -> Xf (A2 reused as c2 scratch; U1h as c2 scratch) ----
  k_fft256<-1,2,0><<<2*NA, 64, 0, stream>>>((const void*)x, (void*)A2);
  k_transpose<<<2*20*8, 256, 0, stream>>>((c2*)A2, (c2*)U1h, NA, NB, 20, 8);
  k_fft625<-1,0,0,0,0,256,256,0,0><<<2*NB, 128, 0, stream>>>((const void*)U1h, (void*)Xf, Wg, 0,0,0,0,0,0, 314, nullptr);
  // ---- S0 ----
  k_conv<<<2*10, 256, 0, stream>>>(x, Sb);

  // ================= order-1 (all decimated) =================
  k_fft625<1,1,1,0,1,64,256,1,0><<<32*64, 128, 0, stream>>>((const void*)Xf, (void*)A1, Wg, 0,16,0,0,0,0, 624, nullptr);
  k_fft625<1,1,1,0,1,64,256,1,1><<<32*64, 128, 0, stream>>>((const void*)Xf, (void*)A1, Wg, 0,16,0,0,0,32, 624, nullptr);
  k_fft625<1,1,1,0,1,64,256,0,0><<<160*64, 128, 0, stream>>>((const void*)Xf, (void*)A1, Wg, 16,80,0,0,0,64, 624, nullptr);
  k_fft64g<1><<<224*G2N, 256, 0, stream>>>(A1, Ur, B);
  k_conv2d<1><<<32*10, 256, 0, stream>>>(Ur, Sb, 0, 16, (const int*)nullptr);
  k_conv2d<1><<<160*10, 256, 0, stream>>>(Ur + 64ULL*40000, Sb, 16, 80, (const int*)nullptr);
  // second stage forward over ALL 224 slots -> completed spectra in U1h
  k_fft625<-1,0,0,1,1,64,64,0,0><<<224*64, 128, 0, stream>>>((const void*)B, (void*)U1h, Wg, 0,0,0,0,0,0, 624, nullptr);

  // ================= order-2, M=40000 tier (j2 <= 3) =================
  // dec j2<=3 (96 paths, table) -> A2 slots 128-223
  k_fft625<1,4,1,1,1,64,64,0,0><<<96*64, 128, 0, stream>>>((const void*)(U1h + 64ULL*40000), (void*)A2, Wg,
                                                           0,0,0,0,0, 128, 624, tab + 448);
  // c0 j2 in {2,3} -> slots 64-127
  k_fft625<1,3,1,1,1,64,64,0,0><<<64*64, 128, 0, stream>>>((const void*)U1h, (void*)A2, Wg, 0,16,2,2,16, 64, 624, nullptr);
  // c0 j2=1, two phases -> slots 0-31 / 32-63
  k_fft625<1,3,1,1,1,64,64,0,0><<<32*64, 128, 0, stream>>>((const void*)U1h, (void*)A2, Wg, 0,16,1,1,16, 0, 624, nullptr);
  k_fft625<1,3,1,1,1,64,64,0,1><<<32*64, 128, 0, stream>>>((const void*)U1h, (void*)A2, Wg, 0,16,1,1,16, 32, 624, nullptr);
  k_fft64g<0><<<224*G2N, 256, 0, stream>>>(A2, Ur, (unsigned*)nullptr);
  k_conv2e<<<32*10, 256, 0, stream>>>(Ur, Ur + 32ULL*40000, Sb);
  k_conv2d<3><<<160*10, 256, 0, stream>>>(Ur + 64ULL*40000, Sb, 0, 0, tab);

  // ================= order-2, M=10000 tier (j2 >= 4) =================
  // c0 j2 in {4,5} -> 10k slots 0-63
  k_fft625<1,3,1,1,1,16,64,0,0><<<64*16, 128, 0, stream>>>((const void*)U1h, (void*)A2t, Wg, 0,16,2,4,16, 0, 624, nullptr);
  // dec j2>=4 (224 paths, table) -> 10k slots 64-287
  k_fft625<1,4,1,1,1,16,64,0,0><<<224*16, 128, 0, stream>>>((const void*)(U1h + 64ULL*40000), (void*)A2t, Wg,
                                                            0,0,0,0,0, 64, 624, tab + 544);
  k_fft16g<<<704, 256, 0, stream>>>(A2t, Urt);
  k_conv2q<<<288*10, 256, 0, stream>>>(Urt, Sb, tab + 160);

  // ---- global min-max normalize (standardize cancels) + tile(3,1,1) ----
  k_minmax1<<<512, 256, 0, stream>>>(Sb, 2*SROWS*TD, pmn, pmx);
  k_minmax2<<<1, 256, 0, stream>>>(pmn, pmx, 512, scal);
  k_final<<<(out_size+255)/256, 256, 0, stream>>>(Sb, scal, (float*)d_out, out_size);
}